// Round 1
// baseline (2028.862 us; speedup 1.0000x reference)
//
#include <hip/hip_runtime.h>
#include <math.h>

// ---------------------------------------------------------------- utilities
__device__ __forceinline__ float wave_sum(float v){
  #pragma unroll
  for (int m = 32; m; m >>= 1) v += __shfl_xor(v, m, 64);
  return v;
}
__device__ __forceinline__ float wave_max(float v){
  #pragma unroll
  for (int m = 32; m; m >>= 1) v = fmaxf(v, __shfl_xor(v, m, 64));
  return v;
}
// order-preserving float<->uint for atomicMax on signed floats
__device__ __forceinline__ unsigned fenc(float f){
  unsigned u = __float_as_uint(f);
  return (u >> 31) ? ~u : (u | 0x80000000u);
}
__device__ __forceinline__ float fdec(unsigned e){
  return (e >> 31) ? __uint_as_float(e & 0x7fffffffu) : __uint_as_float(~e);
}
__device__ __forceinline__ float sigm(float x){ return 1.f / (1.f + expf(-x)); }

// ------------------------------------------------------------ CSR building
__global__ void k_build_edges(const int* __restrict__ ei, int E2, int E,
                              int* __restrict__ src, int* __restrict__ dst,
                              int* __restrict__ deg){
  int e = blockIdx.x * blockDim.x + threadIdx.x;
  if (e >= E2) return;
  int s = ei[e];                                  // send = cat(ei0,ei1) = ei flat
  int d = (e < E) ? ei[e + E] : ei[e - E];        // recv = cat(ei1,ei0)
  src[e] = s; dst[e] = d;
  atomicAdd(&deg[d], 1);
}

__global__ void k_scan(const int* __restrict__ deg, int* __restrict__ rowptr, int N){
  __shared__ int part[1024];
  int t = threadIdx.x;
  int chunk = (N + 1023) / 1024;
  int lo = t * chunk, hi = lo + chunk; if (hi > N) hi = N;
  int s = 0;
  for (int i = lo; i < hi; ++i) s += deg[i];
  part[t] = s;
  __syncthreads();
  for (int off = 1; off < 1024; off <<= 1){
    int v = (t >= off) ? part[t - off] : 0;
    __syncthreads();
    part[t] += v;
    __syncthreads();
  }
  int run = part[t] - s;   // exclusive prefix
  for (int i = lo; i < hi; ++i){ rowptr[i] = run; run += deg[i]; }
  if (t == 1023) rowptr[N] = part[1023];
}

__global__ void k_fill(const int* __restrict__ dst, const int* __restrict__ rowptr,
                       int* __restrict__ cur, int* __restrict__ eids, int E2){
  int e = blockIdx.x * blockDim.x + threadIdx.x;
  if (e >= E2) return;
  int d = dst[e];
  int pos = rowptr[d] + atomicAdd(&cur[d], 1);
  eids[pos] = e;
}

// ---------------------------------------------------------- node embedding
__global__ void k_node_embed(const float* __restrict__ x, const float* __restrict__ nw,
                             const float* __restrict__ nb, const float* __restrict__ zemb,
                             float* __restrict__ nf, int N){
  int n = blockIdx.x * 4 + (threadIdx.x >> 6);
  if (n >= N) return;
  int l = threadIdx.x & 63;
  float xv[6];
  #pragma unroll
  for (int k = 0; k < 6; ++k) xv[k] = x[n*6 + k];
  float v = nb[l];
  #pragma unroll
  for (int k = 0; k < 6; ++k) v += xv[k] * nw[k*64 + l];
  v = fmaxf(v, 0.f);
  const float allowed[6] = {8.f, 23.f, 39.f, 54.f, 90.f, 180.f};
  float r = rintf(xv[2]);
  int zi = 0; float bd = fabsf(r - allowed[0]);
  #pragma unroll
  for (int k = 1; k < 6; ++k){ float d = fabsf(r - allowed[k]); if (d < bd){ bd = d; zi = k; } }
  v += zemb[zi*64 + l];
  nf[(size_t)n*64 + l] = v;
}

// ------------------------------------------------------------------- CBAM
__global__ void k_colpool(const float* __restrict__ buf, int R,
                          unsigned* __restrict__ pmax, float* __restrict__ psum){
  int tx = threadIdx.x & 63;
  int ty = threadIdx.x >> 6;   // 0..3
  float m = -INFINITY, s = 0.f;
  for (int r = blockIdx.x*4 + ty; r < R; r += gridDim.x*4){
    float v = buf[(size_t)r*64 + tx];
    m = fmaxf(m, v); s += v;
  }
  __shared__ float sm[4][64], ss[4][64];
  sm[ty][tx] = m; ss[ty][tx] = s;
  __syncthreads();
  if (ty == 0){
    #pragma unroll
    for (int k = 1; k < 4; ++k){ m = fmaxf(m, sm[k][tx]); s += ss[k][tx]; }
    atomicMax(&pmax[tx], fenc(m));
    atomicAdd(&psum[tx], s);
  }
}

__global__ void k_cbam_mlp(const unsigned* __restrict__ pmax, const float* __restrict__ psum,
                           float invR,
                           const float* __restrict__ w1, const float* __restrict__ b1,
                           const float* __restrict__ w2, const float* __restrict__ b2,
                           float* __restrict__ ch){
  __shared__ float pool[128];
  __shared__ float h[4];
  int t = threadIdx.x;   // 64 threads
  pool[t]      = fdec(pmax[t]);
  pool[64 + t] = psum[t] * invR;
  __syncthreads();
  if (t < 4){
    float a = b1[t];
    for (int k = 0; k < 128; ++k) a += pool[k] * w1[k*4 + t];
    h[t] = fmaxf(a, 0.f);
  }
  __syncthreads();
  float a = b2[t];
  #pragma unroll
  for (int k = 0; k < 4; ++k) a += h[k] * w2[k*64 + t];
  ch[t] = sigm(a);
}

__global__ void k_chmul_rowpool(float* __restrict__ buf, const float* __restrict__ ch,
                                float* __restrict__ rp, int R){
  int r = blockIdx.x*4 + (threadIdx.x >> 6);
  if (r >= R) return;
  int l = threadIdx.x & 63;
  float v = buf[(size_t)r*64 + l] * ch[l];
  buf[(size_t)r*64 + l] = v;
  float m = wave_max(v);
  float s = wave_sum(v);
  if (l == 0){ rp[(size_t)r*2] = m; rp[(size_t)r*2 + 1] = s * (1.f/64.f); }
}

__global__ void k_spatial(float* __restrict__ buf, const float* __restrict__ rp,
                          const float* __restrict__ cw, const float* __restrict__ cb, int R){
  int r = blockIdx.x*4 + (threadIdx.x >> 6);
  if (r >= R) return;
  int l = threadIdx.x & 63;
  float sp = cb[0];
  #pragma unroll
  for (int t = 0; t < 7; ++t){
    int rr = r + t - 3;
    if (rr >= 0 && rr < R)
      sp += cw[t] * rp[(size_t)rr*2] + cw[7 + t] * rp[(size_t)rr*2 + 1];
  }
  buf[(size_t)r*64 + l] *= sigm(sp);
}

// ------------------------------------------------------------ edge features
__global__ void k_edge_feat(const float* __restrict__ x, const float* __restrict__ ea,
                            const int* __restrict__ src, const int* __restrict__ dst,
                            const float* __restrict__ ew, const float* __restrict__ eb,
                            float* __restrict__ ef, int E2, int E){
  int e = blockIdx.x*4 + (threadIdx.x >> 6);
  if (e >= E2) return;
  int l = threadIdx.x & 63;
  int s = src[e], d = dst[e];
  int row = (e < E) ? e : e - E;
  float f[7];
  #pragma unroll
  for (int k = 0; k < 4; ++k) f[k] = ea[(size_t)row*4 + k];
  #pragma unroll
  for (int c = 0; c < 3; ++c) f[4+c] = x[s*6 + c] - x[d*6 + c];
  float v = eb[l];
  #pragma unroll
  for (int k = 0; k < 7; ++k) v += f[k] * ew[k*64 + l];
  ef[(size_t)e*64 + l] = fmaxf(v, 0.f);
}

// ------------------------------------- fused agg (segment_sum) + concat-LN
__global__ void k_comb(const float* __restrict__ nf, const float* __restrict__ ef,
                       const int* __restrict__ rowptr, const int* __restrict__ eids,
                       const float* __restrict__ g, const float* __restrict__ b,
                       float* __restrict__ comb, int N){
  int n = blockIdx.x*4 + (threadIdx.x >> 6);
  if (n >= N) return;
  int l = threadIdx.x & 63;
  int lo = rowptr[n], hi = rowptr[n+1];
  float agg = 0.f;
  for (int i = lo; i < hi; ++i){
    int e = eids[i];
    agg += ef[(size_t)e*64 + l];
  }
  float a = nf[(size_t)n*64 + l];
  float v0 = a, v1 = agg - a;
  float mean = wave_sum(v0 + v1) * (1.f/128.f);
  float d0 = v0 - mean, d1 = v1 - mean;
  float var = wave_sum(d0*d0 + d1*d1) * (1.f/128.f);
  float rs = rsqrtf(var + 1e-5f);
  comb[(size_t)n*128 + l]      = d0 * rs * g[l]      + b[l];
  comb[(size_t)n*128 + 64 + l] = d1 * rs * g[64 + l] + b[64 + l];
}

// ------------------------------------------------------------ generic GEMM
// out[n, col0..] = in[n, :K] @ W[:K, cols] (+bias). Block: BN rows x 64 cols.
template<int K, int BN>
__global__ __launch_bounds__(256) void k_gemm(
    const float* __restrict__ in, const float* __restrict__ W, int ldw,
    const float* __restrict__ bias, float* __restrict__ out, int ldo, int nrows){
  constexpr int PAD = BN + 4;
  __shared__ float s_in[K * PAD];          // transposed [k][node]
  int n0 = blockIdx.x * BN;
  int tid = threadIdx.x;
  for (int idx = tid; idx < BN * K; idx += 256){
    int r = idx / K, k = idx - r * K;
    float v = (n0 + r < nrows) ? in[(size_t)(n0 + r) * K + k] : 0.f;
    s_in[k * PAD + r] = v;
  }
  __syncthreads();
  int tx = tid & 15, ty = tid >> 4;
  constexpr int NT = BN / 16;
  int col0 = blockIdx.y * 64 + tx * 4;
  float acc[NT][4] = {};
  for (int k = 0; k < K; ++k){
    const float4 wv = *reinterpret_cast<const float4*>(&W[(size_t)k * ldw + col0]);
    #pragma unroll
    for (int i = 0; i < NT; ++i){
      float cv = s_in[k * PAD + ty * NT + i];
      acc[i][0] += cv * wv.x;
      acc[i][1] += cv * wv.y;
      acc[i][2] += cv * wv.z;
      acc[i][3] += cv * wv.w;
    }
  }
  float4 bv = make_float4(0.f, 0.f, 0.f, 0.f);
  if (bias) bv = *reinterpret_cast<const float4*>(&bias[col0]);
  #pragma unroll
  for (int i = 0; i < NT; ++i){
    int n = n0 + ty * NT + i;
    if (n < nrows){
      float4 o = make_float4(acc[i][0] + bv.x, acc[i][1] + bv.y,
                             acc[i][2] + bv.z, acc[i][3] + bv.w);
      *reinterpret_cast<float4*>(&out[(size_t)n * ldo + col0]) = o;
    }
  }
}

// ----------------------- fused attention (softmax over CSR) + skip + LN
__global__ void k_attn(const float* __restrict__ qkvs, const int* __restrict__ rowptr,
                       const int* __restrict__ eids, const int* __restrict__ src,
                       float* __restrict__ alpha, const float* __restrict__ ltg,
                       const float* __restrict__ ltb, float* __restrict__ outb, int N){
  int n = blockIdx.x*4 + (threadIdx.x >> 6);
  if (n >= N) return;
  int l = threadIdx.x & 63;
  int lo = rowptr[n], hi = rowptr[n+1];
  size_t qb = (size_t)n * 1024;
  float q0 = qkvs[qb +   0 + l];
  float q1 = qkvs[qb +  64 + l];
  float q2 = qkvs[qb + 128 + l];
  float q3 = qkvs[qb + 192 + l];
  float m0 = -INFINITY, m1 = -INFINITY, m2 = -INFINITY, m3 = -INFINITY;
  for (int i = lo; i < hi; ++i){
    int e = eids[i];
    const float* kb = &qkvs[(size_t)src[e]*1024 + 256];
    float a0 = wave_sum(q0 * kb[l])       * 0.125f;
    float a1 = wave_sum(q1 * kb[64 + l])  * 0.125f;
    float a2 = wave_sum(q2 * kb[128 + l]) * 0.125f;
    float a3 = wave_sum(q3 * kb[192 + l]) * 0.125f;
    m0 = fmaxf(m0, a0); m1 = fmaxf(m1, a1); m2 = fmaxf(m2, a2); m3 = fmaxf(m3, a3);
    if (l == 0)
      *reinterpret_cast<float4*>(&alpha[(size_t)e*4]) = make_float4(a0, a1, a2, a3);
  }
  float s0=0.f, s1=0.f, s2=0.f, s3=0.f;
  float o0=0.f, o1=0.f, o2=0.f, o3=0.f;
  for (int i = lo; i < hi; ++i){
    int e = eids[i];
    const float* vb = &qkvs[(size_t)src[e]*1024 + 512];
    float4 al = *reinterpret_cast<const float4*>(&alpha[(size_t)e*4]);
    float w0 = expf(al.x - m0); s0 += w0; o0 += w0 * vb[l];
    float w1 = expf(al.y - m1); s1 += w1; o1 += w1 * vb[64 + l];
    float w2 = expf(al.z - m2); s2 += w2; o2 += w2 * vb[128 + l];
    float w3 = expf(al.w - m3); s3 += w3; o3 += w3 * vb[192 + l];
  }
  float t0 = qkvs[qb + 768 + l];
  float t1 = qkvs[qb + 832 + l];
  float t2 = qkvs[qb + 896 + l];
  float t3 = qkvs[qb + 960 + l];
  if (hi > lo){
    t0 += o0 / s0; t1 += o1 / s1; t2 += o2 / s2; t3 += o3 / s3;
  }
  float mean = wave_sum(t0 + t1 + t2 + t3) * (1.f/256.f);
  float d0 = t0 - mean, d1 = t1 - mean, d2 = t2 - mean, d3 = t3 - mean;
  float var = wave_sum(d0*d0 + d1*d1 + d2*d2 + d3*d3) * (1.f/256.f);
  float rs = rsqrtf(var + 1e-5f);
  size_t ob = (size_t)n * 256;
  outb[ob +       l] = d0 * rs * ltg[l]       + ltb[l];
  outb[ob +  64 + l] = d1 * rs * ltg[64 + l]  + ltb[64 + l];
  outb[ob + 128 + l] = d2 * rs * ltg[128 + l] + ltb[128 + l];
  outb[ob + 192 + l] = d3 * rs * ltg[192 + l] + ltb[192 + l];
}

// ------------------------------------------- gated fusion: nf update in place
__global__ __launch_bounds__(256) void k_gate(
    float* __restrict__ nf, const float* __restrict__ pn,
    const float* __restrict__ gfw, const float* __restrict__ gfb, int N){
  __shared__ float s_w[128 * 64];   // 32 KB
  int tid = threadIdx.x;
  for (int idx = tid; idx < 128*64; idx += 256) s_w[idx] = gfw[idx];
  __syncthreads();
  int wv = tid >> 6, l = tid & 63;
  float gb = gfb[l];
  for (int n = blockIdx.x*4 + wv; n < N; n += gridDim.x*4){
    float nfv = nf[(size_t)n*64 + l];
    float pnv = pn[(size_t)n*64 + l];
    float g = gb;
    #pragma unroll 8
    for (int k = 0; k < 64; ++k){
      g += __shfl(nfv, k, 64) * s_w[k*64 + l];
      g += __shfl(pnv, k, 64) * s_w[(64 + k)*64 + l];
    }
    g = sigm(g);
    // nf_new = nf*g + pn*(1-g) + nf  (the +x0 residual)
    nf[(size_t)n*64 + l] = nfv * (1.f + g) + pnv * (1.f - g);
  }
}

// -------------------------------------------------- edge update (+residual)
__global__ void k_edge_upd(float* __restrict__ ef, const float* __restrict__ P,
                           const int* __restrict__ src, const int* __restrict__ dst,
                           const float* __restrict__ peb, int E2){
  int idx = blockIdx.x * blockDim.x + threadIdx.x;
  int e = idx >> 6;
  if (e >= E2) return;
  int l = idx & 63;
  int s = src[e], d = dst[e];
  ef[(size_t)e*64 + l] += P[(size_t)s*64 + l] - P[(size_t)d*64 + l] + peb[l];
}

// ------------------------------------------------------------- classifier
__global__ void k_final(const float* __restrict__ A, const float* __restrict__ B,
                        const int* __restrict__ ei, const float* __restrict__ cb1,
                        const float* __restrict__ cw2, const float* __restrict__ cb2,
                        float* __restrict__ dout, int E){
  int e = blockIdx.x*4 + (threadIdx.x >> 6);
  if (e >= E) return;
  int l = threadIdx.x & 63;
  int i0 = ei[e], i1 = ei[E + e];
  float h = fmaxf(A[(size_t)i0*64 + l] + B[(size_t)i1*64 + l] + cb1[l], 0.f);
  float p = wave_sum(h * cw2[l]);
  if (l == 0) dout[e] = p + cb2[0];
}

// ===========================================================================
extern "C" void kernel_launch(void* const* d_in, const int* in_sizes, int n_in,
                              void* d_out, int out_size, void* d_ws, size_t ws_size,
                              hipStream_t stream){
  const float* x         = (const float*)d_in[0];
  const float* edge_attr = (const float*)d_in[1];
  const float* node_w    = (const float*)d_in[2];
  const float* node_b    = (const float*)d_in[3];
  const float* edge_w    = (const float*)d_in[4];
  const float* edge_b    = (const float*)d_in[5];
  const float* z_emb     = (const float*)d_in[6];
  const float* cn_w1     = (const float*)d_in[7];
  const float* cn_b1     = (const float*)d_in[8];
  const float* cn_w2     = (const float*)d_in[9];
  const float* cn_b2     = (const float*)d_in[10];
  const float* cn_cw     = (const float*)d_in[11];
  const float* cn_cb     = (const float*)d_in[12];
  const float* ce_w1     = (const float*)d_in[13];
  const float* ce_b1     = (const float*)d_in[14];
  const float* ce_w2     = (const float*)d_in[15];
  const float* ce_b2     = (const float*)d_in[16];
  const float* ce_cw     = (const float*)d_in[17];
  const float* ce_cb     = (const float*)d_in[18];
  const float* Wq        = (const float*)d_in[19];
  const float* bq        = (const float*)d_in[20];
  const float* Wk        = (const float*)d_in[21];
  const float* bk        = (const float*)d_in[22];
  const float* Wv        = (const float*)d_in[23];
  const float* bv        = (const float*)d_in[24];
  const float* Ws        = (const float*)d_in[25];
  const float* bs        = (const float*)d_in[26];
  const float* lt_g      = (const float*)d_in[27];
  const float* lt_b      = (const float*)d_in[28];
  const float* lc_g      = (const float*)d_in[29];
  const float* lc_b      = (const float*)d_in[30];
  const float* pe_w      = (const float*)d_in[31];
  const float* pe_b      = (const float*)d_in[32];
  const float* pn_w      = (const float*)d_in[33];
  const float* pn_b      = (const float*)d_in[34];
  const float* gf_w      = (const float*)d_in[35];
  const float* gf_b      = (const float*)d_in[36];
  const float* c_w1      = (const float*)d_in[37];
  const float* c_b1      = (const float*)d_in[38];
  const float* c_w2      = (const float*)d_in[39];
  const float* c_b2      = (const float*)d_in[40];
  const int*   edge_index= (const int*)d_in[41];

  const int N  = in_sizes[0] / 6;
  const int E  = in_sizes[1] / 4;
  const int E2 = 2 * E;

  // ---------------- workspace layout
  char* p = (char*)d_ws;
  auto alloc = [&](size_t bytes)->char*{
    char* r = p; p += (bytes + 255) & ~(size_t)255; return r;
  };
  int*      w_src    = (int*)     alloc((size_t)E2 * 4);
  int*      w_dst    = (int*)     alloc((size_t)E2 * 4);
  int*      w_deg    = (int*)     alloc((size_t)N * 4);
  int*      w_rowptr = (int*)     alloc((size_t)(N + 1) * 4);
  int*      w_cur    = (int*)     alloc((size_t)N * 4);
  int*      w_eids   = (int*)     alloc((size_t)E2 * 4);
  float*    w_nf     = (float*)   alloc((size_t)N * 64 * 4);
  float*    w_ef     = (float*)   alloc((size_t)E2 * 64 * 4);
  float*    w_comb   = (float*)   alloc((size_t)N * 128 * 4);
  float*    w_qkvs   = (float*)   alloc((size_t)N * 1024 * 4);
  float*    w_outb   = (float*)   alloc((size_t)N * 256 * 4);
  float*    w_pn     = (float*)   alloc((size_t)N * 64 * 4);
  float*    w_P      = (float*)   alloc((size_t)N * 64 * 4);
  float*    w_alpha  = (float*)   alloc((size_t)E2 * 4 * 4);  // also reused as rp
  unsigned* w_pmax   = (unsigned*)alloc(64 * 4);
  float*    w_psum   = (float*)   alloc(64 * 4);
  float*    w_ch     = (float*)   alloc(64 * 4);
  unsigned* w_pmax2  = (unsigned*)alloc(64 * 4);
  float*    w_psum2  = (float*)   alloc(64 * 4);
  float*    w_ch2    = (float*)   alloc(64 * 4);
  float*    w_rp     = w_alpha;               // [max rows][2], fits in alpha
  float*    w_A      = w_comb;                // classifier reuse (post-loop)
  float*    w_B      = w_comb + (size_t)N * 64;

  hipMemsetAsync(w_deg,  0, (size_t)N * 4, stream);
  hipMemsetAsync(w_cur,  0, (size_t)N * 4, stream);
  hipMemsetAsync(w_pmax, 0, 64 * 4, stream);
  hipMemsetAsync(w_psum, 0, 64 * 4, stream);
  hipMemsetAsync(w_pmax2,0, 64 * 4, stream);
  hipMemsetAsync(w_psum2,0, 64 * 4, stream);

  // ---------------- CSR + embeddings
  k_build_edges<<<(E2 + 255)/256, 256, 0, stream>>>(edge_index, E2, E, w_src, w_dst, w_deg);
  k_scan<<<1, 1024, 0, stream>>>(w_deg, w_rowptr, N);
  k_fill<<<(E2 + 255)/256, 256, 0, stream>>>(w_dst, w_rowptr, w_cur, w_eids, E2);
  k_node_embed<<<(N + 3)/4, 256, 0, stream>>>(x, node_w, node_b, z_emb, w_nf, N);

  // node CBAM
  k_colpool<<<512, 256, 0, stream>>>(w_nf, N, w_pmax, w_psum);
  k_cbam_mlp<<<1, 64, 0, stream>>>(w_pmax, w_psum, 1.f/(float)N,
                                   cn_w1, cn_b1, cn_w2, cn_b2, w_ch);
  k_chmul_rowpool<<<(N + 3)/4, 256, 0, stream>>>(w_nf, w_ch, w_rp, N);
  k_spatial<<<(N + 3)/4, 256, 0, stream>>>(w_nf, w_rp, cn_cw, cn_cb, N);

  // edge features + CBAM
  k_edge_feat<<<(E2 + 3)/4, 256, 0, stream>>>(x, edge_attr, w_src, w_dst,
                                              edge_w, edge_b, w_ef, E2, E);
  k_colpool<<<512, 256, 0, stream>>>(w_ef, E2, w_pmax2, w_psum2);
  k_cbam_mlp<<<1, 64, 0, stream>>>(w_pmax2, w_psum2, 1.f/(float)E2,
                                   ce_w1, ce_b1, ce_w2, ce_b2, w_ch2);
  k_chmul_rowpool<<<(E2 + 3)/4, 256, 0, stream>>>(w_ef, w_ch2, w_rp, E2);
  k_spatial<<<(E2 + 3)/4, 256, 0, stream>>>(w_ef, w_rp, ce_cw, ce_cb, E2);

  // ---------------- message-passing iterations
  for (int i = 0; i < 3; ++i){
    k_comb<<<(N + 3)/4, 256, 0, stream>>>(w_nf, w_ef, w_rowptr, w_eids,
                                          lc_g + (size_t)i*128, lc_b + (size_t)i*128,
                                          w_comb, N);
    dim3 g128((N + 63)/64, 4);
    k_gemm<128,64><<<g128, 256, 0, stream>>>(w_comb, Wq + (size_t)i*128*256, 256,
                                             bq + (size_t)i*256, w_qkvs +   0, 1024, N);
    k_gemm<128,64><<<g128, 256, 0, stream>>>(w_comb, Wk + (size_t)i*128*256, 256,
                                             bk + (size_t)i*256, w_qkvs + 256, 1024, N);
    k_gemm<128,64><<<g128, 256, 0, stream>>>(w_comb, Wv + (size_t)i*128*256, 256,
                                             bv + (size_t)i*256, w_qkvs + 512, 1024, N);
    k_gemm<128,64><<<g128, 256, 0, stream>>>(w_comb, Ws + (size_t)i*128*256, 256,
                                             bs + (size_t)i*256, w_qkvs + 768, 1024, N);
    k_attn<<<(N + 3)/4, 256, 0, stream>>>(w_qkvs, w_rowptr, w_eids, w_src, w_alpha,
                                          lt_g + (size_t)i*256, lt_b + (size_t)i*256,
                                          w_outb, N);
    dim3 g256((N + 31)/32, 1);
    k_gemm<256,32><<<g256, 256, 0, stream>>>(w_outb, pn_w + (size_t)i*256*64, 64,
                                             pn_b + (size_t)i*64, w_pn, 64, N);
    k_gemm<256,32><<<g256, 256, 0, stream>>>(w_outb, pe_w + (size_t)i*256*64, 64,
                                             nullptr, w_P, 64, N);
    k_gate<<<1250, 256, 0, stream>>>(w_nf, w_pn, gf_w + (size_t)i*128*64,
                                     gf_b + (size_t)i*64, N);
    k_edge_upd<<<((size_t)E2*64 + 255)/256, 256, 0, stream>>>(w_ef, w_P, w_src, w_dst,
                                                              pe_b + (size_t)i*64, E2);
  }

  // ---------------- classifier
  dim3 g64((N + 63)/64, 1);
  k_gemm<64,64><<<g64, 256, 0, stream>>>(w_nf, c_w1,           64, nullptr, w_A, 64, N);
  k_gemm<64,64><<<g64, 256, 0, stream>>>(w_nf, c_w1 + 64*64,   64, nullptr, w_B, 64, N);
  k_final<<<(E + 3)/4, 256, 0, stream>>>(w_A, w_B, edge_index, c_b1, c_w2, c_b2,
                                         (float*)d_out, E);
}

// Round 2
// 1413.720 us; speedup vs baseline: 1.4351x; 1.4351x over previous
//
#include <hip/hip_runtime.h>
#include <math.h>

typedef __attribute__((ext_vector_type(8))) short short8;
typedef __attribute__((ext_vector_type(4))) float f32x4;

// ---------------------------------------------------------------- utilities
__device__ __forceinline__ float wave_sum(float v){
  #pragma unroll
  for (int m = 32; m; m >>= 1) v += __shfl_xor(v, m, 64);
  return v;
}
__device__ __forceinline__ float wave_max(float v){
  #pragma unroll
  for (int m = 32; m; m >>= 1) v = fmaxf(v, __shfl_xor(v, m, 64));
  return v;
}
__device__ __forceinline__ unsigned fenc(float f){
  unsigned u = __float_as_uint(f);
  return (u >> 31) ? ~u : (u | 0x80000000u);
}
__device__ __forceinline__ float fdec(unsigned e){
  return (e >> 31) ? __uint_as_float(e & 0x7fffffffu) : __uint_as_float(~e);
}
__device__ __forceinline__ float sigm(float x){ return 1.f / (1.f + expf(-x)); }
__device__ __forceinline__ unsigned short f2bf(float f){
  union { float f; unsigned u; } x; x.f = f;
  unsigned r = x.u + 0x7fffu + ((x.u >> 16) & 1u);
  return (unsigned short)(r >> 16);
}
__device__ __forceinline__ float bf2f(unsigned short h){
  union { unsigned u; float f; } x; x.u = ((unsigned)h) << 16;
  return x.f;
}

// ------------------------------------------------------------ CSR building
__global__ void k_build_edges(const int* __restrict__ ei, int E2, int E,
                              int* __restrict__ src, int* __restrict__ dst,
                              int* __restrict__ deg){
  int e = blockIdx.x * blockDim.x + threadIdx.x;
  if (e >= E2) return;
  int s = ei[e];
  int d = (e < E) ? ei[e + E] : ei[e - E];
  src[e] = s; dst[e] = d;
  atomicAdd(&deg[d], 1);
}

__global__ void k_scan(const int* __restrict__ deg, int* __restrict__ rowptr, int N){
  __shared__ int part[1024];
  int t = threadIdx.x;
  int chunk = (N + 1023) / 1024;
  int lo = t * chunk, hi = lo + chunk; if (hi > N) hi = N;
  int s = 0;
  for (int i = lo; i < hi; ++i) s += deg[i];
  part[t] = s;
  __syncthreads();
  for (int off = 1; off < 1024; off <<= 1){
    int v = (t >= off) ? part[t - off] : 0;
    __syncthreads();
    part[t] += v;
    __syncthreads();
  }
  int run = part[t] - s;
  for (int i = lo; i < hi; ++i){ rowptr[i] = run; run += deg[i]; }
  if (t == 1023) rowptr[N] = part[1023];
}

__global__ void k_fill(const int* __restrict__ src, const int* __restrict__ dst,
                       const int* __restrict__ rowptr,
                       int* __restrict__ cur, int* __restrict__ eids,
                       int* __restrict__ csrc, int E2){
  int e = blockIdx.x * blockDim.x + threadIdx.x;
  if (e >= E2) return;
  int d = dst[e];
  int pos = rowptr[d] + atomicAdd(&cur[d], 1);
  eids[pos] = e;
  csrc[pos] = src[e];
}

// ---------------------------------------------------------- node embedding
__global__ void k_node_embed(const float* __restrict__ x, const float* __restrict__ nw,
                             const float* __restrict__ nb, const float* __restrict__ zemb,
                             float* __restrict__ nf, int N){
  int n = blockIdx.x * 4 + (threadIdx.x >> 6);
  if (n >= N) return;
  int l = threadIdx.x & 63;
  float xv[6];
  #pragma unroll
  for (int k = 0; k < 6; ++k) xv[k] = x[n*6 + k];
  float v = nb[l];
  #pragma unroll
  for (int k = 0; k < 6; ++k) v += xv[k] * nw[k*64 + l];
  v = fmaxf(v, 0.f);
  const float allowed[6] = {8.f, 23.f, 39.f, 54.f, 90.f, 180.f};
  float r = rintf(xv[2]);
  int zi = 0; float bd = fabsf(r - allowed[0]);
  #pragma unroll
  for (int k = 1; k < 6; ++k){ float d = fabsf(r - allowed[k]); if (d < bd){ bd = d; zi = k; } }
  v += zemb[zi*64 + l];
  nf[(size_t)n*64 + l] = v;
}

// ------------------------------------------------------------------- CBAM
__global__ void k_colpool(const float* __restrict__ buf, int R,
                          unsigned* __restrict__ pmax, float* __restrict__ psum){
  int tx = threadIdx.x & 63;
  int ty = threadIdx.x >> 6;
  float m = -INFINITY, s = 0.f;
  for (int r = blockIdx.x*4 + ty; r < R; r += gridDim.x*4){
    float v = buf[(size_t)r*64 + tx];
    m = fmaxf(m, v); s += v;
  }
  __shared__ float sm[4][64], ss[4][64];
  sm[ty][tx] = m; ss[ty][tx] = s;
  __syncthreads();
  if (ty == 0){
    #pragma unroll
    for (int k = 1; k < 4; ++k){ m = fmaxf(m, sm[k][tx]); s += ss[k][tx]; }
    atomicMax(&pmax[tx], fenc(m));
    atomicAdd(&psum[tx], s);
  }
}

__global__ void k_cbam_mlp(const unsigned* __restrict__ pmax, const float* __restrict__ psum,
                           float invR,
                           const float* __restrict__ w1, const float* __restrict__ b1,
                           const float* __restrict__ w2, const float* __restrict__ b2,
                           float* __restrict__ ch){
  __shared__ float pool[128];
  __shared__ float h[4];
  int t = threadIdx.x;
  pool[t]      = fdec(pmax[t]);
  pool[64 + t] = psum[t] * invR;
  __syncthreads();
  if (t < 4){
    float a = b1[t];
    for (int k = 0; k < 128; ++k) a += pool[k] * w1[k*4 + t];
    h[t] = fmaxf(a, 0.f);
  }
  __syncthreads();
  float a = b2[t];
  #pragma unroll
  for (int k = 0; k < 4; ++k) a += h[k] * w2[k*64 + t];
  ch[t] = sigm(a);
}

__global__ void k_chmul_rowpool(float* __restrict__ buf, const float* __restrict__ ch,
                                float* __restrict__ rp, int R){
  int r = blockIdx.x*4 + (threadIdx.x >> 6);
  if (r >= R) return;
  int l = threadIdx.x & 63;
  float v = buf[(size_t)r*64 + l] * ch[l];
  buf[(size_t)r*64 + l] = v;
  float m = wave_max(v);
  float s = wave_sum(v);
  if (l == 0){ rp[(size_t)r*2] = m; rp[(size_t)r*2 + 1] = s * (1.f/64.f); }
}

__global__ void k_spatial(float* __restrict__ buf, const float* __restrict__ rp,
                          const float* __restrict__ cw, const float* __restrict__ cb, int R){
  int r = blockIdx.x*4 + (threadIdx.x >> 6);
  if (r >= R) return;
  int l = threadIdx.x & 63;
  float sp = cb[0];
  #pragma unroll
  for (int t = 0; t < 7; ++t){
    int rr = r + t - 3;
    if (rr >= 0 && rr < R)
      sp += cw[t] * rp[(size_t)rr*2] + cw[7 + t] * rp[(size_t)rr*2 + 1];
  }
  buf[(size_t)r*64 + l] *= sigm(sp);
}

// ------------------------------------------------------------ edge features
__global__ void k_edge_feat(const float* __restrict__ x, const float* __restrict__ ea,
                            const int* __restrict__ src, const int* __restrict__ dst,
                            const float* __restrict__ ew, const float* __restrict__ eb,
                            float* __restrict__ ef, int E2, int E){
  int e = blockIdx.x*4 + (threadIdx.x >> 6);
  if (e >= E2) return;
  int l = threadIdx.x & 63;
  int s = src[e], d = dst[e];
  int row = (e < E) ? e : e - E;
  float f[7];
  #pragma unroll
  for (int k = 0; k < 4; ++k) f[k] = ea[(size_t)row*4 + k];
  #pragma unroll
  for (int c = 0; c < 3; ++c) f[4+c] = x[s*6 + c] - x[d*6 + c];
  float v = eb[l];
  #pragma unroll
  for (int k = 0; k < 7; ++k) v += f[k] * ew[k*64 + l];
  ef[(size_t)e*64 + l] = fmaxf(v, 0.f);
}

// ------------------------------------- fused agg (segment_sum) + concat-LN
// comb written as bf16 (feeds the MFMA GEMM only)
__global__ void k_comb(const float* __restrict__ nf, const float* __restrict__ ef,
                       const int* __restrict__ rowptr, const int* __restrict__ eids,
                       const float* __restrict__ g, const float* __restrict__ b,
                       unsigned short* __restrict__ comb, int N){
  int n = blockIdx.x*4 + (threadIdx.x >> 6);
  if (n >= N) return;
  int l = threadIdx.x & 63;
  int lo = rowptr[n], hi = rowptr[n+1];
  float agg = 0.f;
  for (int i = lo; i < hi; ++i){
    int e = eids[i];
    agg += ef[(size_t)e*64 + l];
  }
  float a = nf[(size_t)n*64 + l];
  float v0 = a, v1 = agg - a;
  float mean = wave_sum(v0 + v1) * (1.f/128.f);
  float d0 = v0 - mean, d1 = v1 - mean;
  float var = wave_sum(d0*d0 + d1*d1) * (1.f/128.f);
  float rs = rsqrtf(var + 1e-5f);
  comb[(size_t)n*128 + l]      = f2bf(d0 * rs * g[l]      + b[l]);
  comb[(size_t)n*128 + 64 + l] = f2bf(d1 * rs * g[64 + l] + b[64 + l]);
}

// ------------------------------------------------ weight pack (fp32 -> bf16^T)
__global__ void k_pack_w(const float* __restrict__ Wq, const float* __restrict__ Wk,
                         const float* __restrict__ Wv, const float* __restrict__ Ws,
                         const float* __restrict__ bq, const float* __restrict__ bk,
                         const float* __restrict__ bv, const float* __restrict__ bs,
                         unsigned short* __restrict__ Bt, float* __restrict__ bias){
  int g = blockIdx.x, k = threadIdx.x;            // g: output col 0..1023, k: 0..127
  const float* W  = (g < 256) ? Wq : (g < 512) ? Wk : (g < 768) ? Wv : Ws;
  const float* bb = (g < 256) ? bq : (g < 512) ? bk : (g < 768) ? bv : bs;
  int c = g & 255;
  Bt[(size_t)g*128 + k] = f2bf(W[(size_t)k*256 + c]);
  if (k == 0) bias[g] = bb[c];
}

__global__ void k_pack_w2(const float* __restrict__ pnw, const float* __restrict__ pew,
                          const float* __restrict__ pnb,
                          unsigned short* __restrict__ Bt, float* __restrict__ bias){
  int g = blockIdx.x, k = threadIdx.x;            // g: 0..127, k: 0..255
  const float* W = (g < 64) ? pnw : pew;
  int c = g & 63;
  Bt[(size_t)g*256 + k] = f2bf(W[(size_t)k*64 + c]);
  if (k == 0) bias[g] = (g < 64) ? pnb[c] : 0.f;
}

// ---------------------------------------------------------- MFMA bf16 GEMM
// C[M, NCOLS] = A[M,K] * Bt[NCOLS,K]^T, K = NSTEPS*128, tiles 128x128.
// MODE 0: NCOLS=1024; cols 0-255 -> q(f32), 256-511 -> k(bf16),
//         512-767 -> v(bf16), 768-1023 -> s(f32).
// MODE 1: NCOLS=128; all -> o_f0 (f32, ld 128).
template<int NSTEPS, int MODE>
__global__ __launch_bounds__(256) void k_mfma(
    const unsigned short* __restrict__ A, int lda,
    const unsigned short* __restrict__ Bt, int ldb,
    const float* __restrict__ bias,
    float* __restrict__ o_f0, unsigned short* __restrict__ o_h0,
    unsigned short* __restrict__ o_h1, float* __restrict__ o_f1, int M){
  __shared__ char lds[65536];
  char* ldsA = lds;
  char* ldsB = lds + 32768;
  int tid = threadIdx.x;
  int nbase = blockIdx.x * 128;
  int mbase = blockIdx.y * 128;
  int l = tid & 63, wid = tid >> 6;
  int wm = (wid >> 1) * 64, wn = (wid & 1) * 64;
  f32x4 acc[4][4] = {};
  const char* Ab  = (const char*)A;
  const char* Btb = (const char*)Bt;
  for (int ks = 0; ks < NSTEPS; ++ks){
    #pragma unroll
    for (int it = 0; it < 8; ++it){
      int c = tid + it*256;            // 0..2047 chunks of 16B
      int row = c >> 4;
      int kb = (c & 15) << 4;
      int off = (row << 8) + (kb ^ ((row & 7) << 4));
      uint4 va = make_uint4(0,0,0,0);
      int gr = mbase + row;
      if (gr < M)
        va = *reinterpret_cast<const uint4*>(Ab + (size_t)gr*(lda*2) + ks*256 + kb);
      *reinterpret_cast<uint4*>(ldsA + off) = va;
      uint4 vb = *reinterpret_cast<const uint4*>(
                   Btb + (size_t)(nbase + row)*(ldb*2) + ks*256 + kb);
      *reinterpret_cast<uint4*>(ldsB + off) = vb;
    }
    __syncthreads();
    #pragma unroll
    for (int kk = 0; kk < 4; ++kk){
      int kbyte = kk*64 + (l >> 4)*16;
      short8 af[4], bf[4];
      #pragma unroll
      for (int m = 0; m < 4; ++m){
        int fr = wm + m*16 + (l & 15);
        af[m] = *reinterpret_cast<const short8*>(ldsA + (fr << 8) + (kbyte ^ ((fr & 7) << 4)));
      }
      #pragma unroll
      for (int n = 0; n < 4; ++n){
        int fc = wn + n*16 + (l & 15);
        bf[n] = *reinterpret_cast<const short8*>(ldsB + (fc << 8) + (kbyte ^ ((fc & 7) << 4)));
      }
      #pragma unroll
      for (int m = 0; m < 4; ++m)
        #pragma unroll
        for (int n = 0; n < 4; ++n)
          acc[m][n] = __builtin_amdgcn_mfma_f32_16x16x32_bf16(af[m], bf[n], acc[m][n], 0, 0, 0);
    }
    __syncthreads();
  }
  // epilogue
  #pragma unroll
  for (int n = 0; n < 4; ++n){
    int gcol = nbase + wn + n*16 + (l & 15);
    float bv = bias ? bias[gcol] : 0.f;
    #pragma unroll
    for (int m = 0; m < 4; ++m){
      int grow = mbase + wm + m*16 + (l >> 4)*4;
      #pragma unroll
      for (int r = 0; r < 4; ++r){
        int gr = grow + r;
        if (gr < M){
          float val = acc[m][n][r] + bv;
          if (MODE == 1){
            o_f0[(size_t)gr*128 + gcol] = val;
          } else {
            int seg = gcol >> 8, c = gcol & 255;
            if      (seg == 0) o_f0[(size_t)gr*256 + c] = val;
            else if (seg == 1) o_h0[(size_t)gr*256 + c] = f2bf(val);
            else if (seg == 2) o_h1[(size_t)gr*256 + c] = f2bf(val);
            else               o_f1[(size_t)gr*256 + c] = val;
          }
        }
      }
    }
  }
}

// ----------------------- fused attention (softmax over CSR) + skip + LN
__global__ void k_attn(const float* __restrict__ q, const unsigned short* __restrict__ kbuf,
                       const unsigned short* __restrict__ vbuf, const float* __restrict__ sbuf,
                       const int* __restrict__ rowptr, const int* __restrict__ csrc,
                       float* __restrict__ alpha, const float* __restrict__ ltg,
                       const float* __restrict__ ltb, unsigned short* __restrict__ outb, int N){
  int n = blockIdx.x*4 + (threadIdx.x >> 6);
  if (n >= N) return;
  int l = threadIdx.x & 63;
  int lo = rowptr[n], hi = rowptr[n+1];
  size_t qb = (size_t)n * 256;
  float q0 = q[qb +   0 + l];
  float q1 = q[qb +  64 + l];
  float q2 = q[qb + 128 + l];
  float q3 = q[qb + 192 + l];
  float m0 = -INFINITY, m1 = -INFINITY, m2 = -INFINITY, m3 = -INFINITY;
  for (int i = lo; i < hi; ++i){
    const unsigned short* kr = kbuf + (size_t)csrc[i]*256;
    float a0 = wave_sum(q0 * bf2f(kr[l]))       * 0.125f;
    float a1 = wave_sum(q1 * bf2f(kr[64 + l]))  * 0.125f;
    float a2 = wave_sum(q2 * bf2f(kr[128 + l])) * 0.125f;
    float a3 = wave_sum(q3 * bf2f(kr[192 + l])) * 0.125f;
    m0 = fmaxf(m0, a0); m1 = fmaxf(m1, a1); m2 = fmaxf(m2, a2); m3 = fmaxf(m3, a3);
    if (l == 0)
      *reinterpret_cast<float4*>(&alpha[(size_t)i*4]) = make_float4(a0, a1, a2, a3);
  }
  float s0=0.f, s1=0.f, s2=0.f, s3=0.f;
  float o0=0.f, o1=0.f, o2=0.f, o3=0.f;
  for (int i = lo; i < hi; ++i){
    const unsigned short* vr = vbuf + (size_t)csrc[i]*256;
    float4 al = *reinterpret_cast<const float4*>(&alpha[(size_t)i*4]);
    float w0 = expf(al.x - m0); s0 += w0; o0 += w0 * bf2f(vr[l]);
    float w1 = expf(al.y - m1); s1 += w1; o1 += w1 * bf2f(vr[64 + l]);
    float w2 = expf(al.z - m2); s2 += w2; o2 += w2 * bf2f(vr[128 + l]);
    float w3 = expf(al.w - m3); s3 += w3; o3 += w3 * bf2f(vr[192 + l]);
  }
  float t0 = sbuf[qb + l];
  float t1 = sbuf[qb + 64 + l];
  float t2 = sbuf[qb + 128 + l];
  float t3 = sbuf[qb + 192 + l];
  if (hi > lo){
    t0 += o0 / s0; t1 += o1 / s1; t2 += o2 / s2; t3 += o3 / s3;
  }
  float mean = wave_sum(t0 + t1 + t2 + t3) * (1.f/256.f);
  float d0 = t0 - mean, d1 = t1 - mean, d2 = t2 - mean, d3 = t3 - mean;
  float var = wave_sum(d0*d0 + d1*d1 + d2*d2 + d3*d3) * (1.f/256.f);
  float rs = rsqrtf(var + 1e-5f);
  size_t ob = (size_t)n * 256;
  outb[ob +       l] = f2bf(d0 * rs * ltg[l]       + ltb[l]);
  outb[ob +  64 + l] = f2bf(d1 * rs * ltg[64 + l]  + ltb[64 + l]);
  outb[ob + 128 + l] = f2bf(d2 * rs * ltg[128 + l] + ltb[128 + l]);
  outb[ob + 192 + l] = f2bf(d3 * rs * ltg[192 + l] + ltb[192 + l]);
}

// ------------------------------------------- gated fusion: nf update in place
__global__ __launch_bounds__(256) void k_gate(
    float* __restrict__ nf, const float* __restrict__ pnP,
    const float* __restrict__ gfw, const float* __restrict__ gfb, int N){
  __shared__ float s_w[128 * 64];
  int tid = threadIdx.x;
  for (int idx = tid; idx < 128*64; idx += 256) s_w[idx] = gfw[idx];
  __syncthreads();
  int wv = tid >> 6, l = tid & 63;
  float gb = gfb[l];
  for (int n = blockIdx.x*4 + wv; n < N; n += gridDim.x*4){
    float nfv = nf[(size_t)n*64 + l];
    float pnv = pnP[(size_t)n*128 + l];
    float g = gb;
    #pragma unroll 8
    for (int k = 0; k < 64; ++k){
      g += __shfl(nfv, k, 64) * s_w[k*64 + l];
      g += __shfl(pnv, k, 64) * s_w[(64 + k)*64 + l];
    }
    g = sigm(g);
    nf[(size_t)n*64 + l] = nfv * (1.f + g) + pnv * (1.f - g);
  }
}

// -------------------------------------------------- edge update (+residual)
__global__ void k_edge_upd(float* __restrict__ ef, const float* __restrict__ pnP,
                           const int* __restrict__ src, const int* __restrict__ dst,
                           const float* __restrict__ peb, int E2){
  int idx = blockIdx.x * blockDim.x + threadIdx.x;
  int e = idx >> 6;
  if (e >= E2) return;
  int l = idx & 63;
  int s = src[e], d = dst[e];
  ef[(size_t)e*64 + l] += pnP[(size_t)s*128 + 64 + l] - pnP[(size_t)d*128 + 64 + l] + peb[l];
}

// ------------------------------------------------------------- classifier
template<int K, int BN>
__global__ __launch_bounds__(256) void k_gemm(
    const float* __restrict__ in, const float* __restrict__ W, int ldw,
    const float* __restrict__ bias, float* __restrict__ out, int ldo, int nrows){
  constexpr int PAD = BN + 4;
  __shared__ float s_in[K * PAD];
  int n0 = blockIdx.x * BN;
  int tid = threadIdx.x;
  for (int idx = tid; idx < BN * K; idx += 256){
    int r = idx / K, k = idx - r * K;
    float v = (n0 + r < nrows) ? in[(size_t)(n0 + r) * K + k] : 0.f;
    s_in[k * PAD + r] = v;
  }
  __syncthreads();
  int tx = tid & 15, ty = tid >> 4;
  constexpr int NT = BN / 16;
  int col0 = blockIdx.y * 64 + tx * 4;
  float acc[NT][4] = {};
  for (int k = 0; k < K; ++k){
    const float4 wv = *reinterpret_cast<const float4*>(&W[(size_t)k * ldw + col0]);
    #pragma unroll
    for (int i = 0; i < NT; ++i){
      float cv = s_in[k * PAD + ty * NT + i];
      acc[i][0] += cv * wv.x;
      acc[i][1] += cv * wv.y;
      acc[i][2] += cv * wv.z;
      acc[i][3] += cv * wv.w;
    }
  }
  #pragma unroll
  for (int i = 0; i < NT; ++i){
    int n = n0 + ty * NT + i;
    if (n < nrows){
      float4 o = make_float4(acc[i][0], acc[i][1], acc[i][2], acc[i][3]);
      *reinterpret_cast<float4*>(&out[(size_t)n * ldo + col0]) = o;
    }
  }
}

__global__ void k_final(const float* __restrict__ A, const float* __restrict__ B,
                        const int* __restrict__ ei, const float* __restrict__ cb1,
                        const float* __restrict__ cw2, const float* __restrict__ cb2,
                        float* __restrict__ dout, int E){
  int e = blockIdx.x*4 + (threadIdx.x >> 6);
  if (e >= E) return;
  int l = threadIdx.x & 63;
  int i0 = ei[e], i1 = ei[E + e];
  float h = fmaxf(A[(size_t)i0*64 + l] + B[(size_t)i1*64 + l] + cb1[l], 0.f);
  float p = wave_sum(h * cw2[l]);
  if (l == 0) dout[e] = p + cb2[0];
}

// ===========================================================================
extern "C" void kernel_launch(void* const* d_in, const int* in_sizes, int n_in,
                              void* d_out, int out_size, void* d_ws, size_t ws_size,
                              hipStream_t stream){
  const float* x         = (const float*)d_in[0];
  const float* edge_attr = (const float*)d_in[1];
  const float* node_w    = (const float*)d_in[2];
  const float* node_b    = (const float*)d_in[3];
  const float* edge_w    = (const float*)d_in[4];
  const float* edge_b    = (const float*)d_in[5];
  const float* z_emb     = (const float*)d_in[6];
  const float* cn_w1     = (const float*)d_in[7];
  const float* cn_b1     = (const float*)d_in[8];
  const float* cn_w2     = (const float*)d_in[9];
  const float* cn_b2     = (const float*)d_in[10];
  const float* cn_cw     = (const float*)d_in[11];
  const float* cn_cb     = (const float*)d_in[12];
  const float* ce_w1     = (const float*)d_in[13];
  const float* ce_b1     = (const float*)d_in[14];
  const float* ce_w2     = (const float*)d_in[15];
  const float* ce_b2     = (const float*)d_in[16];
  const float* ce_cw     = (const float*)d_in[17];
  const float* ce_cb     = (const float*)d_in[18];
  const float* Wq        = (const float*)d_in[19];
  const float* bq        = (const float*)d_in[20];
  const float* Wk        = (const float*)d_in[21];
  const float* bk        = (const float*)d_in[22];
  const float* Wv        = (const float*)d_in[23];
  const float* bv        = (const float*)d_in[24];
  const float* Ws        = (const float*)d_in[25];
  const float* bs        = (const float*)d_in[26];
  const float* lt_g      = (const float*)d_in[27];
  const float* lt_b      = (const float*)d_in[28];
  const float* lc_g      = (const float*)d_in[29];
  const float* lc_b      = (const float*)d_in[30];
  const float* pe_w      = (const float*)d_in[31];
  const float* pe_b      = (const float*)d_in[32];
  const float* pn_w      = (const float*)d_in[33];
  const float* pn_b      = (const float*)d_in[34];
  const float* gf_w      = (const float*)d_in[35];
  const float* gf_b      = (const float*)d_in[36];
  const float* c_w1      = (const float*)d_in[37];
  const float* c_b1      = (const float*)d_in[38];
  const float* c_w2      = (const float*)d_in[39];
  const float* c_b2      = (const float*)d_in[40];
  const int*   edge_index= (const int*)d_in[41];

  const int N  = in_sizes[0] / 6;
  const int E  = in_sizes[1] / 4;
  const int E2 = 2 * E;

  // ---------------- workspace layout
  char* p = (char*)d_ws;
  auto alloc = [&](size_t bytes)->char*{
    char* r = p; p += (bytes + 255) & ~(size_t)255; return r;
  };
  int*            w_src    = (int*)           alloc((size_t)E2 * 4);
  int*            w_dst    = (int*)           alloc((size_t)E2 * 4);
  int*            w_deg    = (int*)           alloc((size_t)N * 4);
  int*            w_rowptr = (int*)           alloc((size_t)(N + 1) * 4);
  int*            w_cur    = (int*)           alloc((size_t)N * 4);
  int*            w_eids   = (int*)           alloc((size_t)E2 * 4);
  int*            w_csrc   = (int*)           alloc((size_t)E2 * 4);
  float*          w_nf     = (float*)         alloc((size_t)N * 64 * 4);
  float*          w_ef     = (float*)         alloc((size_t)E2 * 64 * 4);
  unsigned short* w_comb   = (unsigned short*)alloc((size_t)N * 128 * 2);
  float*          w_q      = (float*)         alloc((size_t)N * 256 * 4);
  unsigned short* w_k      = (unsigned short*)alloc((size_t)N * 256 * 2);
  unsigned short* w_v      = (unsigned short*)alloc((size_t)N * 256 * 2);
  float*          w_s      = (float*)         alloc((size_t)N * 256 * 4);
  unsigned short* w_outb   = (unsigned short*)alloc((size_t)N * 256 * 2);
  float*          w_pnP    = (float*)         alloc((size_t)N * 128 * 4);
  float*          w_alpha  = (float*)         alloc((size_t)E2 * 4 * 4);
  float*          w_A      = (float*)         alloc((size_t)N * 64 * 4);
  float*          w_B      = (float*)         alloc((size_t)N * 64 * 4);
  unsigned short* w_Bt     = (unsigned short*)alloc((size_t)1024 * 128 * 2);
  float*          w_bias   = (float*)         alloc(1024 * 4);
  unsigned short* w_Bt2    = (unsigned short*)alloc((size_t)128 * 256 * 2);
  float*          w_bias2  = (float*)         alloc(128 * 4);
  unsigned*       w_pmax   = (unsigned*)      alloc(64 * 4);
  float*          w_psum   = (float*)         alloc(64 * 4);
  float*          w_ch     = (float*)         alloc(64 * 4);
  unsigned*       w_pmax2  = (unsigned*)      alloc(64 * 4);
  float*          w_psum2  = (float*)         alloc(64 * 4);
  float*          w_ch2    = (float*)         alloc(64 * 4);
  float*          w_rp     = w_alpha;

  hipMemsetAsync(w_deg,  0, (size_t)N * 4, stream);
  hipMemsetAsync(w_cur,  0, (size_t)N * 4, stream);
  hipMemsetAsync(w_pmax, 0, 64 * 4, stream);
  hipMemsetAsync(w_psum, 0, 64 * 4, stream);
  hipMemsetAsync(w_pmax2,0, 64 * 4, stream);
  hipMemsetAsync(w_psum2,0, 64 * 4, stream);

  // ---------------- CSR + embeddings
  k_build_edges<<<(E2 + 255)/256, 256, 0, stream>>>(edge_index, E2, E, w_src, w_dst, w_deg);
  k_scan<<<1, 1024, 0, stream>>>(w_deg, w_rowptr, N);
  k_fill<<<(E2 + 255)/256, 256, 0, stream>>>(w_src, w_dst, w_rowptr, w_cur, w_eids, w_csrc, E2);
  k_node_embed<<<(N + 3)/4, 256, 0, stream>>>(x, node_w, node_b, z_emb, w_nf, N);

  // node CBAM
  k_colpool<<<512, 256, 0, stream>>>(w_nf, N, w_pmax, w_psum);
  k_cbam_mlp<<<1, 64, 0, stream>>>(w_pmax, w_psum, 1.f/(float)N,
                                   cn_w1, cn_b1, cn_w2, cn_b2, w_ch);
  k_chmul_rowpool<<<(N + 3)/4, 256, 0, stream>>>(w_nf, w_ch, w_rp, N);
  k_spatial<<<(N + 3)/4, 256, 0, stream>>>(w_nf, w_rp, cn_cw, cn_cb, N);

  // edge features + CBAM
  k_edge_feat<<<(E2 + 3)/4, 256, 0, stream>>>(x, edge_attr, w_src, w_dst,
                                              edge_w, edge_b, w_ef, E2, E);
  k_colpool<<<512, 256, 0, stream>>>(w_ef, E2, w_pmax2, w_psum2);
  k_cbam_mlp<<<1, 64, 0, stream>>>(w_pmax2, w_psum2, 1.f/(float)E2,
                                   ce_w1, ce_b1, ce_w2, ce_b2, w_ch2);
  k_chmul_rowpool<<<(E2 + 3)/4, 256, 0, stream>>>(w_ef, w_ch2, w_rp, E2);
  k_spatial<<<(E2 + 3)/4, 256, 0, stream>>>(w_ef, w_rp, ce_cw, ce_cb, E2);

  // ---------------- message-passing iterations
  const int MB = (N + 127) / 128;
  for (int i = 0; i < 3; ++i){
    k_comb<<<(N + 3)/4, 256, 0, stream>>>(w_nf, w_ef, w_rowptr, w_eids,
                                          lc_g + (size_t)i*128, lc_b + (size_t)i*128,
                                          w_comb, N);
    k_pack_w<<<1024, 128, 0, stream>>>(Wq + (size_t)i*128*256, Wk + (size_t)i*128*256,
                                       Wv + (size_t)i*128*256, Ws + (size_t)i*128*256,
                                       bq + (size_t)i*256, bk + (size_t)i*256,
                                       bv + (size_t)i*256, bs + (size_t)i*256,
                                       w_Bt, w_bias);
    k_mfma<1,0><<<dim3(8, MB), 256, 0, stream>>>(w_comb, 128, w_Bt, 128, w_bias,
                                                 w_q, w_k, w_v, w_s, N);
    k_attn<<<(N + 3)/4, 256, 0, stream>>>(w_q, w_k, w_v, w_s, w_rowptr, w_csrc, w_alpha,
                                          lt_g + (size_t)i*256, lt_b + (size_t)i*256,
                                          w_outb, N);
    k_pack_w2<<<128, 256, 0, stream>>>(pn_w + (size_t)i*256*64, pe_w + (size_t)i*256*64,
                                       pn_b + (size_t)i*64, w_Bt2, w_bias2);
    k_mfma<2,1><<<dim3(1, MB), 256, 0, stream>>>(w_outb, 256, w_Bt2, 256, w_bias2,
                                                 w_pnP, nullptr, nullptr, nullptr, N);
    k_gate<<<1250, 256, 0, stream>>>(w_nf, w_pnP, gf_w + (size_t)i*128*64,
                                     gf_b + (size_t)i*64, N);
    k_edge_upd<<<((size_t)E2*64 + 255)/256, 256, 0, stream>>>(w_ef, w_pnP, w_src, w_dst,
                                                              pe_b + (size_t)i*64, E2);
  }

  // ---------------- classifier
  dim3 g64((N + 63)/64, 1);
  k_gemm<64,64><<<g64, 256, 0, stream>>>(w_nf, c_w1,         64, nullptr, w_A, 64, N);
  k_gemm<64,64><<<g64, 256, 0, stream>>>(w_nf, c_w1 + 64*64, 64, nullptr, w_B, 64, N);
  k_final<<<(E + 3)/4, 256, 0, stream>>>(w_A, w_B, edge_index, c_b1, c_w2, c_b2,
                                         (float*)d_out, E);
}

// Round 3
// 1149.496 us; speedup vs baseline: 1.7650x; 1.2299x over previous
//
#include <hip/hip_runtime.h>
#include <math.h>

typedef __attribute__((ext_vector_type(8))) short short8;
typedef __attribute__((ext_vector_type(4))) float f32x4;

// ---------------------------------------------------------------- utilities
__device__ __forceinline__ float wave_sum(float v){
  #pragma unroll
  for (int m = 32; m; m >>= 1) v += __shfl_xor(v, m, 64);
  return v;
}
__device__ __forceinline__ float wave_max(float v){
  #pragma unroll
  for (int m = 32; m; m >>= 1) v = fmaxf(v, __shfl_xor(v, m, 64));
  return v;
}
__device__ __forceinline__ unsigned fenc(float f){
  unsigned u = __float_as_uint(f);
  return (u >> 31) ? ~u : (u | 0x80000000u);
}
__device__ __forceinline__ float fdec(unsigned e){
  return (e >> 31) ? __uint_as_float(e & 0x7fffffffu) : __uint_as_float(~e);
}
__device__ __forceinline__ float sigm(float x){ return 1.f / (1.f + __expf(-x)); }
__device__ __forceinline__ unsigned short f2bf(float f){
  union { float f; unsigned u; } x; x.f = f;
  unsigned r = x.u + 0x7fffu + ((x.u >> 16) & 1u);
  return (unsigned short)(r >> 16);
}
__device__ __forceinline__ float bf2f(unsigned short h){
  union { unsigned u; float f; } x; x.u = ((unsigned)h) << 16;
  return x.f;
}

// ------------------------------------------------------------ CSR building
__global__ void k_build_edges(const int* __restrict__ ei, int E2, int E,
                              int* __restrict__ src, int* __restrict__ dst,
                              int* __restrict__ deg){
  int e = blockIdx.x * blockDim.x + threadIdx.x;
  if (e >= E2) return;
  int s = ei[e];
  int d = (e < E) ? ei[e + E] : ei[e - E];
  src[e] = s; dst[e] = d;
  atomicAdd(&deg[d], 1);
}

__global__ void k_scan(const int* __restrict__ deg, int* __restrict__ rowptr, int N){
  __shared__ int part[1024];
  int t = threadIdx.x;
  int chunk = (N + 1023) / 1024;
  int lo = t * chunk, hi = lo + chunk; if (hi > N) hi = N;
  int s = 0;
  for (int i = lo; i < hi; ++i) s += deg[i];
  part[t] = s;
  __syncthreads();
  for (int off = 1; off < 1024; off <<= 1){
    int v = (t >= off) ? part[t - off] : 0;
    __syncthreads();
    part[t] += v;
    __syncthreads();
  }
  int run = part[t] - s;
  for (int i = lo; i < hi; ++i){ rowptr[i] = run; run += deg[i]; }
  if (t == 1023) rowptr[N] = part[1023];
}

__global__ void k_fill(const int* __restrict__ src, const int* __restrict__ dst,
                       const int* __restrict__ rowptr,
                       int* __restrict__ cur, int* __restrict__ eids,
                       int* __restrict__ csrc, int E2){
  int e = blockIdx.x * blockDim.x + threadIdx.x;
  if (e >= E2) return;
  int d = dst[e];
  int pos = rowptr[d] + atomicAdd(&cur[d], 1);
  eids[pos] = e;
  csrc[pos] = src[e];
}

// ---------------------------------------------------------- node embedding
__global__ void k_node_embed(const float* __restrict__ x, const float* __restrict__ nw,
                             const float* __restrict__ nb, const float* __restrict__ zemb,
                             float* __restrict__ nf, int N){
  int n = blockIdx.x * 4 + (threadIdx.x >> 6);
  if (n >= N) return;
  int l = threadIdx.x & 63;
  float xv[6];
  #pragma unroll
  for (int k = 0; k < 6; ++k) xv[k] = x[n*6 + k];
  float v = nb[l];
  #pragma unroll
  for (int k = 0; k < 6; ++k) v += xv[k] * nw[k*64 + l];
  v = fmaxf(v, 0.f);
  const float allowed[6] = {8.f, 23.f, 39.f, 54.f, 90.f, 180.f};
  float r = rintf(xv[2]);
  int zi = 0; float bd = fabsf(r - allowed[0]);
  #pragma unroll
  for (int k = 1; k < 6; ++k){ float d = fabsf(r - allowed[k]); if (d < bd){ bd = d; zi = k; } }
  v += zemb[zi*64 + l];
  nf[(size_t)n*64 + l] = v;
}

// ------------------------------------------------------------------- CBAM (node)
__global__ void k_colpool(const float* __restrict__ buf, int R,
                          unsigned* __restrict__ pmax, float* __restrict__ psum){
  int tx = threadIdx.x & 63;
  int ty = threadIdx.x >> 6;
  float m = -INFINITY, s = 0.f;
  for (int r = blockIdx.x*4 + ty; r < R; r += gridDim.x*4){
    float v = buf[(size_t)r*64 + tx];
    m = fmaxf(m, v); s += v;
  }
  __shared__ float sm[4][64], ss[4][64];
  sm[ty][tx] = m; ss[ty][tx] = s;
  __syncthreads();
  if (ty == 0){
    #pragma unroll
    for (int k = 1; k < 4; ++k){ m = fmaxf(m, sm[k][tx]); s += ss[k][tx]; }
    atomicMax(&pmax[tx], fenc(m));
    atomicAdd(&psum[tx], s);
  }
}

__global__ void k_cbam_mlp(const unsigned* __restrict__ pmax, const float* __restrict__ psum,
                           float invR,
                           const float* __restrict__ w1, const float* __restrict__ b1,
                           const float* __restrict__ w2, const float* __restrict__ b2,
                           float* __restrict__ ch){
  __shared__ float pool[128];
  __shared__ float h[4];
  int t = threadIdx.x;
  pool[t]      = fdec(pmax[t]);
  pool[64 + t] = psum[t] * invR;
  __syncthreads();
  if (t < 4){
    float a = b1[t];
    for (int k = 0; k < 128; ++k) a += pool[k] * w1[k*4 + t];
    h[t] = fmaxf(a, 0.f);
  }
  __syncthreads();
  float a = b2[t];
  #pragma unroll
  for (int k = 0; k < 4; ++k) a += h[k] * w2[k*64 + t];
  ch[t] = sigm(a);
}

__global__ void k_chmul_rowpool(float* __restrict__ buf, const float* __restrict__ ch,
                                float* __restrict__ rp, int R){
  int r = blockIdx.x*4 + (threadIdx.x >> 6);
  if (r >= R) return;
  int l = threadIdx.x & 63;
  float v = buf[(size_t)r*64 + l] * ch[l];
  buf[(size_t)r*64 + l] = v;
  float m = wave_max(v);
  float s = wave_sum(v);
  if (l == 0){ rp[(size_t)r*2] = m; rp[(size_t)r*2 + 1] = s * (1.f/64.f); }
}

__global__ void k_spatial(float* __restrict__ buf, const float* __restrict__ rp,
                          const float* __restrict__ cw, const float* __restrict__ cb, int R){
  int r = blockIdx.x*4 + (threadIdx.x >> 6);
  if (r >= R) return;
  int l = threadIdx.x & 63;
  float sp = cb[0];
  #pragma unroll
  for (int t = 0; t < 7; ++t){
    int rr = r + t - 3;
    if (rr >= 0 && rr < R)
      sp += cw[t] * rp[(size_t)rr*2] + cw[7 + t] * rp[(size_t)rr*2 + 1];
  }
  buf[(size_t)r*64 + l] *= sigm(sp);
}

// ---------------------------------------------- edge raw-feature helper (inline)
// raw(e)[l] = relu(eb[l] + sum_k ea[row,k]*ew[k,l] + sum_c (x[s,c]-x[d,c])*ew[4+c,l])

// edge column-pool over raw (before channel attention), ef never stored
__global__ void k_ecol(const float* __restrict__ x, const float* __restrict__ ea,
                       const int* __restrict__ src, const int* __restrict__ dst,
                       const float* __restrict__ ew, const float* __restrict__ eb,
                       unsigned* __restrict__ pmax, float* __restrict__ psum,
                       int E2, int E){
  __shared__ float s_ew[448];
  int tid = threadIdx.x;
  for (int idx = tid; idx < 448; idx += 256) s_ew[idx] = ew[idx];
  __syncthreads();
  int tx = tid & 63, ty = tid >> 6;
  float ebl = eb[tx];
  float m = -INFINITY, s = 0.f;
  for (int e = blockIdx.x*4 + ty; e < E2; e += gridDim.x*4){
    int sn = src[e], dn = dst[e];
    int row = (e < E) ? e : e - E;
    float v = ebl;
    #pragma unroll
    for (int k = 0; k < 4; ++k) v += ea[(size_t)row*4 + k] * s_ew[k*64 + tx];
    #pragma unroll
    for (int c = 0; c < 3; ++c) v += (x[sn*6 + c] - x[dn*6 + c]) * s_ew[(4+c)*64 + tx];
    v = fmaxf(v, 0.f);
    m = fmaxf(m, v); s += v;
  }
  __shared__ float sm[4][64], ss[4][64];
  sm[ty][tx] = m; ss[ty][tx] = s;
  __syncthreads();
  if (ty == 0){
    #pragma unroll
    for (int k = 1; k < 4; ++k){ m = fmaxf(m, sm[k][tx]); s += ss[k][tx]; }
    atomicMax(&pmax[tx], fenc(m));
    atomicAdd(&psum[tx], s);
  }
}

// edge row-pool of raw*ch (for spatial conv input), rp stored [E2][2]
__global__ void k_erp(const float* __restrict__ x, const float* __restrict__ ea,
                      const int* __restrict__ src, const int* __restrict__ dst,
                      const float* __restrict__ ew, const float* __restrict__ eb,
                      const float* __restrict__ ch,
                      float* __restrict__ rp, int E2, int E){
  __shared__ float s_ew[448];
  int tid = threadIdx.x;
  for (int idx = tid; idx < 448; idx += 256) s_ew[idx] = ew[idx];
  __syncthreads();
  int e = blockIdx.x*4 + (tid >> 6);
  if (e >= E2) return;
  int l = tid & 63;
  int sn = src[e], dn = dst[e];
  int row = (e < E) ? e : e - E;
  float v = eb[l];
  #pragma unroll
  for (int k = 0; k < 4; ++k) v += ea[(size_t)row*4 + k] * s_ew[k*64 + l];
  #pragma unroll
  for (int c = 0; c < 3; ++c) v += (x[sn*6 + c] - x[dn*6 + c]) * s_ew[(4+c)*64 + l];
  v = fmaxf(v, 0.f) * ch[l];
  float m = wave_max(v);
  float s = wave_sum(v);
  if (l == 0){ rp[(size_t)e*2] = m; rp[(size_t)e*2 + 1] = s * (1.f/64.f); }
}

// agg0[n] = segment_sum over CSR of full ef0(e) = raw*ch*sigm(conv(rp,e))
__global__ void k_agg0(const float* __restrict__ x, const float* __restrict__ ea,
                       const int* __restrict__ rowptr, const int* __restrict__ eids,
                       const int* __restrict__ csrc,
                       const float* __restrict__ ew, const float* __restrict__ eb,
                       const float* __restrict__ ch, const float* __restrict__ rp,
                       const float* __restrict__ ccw, const float* __restrict__ ccb,
                       float* __restrict__ agg, int N, int E, int E2){
  __shared__ float s_ew[448];
  int tid = threadIdx.x;
  for (int idx = tid; idx < 448; idx += 256) s_ew[idx] = ew[idx];
  __syncthreads();
  int n = blockIdx.x*4 + (tid >> 6);
  if (n >= N) return;
  int l = tid & 63;
  float cw[14];
  #pragma unroll
  for (int t = 0; t < 14; ++t) cw[t] = ccw[t];
  float cb = ccb[0];
  float chl = ch[l], ebl = eb[l];
  float x0 = x[n*6], x1 = x[n*6+1], x2 = x[n*6+2];
  int lo = rowptr[n], hi = rowptr[n+1];
  float acc = 0.f;
  for (int i = lo; i < hi; ++i){
    int e = eids[i], sn = csrc[i];
    int row = (e < E) ? e : e - E;
    float v = ebl;
    #pragma unroll
    for (int k = 0; k < 4; ++k) v += ea[(size_t)row*4 + k] * s_ew[k*64 + l];
    v += (x[sn*6]   - x0) * s_ew[4*64 + l];
    v += (x[sn*6+1] - x1) * s_ew[5*64 + l];
    v += (x[sn*6+2] - x2) * s_ew[6*64 + l];
    v = fmaxf(v, 0.f) * chl;
    float sp = cb;
    #pragma unroll
    for (int t = 0; t < 7; ++t){
      int rr = e + t - 3;
      if (rr >= 0 && rr < E2)
        sp += cw[t] * rp[(size_t)rr*2] + cw[7+t] * rp[(size_t)rr*2 + 1];
    }
    acc += v * sigm(sp);
  }
  agg[(size_t)n*64 + l] = acc;
}

// ------------------------------------- concat-LN (nf, agg-nf) -> comb bf16
__global__ void k_comb(const float* __restrict__ nf, const float* __restrict__ agg,
                       const float* __restrict__ g, const float* __restrict__ b,
                       unsigned short* __restrict__ comb, int N){
  int n = blockIdx.x*4 + (threadIdx.x >> 6);
  if (n >= N) return;
  int l = threadIdx.x & 63;
  float a = nf[(size_t)n*64 + l];
  float v0 = a, v1 = agg[(size_t)n*64 + l] - a;
  float mean = wave_sum(v0 + v1) * (1.f/128.f);
  float d0 = v0 - mean, d1 = v1 - mean;
  float var = wave_sum(d0*d0 + d1*d1) * (1.f/128.f);
  float rs = rsqrtf(var + 1e-5f);
  comb[(size_t)n*128 + l]      = f2bf(d0 * rs * g[l]      + b[l]);
  comb[(size_t)n*128 + 64 + l] = f2bf(d1 * rs * g[64 + l] + b[64 + l]);
}

// ------------------------------------------------ weight pack (fp32 -> bf16^T)
__global__ void k_pack_w(const float* __restrict__ Wq, const float* __restrict__ Wk,
                         const float* __restrict__ Wv, const float* __restrict__ Ws,
                         const float* __restrict__ bq, const float* __restrict__ bk,
                         const float* __restrict__ bv, const float* __restrict__ bs,
                         unsigned short* __restrict__ Bt, float* __restrict__ bias){
  int g = blockIdx.x, k = threadIdx.x;
  const float* W  = (g < 256) ? Wq : (g < 512) ? Wk : (g < 768) ? Wv : Ws;
  const float* bb = (g < 256) ? bq : (g < 512) ? bk : (g < 768) ? bv : bs;
  int c = g & 255;
  Bt[(size_t)g*128 + k] = f2bf(W[(size_t)k*256 + c]);
  if (k == 0) bias[g] = bb[c];
}

__global__ void k_pack_w2(const float* __restrict__ pnw, const float* __restrict__ pew,
                          const float* __restrict__ pnb,
                          unsigned short* __restrict__ Bt, float* __restrict__ bias){
  int g = blockIdx.x, k = threadIdx.x;
  const float* W = (g < 64) ? pnw : pew;
  int c = g & 63;
  Bt[(size_t)g*256 + k] = f2bf(W[(size_t)k*64 + c]);
  if (k == 0) bias[g] = (g < 64) ? pnb[c] : 0.f;
}

// ---------------------------------------------------------- MFMA bf16 GEMM
template<int NSTEPS, int MODE>
__global__ __launch_bounds__(256) void k_mfma(
    const unsigned short* __restrict__ A, int lda,
    const unsigned short* __restrict__ Bt, int ldb,
    const float* __restrict__ bias,
    float* __restrict__ o_f0, unsigned short* __restrict__ o_h0,
    unsigned short* __restrict__ o_h1, float* __restrict__ o_f1, int M){
  __shared__ char lds[65536];
  char* ldsA = lds;
  char* ldsB = lds + 32768;
  int tid = threadIdx.x;
  int nbase = blockIdx.x * 128;
  int mbase = blockIdx.y * 128;
  int l = tid & 63, wid = tid >> 6;
  int wm = (wid >> 1) * 64, wn = (wid & 1) * 64;
  f32x4 acc[4][4] = {};
  const char* Ab  = (const char*)A;
  const char* Btb = (const char*)Bt;
  for (int ks = 0; ks < NSTEPS; ++ks){
    #pragma unroll
    for (int it = 0; it < 8; ++it){
      int c = tid + it*256;
      int row = c >> 4;
      int kb = (c & 15) << 4;
      int off = (row << 8) + (kb ^ ((row & 7) << 4));
      uint4 va = make_uint4(0,0,0,0);
      int gr = mbase + row;
      if (gr < M)
        va = *reinterpret_cast<const uint4*>(Ab + (size_t)gr*(lda*2) + ks*256 + kb);
      *reinterpret_cast<uint4*>(ldsA + off) = va;
      uint4 vb = *reinterpret_cast<const uint4*>(
                   Btb + (size_t)(nbase + row)*(ldb*2) + ks*256 + kb);
      *reinterpret_cast<uint4*>(ldsB + off) = vb;
    }
    __syncthreads();
    #pragma unroll
    for (int kk = 0; kk < 4; ++kk){
      int kbyte = kk*64 + (l >> 4)*16;
      short8 af[4], bf[4];
      #pragma unroll
      for (int m = 0; m < 4; ++m){
        int fr = wm + m*16 + (l & 15);
        af[m] = *reinterpret_cast<const short8*>(ldsA + (fr << 8) + (kbyte ^ ((fr & 7) << 4)));
      }
      #pragma unroll
      for (int n = 0; n < 4; ++n){
        int fc = wn + n*16 + (l & 15);
        bf[n] = *reinterpret_cast<const short8*>(ldsB + (fc << 8) + (kbyte ^ ((fc & 7) << 4)));
      }
      #pragma unroll
      for (int m = 0; m < 4; ++m)
        #pragma unroll
        for (int n = 0; n < 4; ++n)
          acc[m][n] = __builtin_amdgcn_mfma_f32_16x16x32_bf16(af[m], bf[n], acc[m][n], 0, 0, 0);
    }
    __syncthreads();
  }
  #pragma unroll
  for (int n = 0; n < 4; ++n){
    int gcol = nbase + wn + n*16 + (l & 15);
    float bv = bias ? bias[gcol] : 0.f;
    #pragma unroll
    for (int m = 0; m < 4; ++m){
      int grow = mbase + wm + m*16 + (l >> 4)*4;
      #pragma unroll
      for (int r = 0; r < 4; ++r){
        int gr = grow + r;
        if (gr < M){
          float val = acc[m][n][r] + bv;
          if (MODE == 1){
            o_f0[(size_t)gr*128 + gcol] = val;
          } else {
            int seg = gcol >> 8, c = gcol & 255;
            if      (seg == 0) o_f0[(size_t)gr*256 + c] = val;
            else if (seg == 1) o_h0[(size_t)gr*256 + c] = f2bf(val);
            else if (seg == 2) o_h1[(size_t)gr*256 + c] = f2bf(val);
            else               o_f1[(size_t)gr*256 + c] = val;
          }
        }
      }
    }
  }
}

// -------------- single-pass fused attention + skip + LN (lane-partitioned)
// lane l: head h=l>>4, dims 4*(l&15).. ; global col = 4*l
__global__ void k_attn(const float* __restrict__ q, const unsigned short* __restrict__ kbuf,
                       const unsigned short* __restrict__ vbuf, const float* __restrict__ sbuf,
                       const int* __restrict__ rowptr, const int* __restrict__ csrc,
                       const float* __restrict__ ltg, const float* __restrict__ ltb,
                       unsigned short* __restrict__ outb, int N){
  int n = blockIdx.x*4 + (threadIdx.x >> 6);
  if (n >= N) return;
  int l = threadIdx.x & 63;
  int lo = rowptr[n], hi = rowptr[n+1];
  size_t base = (size_t)n*256 + l*4;
  float4 qv = *reinterpret_cast<const float4*>(q + base);
  qv.x *= 0.125f; qv.y *= 0.125f; qv.z *= 0.125f; qv.w *= 0.125f;
  float o0 = 0.f, o1 = 0.f, o2 = 0.f, o3 = 0.f, s = 0.f;
  for (int i = lo; i < hi; ++i){
    size_t sb = (size_t)csrc[i]*256 + l*4;
    ushort4 kv = *reinterpret_cast<const ushort4*>(kbuf + sb);
    ushort4 vv = *reinterpret_cast<const ushort4*>(vbuf + sb);
    float a = qv.x*bf2f(kv.x) + qv.y*bf2f(kv.y) + qv.z*bf2f(kv.z) + qv.w*bf2f(kv.w);
    a += __shfl_xor(a, 1, 64);
    a += __shfl_xor(a, 2, 64);
    a += __shfl_xor(a, 4, 64);
    a += __shfl_xor(a, 8, 64);
    float w = __expf(a);           // no max-subtraction: |a| <~ 5 here, safe in fp32
    s += w;
    o0 += w*bf2f(vv.x); o1 += w*bf2f(vv.y); o2 += w*bf2f(vv.z); o3 += w*bf2f(vv.w);
  }
  float4 t = *reinterpret_cast<const float4*>(sbuf + base);
  if (hi > lo){
    float r = 1.f / s;
    t.x += o0*r; t.y += o1*r; t.z += o2*r; t.w += o3*r;
  }
  float mean = wave_sum(t.x + t.y + t.z + t.w) * (1.f/256.f);
  float dx = t.x - mean, dy = t.y - mean, dz = t.z - mean, dw = t.w - mean;
  float var = wave_sum(dx*dx + dy*dy + dz*dz + dw*dw) * (1.f/256.f);
  float rs = rsqrtf(var + 1e-5f);
  float4 g = *reinterpret_cast<const float4*>(ltg + l*4);
  float4 b = *reinterpret_cast<const float4*>(ltb + l*4);
  ushort4 o;
  o.x = f2bf(dx*rs*g.x + b.x);
  o.y = f2bf(dy*rs*g.y + b.y);
  o.z = f2bf(dz*rs*g.z + b.z);
  o.w = f2bf(dw*rs*g.w + b.w);
  *reinterpret_cast<ushort4*>(outb + base) = o;
}

// --------------- gated fusion (nf) + agg-space edge update, one kernel
__global__ __launch_bounds__(256) void k_gate_agg(
    float* __restrict__ nf, float* __restrict__ agg,
    const float* __restrict__ pnP,
    const int* __restrict__ rowptr, const int* __restrict__ csrc,
    const float* __restrict__ gfw, const float* __restrict__ gfb,
    const float* __restrict__ peb, int N){
  __shared__ float s_w[128 * 64];
  int tid = threadIdx.x;
  for (int idx = tid; idx < 128*64; idx += 256) s_w[idx] = gfw[idx];
  __syncthreads();
  int wv = tid >> 6, l = tid & 63;
  float gb = gfb[l], pebl = peb[l];
  for (int n = blockIdx.x*4 + wv; n < N; n += gridDim.x*4){
    float nfv = nf[(size_t)n*64 + l];
    float pnv = pnP[(size_t)n*128 + l];
    float g = gb;
    #pragma unroll 8
    for (int k = 0; k < 64; ++k){
      g += __shfl(nfv, k, 64) * s_w[k*64 + l];
      g += __shfl(pnv, k, 64) * s_w[(64 + k)*64 + l];
    }
    g = sigm(g);
    nf[(size_t)n*64 + l] = nfv * (1.f + g) + pnv * (1.f - g);
    // agg += sum_{e in(n)} P[src] - deg*(P[n] - peb)
    int lo = rowptr[n], hi = rowptr[n+1];
    float sp = 0.f;
    for (int i = lo; i < hi; ++i)
      sp += pnP[(size_t)csrc[i]*128 + 64 + l];
    float Pn = pnP[(size_t)n*128 + 64 + l];
    agg[(size_t)n*64 + l] += sp - (float)(hi - lo) * (Pn - pebl);
  }
}

// ------------------------------------------------------------- classifier
template<int K, int BN>
__global__ __launch_bounds__(256) void k_gemm(
    const float* __restrict__ in, const float* __restrict__ W, int ldw,
    const float* __restrict__ bias, float* __restrict__ out, int ldo, int nrows){
  constexpr int PAD = BN + 4;
  __shared__ float s_in[K * PAD];
  int n0 = blockIdx.x * BN;
  int tid = threadIdx.x;
  for (int idx = tid; idx < BN * K; idx += 256){
    int r = idx / K, k = idx - r * K;
    float v = (n0 + r < nrows) ? in[(size_t)(n0 + r) * K + k] : 0.f;
    s_in[k * PAD + r] = v;
  }
  __syncthreads();
  int tx = tid & 15, ty = tid >> 4;
  constexpr int NT = BN / 16;
  int col0 = blockIdx.y * 64 + tx * 4;
  float acc[NT][4] = {};
  for (int k = 0; k < K; ++k){
    const float4 wv = *reinterpret_cast<const float4*>(&W[(size_t)k * ldw + col0]);
    #pragma unroll
    for (int i = 0; i < NT; ++i){
      float cv = s_in[k * PAD + ty * NT + i];
      acc[i][0] += cv * wv.x;
      acc[i][1] += cv * wv.y;
      acc[i][2] += cv * wv.z;
      acc[i][3] += cv * wv.w;
    }
  }
  #pragma unroll
  for (int i = 0; i < NT; ++i){
    int n = n0 + ty * NT + i;
    if (n < nrows){
      float4 o = make_float4(acc[i][0], acc[i][1], acc[i][2], acc[i][3]);
      *reinterpret_cast<float4*>(&out[(size_t)n * ldo + col0]) = o;
    }
  }
}

__global__ void k_final(const float* __restrict__ A, const float* __restrict__ B,
                        const int* __restrict__ ei, const float* __restrict__ cb1,
                        const float* __restrict__ cw2, const float* __restrict__ cb2,
                        float* __restrict__ dout, int E){
  int e = blockIdx.x*4 + (threadIdx.x >> 6);
  if (e >= E) return;
  int l = threadIdx.x & 63;
  int i0 = ei[e], i1 = ei[E + e];
  float h = fmaxf(A[(size_t)i0*64 + l] + B[(size_t)i1*64 + l] + cb1[l], 0.f);
  float p = wave_sum(h * cw2[l]);
  if (l == 0) dout[e] = p + cb2[0];
}

// ===========================================================================
extern "C" void kernel_launch(void* const* d_in, const int* in_sizes, int n_in,
                              void* d_out, int out_size, void* d_ws, size_t ws_size,
                              hipStream_t stream){
  const float* x         = (const float*)d_in[0];
  const float* edge_attr = (const float*)d_in[1];
  const float* node_w    = (const float*)d_in[2];
  const float* node_b    = (const float*)d_in[3];
  const float* edge_w    = (const float*)d_in[4];
  const float* edge_b    = (const float*)d_in[5];
  const float* z_emb     = (const float*)d_in[6];
  const float* cn_w1     = (const float*)d_in[7];
  const float* cn_b1     = (const float*)d_in[8];
  const float* cn_w2     = (const float*)d_in[9];
  const float* cn_b2     = (const float*)d_in[10];
  const float* cn_cw     = (const float*)d_in[11];
  const float* cn_cb     = (const float*)d_in[12];
  const float* ce_w1     = (const float*)d_in[13];
  const float* ce_b1     = (const float*)d_in[14];
  const float* ce_w2     = (const float*)d_in[15];
  const float* ce_b2     = (const float*)d_in[16];
  const float* ce_cw     = (const float*)d_in[17];
  const float* ce_cb     = (const float*)d_in[18];
  const float* Wq        = (const float*)d_in[19];
  const float* bq        = (const float*)d_in[20];
  const float* Wk        = (const float*)d_in[21];
  const float* bk        = (const float*)d_in[22];
  const float* Wv        = (const float*)d_in[23];
  const float* bv        = (const float*)d_in[24];
  const float* Ws        = (const float*)d_in[25];
  const float* bs        = (const float*)d_in[26];
  const float* lt_g      = (const float*)d_in[27];
  const float* lt_b      = (const float*)d_in[28];
  const float* lc_g      = (const float*)d_in[29];
  const float* lc_b      = (const float*)d_in[30];
  const float* pe_w      = (const float*)d_in[31];
  const float* pe_b      = (const float*)d_in[32];
  const float* pn_w      = (const float*)d_in[33];
  const float* pn_b      = (const float*)d_in[34];
  const float* gf_w      = (const float*)d_in[35];
  const float* gf_b      = (const float*)d_in[36];
  const float* c_w1      = (const float*)d_in[37];
  const float* c_b1      = (const float*)d_in[38];
  const float* c_w2      = (const float*)d_in[39];
  const float* c_b2      = (const float*)d_in[40];
  const int*   edge_index= (const int*)d_in[41];

  const int N  = in_sizes[0] / 6;
  const int E  = in_sizes[1] / 4;
  const int E2 = 2 * E;

  // ---------------- workspace layout
  char* p = (char*)d_ws;
  auto alloc = [&](size_t bytes)->char*{
    char* r = p; p += (bytes + 255) & ~(size_t)255; return r;
  };
  int*            w_src    = (int*)           alloc((size_t)E2 * 4);
  int*            w_dst    = (int*)           alloc((size_t)E2 * 4);
  int*            w_deg    = (int*)           alloc((size_t)N * 4);
  int*            w_rowptr = (int*)           alloc((size_t)(N + 1) * 4);
  int*            w_cur    = (int*)           alloc((size_t)N * 4);
  int*            w_eids   = (int*)           alloc((size_t)E2 * 4);
  int*            w_csrc   = (int*)           alloc((size_t)E2 * 4);
  float*          w_nf     = (float*)         alloc((size_t)N * 64 * 4);
  float*          w_agg    = (float*)         alloc((size_t)N * 64 * 4);
  unsigned short* w_comb   = (unsigned short*)alloc((size_t)N * 128 * 2);
  float*          w_q      = (float*)         alloc((size_t)N * 256 * 4);
  unsigned short* w_k      = (unsigned short*)alloc((size_t)N * 256 * 2);
  unsigned short* w_v      = (unsigned short*)alloc((size_t)N * 256 * 2);
  float*          w_s      = (float*)         alloc((size_t)N * 256 * 4);
  unsigned short* w_outb   = (unsigned short*)alloc((size_t)N * 256 * 2);
  float*          w_pnP    = (float*)         alloc((size_t)N * 128 * 4);
  float*          w_rp     = (float*)         alloc((size_t)E2 * 2 * 4);
  float*          w_A      = (float*)         alloc((size_t)N * 64 * 4);
  float*          w_B      = (float*)         alloc((size_t)N * 64 * 4);
  unsigned short* w_Bt     = (unsigned short*)alloc((size_t)3 * 1024 * 128 * 2);
  float*          w_bias   = (float*)         alloc((size_t)3 * 1024 * 4);
  unsigned short* w_Bt2    = (unsigned short*)alloc((size_t)3 * 128 * 256 * 2);
  float*          w_bias2  = (float*)         alloc((size_t)3 * 128 * 4);
  unsigned*       w_pmax   = (unsigned*)      alloc(64 * 4);
  float*          w_psum   = (float*)         alloc(64 * 4);
  float*          w_ch     = (float*)         alloc(64 * 4);
  unsigned*       w_pmax2  = (unsigned*)      alloc(64 * 4);
  float*          w_psum2  = (float*)         alloc(64 * 4);
  float*          w_ch2    = (float*)         alloc(64 * 4);

  hipMemsetAsync(w_deg,  0, (size_t)N * 4, stream);
  hipMemsetAsync(w_cur,  0, (size_t)N * 4, stream);
  hipMemsetAsync(w_pmax, 0, 64 * 4, stream);
  hipMemsetAsync(w_psum, 0, 64 * 4, stream);
  hipMemsetAsync(w_pmax2,0, 64 * 4, stream);
  hipMemsetAsync(w_psum2,0, 64 * 4, stream);

  // ---------------- CSR + embeddings
  k_build_edges<<<(E2 + 255)/256, 256, 0, stream>>>(edge_index, E2, E, w_src, w_dst, w_deg);
  k_scan<<<1, 1024, 0, stream>>>(w_deg, w_rowptr, N);
  k_fill<<<(E2 + 255)/256, 256, 0, stream>>>(w_src, w_dst, w_rowptr, w_cur, w_eids, w_csrc, E2);
  k_node_embed<<<(N + 3)/4, 256, 0, stream>>>(x, node_w, node_b, z_emb, w_nf, N);

  // node CBAM (nf materialized: small)
  k_colpool<<<512, 256, 0, stream>>>(w_nf, N, w_pmax, w_psum);
  k_cbam_mlp<<<1, 64, 0, stream>>>(w_pmax, w_psum, 1.f/(float)N,
                                   cn_w1, cn_b1, cn_w2, cn_b2, w_ch);
  k_chmul_rowpool<<<(N + 3)/4, 256, 0, stream>>>(w_nf, w_ch, w_rp, N);
  k_spatial<<<(N + 3)/4, 256, 0, stream>>>(w_nf, w_rp, cn_cw, cn_cb, N);

  // edge CBAM, fully on-the-fly (ef never materialized)
  k_ecol<<<512, 256, 0, stream>>>(x, edge_attr, w_src, w_dst, edge_w, edge_b,
                                  w_pmax2, w_psum2, E2, E);
  k_cbam_mlp<<<1, 64, 0, stream>>>(w_pmax2, w_psum2, 1.f/(float)E2,
                                   ce_w1, ce_b1, ce_w2, ce_b2, w_ch2);
  k_erp<<<(E2 + 3)/4, 256, 0, stream>>>(x, edge_attr, w_src, w_dst, edge_w, edge_b,
                                        w_ch2, w_rp, E2, E);
  k_agg0<<<(N + 3)/4, 256, 0, stream>>>(x, edge_attr, w_rowptr, w_eids, w_csrc,
                                        edge_w, edge_b, w_ch2, w_rp, ce_cw, ce_cb,
                                        w_agg, N, E, E2);

  // pack all iteration weights up front
  for (int i = 0; i < 3; ++i){
    k_pack_w<<<1024, 128, 0, stream>>>(Wq + (size_t)i*128*256, Wk + (size_t)i*128*256,
                                       Wv + (size_t)i*128*256, Ws + (size_t)i*128*256,
                                       bq + (size_t)i*256, bk + (size_t)i*256,
                                       bv + (size_t)i*256, bs + (size_t)i*256,
                                       w_Bt + (size_t)i*1024*128, w_bias + (size_t)i*1024);
    k_pack_w2<<<128, 256, 0, stream>>>(pn_w + (size_t)i*256*64, pe_w + (size_t)i*256*64,
                                       pn_b + (size_t)i*64,
                                       w_Bt2 + (size_t)i*128*256, w_bias2 + (size_t)i*128);
  }

  // ---------------- message-passing iterations
  const int MB = (N + 127) / 128;
  for (int i = 0; i < 3; ++i){
    k_comb<<<(N + 3)/4, 256, 0, stream>>>(w_nf, w_agg,
                                          lc_g + (size_t)i*128, lc_b + (size_t)i*128,
                                          w_comb, N);
    k_mfma<1,0><<<dim3(8, MB), 256, 0, stream>>>(w_comb, 128,
                                                 w_Bt + (size_t)i*1024*128, 128,
                                                 w_bias + (size_t)i*1024,
                                                 w_q, w_k, w_v, w_s, N);
    k_attn<<<(N + 3)/4, 256, 0, stream>>>(w_q, w_k, w_v, w_s, w_rowptr, w_csrc,
                                          lt_g + (size_t)i*256, lt_b + (size_t)i*256,
                                          w_outb, N);
    k_mfma<2,1><<<dim3(1, MB), 256, 0, stream>>>(w_outb, 256,
                                                 w_Bt2 + (size_t)i*128*256, 256,
                                                 w_bias2 + (size_t)i*128,
                                                 w_pnP, nullptr, nullptr, nullptr, N);
    k_gate_agg<<<1250, 256, 0, stream>>>(w_nf, w_agg, w_pnP, w_rowptr, w_csrc,
                                         gf_w + (size_t)i*128*64, gf_b + (size_t)i*64,
                                         pe_b + (size_t)i*64, N);
  }

  // ---------------- classifier
  dim3 g64((N + 63)/64, 1);
  k_gemm<64,64><<<g64, 256, 0, stream>>>(w_nf, c_w1,         64, nullptr, w_A, 64, N);
  k_gemm<64,64><<<g64, 256, 0, stream>>>(w_nf, c_w1 + 64*64, 64, nullptr, w_B, 64, N);
  k_final<<<(E + 3)/4, 256, 0, stream>>>(w_A, w_B, edge_index, c_b1, c_w2, c_b2,
                                         (float*)d_out, E);
}

// Round 4
// 902.399 us; speedup vs baseline: 2.2483x; 1.2738x over previous
//
#include <hip/hip_runtime.h>
#include <math.h>

typedef __attribute__((ext_vector_type(8))) short short8;
typedef __attribute__((ext_vector_type(4))) float f32x4;

// ---------------------------------------------------------------- utilities
__device__ __forceinline__ float wave_sum(float v){
  #pragma unroll
  for (int m = 32; m; m >>= 1) v += __shfl_xor(v, m, 64);
  return v;
}
__device__ __forceinline__ float wave_max(float v){
  #pragma unroll
  for (int m = 32; m; m >>= 1) v = fmaxf(v, __shfl_xor(v, m, 64));
  return v;
}
__device__ __forceinline__ unsigned fenc(float f){
  unsigned u = __float_as_uint(f);
  return (u >> 31) ? ~u : (u | 0x80000000u);
}
__device__ __forceinline__ float fdec(unsigned e){
  return (e >> 31) ? __uint_as_float(e & 0x7fffffffu) : __uint_as_float(~e);
}
__device__ __forceinline__ float sigm(float x){ return 1.f / (1.f + __expf(-x)); }
__device__ __forceinline__ unsigned short f2bf(float f){
  union { float f; unsigned u; } x; x.f = f;
  unsigned r = x.u + 0x7fffu + ((x.u >> 16) & 1u);
  return (unsigned short)(r >> 16);
}
__device__ __forceinline__ float bf2f(unsigned short h){
  union { unsigned u; float f; } x; x.u = ((unsigned)h) << 16;
  return x.f;
}

// ------------------------------------------------------------ CSR building
__global__ void k_build_edges(const int* __restrict__ ei, int E2, int E,
                              int* __restrict__ src, int* __restrict__ dst,
                              int* __restrict__ deg){
  int e = blockIdx.x * blockDim.x + threadIdx.x;
  if (e >= E2) return;
  int s = ei[e];
  int d = (e < E) ? ei[e + E] : ei[e - E];
  src[e] = s; dst[e] = d;
  atomicAdd(&deg[d], 1);
}

__global__ void k_scan(const int* __restrict__ deg, int* __restrict__ rowptr, int N){
  __shared__ int part[1024];
  int t = threadIdx.x;
  int chunk = (N + 1023) / 1024;
  int lo = t * chunk, hi = lo + chunk; if (hi > N) hi = N;
  int s = 0;
  for (int i = lo; i < hi; ++i) s += deg[i];
  part[t] = s;
  __syncthreads();
  for (int off = 1; off < 1024; off <<= 1){
    int v = (t >= off) ? part[t - off] : 0;
    __syncthreads();
    part[t] += v;
    __syncthreads();
  }
  int run = part[t] - s;
  for (int i = lo; i < hi; ++i){ rowptr[i] = run; run += deg[i]; }
  if (t == 1023) rowptr[N] = part[1023];
}

__global__ void k_fill(const int* __restrict__ src, const int* __restrict__ dst,
                       const int* __restrict__ rowptr,
                       int* __restrict__ cur, int* __restrict__ csrc,
                       int* __restrict__ epos, int E2){
  int e = blockIdx.x * blockDim.x + threadIdx.x;
  if (e >= E2) return;
  int d = dst[e];
  int pos = rowptr[d] + atomicAdd(&cur[d], 1);
  csrc[pos] = src[e];
  epos[e] = pos;
}

// ------------------------- fused node embedding + column pool (max/mean)
__global__ void k_embed_pool(const float* __restrict__ x, const float* __restrict__ nw,
                             const float* __restrict__ nb, const float* __restrict__ zemb,
                             float* __restrict__ nf,
                             unsigned* __restrict__ pmax, float* __restrict__ psum, int N){
  int tx = threadIdx.x & 63;
  int ty = threadIdx.x >> 6;
  const float allowed[6] = {8.f, 23.f, 39.f, 54.f, 90.f, 180.f};
  float m = -INFINITY, s = 0.f;
  for (int n = blockIdx.x*4 + ty; n < N; n += gridDim.x*4){
    float xv[6];
    #pragma unroll
    for (int k = 0; k < 6; ++k) xv[k] = x[n*6 + k];
    float v = nb[tx];
    #pragma unroll
    for (int k = 0; k < 6; ++k) v += xv[k] * nw[k*64 + tx];
    v = fmaxf(v, 0.f);
    float r = rintf(xv[2]);
    int zi = 0; float bd = fabsf(r - allowed[0]);
    #pragma unroll
    for (int k = 1; k < 6; ++k){ float d = fabsf(r - allowed[k]); if (d < bd){ bd = d; zi = k; } }
    v += zemb[zi*64 + tx];
    nf[(size_t)n*64 + tx] = v;
    m = fmaxf(m, v); s += v;
  }
  __shared__ float sm[4][64], ss[4][64];
  sm[ty][tx] = m; ss[ty][tx] = s;
  __syncthreads();
  if (ty == 0){
    #pragma unroll
    for (int k = 1; k < 4; ++k){ m = fmaxf(m, sm[k][tx]); s += ss[k][tx]; }
    atomicMax(&pmax[tx], fenc(m));
    atomicAdd(&psum[tx], s);
  }
}

// ------------------------------------------------------------------- CBAM MLP
__global__ void k_cbam_mlp(const unsigned* __restrict__ pmax, const float* __restrict__ psum,
                           float invR,
                           const float* __restrict__ w1, const float* __restrict__ b1,
                           const float* __restrict__ w2, const float* __restrict__ b2,
                           float* __restrict__ ch){
  __shared__ float pool[128];
  __shared__ float h[4];
  int t = threadIdx.x;
  pool[t]      = fdec(pmax[t]);
  pool[64 + t] = psum[t] * invR;
  __syncthreads();
  if (t < 4){
    float a = b1[t];
    for (int k = 0; k < 128; ++k) a += pool[k] * w1[k*4 + t];
    h[t] = fmaxf(a, 0.f);
  }
  __syncthreads();
  float a = b2[t];
  #pragma unroll
  for (int k = 0; k < 4; ++k) a += h[k] * w2[k*64 + t];
  ch[t] = sigm(a);
}

__global__ void k_chmul_rowpool(float* __restrict__ buf, const float* __restrict__ ch,
                                float* __restrict__ rp, int R){
  int r = blockIdx.x*4 + (threadIdx.x >> 6);
  if (r >= R) return;
  int l = threadIdx.x & 63;
  float v = buf[(size_t)r*64 + l] * ch[l];
  buf[(size_t)r*64 + l] = v;
  float m = wave_max(v);
  float s = wave_sum(v);
  if (l == 0){ rp[(size_t)r*2] = m; rp[(size_t)r*2 + 1] = s * (1.f/64.f); }
}

__global__ void k_spatial(float* __restrict__ buf, const float* __restrict__ rp,
                          const float* __restrict__ cw, const float* __restrict__ cb, int R){
  int r = blockIdx.x*4 + (threadIdx.x >> 6);
  if (r >= R) return;
  int l = threadIdx.x & 63;
  float sp = cb[0];
  #pragma unroll
  for (int t = 0; t < 7; ++t){
    int rr = r + t - 3;
    if (rr >= 0 && rr < R)
      sp += cw[t] * rp[(size_t)rr*2] + cw[7 + t] * rp[(size_t)rr*2 + 1];
  }
  buf[(size_t)r*64 + l] *= sigm(sp);
}

// ------------------------------------------- edge column-pool (raw features)
__global__ void k_ecol(const float* __restrict__ x, const float* __restrict__ ea,
                       const int* __restrict__ src, const int* __restrict__ dst,
                       const float* __restrict__ ew, const float* __restrict__ eb,
                       unsigned* __restrict__ pmax, float* __restrict__ psum,
                       int E2, int E){
  __shared__ float s_ew[448];
  int tid = threadIdx.x;
  for (int idx = tid; idx < 448; idx += 256) s_ew[idx] = ew[idx];
  __syncthreads();
  int tx = tid & 63, ty = tid >> 6;
  float ebl = eb[tx];
  float m = -INFINITY, s = 0.f;
  for (int e = blockIdx.x*4 + ty; e < E2; e += gridDim.x*4){
    int sn = src[e], dn = dst[e];
    int row = (e < E) ? e : e - E;
    float v = ebl;
    #pragma unroll
    for (int k = 0; k < 4; ++k) v += ea[(size_t)row*4 + k] * s_ew[k*64 + tx];
    #pragma unroll
    for (int c = 0; c < 3; ++c) v += (x[sn*6 + c] - x[dn*6 + c]) * s_ew[(4+c)*64 + tx];
    v = fmaxf(v, 0.f);
    m = fmaxf(m, v); s += v;
  }
  __shared__ float sm[4][64], ss[4][64];
  sm[ty][tx] = m; ss[ty][tx] = s;
  __syncthreads();
  if (ty == 0){
    #pragma unroll
    for (int k = 1; k < 4; ++k){ m = fmaxf(m, sm[k][tx]); s += ss[k][tx]; }
    atomicMax(&pmax[tx], fenc(m));
    atomicAdd(&psum[tx], s);
  }
}

// ------------- edge row-pool + scatter-store ef0=raw*ch (fp32, CSR order)
__global__ void k_erp2(const float* __restrict__ x, const float* __restrict__ ea,
                       const int* __restrict__ src, const int* __restrict__ dst,
                       const int* __restrict__ epos,
                       const float* __restrict__ ew, const float* __restrict__ eb,
                       const float* __restrict__ ch,
                       float* __restrict__ rp, float* __restrict__ ef0, int E2, int E){
  __shared__ float s_ew[448];
  int tid = threadIdx.x;
  for (int idx = tid; idx < 448; idx += 256) s_ew[idx] = ew[idx];
  __syncthreads();
  int e = blockIdx.x*4 + (tid >> 6);
  if (e >= E2) return;
  int l = tid & 63;
  int sn = src[e], dn = dst[e];
  int row = (e < E) ? e : e - E;
  float v = eb[l];
  #pragma unroll
  for (int k = 0; k < 4; ++k) v += ea[(size_t)row*4 + k] * s_ew[k*64 + l];
  #pragma unroll
  for (int c = 0; c < 3; ++c) v += (x[sn*6 + c] - x[dn*6 + c]) * s_ew[(4+c)*64 + l];
  v = fmaxf(v, 0.f) * ch[l];
  float m = wave_max(v);
  float s = wave_sum(v);
  if (l == 0){ rp[(size_t)e*2] = m; rp[(size_t)e*2 + 1] = s * (1.f/64.f); }
  ef0[(size_t)epos[e]*64 + l] = v;
}

// ------------------- per-edge spatial sigmoid, stored in CSR slot
__global__ void k_se(const float* __restrict__ rp, const int* __restrict__ epos,
                     const float* __restrict__ ccw, const float* __restrict__ ccb,
                     float* __restrict__ se, int E2){
  int e = blockIdx.x * blockDim.x + threadIdx.x;
  if (e >= E2) return;
  float sp = ccb[0];
  #pragma unroll
  for (int t = 0; t < 7; ++t){
    int rr = e + t - 3;
    if (rr >= 0 && rr < E2)
      sp += ccw[t] * rp[(size_t)rr*2] + ccw[7+t] * rp[(size_t)rr*2 + 1];
  }
  se[epos[e]] = sigm(sp);
}

// ------------- agg0 = streamed sum(se*ef0) over CSR + fused concat-LN comb0
__global__ void k_aggb(const float* __restrict__ ef0, const float* __restrict__ se,
                       const int* __restrict__ rowptr, const float* __restrict__ nf,
                       const float* __restrict__ g, const float* __restrict__ b,
                       float* __restrict__ agg, unsigned short* __restrict__ comb, int N){
  int n = blockIdx.x*4 + (threadIdx.x >> 6);
  if (n >= N) return;
  int l = threadIdx.x & 63;
  int lo = rowptr[n], hi = rowptr[n+1];
  float acc = 0.f;
  int i = lo;
  for (; i + 4 <= hi; i += 4){
    float s0 = se[i], s1 = se[i+1], s2 = se[i+2], s3 = se[i+3];
    float e0 = ef0[(size_t)i*64 + l];
    float e1 = ef0[(size_t)(i+1)*64 + l];
    float e2 = ef0[(size_t)(i+2)*64 + l];
    float e3 = ef0[(size_t)(i+3)*64 + l];
    acc += s0*e0 + s1*e1 + s2*e2 + s3*e3;
  }
  for (; i < hi; ++i) acc += se[i] * ef0[(size_t)i*64 + l];
  agg[(size_t)n*64 + l] = acc;
  float a = nf[(size_t)n*64 + l];
  float v0 = a, v1 = acc - a;
  float mean = wave_sum(v0 + v1) * (1.f/128.f);
  float d0 = v0 - mean, d1 = v1 - mean;
  float var = wave_sum(d0*d0 + d1*d1) * (1.f/128.f);
  float rs = rsqrtf(var + 1e-5f);
  comb[(size_t)n*128 + l]      = f2bf(d0 * rs * g[l]      + b[l]);
  comb[(size_t)n*128 + 64 + l] = f2bf(d1 * rs * g[64 + l] + b[64 + l]);
}

// ------------------------------- coalesced LDS-transpose weight packs
// QKVS: Wq/Wk/Wv/Ws each [3*128][256] fp32 -> Bt [3][1024][128] bf16
__global__ __launch_bounds__(256) void k_packT1(
    const float* __restrict__ Wq, const float* __restrict__ Wk,
    const float* __restrict__ Wv, const float* __restrict__ Ws,
    unsigned short* __restrict__ Bt){
  __shared__ float t[64][65];
  int bx = blockIdx.x, by = blockIdx.y, bz = blockIdx.z;
  const float* W = (bz == 0) ? Wq : (bz == 1) ? Wk : (bz == 2) ? Wv : Ws;
  int tx = threadIdx.x & 63, ty = threadIdx.x >> 6;
  int R0 = by*64, C0 = bx*64;
  for (int r = ty; r < 64; r += 4)
    t[r][tx] = W[(size_t)(R0 + r)*256 + C0 + tx];
  __syncthreads();
  int iter = by >> 1, kr0 = (by & 1)*64;
  for (int r = ty; r < 64; r += 4)
    Bt[(size_t)iter*1024*128 + (size_t)(bz*256 + C0 + r)*128 + kr0 + tx] = f2bf(t[tx][r]);
}

// pn/pe: each [3*256][64] fp32 -> Bt2 [3][128][256] bf16
__global__ __launch_bounds__(256) void k_packT2(
    const float* __restrict__ Wn, const float* __restrict__ We,
    unsigned short* __restrict__ Bt2){
  __shared__ float t[64][65];
  int by = blockIdx.y, bz = blockIdx.z;
  const float* W = (bz == 0) ? Wn : We;
  int tx = threadIdx.x & 63, ty = threadIdx.x >> 6;
  int R0 = by*64;
  for (int r = ty; r < 64; r += 4)
    t[r][tx] = W[(size_t)(R0 + r)*64 + tx];
  __syncthreads();
  int iter = by >> 2, kr0 = (by & 3)*64;
  for (int r = ty; r < 64; r += 4)
    Bt2[(size_t)iter*128*256 + (size_t)(bz*64 + r)*256 + kr0 + tx] = f2bf(t[tx][r]);
}

__global__ void k_biasp(const float* __restrict__ bq, const float* __restrict__ bk,
                        const float* __restrict__ bv, const float* __restrict__ bs,
                        const float* __restrict__ pnb,
                        float* __restrict__ bias, float* __restrict__ bias2){
  int i = blockIdx.x, t = threadIdx.x;
  const float* bb = (t < 256) ? bq : (t < 512) ? bk : (t < 768) ? bv : bs;
  bias[i*1024 + t] = bb[i*256 + (t & 255)];
  if (t < 64)       bias2[i*128 + t] = pnb[i*64 + t];
  else if (t < 128) bias2[i*128 + t] = 0.f;
}

// ---------------------------------------------------------- MFMA bf16 GEMM
template<int NSTEPS, int MODE>
__global__ __launch_bounds__(256) void k_mfma(
    const unsigned short* __restrict__ A, int lda,
    const unsigned short* __restrict__ Bt, int ldb,
    const float* __restrict__ bias,
    float* __restrict__ o_f0, unsigned short* __restrict__ o_h0,
    unsigned short* __restrict__ o_h1, float* __restrict__ o_f1, int M){
  __shared__ char lds[65536];
  char* ldsA = lds;
  char* ldsB = lds + 32768;
  int tid = threadIdx.x;
  int nbase = blockIdx.x * 128;
  int mbase = blockIdx.y * 128;
  int l = tid & 63, wid = tid >> 6;
  int wm = (wid >> 1) * 64, wn = (wid & 1) * 64;
  f32x4 acc[4][4] = {};
  const char* Ab  = (const char*)A;
  const char* Btb = (const char*)Bt;
  for (int ks = 0; ks < NSTEPS; ++ks){
    #pragma unroll
    for (int it = 0; it < 8; ++it){
      int c = tid + it*256;
      int row = c >> 4;
      int kb = (c & 15) << 4;
      int off = (row << 8) + (kb ^ ((row & 7) << 4));
      uint4 va = make_uint4(0,0,0,0);
      int gr = mbase + row;
      if (gr < M)
        va = *reinterpret_cast<const uint4*>(Ab + (size_t)gr*(lda*2) + ks*256 + kb);
      *reinterpret_cast<uint4*>(ldsA + off) = va;
      uint4 vb = *reinterpret_cast<const uint4*>(
                   Btb + (size_t)(nbase + row)*(ldb*2) + ks*256 + kb);
      *reinterpret_cast<uint4*>(ldsB + off) = vb;
    }
    __syncthreads();
    #pragma unroll
    for (int kk = 0; kk < 4; ++kk){
      int kbyte = kk*64 + (l >> 4)*16;
      short8 af[4], bf[4];
      #pragma unroll
      for (int m = 0; m < 4; ++m){
        int fr = wm + m*16 + (l & 15);
        af[m] = *reinterpret_cast<const short8*>(ldsA + (fr << 8) + (kbyte ^ ((fr & 7) << 4)));
      }
      #pragma unroll
      for (int n = 0; n < 4; ++n){
        int fc = wn + n*16 + (l & 15);
        bf[n] = *reinterpret_cast<const short8*>(ldsB + (fc << 8) + (kbyte ^ ((fc & 7) << 4)));
      }
      #pragma unroll
      for (int m = 0; m < 4; ++m)
        #pragma unroll
        for (int n = 0; n < 4; ++n)
          acc[m][n] = __builtin_amdgcn_mfma_f32_16x16x32_bf16(af[m], bf[n], acc[m][n], 0, 0, 0);
    }
    __syncthreads();
  }
  #pragma unroll
  for (int n = 0; n < 4; ++n){
    int gcol = nbase + wn + n*16 + (l & 15);
    float bv = bias ? bias[gcol] : 0.f;
    #pragma unroll
    for (int m = 0; m < 4; ++m){
      int grow = mbase + wm + m*16 + (l >> 4)*4;
      #pragma unroll
      for (int r = 0; r < 4; ++r){
        int gr = grow + r;
        if (gr < M){
          float val = acc[m][n][r] + bv;
          if (MODE == 1){
            o_f0[(size_t)gr*128 + gcol] = val;
          } else {
            int seg = gcol >> 8, c = gcol & 255;
            if      (seg == 0) o_f0[(size_t)gr*256 + c] = val;
            else if (seg == 1) o_h0[(size_t)gr*256 + c] = f2bf(val);
            else if (seg == 2) o_h1[(size_t)gr*256 + c] = f2bf(val);
            else               o_f1[(size_t)gr*256 + c] = val;
          }
        }
      }
    }
  }
}

// -------------- single-pass fused attention + skip + LN (lane-partitioned)
// lane l: head h=l>>4, dims 4*(l&15).. ; global col = 4*l. Unroll-4 gather.
__global__ void k_attn(const float* __restrict__ q, const unsigned short* __restrict__ kbuf,
                       const unsigned short* __restrict__ vbuf, const float* __restrict__ sbuf,
                       const int* __restrict__ rowptr, const int* __restrict__ csrc,
                       const float* __restrict__ ltg, const float* __restrict__ ltb,
                       unsigned short* __restrict__ outb, int N){
  int n = blockIdx.x*4 + (threadIdx.x >> 6);
  if (n >= N) return;
  int l = threadIdx.x & 63;
  int lo = rowptr[n], hi = rowptr[n+1];
  size_t base = (size_t)n*256 + l*4;
  float4 qv = *reinterpret_cast<const float4*>(q + base);
  qv.x *= 0.125f; qv.y *= 0.125f; qv.z *= 0.125f; qv.w *= 0.125f;
  float o0 = 0.f, o1 = 0.f, o2 = 0.f, o3 = 0.f, s = 0.f;
  int i = lo;
  for (; i + 4 <= hi; i += 4){
    int c0 = csrc[i], c1 = csrc[i+1], c2 = csrc[i+2], c3 = csrc[i+3];
    const int l4 = l*4;
    ushort4 k0 = *reinterpret_cast<const ushort4*>(kbuf + (size_t)c0*256 + l4);
    ushort4 k1 = *reinterpret_cast<const ushort4*>(kbuf + (size_t)c1*256 + l4);
    ushort4 k2 = *reinterpret_cast<const ushort4*>(kbuf + (size_t)c2*256 + l4);
    ushort4 k3 = *reinterpret_cast<const ushort4*>(kbuf + (size_t)c3*256 + l4);
    ushort4 v0 = *reinterpret_cast<const ushort4*>(vbuf + (size_t)c0*256 + l4);
    ushort4 v1 = *reinterpret_cast<const ushort4*>(vbuf + (size_t)c1*256 + l4);
    ushort4 v2 = *reinterpret_cast<const ushort4*>(vbuf + (size_t)c2*256 + l4);
    ushort4 v3 = *reinterpret_cast<const ushort4*>(vbuf + (size_t)c3*256 + l4);
    float a0 = qv.x*bf2f(k0.x) + qv.y*bf2f(k0.y) + qv.z*bf2f(k0.z) + qv.w*bf2f(k0.w);
    float a1 = qv.x*bf2f(k1.x) + qv.y*bf2f(k1.y) + qv.z*bf2f(k1.z) + qv.w*bf2f(k1.w);
    float a2 = qv.x*bf2f(k2.x) + qv.y*bf2f(k2.y) + qv.z*bf2f(k2.z) + qv.w*bf2f(k2.w);
    float a3 = qv.x*bf2f(k3.x) + qv.y*bf2f(k3.y) + qv.z*bf2f(k3.z) + qv.w*bf2f(k3.w);
    #pragma unroll
    for (int m = 1; m < 16; m <<= 1){
      a0 += __shfl_xor(a0, m, 64);
      a1 += __shfl_xor(a1, m, 64);
      a2 += __shfl_xor(a2, m, 64);
      a3 += __shfl_xor(a3, m, 64);
    }
    float w0 = __expf(a0), w1 = __expf(a1), w2 = __expf(a2), w3 = __expf(a3);
    s += (w0 + w1) + (w2 + w3);
    o0 += w0*bf2f(v0.x) + w1*bf2f(v1.x) + w2*bf2f(v2.x) + w3*bf2f(v3.x);
    o1 += w0*bf2f(v0.y) + w1*bf2f(v1.y) + w2*bf2f(v2.y) + w3*bf2f(v3.y);
    o2 += w0*bf2f(v0.z) + w1*bf2f(v1.z) + w2*bf2f(v2.z) + w3*bf2f(v3.z);
    o3 += w0*bf2f(v0.w) + w1*bf2f(v1.w) + w2*bf2f(v2.w) + w3*bf2f(v3.w);
  }
  for (; i < hi; ++i){
    size_t sb = (size_t)csrc[i]*256 + l*4;
    ushort4 kv = *reinterpret_cast<const ushort4*>(kbuf + sb);
    ushort4 vv = *reinterpret_cast<const ushort4*>(vbuf + sb);
    float a = qv.x*bf2f(kv.x) + qv.y*bf2f(kv.y) + qv.z*bf2f(kv.z) + qv.w*bf2f(kv.w);
    #pragma unroll
    for (int m = 1; m < 16; m <<= 1) a += __shfl_xor(a, m, 64);
    float w = __expf(a);
    s += w;
    o0 += w*bf2f(vv.x); o1 += w*bf2f(vv.y); o2 += w*bf2f(vv.z); o3 += w*bf2f(vv.w);
  }
  float4 t = *reinterpret_cast<const float4*>(sbuf + base);
  if (hi > lo){
    float r = 1.f / s;
    t.x += o0*r; t.y += o1*r; t.z += o2*r; t.w += o3*r;
  }
  float mean = wave_sum(t.x + t.y + t.z + t.w) * (1.f/256.f);
  float dx = t.x - mean, dy = t.y - mean, dz = t.z - mean, dw = t.w - mean;
  float var = wave_sum(dx*dx + dy*dy + dz*dz + dw*dw) * (1.f/256.f);
  float rs = rsqrtf(var + 1e-5f);
  float4 g = *reinterpret_cast<const float4*>(ltg + l*4);
  float4 b = *reinterpret_cast<const float4*>(ltb + l*4);
  ushort4 o;
  o.x = f2bf(dx*rs*g.x + b.x);
  o.y = f2bf(dy*rs*g.y + b.y);
  o.z = f2bf(dz*rs*g.z + b.z);
  o.w = f2bf(dw*rs*g.w + b.w);
  *reinterpret_cast<ushort4*>(outb + base) = o;
}

// ------ gated fusion (nf) + agg-space edge update + NEXT iter's comb-LN
__global__ __launch_bounds__(256) void k_gate_agg(
    float* __restrict__ nf, float* __restrict__ agg,
    const float* __restrict__ pnP,
    const int* __restrict__ rowptr, const int* __restrict__ csrc,
    const float* __restrict__ gfw, const float* __restrict__ gfb,
    const float* __restrict__ peb,
    const float* __restrict__ cg, const float* __restrict__ cbv,
    unsigned short* __restrict__ comb, int doComb, int N){
  __shared__ float s_w[128 * 64];
  int tid = threadIdx.x;
  for (int idx = tid; idx < 128*64; idx += 256) s_w[idx] = gfw[idx];
  __syncthreads();
  int wv = tid >> 6, l = tid & 63;
  float gb = gfb[l], pebl = peb[l];
  for (int n = blockIdx.x*4 + wv; n < N; n += gridDim.x*4){
    float nfv = nf[(size_t)n*64 + l];
    float pnv = pnP[(size_t)n*128 + l];
    float g = gb;
    #pragma unroll 8
    for (int k = 0; k < 64; ++k){
      g += __shfl(nfv, k, 64) * s_w[k*64 + l];
      g += __shfl(pnv, k, 64) * s_w[(64 + k)*64 + l];
    }
    g = sigm(g);
    float nfn = nfv * (1.f + g) + pnv * (1.f - g);
    nf[(size_t)n*64 + l] = nfn;
    // agg += sum_{e in(n)} P[src] - deg*(P[n] - peb)
    int lo = rowptr[n], hi = rowptr[n+1];
    float sp = 0.f;
    int i = lo;
    for (; i + 4 <= hi; i += 4){
      int c0 = csrc[i], c1 = csrc[i+1], c2 = csrc[i+2], c3 = csrc[i+3];
      float p0 = pnP[(size_t)c0*128 + 64 + l];
      float p1 = pnP[(size_t)c1*128 + 64 + l];
      float p2 = pnP[(size_t)c2*128 + 64 + l];
      float p3 = pnP[(size_t)c3*128 + 64 + l];
      sp += (p0 + p1) + (p2 + p3);
    }
    for (; i < hi; ++i) sp += pnP[(size_t)csrc[i]*128 + 64 + l];
    float Pn = pnP[(size_t)n*128 + 64 + l];
    float aggn = agg[(size_t)n*64 + l] + sp - (float)(hi - lo) * (Pn - pebl);
    agg[(size_t)n*64 + l] = aggn;
    if (doComb){
      float v0 = nfn, v1 = aggn - nfn;
      float mean = wave_sum(v0 + v1) * (1.f/128.f);
      float d0 = v0 - mean, d1 = v1 - mean;
      float var = wave_sum(d0*d0 + d1*d1) * (1.f/128.f);
      float rs = rsqrtf(var + 1e-5f);
      comb[(size_t)n*128 + l]      = f2bf(d0 * rs * cg[l]      + cbv[l]);
      comb[(size_t)n*128 + 64 + l] = f2bf(d1 * rs * cg[64 + l] + cbv[64 + l]);
    }
  }
}

// ------------------------------------------------------------- classifier
template<int K, int BN>
__global__ __launch_bounds__(256) void k_gemm(
    const float* __restrict__ in, const float* __restrict__ W, int ldw,
    const float* __restrict__ bias, float* __restrict__ out, int ldo, int nrows){
  constexpr int PAD = BN + 4;
  __shared__ float s_in[K * PAD];
  int n0 = blockIdx.x * BN;
  int tid = threadIdx.x;
  for (int idx = tid; idx < BN * K; idx += 256){
    int r = idx / K, k = idx - r * K;
    float v = (n0 + r < nrows) ? in[(size_t)(n0 + r) * K + k] : 0.f;
    s_in[k * PAD + r] = v;
  }
  __syncthreads();
  int tx = tid & 15, ty = tid >> 4;
  constexpr int NT = BN / 16;
  int col0 = blockIdx.y * 64 + tx * 4;
  float acc[NT][4] = {};
  for (int k = 0; k < K; ++k){
    const float4 wv = *reinterpret_cast<const float4*>(&W[(size_t)k * ldw + col0]);
    #pragma unroll
    for (int i = 0; i < NT; ++i){
      float cv = s_in[k * PAD + ty * NT + i];
      acc[i][0] += cv * wv.x;
      acc[i][1] += cv * wv.y;
      acc[i][2] += cv * wv.z;
      acc[i][3] += cv * wv.w;
    }
  }
  #pragma unroll
  for (int i = 0; i < NT; ++i){
    int n = n0 + ty * NT + i;
    if (n < nrows){
      float4 o = make_float4(acc[i][0], acc[i][1], acc[i][2], acc[i][3]);
      *reinterpret_cast<float4*>(&out[(size_t)n * ldo + col0]) = o;
    }
  }
}

__global__ void k_final(const float* __restrict__ A, const float* __restrict__ B,
                        const int* __restrict__ ei, const float* __restrict__ cb1,
                        const float* __restrict__ cw2, const float* __restrict__ cb2,
                        float* __restrict__ dout, int E){
  int e = blockIdx.x*4 + (threadIdx.x >> 6);
  if (e >= E) return;
  int l = threadIdx.x & 63;
  int i0 = ei[e], i1 = ei[E + e];
  float h = fmaxf(A[(size_t)i0*64 + l] + B[(size_t)i1*64 + l] + cb1[l], 0.f);
  float p = wave_sum(h * cw2[l]);
  if (l == 0) dout[e] = p + cb2[0];
}

// ===========================================================================
extern "C" void kernel_launch(void* const* d_in, const int* in_sizes, int n_in,
                              void* d_out, int out_size, void* d_ws, size_t ws_size,
                              hipStream_t stream){
  const float* x         = (const float*)d_in[0];
  const float* edge_attr = (const float*)d_in[1];
  const float* node_w    = (const float*)d_in[2];
  const float* node_b    = (const float*)d_in[3];
  const float* edge_w    = (const float*)d_in[4];
  const float* edge_b    = (const float*)d_in[5];
  const float* z_emb     = (const float*)d_in[6];
  const float* cn_w1     = (const float*)d_in[7];
  const float* cn_b1     = (const float*)d_in[8];
  const float* cn_w2     = (const float*)d_in[9];
  const float* cn_b2     = (const float*)d_in[10];
  const float* cn_cw     = (const float*)d_in[11];
  const float* cn_cb     = (const float*)d_in[12];
  const float* ce_w1     = (const float*)d_in[13];
  const float* ce_b1     = (const float*)d_in[14];
  const float* ce_w2     = (const float*)d_in[15];
  const float* ce_b2     = (const float*)d_in[16];
  const float* ce_cw     = (const float*)d_in[17];
  const float* ce_cb     = (const float*)d_in[18];
  const float* Wq        = (const float*)d_in[19];
  const float* bq        = (const float*)d_in[20];
  const float* Wk        = (const float*)d_in[21];
  const float* bk        = (const float*)d_in[22];
  const float* Wv        = (const float*)d_in[23];
  const float* bv        = (const float*)d_in[24];
  const float* Ws        = (const float*)d_in[25];
  const float* bs        = (const float*)d_in[26];
  const float* lt_g      = (const float*)d_in[27];
  const float* lt_b      = (const float*)d_in[28];
  const float* lc_g      = (const float*)d_in[29];
  const float* lc_b      = (const float*)d_in[30];
  const float* pe_w      = (const float*)d_in[31];
  const float* pe_b      = (const float*)d_in[32];
  const float* pn_w      = (const float*)d_in[33];
  const float* pn_b      = (const float*)d_in[34];
  const float* gf_w      = (const float*)d_in[35];
  const float* gf_b      = (const float*)d_in[36];
  const float* c_w1      = (const float*)d_in[37];
  const float* c_b1      = (const float*)d_in[38];
  const float* c_w2      = (const float*)d_in[39];
  const float* c_b2      = (const float*)d_in[40];
  const int*   edge_index= (const int*)d_in[41];

  const int N  = in_sizes[0] / 6;
  const int E  = in_sizes[1] / 4;
  const int E2 = 2 * E;

  // ---------------- workspace layout
  char* p = (char*)d_ws;
  auto alloc = [&](size_t bytes)->char*{
    char* r = p; p += (bytes + 255) & ~(size_t)255; return r;
  };
  int*            w_src    = (int*)           alloc((size_t)E2 * 4);
  int*            w_dst    = (int*)           alloc((size_t)E2 * 4);
  int*            w_deg    = (int*)           alloc((size_t)N * 4);
  int*            w_rowptr = (int*)           alloc((size_t)(N + 1) * 4);
  int*            w_cur    = (int*)           alloc((size_t)N * 4);
  int*            w_csrc   = (int*)           alloc((size_t)E2 * 4);
  int*            w_epos   = (int*)           alloc((size_t)E2 * 4);
  float*          w_nf     = (float*)         alloc((size_t)N * 64 * 4);
  float*          w_agg    = (float*)         alloc((size_t)N * 64 * 4);
  float*          w_ef0    = (float*)         alloc((size_t)E2 * 64 * 4);
  float*          w_se     = (float*)         alloc((size_t)E2 * 4);
  unsigned short* w_comb   = (unsigned short*)alloc((size_t)N * 128 * 2);
  float*          w_q      = (float*)         alloc((size_t)N * 256 * 4);
  unsigned short* w_k      = (unsigned short*)alloc((size_t)N * 256 * 2);
  unsigned short* w_v      = (unsigned short*)alloc((size_t)N * 256 * 2);
  float*          w_s      = (float*)         alloc((size_t)N * 256 * 4);
  unsigned short* w_outb   = (unsigned short*)alloc((size_t)N * 256 * 2);
  float*          w_pnP    = (float*)         alloc((size_t)N * 128 * 4);
  float*          w_rp     = (float*)         alloc((size_t)E2 * 2 * 4);
  float*          w_A      = (float*)         alloc((size_t)N * 64 * 4);
  float*          w_B      = (float*)         alloc((size_t)N * 64 * 4);
  unsigned short* w_Bt     = (unsigned short*)alloc((size_t)3 * 1024 * 128 * 2);
  float*          w_bias   = (float*)         alloc((size_t)3 * 1024 * 4);
  unsigned short* w_Bt2    = (unsigned short*)alloc((size_t)3 * 128 * 256 * 2);
  float*          w_bias2  = (float*)         alloc((size_t)3 * 128 * 4);
  unsigned*       w_pmax   = (unsigned*)      alloc(64 * 4);
  float*          w_psum   = (float*)         alloc(64 * 4);
  float*          w_ch     = (float*)         alloc(64 * 4);
  unsigned*       w_pmax2  = (unsigned*)      alloc(64 * 4);
  float*          w_psum2  = (float*)         alloc(64 * 4);
  float*          w_ch2    = (float*)         alloc(64 * 4);

  hipMemsetAsync(w_deg,  0, (size_t)N * 4, stream);
  hipMemsetAsync(w_cur,  0, (size_t)N * 4, stream);
  hipMemsetAsync(w_pmax, 0, 64 * 4, stream);
  hipMemsetAsync(w_psum, 0, 64 * 4, stream);
  hipMemsetAsync(w_pmax2,0, 64 * 4, stream);
  hipMemsetAsync(w_psum2,0, 64 * 4, stream);

  // ---------------- CSR + node embedding/CBAM
  k_build_edges<<<(E2 + 255)/256, 256, 0, stream>>>(edge_index, E2, E, w_src, w_dst, w_deg);
  k_scan<<<1, 1024, 0, stream>>>(w_deg, w_rowptr, N);
  k_fill<<<(E2 + 255)/256, 256, 0, stream>>>(w_src, w_dst, w_rowptr, w_cur, w_csrc, w_epos, E2);
  k_embed_pool<<<512, 256, 0, stream>>>(x, node_w, node_b, z_emb, w_nf, w_pmax, w_psum, N);
  k_cbam_mlp<<<1, 64, 0, stream>>>(w_pmax, w_psum, 1.f/(float)N,
                                   cn_w1, cn_b1, cn_w2, cn_b2, w_ch);
  k_chmul_rowpool<<<(N + 3)/4, 256, 0, stream>>>(w_nf, w_ch, w_rp, N);
  k_spatial<<<(N + 3)/4, 256, 0, stream>>>(w_nf, w_rp, cn_cw, cn_cb, N);

  // ---------------- edge CBAM -> ef0 (CSR order) -> agg0 + comb0
  k_ecol<<<2048, 256, 0, stream>>>(x, edge_attr, w_src, w_dst, edge_w, edge_b,
                                   w_pmax2, w_psum2, E2, E);
  k_cbam_mlp<<<1, 64, 0, stream>>>(w_pmax2, w_psum2, 1.f/(float)E2,
                                   ce_w1, ce_b1, ce_w2, ce_b2, w_ch2);
  k_erp2<<<(E2 + 3)/4, 256, 0, stream>>>(x, edge_attr, w_src, w_dst, w_epos,
                                         edge_w, edge_b, w_ch2, w_rp, w_ef0, E2, E);
  k_se<<<(E2 + 255)/256, 256, 0, stream>>>(w_rp, w_epos, ce_cw, ce_cb, w_se, E2);
  k_aggb<<<(N + 3)/4, 256, 0, stream>>>(w_ef0, w_se, w_rowptr, w_nf,
                                        lc_g, lc_b, w_agg, w_comb, N);

  // ---------------- pack all iteration weights
  k_packT1<<<dim3(4, 6, 4), 256, 0, stream>>>(Wq, Wk, Wv, Ws, w_Bt);
  k_packT2<<<dim3(1, 12, 2), 256, 0, stream>>>(pn_w, pe_w, w_Bt2);
  k_biasp<<<3, 1024, 0, stream>>>(bq, bk, bv, bs, pn_b, w_bias, w_bias2);

  // ---------------- message-passing iterations
  const int MB = (N + 127) / 128;
  for (int i = 0; i < 3; ++i){
    k_mfma<1,0><<<dim3(8, MB), 256, 0, stream>>>(w_comb, 128,
                                                 w_Bt + (size_t)i*1024*128, 128,
                                                 w_bias + (size_t)i*1024,
                                                 w_q, w_k, w_v, w_s, N);
    k_attn<<<(N + 3)/4, 256, 0, stream>>>(w_q, w_k, w_v, w_s, w_rowptr, w_csrc,
                                          lt_g + (size_t)i*256, lt_b + (size_t)i*256,
                                          w_outb, N);
    k_mfma<2,1><<<dim3(1, MB), 256, 0, stream>>>(w_outb, 256,
                                                 w_Bt2 + (size_t)i*128*256, 256,
                                                 w_bias2 + (size_t)i*128,
                                                 w_pnP, nullptr, nullptr, nullptr, N);
    int doComb = (i < 2) ? 1 : 0;
    const float* cg  = lc_g + (size_t)(i < 2 ? i+1 : 0)*128;
    const float* cbv = lc_b + (size_t)(i < 2 ? i+1 : 0)*128;
    k_gate_agg<<<1250, 256, 0, stream>>>(w_nf, w_agg, w_pnP, w_rowptr, w_csrc,
                                         gf_w + (size_t)i*128*64, gf_b + (size_t)i*64,
                                         pe_b + (size_t)i*64,
                                         cg, cbv, w_comb, doComb, N);
  }

  // ---------------- classifier
  dim3 g64((N + 63)/64, 1);
  k_gemm<64,64><<<g64, 256, 0, stream>>>(w_nf, c_w1,         64, nullptr, w_A, 64, N);
  k_gemm<64,64><<<g64, 256, 0, stream>>>(w_nf, c_w1 + 64*64, 64, nullptr, w_B, 64, N);
  k_final<<<(E + 3)/4, 256, 0, stream>>>(w_A, w_B, edge_index, c_b1, c_w2, c_b2,
                                         (float*)d_out, E);
}

// Round 5
// 879.706 us; speedup vs baseline: 2.3063x; 1.0258x over previous
//
#include <hip/hip_runtime.h>
#include <math.h>

typedef __attribute__((ext_vector_type(8))) short short8;
typedef __attribute__((ext_vector_type(4))) float f32x4;

// ---------------------------------------------------------------- utilities
__device__ __forceinline__ float wave_sum(float v){
  #pragma unroll
  for (int m = 32; m; m >>= 1) v += __shfl_xor(v, m, 64);
  return v;
}
__device__ __forceinline__ float wave_max(float v){
  #pragma unroll
  for (int m = 32; m; m >>= 1) v = fmaxf(v, __shfl_xor(v, m, 64));
  return v;
}
__device__ __forceinline__ unsigned fenc(float f){
  unsigned u = __float_as_uint(f);
  return (u >> 31) ? ~u : (u | 0x80000000u);
}
__device__ __forceinline__ float fdec(unsigned e){
  return (e >> 31) ? __uint_as_float(e & 0x7fffffffu) : __uint_as_float(~e);
}
__device__ __forceinline__ float sigm(float x){ return 1.f / (1.f + __expf(-x)); }
__device__ __forceinline__ unsigned short f2bf(float f){
  union { float f; unsigned u; } x; x.f = f;
  unsigned r = x.u + 0x7fffu + ((x.u >> 16) & 1u);
  return (unsigned short)(r >> 16);
}
__device__ __forceinline__ float bf2f(unsigned short h){
  union { unsigned u; float f; } x; x.u = ((unsigned)h) << 16;
  return x.f;
}

// ------------------------------------------------------------ CSR building
__global__ void k_build_edges(const int* __restrict__ ei, int E2, int E,
                              int* __restrict__ src, int* __restrict__ dst,
                              int* __restrict__ deg){
  int e = blockIdx.x * blockDim.x + threadIdx.x;
  if (e >= E2) return;
  int s = ei[e];
  int d = (e < E) ? ei[e + E] : ei[e - E];
  src[e] = s; dst[e] = d;
  atomicAdd(&deg[d], 1);
}

__global__ void k_scan(const int* __restrict__ deg, int* __restrict__ rowptr, int N){
  __shared__ int part[1024];
  int t = threadIdx.x;
  int chunk = (N + 1023) / 1024;
  int lo = t * chunk, hi = lo + chunk; if (hi > N) hi = N;
  int s = 0;
  for (int i = lo; i < hi; ++i) s += deg[i];
  part[t] = s;
  __syncthreads();
  for (int off = 1; off < 1024; off <<= 1){
    int v = (t >= off) ? part[t - off] : 0;
    __syncthreads();
    part[t] += v;
    __syncthreads();
  }
  int run = part[t] - s;
  for (int i = lo; i < hi; ++i){ rowptr[i] = run; run += deg[i]; }
  if (t == 1023) rowptr[N] = part[1023];
}

__global__ void k_fill(const int* __restrict__ src, const int* __restrict__ dst,
                       const int* __restrict__ rowptr,
                       int* __restrict__ cur, int* __restrict__ csrc,
                       int* __restrict__ epos, int E2){
  int e = blockIdx.x * blockDim.x + threadIdx.x;
  if (e >= E2) return;
  int d = dst[e];
  int pos = rowptr[d] + atomicAdd(&cur[d], 1);
  csrc[pos] = src[e];
  epos[e] = pos;
}

// ------------------------- fused node embedding + column pool (max/mean)
__global__ void k_embed_pool(const float* __restrict__ x, const float* __restrict__ nw,
                             const float* __restrict__ nb, const float* __restrict__ zemb,
                             float* __restrict__ nf,
                             unsigned* __restrict__ pmax, float* __restrict__ psum, int N){
  int tx = threadIdx.x & 63;
  int ty = threadIdx.x >> 6;
  const float allowed[6] = {8.f, 23.f, 39.f, 54.f, 90.f, 180.f};
  float m = -INFINITY, s = 0.f;
  for (int n = blockIdx.x*4 + ty; n < N; n += gridDim.x*4){
    float xv[6];
    #pragma unroll
    for (int k = 0; k < 6; ++k) xv[k] = x[n*6 + k];
    float v = nb[tx];
    #pragma unroll
    for (int k = 0; k < 6; ++k) v += xv[k] * nw[k*64 + tx];
    v = fmaxf(v, 0.f);
    float r = rintf(xv[2]);
    int zi = 0; float bd = fabsf(r - allowed[0]);
    #pragma unroll
    for (int k = 1; k < 6; ++k){ float d = fabsf(r - allowed[k]); if (d < bd){ bd = d; zi = k; } }
    v += zemb[zi*64 + tx];
    nf[(size_t)n*64 + tx] = v;
    m = fmaxf(m, v); s += v;
  }
  __shared__ float sm[4][64], ss[4][64];
  sm[ty][tx] = m; ss[ty][tx] = s;
  __syncthreads();
  if (ty == 0){
    #pragma unroll
    for (int k = 1; k < 4; ++k){ m = fmaxf(m, sm[k][tx]); s += ss[k][tx]; }
    atomicMax(&pmax[tx], fenc(m));
    atomicAdd(&psum[tx], s);
  }
}

// ------------------------------------------------------------------- CBAM MLP
__global__ void k_cbam_mlp(const unsigned* __restrict__ pmax, const float* __restrict__ psum,
                           float invR,
                           const float* __restrict__ w1, const float* __restrict__ b1,
                           const float* __restrict__ w2, const float* __restrict__ b2,
                           float* __restrict__ ch){
  __shared__ float pool[128];
  __shared__ float h[4];
  int t = threadIdx.x;
  pool[t]      = fdec(pmax[t]);
  pool[64 + t] = psum[t] * invR;
  __syncthreads();
  if (t < 4){
    float a = b1[t];
    for (int k = 0; k < 128; ++k) a += pool[k] * w1[k*4 + t];
    h[t] = fmaxf(a, 0.f);
  }
  __syncthreads();
  float a = b2[t];
  #pragma unroll
  for (int k = 0; k < 4; ++k) a += h[k] * w2[k*64 + t];
  ch[t] = sigm(a);
}

__global__ void k_chmul_rowpool(float* __restrict__ buf, const float* __restrict__ ch,
                                float* __restrict__ rp, int R){
  int r = blockIdx.x*4 + (threadIdx.x >> 6);
  if (r >= R) return;
  int l = threadIdx.x & 63;
  float v = buf[(size_t)r*64 + l] * ch[l];
  buf[(size_t)r*64 + l] = v;
  float m = wave_max(v);
  float s = wave_sum(v);
  if (l == 0){ rp[(size_t)r*2] = m; rp[(size_t)r*2 + 1] = s * (1.f/64.f); }
}

__global__ void k_spatial(float* __restrict__ buf, const float* __restrict__ rp,
                          const float* __restrict__ cw, const float* __restrict__ cb, int R){
  int r = blockIdx.x*4 + (threadIdx.x >> 6);
  if (r >= R) return;
  int l = threadIdx.x & 63;
  float sp = cb[0];
  #pragma unroll
  for (int t = 0; t < 7; ++t){
    int rr = r + t - 3;
    if (rr >= 0 && rr < R)
      sp += cw[t] * rp[(size_t)rr*2] + cw[7 + t] * rp[(size_t)rr*2 + 1];
  }
  buf[(size_t)r*64 + l] *= sigm(sp);
}

// ------------------------------------------- edge column-pool (raw features)
__global__ void k_ecol(const float* __restrict__ x, const float* __restrict__ ea,
                       const int* __restrict__ src, const int* __restrict__ dst,
                       const float* __restrict__ ew, const float* __restrict__ eb,
                       unsigned* __restrict__ pmax, float* __restrict__ psum,
                       int E2, int E){
  __shared__ float s_ew[448];
  int tid = threadIdx.x;
  for (int idx = tid; idx < 448; idx += 256) s_ew[idx] = ew[idx];
  __syncthreads();
  int tx = tid & 63, ty = tid >> 6;
  float ebl = eb[tx];
  float m = -INFINITY, s = 0.f;
  for (int e = blockIdx.x*4 + ty; e < E2; e += gridDim.x*4){
    int sn = src[e], dn = dst[e];
    int row = (e < E) ? e : e - E;
    float v = ebl;
    #pragma unroll
    for (int k = 0; k < 4; ++k) v += ea[(size_t)row*4 + k] * s_ew[k*64 + tx];
    #pragma unroll
    for (int c = 0; c < 3; ++c) v += (x[sn*6 + c] - x[dn*6 + c]) * s_ew[(4+c)*64 + tx];
    v = fmaxf(v, 0.f);
    m = fmaxf(m, v); s += v;
  }
  __shared__ float sm[4][64], ss[4][64];
  sm[ty][tx] = m; ss[ty][tx] = s;
  __syncthreads();
  if (ty == 0){
    #pragma unroll
    for (int k = 1; k < 4; ++k){ m = fmaxf(m, sm[k][tx]); s += ss[k][tx]; }
    atomicMax(&pmax[tx], fenc(m));
    atomicAdd(&psum[tx], s);
  }
}

// ------------- edge row-pool + scatter-store ef0=raw*ch (fp32, CSR order)
// grid-stride: ew staged once per block, not once per 4 edges
__global__ void k_erp2(const float* __restrict__ x, const float* __restrict__ ea,
                       const int* __restrict__ src, const int* __restrict__ dst,
                       const int* __restrict__ epos,
                       const float* __restrict__ ew, const float* __restrict__ eb,
                       const float* __restrict__ ch,
                       float* __restrict__ rp, float* __restrict__ ef0, int E2, int E){
  __shared__ float s_ew[448];
  int tid = threadIdx.x;
  for (int idx = tid; idx < 448; idx += 256) s_ew[idx] = ew[idx];
  __syncthreads();
  int l = tid & 63, ty = tid >> 6;
  float ebl = eb[l], chl = ch[l];
  for (int e = blockIdx.x*4 + ty; e < E2; e += gridDim.x*4){
    int sn = src[e], dn = dst[e];
    int row = (e < E) ? e : e - E;
    float v = ebl;
    #pragma unroll
    for (int k = 0; k < 4; ++k) v += ea[(size_t)row*4 + k] * s_ew[k*64 + l];
    #pragma unroll
    for (int c = 0; c < 3; ++c) v += (x[sn*6 + c] - x[dn*6 + c]) * s_ew[(4+c)*64 + l];
    v = fmaxf(v, 0.f) * chl;
    float m = wave_max(v);
    float s = wave_sum(v);
    if (l == 0){ rp[(size_t)e*2] = m; rp[(size_t)e*2 + 1] = s * (1.f/64.f); }
    ef0[(size_t)epos[e]*64 + l] = v;
  }
}

// ------------------- per-edge spatial sigmoid, stored in CSR slot
__global__ void k_se(const float* __restrict__ rp, const int* __restrict__ epos,
                     const float* __restrict__ ccw, const float* __restrict__ ccb,
                     float* __restrict__ se, int E2){
  int e = blockIdx.x * blockDim.x + threadIdx.x;
  if (e >= E2) return;
  float sp = ccb[0];
  #pragma unroll
  for (int t = 0; t < 7; ++t){
    int rr = e + t - 3;
    if (rr >= 0 && rr < E2)
      sp += ccw[t] * rp[(size_t)rr*2] + ccw[7+t] * rp[(size_t)rr*2 + 1];
  }
  se[epos[e]] = sigm(sp);
}

// ------------- agg0 = streamed sum(se*ef0) over CSR + fused concat-LN comb0
__global__ void k_aggb(const float* __restrict__ ef0, const float* __restrict__ se,
                       const int* __restrict__ rowptr, const float* __restrict__ nf,
                       const float* __restrict__ g, const float* __restrict__ b,
                       float* __restrict__ agg, unsigned short* __restrict__ comb, int N){
  int n = blockIdx.x*4 + (threadIdx.x >> 6);
  if (n >= N) return;
  int l = threadIdx.x & 63;
  int lo = rowptr[n], hi = rowptr[n+1];
  float acc = 0.f;
  int i = lo;
  for (; i + 4 <= hi; i += 4){
    float s0 = se[i], s1 = se[i+1], s2 = se[i+2], s3 = se[i+3];
    float e0 = ef0[(size_t)i*64 + l];
    float e1 = ef0[(size_t)(i+1)*64 + l];
    float e2 = ef0[(size_t)(i+2)*64 + l];
    float e3 = ef0[(size_t)(i+3)*64 + l];
    acc += s0*e0 + s1*e1 + s2*e2 + s3*e3;
  }
  for (; i < hi; ++i) acc += se[i] * ef0[(size_t)i*64 + l];
  agg[(size_t)n*64 + l] = acc;
  float a = nf[(size_t)n*64 + l];
  float v0 = a, v1 = acc - a;
  float mean = wave_sum(v0 + v1) * (1.f/128.f);
  float d0 = v0 - mean, d1 = v1 - mean;
  float var = wave_sum(d0*d0 + d1*d1) * (1.f/128.f);
  float rs = rsqrtf(var + 1e-5f);
  comb[(size_t)n*128 + l]      = f2bf(d0 * rs * g[l]      + b[l]);
  comb[(size_t)n*128 + 64 + l] = f2bf(d1 * rs * g[64 + l] + b[64 + l]);
}

// ------------------------------- coalesced LDS-transpose weight packs
__global__ __launch_bounds__(256) void k_packT1(
    const float* __restrict__ Wq, const float* __restrict__ Wk,
    const float* __restrict__ Wv, const float* __restrict__ Ws,
    unsigned short* __restrict__ Bt){
  __shared__ float t[64][65];
  int bx = blockIdx.x, by = blockIdx.y, bz = blockIdx.z;
  const float* W = (bz == 0) ? Wq : (bz == 1) ? Wk : (bz == 2) ? Wv : Ws;
  int tx = threadIdx.x & 63, ty = threadIdx.x >> 6;
  int R0 = by*64, C0 = bx*64;
  for (int r = ty; r < 64; r += 4)
    t[r][tx] = W[(size_t)(R0 + r)*256 + C0 + tx];
  __syncthreads();
  int iter = by >> 1, kr0 = (by & 1)*64;
  for (int r = ty; r < 64; r += 4)
    Bt[(size_t)iter*1024*128 + (size_t)(bz*256 + C0 + r)*128 + kr0 + tx] = f2bf(t[tx][r]);
}

__global__ __launch_bounds__(256) void k_packT2(
    const float* __restrict__ Wn, const float* __restrict__ We,
    unsigned short* __restrict__ Bt2){
  __shared__ float t[64][65];
  int by = blockIdx.y, bz = blockIdx.z;
  const float* W = (bz == 0) ? Wn : We;
  int tx = threadIdx.x & 63, ty = threadIdx.x >> 6;
  int R0 = by*64;
  for (int r = ty; r < 64; r += 4)
    t[r][tx] = W[(size_t)(R0 + r)*64 + tx];
  __syncthreads();
  int iter = by >> 2, kr0 = (by & 3)*64;
  for (int r = ty; r < 64; r += 4)
    Bt2[(size_t)iter*128*256 + (size_t)(bz*64 + r)*256 + kr0 + tx] = f2bf(t[tx][r]);
}

__global__ void k_biasp(const float* __restrict__ bq, const float* __restrict__ bk,
                        const float* __restrict__ bv, const float* __restrict__ bs,
                        const float* __restrict__ pnb,
                        float* __restrict__ bias, float* __restrict__ bias2){
  int i = blockIdx.x, t = threadIdx.x;
  const float* bb = (t < 256) ? bq : (t < 512) ? bk : (t < 768) ? bv : bs;
  bias[i*1024 + t] = bb[i*256 + (t & 255)];
  if (t < 64)       bias2[i*128 + t] = pnb[i*64 + t];
  else if (t < 128) bias2[i*128 + t] = 0.f;
}

// classifier weight pack: W'[k][j<64]=c_w1[k][j]; W'[k][j>=64]=c_w1[64+k][j-64]
__global__ void k_packC(const float* __restrict__ cw1, float* __restrict__ Wp){
  int idx = blockIdx.x * blockDim.x + threadIdx.x;   // 64*128
  if (idx >= 64*128) return;
  int k = idx >> 7, j = idx & 127;
  Wp[idx] = (j < 64) ? cw1[k*64 + j] : cw1[(64 + k)*64 + (j - 64)];
}

// ---------------------------------------------------------- MFMA bf16 GEMM
template<int NSTEPS, int MODE>
__global__ __launch_bounds__(256) void k_mfma(
    const unsigned short* __restrict__ A, int lda,
    const unsigned short* __restrict__ Bt, int ldb,
    const float* __restrict__ bias,
    float* __restrict__ o_f0, unsigned short* __restrict__ o_h0,
    unsigned short* __restrict__ o_h1, float* __restrict__ o_f1, int M){
  __shared__ char lds[65536];
  char* ldsA = lds;
  char* ldsB = lds + 32768;
  int tid = threadIdx.x;
  int nbase = blockIdx.x * 128;
  int mbase = blockIdx.y * 128;
  int l = tid & 63, wid = tid >> 6;
  int wm = (wid >> 1) * 64, wn = (wid & 1) * 64;
  f32x4 acc[4][4] = {};
  const char* Ab  = (const char*)A;
  const char* Btb = (const char*)Bt;
  for (int ks = 0; ks < NSTEPS; ++ks){
    #pragma unroll
    for (int it = 0; it < 8; ++it){
      int c = tid + it*256;
      int row = c >> 4;
      int kb = (c & 15) << 4;
      int off = (row << 8) + (kb ^ ((row & 7) << 4));
      uint4 va = make_uint4(0,0,0,0);
      int gr = mbase + row;
      if (gr < M)
        va = *reinterpret_cast<const uint4*>(Ab + (size_t)gr*(lda*2) + ks*256 + kb);
      *reinterpret_cast<uint4*>(ldsA + off) = va;
      uint4 vb = *reinterpret_cast<const uint4*>(
                   Btb + (size_t)(nbase + row)*(ldb*2) + ks*256 + kb);
      *reinterpret_cast<uint4*>(ldsB + off) = vb;
    }
    __syncthreads();
    #pragma unroll
    for (int kk = 0; kk < 4; ++kk){
      int kbyte = kk*64 + (l >> 4)*16;
      short8 af[4], bf[4];
      #pragma unroll
      for (int m = 0; m < 4; ++m){
        int fr = wm + m*16 + (l & 15);
        af[m] = *reinterpret_cast<const short8*>(ldsA + (fr << 8) + (kbyte ^ ((fr & 7) << 4)));
      }
      #pragma unroll
      for (int n = 0; n < 4; ++n){
        int fc = wn + n*16 + (l & 15);
        bf[n] = *reinterpret_cast<const short8*>(ldsB + (fc << 8) + (kbyte ^ ((fc & 7) << 4)));
      }
      #pragma unroll
      for (int m = 0; m < 4; ++m)
        #pragma unroll
        for (int n = 0; n < 4; ++n)
          acc[m][n] = __builtin_amdgcn_mfma_f32_16x16x32_bf16(af[m], bf[n], acc[m][n], 0, 0, 0);
    }
    __syncthreads();
  }
  #pragma unroll
  for (int n = 0; n < 4; ++n){
    int gcol = nbase + wn + n*16 + (l & 15);
    float bv = bias ? bias[gcol] : 0.f;
    #pragma unroll
    for (int m = 0; m < 4; ++m){
      int grow = mbase + wm + m*16 + (l >> 4)*4;
      #pragma unroll
      for (int r = 0; r < 4; ++r){
        int gr = grow + r;
        if (gr < M){
          float val = acc[m][n][r] + bv;
          if (MODE == 1){
            o_f0[(size_t)gr*128 + gcol] = val;
          } else {
            int seg = gcol >> 8, c = gcol & 255;
            if      (seg == 0) o_f0[(size_t)gr*256 + c] = val;
            else if (seg == 1) o_h0[(size_t)gr*256 + c] = f2bf(val);
            else if (seg == 2) o_h1[(size_t)gr*256 + c] = f2bf(val);
            else               o_f1[(size_t)gr*256 + c] = val;
          }
        }
      }
    }
  }
}

// -------------- single-pass fused attention + skip + LN (lane-partitioned)
// lane l: head h=l>>4, dims 4*(l&15).. ; global col = 4*l. Unroll-8 gather.
__global__ void k_attn(const float* __restrict__ q, const unsigned short* __restrict__ kbuf,
                       const unsigned short* __restrict__ vbuf, const float* __restrict__ sbuf,
                       const int* __restrict__ rowptr, const int* __restrict__ csrc,
                       const float* __restrict__ ltg, const float* __restrict__ ltb,
                       unsigned short* __restrict__ outb, int N){
  int n = blockIdx.x*4 + (threadIdx.x >> 6);
  if (n >= N) return;
  int l = threadIdx.x & 63;
  int lo = rowptr[n], hi = rowptr[n+1];
  size_t base = (size_t)n*256 + l*4;
  const int l4 = l*4;
  float4 qv = *reinterpret_cast<const float4*>(q + base);
  qv.x *= 0.125f; qv.y *= 0.125f; qv.z *= 0.125f; qv.w *= 0.125f;
  float o0 = 0.f, o1 = 0.f, o2 = 0.f, o3 = 0.f, s = 0.f;
  int i = lo;
  for (; i + 8 <= hi; i += 8){
    ushort4 kk[8], vv[8];
    #pragma unroll
    for (int j = 0; j < 8; ++j){
      int c = csrc[i + j];
      kk[j] = *reinterpret_cast<const ushort4*>(kbuf + (size_t)c*256 + l4);
      vv[j] = *reinterpret_cast<const ushort4*>(vbuf + (size_t)c*256 + l4);
    }
    float a[8];
    #pragma unroll
    for (int j = 0; j < 8; ++j)
      a[j] = qv.x*bf2f(kk[j].x) + qv.y*bf2f(kk[j].y) + qv.z*bf2f(kk[j].z) + qv.w*bf2f(kk[j].w);
    #pragma unroll
    for (int m = 1; m < 16; m <<= 1){
      #pragma unroll
      for (int j = 0; j < 8; ++j) a[j] += __shfl_xor(a[j], m, 64);
    }
    #pragma unroll
    for (int j = 0; j < 8; ++j){
      float w = __expf(a[j]);
      s += w;
      o0 += w*bf2f(vv[j].x); o1 += w*bf2f(vv[j].y);
      o2 += w*bf2f(vv[j].z); o3 += w*bf2f(vv[j].w);
    }
  }
  for (; i < hi; ++i){
    size_t sb = (size_t)csrc[i]*256 + l4;
    ushort4 kv = *reinterpret_cast<const ushort4*>(kbuf + sb);
    ushort4 vv = *reinterpret_cast<const ushort4*>(vbuf + sb);
    float a = qv.x*bf2f(kv.x) + qv.y*bf2f(kv.y) + qv.z*bf2f(kv.z) + qv.w*bf2f(kv.w);
    #pragma unroll
    for (int m = 1; m < 16; m <<= 1) a += __shfl_xor(a, m, 64);
    float w = __expf(a);
    s += w;
    o0 += w*bf2f(vv.x); o1 += w*bf2f(vv.y); o2 += w*bf2f(vv.z); o3 += w*bf2f(vv.w);
  }
  float4 t = *reinterpret_cast<const float4*>(sbuf + base);
  if (hi > lo){
    float r = 1.f / s;
    t.x += o0*r; t.y += o1*r; t.z += o2*r; t.w += o3*r;
  }
  float mean = wave_sum(t.x + t.y + t.z + t.w) * (1.f/256.f);
  float dx = t.x - mean, dy = t.y - mean, dz = t.z - mean, dw = t.w - mean;
  float var = wave_sum(dx*dx + dy*dy + dz*dz + dw*dw) * (1.f/256.f);
  float rs = rsqrtf(var + 1e-5f);
  float4 g = *reinterpret_cast<const float4*>(ltg + l4);
  float4 b = *reinterpret_cast<const float4*>(ltb + l4);
  ushort4 o;
  o.x = f2bf(dx*rs*g.x + b.x);
  o.y = f2bf(dy*rs*g.y + b.y);
  o.z = f2bf(dz*rs*g.z + b.z);
  o.w = f2bf(dw*rs*g.w + b.w);
  *reinterpret_cast<ushort4*>(outb + base) = o;
}

// ------ gated fusion (nf) + agg-space edge update + NEXT iter's comb-LN
__global__ __launch_bounds__(256) void k_gate_agg(
    float* __restrict__ nf, float* __restrict__ agg,
    const float* __restrict__ pnP,
    const int* __restrict__ rowptr, const int* __restrict__ csrc,
    const float* __restrict__ gfw, const float* __restrict__ gfb,
    const float* __restrict__ peb,
    const float* __restrict__ cg, const float* __restrict__ cbv,
    unsigned short* __restrict__ comb, int doComb, int N){
  __shared__ float s_w[128 * 64];
  int tid = threadIdx.x;
  for (int idx = tid; idx < 128*64; idx += 256) s_w[idx] = gfw[idx];
  __syncthreads();
  int wv = tid >> 6, l = tid & 63;
  float gb = gfb[l], pebl = peb[l];
  for (int n = blockIdx.x*4 + wv; n < N; n += gridDim.x*4){
    float nfv = nf[(size_t)n*64 + l];
    float pnv = pnP[(size_t)n*128 + l];
    float g = gb;
    #pragma unroll 8
    for (int k = 0; k < 64; ++k){
      g += __shfl(nfv, k, 64) * s_w[k*64 + l];
      g += __shfl(pnv, k, 64) * s_w[(64 + k)*64 + l];
    }
    g = sigm(g);
    float nfn = nfv * (1.f + g) + pnv * (1.f - g);
    nf[(size_t)n*64 + l] = nfn;
    // agg += sum_{e in(n)} P[src] - deg*(P[n] - peb)
    int lo = rowptr[n], hi = rowptr[n+1];
    float sp = 0.f;
    int i = lo;
    for (; i + 8 <= hi; i += 8){
      float pv[8];
      #pragma unroll
      for (int j = 0; j < 8; ++j)
        pv[j] = pnP[(size_t)csrc[i+j]*128 + 64 + l];
      #pragma unroll
      for (int j = 0; j < 8; ++j) sp += pv[j];
    }
    for (; i < hi; ++i) sp += pnP[(size_t)csrc[i]*128 + 64 + l];
    float Pn = pnP[(size_t)n*128 + 64 + l];
    float aggn = agg[(size_t)n*64 + l] + sp - (float)(hi - lo) * (Pn - pebl);
    agg[(size_t)n*64 + l] = aggn;
    if (doComb){
      float v0 = nfn, v1 = aggn - nfn;
      float mean = wave_sum(v0 + v1) * (1.f/128.f);
      float d0 = v0 - mean, d1 = v1 - mean;
      float var = wave_sum(d0*d0 + d1*d1) * (1.f/128.f);
      float rs = rsqrtf(var + 1e-5f);
      comb[(size_t)n*128 + l]      = f2bf(d0 * rs * cg[l]      + cbv[l]);
      comb[(size_t)n*128 + 64 + l] = f2bf(d1 * rs * cg[64 + l] + cbv[64 + l]);
    }
  }
}

// ------------------------------------------------------------- classifier
template<int K, int BN>
__global__ __launch_bounds__(256) void k_gemm(
    const float* __restrict__ in, const float* __restrict__ W, int ldw,
    const float* __restrict__ bias, float* __restrict__ out, int ldo, int nrows){
  constexpr int PAD = BN + 4;
  __shared__ float s_in[K * PAD];
  int n0 = blockIdx.x * BN;
  int tid = threadIdx.x;
  for (int idx = tid; idx < BN * K; idx += 256){
    int r = idx / K, k = idx - r * K;
    float v = (n0 + r < nrows) ? in[(size_t)(n0 + r) * K + k] : 0.f;
    s_in[k * PAD + r] = v;
  }
  __syncthreads();
  int tx = tid & 15, ty = tid >> 4;
  constexpr int NT = BN / 16;
  int col0 = blockIdx.y * 64 + tx * 4;
  float acc[NT][4] = {};
  for (int k = 0; k < K; ++k){
    const float4 wv = *reinterpret_cast<const float4*>(&W[(size_t)k * ldw + col0]);
    #pragma unroll
    for (int i = 0; i < NT; ++i){
      float cv = s_in[k * PAD + ty * NT + i];
      acc[i][0] += cv * wv.x;
      acc[i][1] += cv * wv.y;
      acc[i][2] += cv * wv.z;
      acc[i][3] += cv * wv.w;
    }
  }
  #pragma unroll
  for (int i = 0; i < NT; ++i){
    int n = n0 + ty * NT + i;
    if (n < nrows){
      float4 o = make_float4(acc[i][0], acc[i][1], acc[i][2], acc[i][3]);
      *reinterpret_cast<float4*>(&out[(size_t)n * ldo + col0]) = o;
    }
  }
}

__global__ void k_final(const float* __restrict__ AB,
                        const int* __restrict__ ei, const float* __restrict__ cb1,
                        const float* __restrict__ cw2, const float* __restrict__ cb2,
                        float* __restrict__ dout, int E){
  int e = blockIdx.x*4 + (threadIdx.x >> 6);
  if (e >= E) return;
  int l = threadIdx.x & 63;
  int i0 = ei[e], i1 = ei[E + e];
  float h = fmaxf(AB[(size_t)i0*128 + l] + AB[(size_t)i1*128 + 64 + l] + cb1[l], 0.f);
  float p = wave_sum(h * cw2[l]);
  if (l == 0) dout[e] = p + cb2[0];
}

// ===========================================================================
extern "C" void kernel_launch(void* const* d_in, const int* in_sizes, int n_in,
                              void* d_out, int out_size, void* d_ws, size_t ws_size,
                              hipStream_t stream){
  const float* x         = (const float*)d_in[0];
  const float* edge_attr = (const float*)d_in[1];
  const float* node_w    = (const float*)d_in[2];
  const float* node_b    = (const float*)d_in[3];
  const float* edge_w    = (const float*)d_in[4];
  const float* edge_b    = (const float*)d_in[5];
  const float* z_emb     = (const float*)d_in[6];
  const float* cn_w1     = (const float*)d_in[7];
  const float* cn_b1     = (const float*)d_in[8];
  const float* cn_w2     = (const float*)d_in[9];
  const float* cn_b2     = (const float*)d_in[10];
  const float* cn_cw     = (const float*)d_in[11];
  const float* cn_cb     = (const float*)d_in[12];
  const float* ce_w1     = (const float*)d_in[13];
  const float* ce_b1     = (const float*)d_in[14];
  const float* ce_w2     = (const float*)d_in[15];
  const float* ce_b2     = (const float*)d_in[16];
  const float* ce_cw     = (const float*)d_in[17];
  const float* ce_cb     = (const float*)d_in[18];
  const float* Wq        = (const float*)d_in[19];
  const float* bq        = (const float*)d_in[20];
  const float* Wk        = (const float*)d_in[21];
  const float* bk        = (const float*)d_in[22];
  const float* Wv        = (const float*)d_in[23];
  const float* bv        = (const float*)d_in[24];
  const float* Ws        = (const float*)d_in[25];
  const float* bs        = (const float*)d_in[26];
  const float* lt_g      = (const float*)d_in[27];
  const float* lt_b      = (const float*)d_in[28];
  const float* lc_g      = (const float*)d_in[29];
  const float* lc_b      = (const float*)d_in[30];
  const float* pe_w      = (const float*)d_in[31];
  const float* pe_b      = (const float*)d_in[32];
  const float* pn_w      = (const float*)d_in[33];
  const float* pn_b      = (const float*)d_in[34];
  const float* gf_w      = (const float*)d_in[35];
  const float* gf_b      = (const float*)d_in[36];
  const float* c_w1      = (const float*)d_in[37];
  const float* c_b1      = (const float*)d_in[38];
  const float* c_w2      = (const float*)d_in[39];
  const float* c_b2      = (const float*)d_in[40];
  const int*   edge_index= (const int*)d_in[41];

  const int N  = in_sizes[0] / 6;
  const int E  = in_sizes[1] / 4;
  const int E2 = 2 * E;

  // ---------------- workspace layout
  char* p = (char*)d_ws;
  auto alloc = [&](size_t bytes)->char*{
    char* r = p; p += (bytes + 255) & ~(size_t)255; return r;
  };
  int*            w_src    = (int*)           alloc((size_t)E2 * 4);
  int*            w_dst    = (int*)           alloc((size_t)E2 * 4);
  int*            w_deg    = (int*)           alloc((size_t)N * 4);
  int*            w_rowptr = (int*)           alloc((size_t)(N + 1) * 4);
  int*            w_cur    = (int*)           alloc((size_t)N * 4);
  int*            w_csrc   = (int*)           alloc((size_t)E2 * 4);
  int*            w_epos   = (int*)           alloc((size_t)E2 * 4);
  float*          w_nf     = (float*)         alloc((size_t)N * 64 * 4);
  float*          w_agg    = (float*)         alloc((size_t)N * 64 * 4);
  float*          w_ef0    = (float*)         alloc((size_t)E2 * 64 * 4);
  float*          w_se     = (float*)         alloc((size_t)E2 * 4);
  unsigned short* w_comb   = (unsigned short*)alloc((size_t)N * 128 * 2);
  float*          w_q      = (float*)         alloc((size_t)N * 256 * 4);
  unsigned short* w_k      = (unsigned short*)alloc((size_t)N * 256 * 2);
  unsigned short* w_v      = (unsigned short*)alloc((size_t)N * 256 * 2);
  float*          w_s      = (float*)         alloc((size_t)N * 256 * 4);
  unsigned short* w_outb   = (unsigned short*)alloc((size_t)N * 256 * 2);
  float*          w_pnP    = (float*)         alloc((size_t)N * 128 * 4);
  float*          w_rp     = (float*)         alloc((size_t)E2 * 2 * 4);
  float*          w_AB     = (float*)         alloc((size_t)N * 128 * 4);
  float*          w_Wp     = (float*)         alloc((size_t)64 * 128 * 4);
  unsigned short* w_Bt     = (unsigned short*)alloc((size_t)3 * 1024 * 128 * 2);
  float*          w_bias   = (float*)         alloc((size_t)3 * 1024 * 4);
  unsigned short* w_Bt2    = (unsigned short*)alloc((size_t)3 * 128 * 256 * 2);
  float*          w_bias2  = (float*)         alloc((size_t)3 * 128 * 4);
  unsigned*       w_pmax   = (unsigned*)      alloc(64 * 4);
  float*          w_psum   = (float*)         alloc(64 * 4);
  float*          w_ch     = (float*)         alloc(64 * 4);
  unsigned*       w_pmax2  = (unsigned*)      alloc(64 * 4);
  float*          w_psum2  = (float*)         alloc(64 * 4);
  float*          w_ch2    = (float*)         alloc(64 * 4);

  hipMemsetAsync(w_deg,  0, (size_t)N * 4, stream);
  hipMemsetAsync(w_cur,  0, (size_t)N * 4, stream);
  hipMemsetAsync(w_pmax, 0, 64 * 4, stream);
  hipMemsetAsync(w_psum, 0, 64 * 4, stream);
  hipMemsetAsync(w_pmax2,0, 64 * 4, stream);
  hipMemsetAsync(w_psum2,0, 64 * 4, stream);

  // ---------------- CSR + node embedding/CBAM
  k_build_edges<<<(E2 + 255)/256, 256, 0, stream>>>(edge_index, E2, E, w_src, w_dst, w_deg);
  k_scan<<<1, 1024, 0, stream>>>(w_deg, w_rowptr, N);
  k_fill<<<(E2 + 255)/256, 256, 0, stream>>>(w_src, w_dst, w_rowptr, w_cur, w_csrc, w_epos, E2);
  k_embed_pool<<<512, 256, 0, stream>>>(x, node_w, node_b, z_emb, w_nf, w_pmax, w_psum, N);
  k_cbam_mlp<<<1, 64, 0, stream>>>(w_pmax, w_psum, 1.f/(float)N,
                                   cn_w1, cn_b1, cn_w2, cn_b2, w_ch);
  k_chmul_rowpool<<<(N + 3)/4, 256, 0, stream>>>(w_nf, w_ch, w_rp, N);
  k_spatial<<<(N + 3)/4, 256, 0, stream>>>(w_nf, w_rp, cn_cw, cn_cb, N);

  // ---------------- edge CBAM -> ef0 (CSR order) -> agg0 + comb0
  k_ecol<<<2048, 256, 0, stream>>>(x, edge_attr, w_src, w_dst, edge_w, edge_b,
                                   w_pmax2, w_psum2, E2, E);
  k_cbam_mlp<<<1, 64, 0, stream>>>(w_pmax2, w_psum2, 1.f/(float)E2,
                                   ce_w1, ce_b1, ce_w2, ce_b2, w_ch2);
  k_erp2<<<2048, 256, 0, stream>>>(x, edge_attr, w_src, w_dst, w_epos,
                                   edge_w, edge_b, w_ch2, w_rp, w_ef0, E2, E);
  k_se<<<(E2 + 255)/256, 256, 0, stream>>>(w_rp, w_epos, ce_cw, ce_cb, w_se, E2);
  k_aggb<<<(N + 3)/4, 256, 0, stream>>>(w_ef0, w_se, w_rowptr, w_nf,
                                        lc_g, lc_b, w_agg, w_comb, N);

  // ---------------- pack all iteration weights
  k_packT1<<<dim3(4, 6, 4), 256, 0, stream>>>(Wq, Wk, Wv, Ws, w_Bt);
  k_packT2<<<dim3(1, 12, 2), 256, 0, stream>>>(pn_w, pe_w, w_Bt2);
  k_biasp<<<3, 1024, 0, stream>>>(bq, bk, bv, bs, pn_b, w_bias, w_bias2);
  k_packC<<<32, 256, 0, stream>>>(c_w1, w_Wp);

  // ---------------- message-passing iterations
  const int MB = (N + 127) / 128;
  for (int i = 0; i < 3; ++i){
    k_mfma<1,0><<<dim3(8, MB), 256, 0, stream>>>(w_comb, 128,
                                                 w_Bt + (size_t)i*1024*128, 128,
                                                 w_bias + (size_t)i*1024,
                                                 w_q, w_k, w_v, w_s, N);
    k_attn<<<(N + 3)/4, 256, 0, stream>>>(w_q, w_k, w_v, w_s, w_rowptr, w_csrc,
                                          lt_g + (size_t)i*256, lt_b + (size_t)i*256,
                                          w_outb, N);
    k_mfma<2,1><<<dim3(1, MB), 256, 0, stream>>>(w_outb, 256,
                                                 w_Bt2 + (size_t)i*128*256, 256,
                                                 w_bias2 + (size_t)i*128,
                                                 w_pnP, nullptr, nullptr, nullptr, N);
    int doComb = (i < 2) ? 1 : 0;
    const float* cg  = lc_g + (size_t)(i < 2 ? i+1 : 0)*128;
    const float* cbv = lc_b + (size_t)(i < 2 ? i+1 : 0)*128;
    k_gate_agg<<<1250, 256, 0, stream>>>(w_nf, w_agg, w_pnP, w_rowptr, w_csrc,
                                         gf_w + (size_t)i*128*64, gf_b + (size_t)i*64,
                                         pe_b + (size_t)i*64,
                                         cg, cbv, w_comb, doComb, N);
  }

  // ---------------- classifier (fused A|B GEMM, then edge head)
  dim3 gAB((N + 63)/64, 2);
  k_gemm<64,64><<<gAB, 256, 0, stream>>>(w_nf, w_Wp, 128, nullptr, w_AB, 128, N);
  k_final<<<(E + 3)/4, 256, 0, stream>>>(w_AB, edge_index, c_b1, c_w2, c_b2,
                                         (float*)d_out, E);
}

// Round 6
// 859.165 us; speedup vs baseline: 2.3614x; 1.0239x over previous
//
#include <hip/hip_runtime.h>
#include <math.h>

typedef __attribute__((ext_vector_type(8))) short short8;
typedef __attribute__((ext_vector_type(4))) float f32x4;

// ---------------------------------------------------------------- utilities
__device__ __forceinline__ float wave_sum(float v){
  #pragma unroll
  for (int m = 32; m; m >>= 1) v += __shfl_xor(v, m, 64);
  return v;
}
__device__ __forceinline__ float wave_max(float v){
  #pragma unroll
  for (int m = 32; m; m >>= 1) v = fmaxf(v, __shfl_xor(v, m, 64));
  return v;
}
__device__ __forceinline__ unsigned fenc(float f){
  unsigned u = __float_as_uint(f);
  return (u >> 31) ? ~u : (u | 0x80000000u);
}
__device__ __forceinline__ float fdec(unsigned e){
  return (e >> 31) ? __uint_as_float(e & 0x7fffffffu) : __uint_as_float(~e);
}
__device__ __forceinline__ float sigm(float x){ return 1.f / (1.f + __expf(-x)); }
__device__ __forceinline__ unsigned short f2bf(float f){
  union { float f; unsigned u; } x; x.f = f;
  unsigned r = x.u + 0x7fffu + ((x.u >> 16) & 1u);
  return (unsigned short)(r >> 16);
}
__device__ __forceinline__ float bf2f(unsigned short h){
  union { unsigned u; float f; } x; x.u = ((unsigned)h) << 16;
  return x.f;
}

// ------------------------------------------------------------ CSR building
__global__ void k_build_edges(const int* __restrict__ ei, int E2, int E,
                              int* __restrict__ src, int* __restrict__ dst,
                              int* __restrict__ deg){
  int e = blockIdx.x * blockDim.x + threadIdx.x;
  if (e >= E2) return;
  int s = ei[e];
  int d = (e < E) ? ei[e + E] : ei[e - E];
  src[e] = s; dst[e] = d;
  atomicAdd(&deg[d], 1);
}

__global__ void k_scan(const int* __restrict__ deg, int* __restrict__ rowptr, int N){
  __shared__ int part[1024];
  int t = threadIdx.x;
  int chunk = (N + 1023) / 1024;
  int lo = t * chunk, hi = lo + chunk; if (hi > N) hi = N;
  int s = 0;
  for (int i = lo; i < hi; ++i) s += deg[i];
  part[t] = s;
  __syncthreads();
  for (int off = 1; off < 1024; off <<= 1){
    int v = (t >= off) ? part[t - off] : 0;
    __syncthreads();
    part[t] += v;
    __syncthreads();
  }
  int run = part[t] - s;
  for (int i = lo; i < hi; ++i){ rowptr[i] = run; run += deg[i]; }
  if (t == 1023) rowptr[N] = part[1023];
}

// fill CSR + gather raw edge features once (edge-per-lane, lane-parallel)
__global__ void k_fill(const int* __restrict__ src, const int* __restrict__ dst,
                       const int* __restrict__ rowptr,
                       int* __restrict__ cur, int* __restrict__ csrc,
                       int* __restrict__ epos,
                       const float* __restrict__ x, const float* __restrict__ ea,
                       float* __restrict__ re8, int E2, int E){
  int e = blockIdx.x * blockDim.x + threadIdx.x;
  if (e >= E2) return;
  int s = src[e], d = dst[e];
  int pos = rowptr[d] + atomicAdd(&cur[d], 1);
  csrc[pos] = s;
  epos[e] = pos;
  int row = (e < E) ? e : e - E;
  float4 eav = *reinterpret_cast<const float4*>(ea + (size_t)row*4);
  float r0 = x[s*6]     - x[d*6];
  float r1 = x[s*6 + 1] - x[d*6 + 1];
  float r2 = x[s*6 + 2] - x[d*6 + 2];
  *reinterpret_cast<float4*>(re8 + (size_t)e*8)     = eav;
  *reinterpret_cast<float4*>(re8 + (size_t)e*8 + 4) = make_float4(r0, r1, r2, 0.f);
}

// ------------------------- fused node embedding + column pool (max/mean)
__global__ void k_embed_pool(const float* __restrict__ x, const float* __restrict__ nw,
                             const float* __restrict__ nb, const float* __restrict__ zemb,
                             float* __restrict__ nf,
                             unsigned* __restrict__ pmax, float* __restrict__ psum, int N){
  int tx = threadIdx.x & 63;
  int ty = threadIdx.x >> 6;
  const float allowed[6] = {8.f, 23.f, 39.f, 54.f, 90.f, 180.f};
  float m = -INFINITY, s = 0.f;
  for (int n = blockIdx.x*4 + ty; n < N; n += gridDim.x*4){
    float xv[6];
    #pragma unroll
    for (int k = 0; k < 6; ++k) xv[k] = x[n*6 + k];
    float v = nb[tx];
    #pragma unroll
    for (int k = 0; k < 6; ++k) v += xv[k] * nw[k*64 + tx];
    v = fmaxf(v, 0.f);
    float r = rintf(xv[2]);
    int zi = 0; float bd = fabsf(r - allowed[0]);
    #pragma unroll
    for (int k = 1; k < 6; ++k){ float d = fabsf(r - allowed[k]); if (d < bd){ bd = d; zi = k; } }
    v += zemb[zi*64 + tx];
    nf[(size_t)n*64 + tx] = v;
    m = fmaxf(m, v); s += v;
  }
  __shared__ float sm[4][64], ss[4][64];
  sm[ty][tx] = m; ss[ty][tx] = s;
  __syncthreads();
  if (ty == 0){
    #pragma unroll
    for (int k = 1; k < 4; ++k){ m = fmaxf(m, sm[k][tx]); s += ss[k][tx]; }
    atomicMax(&pmax[tx], fenc(m));
    atomicAdd(&psum[tx], s);
  }
}

// ------------------------------------------------------------------- CBAM MLP
__global__ void k_cbam_mlp(const unsigned* __restrict__ pmax, const float* __restrict__ psum,
                           float invR,
                           const float* __restrict__ w1, const float* __restrict__ b1,
                           const float* __restrict__ w2, const float* __restrict__ b2,
                           float* __restrict__ ch){
  __shared__ float pool[128];
  __shared__ float h[4];
  int t = threadIdx.x;
  pool[t]      = fdec(pmax[t]);
  pool[64 + t] = psum[t] * invR;
  __syncthreads();
  if (t < 4){
    float a = b1[t];
    for (int k = 0; k < 128; ++k) a += pool[k] * w1[k*4 + t];
    h[t] = fmaxf(a, 0.f);
  }
  __syncthreads();
  float a = b2[t];
  #pragma unroll
  for (int k = 0; k < 4; ++k) a += h[k] * w2[k*64 + t];
  ch[t] = sigm(a);
}

__global__ void k_chmul_rowpool(float* __restrict__ buf, const float* __restrict__ ch,
                                float* __restrict__ rp, int R){
  int r = blockIdx.x*4 + (threadIdx.x >> 6);
  if (r >= R) return;
  int l = threadIdx.x & 63;
  float v = buf[(size_t)r*64 + l] * ch[l];
  buf[(size_t)r*64 + l] = v;
  float m = wave_max(v);
  float s = wave_sum(v);
  if (l == 0){ rp[(size_t)r*2] = m; rp[(size_t)r*2 + 1] = s * (1.f/64.f); }
}

__global__ void k_spatial(float* __restrict__ buf, const float* __restrict__ rp,
                          const float* __restrict__ cw, const float* __restrict__ cb, int R){
  int r = blockIdx.x*4 + (threadIdx.x >> 6);
  if (r >= R) return;
  int l = threadIdx.x & 63;
  float sp = cb[0];
  #pragma unroll
  for (int t = 0; t < 7; ++t){
    int rr = r + t - 3;
    if (rr >= 0 && rr < R)
      sp += cw[t] * rp[(size_t)rr*2] + cw[7 + t] * rp[(size_t)rr*2 + 1];
  }
  buf[(size_t)r*64 + l] *= sigm(sp);
}

// --------------- edge column-pool over raw features (streamed via LDS)
__global__ __launch_bounds__(256) void k_ecol(
    const float* __restrict__ re8,
    const float* __restrict__ ew, const float* __restrict__ eb,
    unsigned* __restrict__ pmax, float* __restrict__ psum, int E2){
  __shared__ float s_ew[448];
  __shared__ float s_re[256];
  int tid = threadIdx.x;
  for (int idx = tid; idx < 448; idx += 256) s_ew[idx] = ew[idx];
  int tx = tid & 63, wv = tid >> 6;
  float ebl = eb[tx];
  float m = -INFINITY, s = 0.f;
  for (int base = blockIdx.x*32; base < E2; base += gridDim.x*32){
    __syncthreads();
    int gidx = base*8 + tid;
    s_re[tid] = (gidx < E2*8) ? re8[gidx] : 0.f;
    __syncthreads();
    #pragma unroll
    for (int j = 0; j < 8; ++j){
      int e = base + wv*8 + j;
      if (e >= E2) break;
      const float* r = &s_re[(wv*8 + j)*8];
      float v = ebl;
      #pragma unroll
      for (int k = 0; k < 7; ++k) v += r[k] * s_ew[k*64 + tx];
      v = fmaxf(v, 0.f);
      m = fmaxf(m, v); s += v;
    }
  }
  __shared__ float sm[4][64], ss[4][64];
  sm[wv][tx] = m; ss[wv][tx] = s;
  __syncthreads();
  if (wv == 0){
    #pragma unroll
    for (int k = 1; k < 4; ++k){ m = fmaxf(m, sm[k][tx]); s += ss[k][tx]; }
    atomicMax(&pmax[tx], fenc(m));
    atomicAdd(&psum[tx], s);
  }
}

// ------ edge row-pool + scatter-store ef0=raw*ch (streamed via LDS)
__global__ __launch_bounds__(256) void k_erp2(
    const float* __restrict__ re8, const int* __restrict__ epos,
    const float* __restrict__ ew, const float* __restrict__ eb,
    const float* __restrict__ ch,
    float* __restrict__ rp, float* __restrict__ ef0, int E2){
  __shared__ float s_ew[448];
  __shared__ float s_re[256];
  __shared__ int   s_ep[32];
  int tid = threadIdx.x;
  for (int idx = tid; idx < 448; idx += 256) s_ew[idx] = ew[idx];
  int tx = tid & 63, wv = tid >> 6;
  float ebl = eb[tx], chl = ch[tx];
  for (int base = blockIdx.x*32; base < E2; base += gridDim.x*32){
    __syncthreads();
    int gidx = base*8 + tid;
    s_re[tid] = (gidx < E2*8) ? re8[gidx] : 0.f;
    if (tid < 32 && base + tid < E2) s_ep[tid] = epos[base + tid];
    __syncthreads();
    #pragma unroll
    for (int j = 0; j < 8; ++j){
      int e = base + wv*8 + j;
      if (e >= E2) break;
      const float* r = &s_re[(wv*8 + j)*8];
      float v = ebl;
      #pragma unroll
      for (int k = 0; k < 7; ++k) v += r[k] * s_ew[k*64 + tx];
      v = fmaxf(v, 0.f) * chl;
      float mm = wave_max(v);
      float sm2 = wave_sum(v);
      if (tx == 0){ rp[(size_t)e*2] = mm; rp[(size_t)e*2 + 1] = sm2 * (1.f/64.f); }
      ef0[(size_t)s_ep[wv*8 + j]*64 + tx] = v;
    }
  }
}

// ------------------- per-edge spatial sigmoid, stored in CSR slot
__global__ void k_se(const float* __restrict__ rp, const int* __restrict__ epos,
                     const float* __restrict__ ccw, const float* __restrict__ ccb,
                     float* __restrict__ se, int E2){
  int e = blockIdx.x * blockDim.x + threadIdx.x;
  if (e >= E2) return;
  float sp = ccb[0];
  #pragma unroll
  for (int t = 0; t < 7; ++t){
    int rr = e + t - 3;
    if (rr >= 0 && rr < E2)
      sp += ccw[t] * rp[(size_t)rr*2] + ccw[7+t] * rp[(size_t)rr*2 + 1];
  }
  se[epos[e]] = sigm(sp);
}

// ------------- agg0 = streamed sum(se*ef0) over CSR + fused concat-LN comb0
__global__ void k_aggb(const float* __restrict__ ef0, const float* __restrict__ se,
                       const int* __restrict__ rowptr, const float* __restrict__ nf,
                       const float* __restrict__ g, const float* __restrict__ b,
                       float* __restrict__ agg, unsigned short* __restrict__ comb, int N){
  int n = blockIdx.x*4 + (threadIdx.x >> 6);
  if (n >= N) return;
  int l = threadIdx.x & 63;
  int lo = rowptr[n], hi = rowptr[n+1];
  float acc = 0.f;
  int i = lo;
  for (; i + 4 <= hi; i += 4){
    float s0 = se[i], s1 = se[i+1], s2 = se[i+2], s3 = se[i+3];
    float e0 = ef0[(size_t)i*64 + l];
    float e1 = ef0[(size_t)(i+1)*64 + l];
    float e2 = ef0[(size_t)(i+2)*64 + l];
    float e3 = ef0[(size_t)(i+3)*64 + l];
    acc += s0*e0 + s1*e1 + s2*e2 + s3*e3;
  }
  for (; i < hi; ++i) acc += se[i] * ef0[(size_t)i*64 + l];
  agg[(size_t)n*64 + l] = acc;
  float a = nf[(size_t)n*64 + l];
  float v0 = a, v1 = acc - a;
  float mean = wave_sum(v0 + v1) * (1.f/128.f);
  float d0 = v0 - mean, d1 = v1 - mean;
  float var = wave_sum(d0*d0 + d1*d1) * (1.f/128.f);
  float rs = rsqrtf(var + 1e-5f);
  comb[(size_t)n*128 + l]      = f2bf(d0 * rs * g[l]      + b[l]);
  comb[(size_t)n*128 + 64 + l] = f2bf(d1 * rs * g[64 + l] + b[64 + l]);
}

// ------------------------------- coalesced LDS-transpose weight packs
__global__ __launch_bounds__(256) void k_packT1(
    const float* __restrict__ Wq, const float* __restrict__ Wk,
    const float* __restrict__ Wv, const float* __restrict__ Ws,
    unsigned short* __restrict__ Bt){
  __shared__ float t[64][65];
  int bx = blockIdx.x, by = blockIdx.y, bz = blockIdx.z;
  const float* W = (bz == 0) ? Wq : (bz == 1) ? Wk : (bz == 2) ? Wv : Ws;
  int tx = threadIdx.x & 63, ty = threadIdx.x >> 6;
  int R0 = by*64, C0 = bx*64;
  for (int r = ty; r < 64; r += 4)
    t[r][tx] = W[(size_t)(R0 + r)*256 + C0 + tx];
  __syncthreads();
  int iter = by >> 1, kr0 = (by & 1)*64;
  for (int r = ty; r < 64; r += 4)
    Bt[(size_t)iter*1024*128 + (size_t)(bz*256 + C0 + r)*128 + kr0 + tx] = f2bf(t[tx][r]);
}

__global__ __launch_bounds__(256) void k_packT2(
    const float* __restrict__ Wn, const float* __restrict__ We,
    unsigned short* __restrict__ Bt2){
  __shared__ float t[64][65];
  int by = blockIdx.y, bz = blockIdx.z;
  const float* W = (bz == 0) ? Wn : We;
  int tx = threadIdx.x & 63, ty = threadIdx.x >> 6;
  int R0 = by*64;
  for (int r = ty; r < 64; r += 4)
    t[r][tx] = W[(size_t)(R0 + r)*64 + tx];
  __syncthreads();
  int iter = by >> 2, kr0 = (by & 3)*64;
  for (int r = ty; r < 64; r += 4)
    Bt2[(size_t)iter*128*256 + (size_t)(bz*64 + r)*256 + kr0 + tx] = f2bf(t[tx][r]);
}

__global__ void k_biasp(const float* __restrict__ bq, const float* __restrict__ bk,
                        const float* __restrict__ bv, const float* __restrict__ bs,
                        const float* __restrict__ pnb,
                        float* __restrict__ bias, float* __restrict__ bias2){
  int i = blockIdx.x, t = threadIdx.x;
  const float* bb = (t < 256) ? bq : (t < 512) ? bk : (t < 768) ? bv : bs;
  bias[i*1024 + t] = bb[i*256 + (t & 255)];
  if (t < 64)       bias2[i*128 + t] = pnb[i*64 + t];
  else if (t < 128) bias2[i*128 + t] = 0.f;
}

__global__ void k_packC(const float* __restrict__ cw1, float* __restrict__ Wp){
  int idx = blockIdx.x * blockDim.x + threadIdx.x;
  if (idx >= 64*128) return;
  int k = idx >> 7, j = idx & 127;
  Wp[idx] = (j < 64) ? cw1[k*64 + j] : cw1[(64 + k)*64 + (j - 64)];
}

// ---------------------------------------------------------- MFMA bf16 GEMM
template<int NSTEPS, int MODE>
__global__ __launch_bounds__(256) void k_mfma(
    const unsigned short* __restrict__ A, int lda,
    const unsigned short* __restrict__ Bt, int ldb,
    const float* __restrict__ bias,
    float* __restrict__ o_f0, unsigned short* __restrict__ o_h0,
    unsigned short* __restrict__ o_h1, float* __restrict__ o_f1, int M){
  __shared__ char lds[65536];
  char* ldsA = lds;
  char* ldsB = lds + 32768;
  int tid = threadIdx.x;
  int nbase = blockIdx.x * 128;
  int mbase = blockIdx.y * 128;
  int l = tid & 63, wid = tid >> 6;
  int wm = (wid >> 1) * 64, wn = (wid & 1) * 64;
  f32x4 acc[4][4] = {};
  const char* Ab  = (const char*)A;
  const char* Btb = (const char*)Bt;
  for (int ks = 0; ks < NSTEPS; ++ks){
    #pragma unroll
    for (int it = 0; it < 8; ++it){
      int c = tid + it*256;
      int row = c >> 4;
      int kb = (c & 15) << 4;
      int off = (row << 8) + (kb ^ ((row & 7) << 4));
      uint4 va = make_uint4(0,0,0,0);
      int gr = mbase + row;
      if (gr < M)
        va = *reinterpret_cast<const uint4*>(Ab + (size_t)gr*(lda*2) + ks*256 + kb);
      *reinterpret_cast<uint4*>(ldsA + off) = va;
      uint4 vb = *reinterpret_cast<const uint4*>(
                   Btb + (size_t)(nbase + row)*(ldb*2) + ks*256 + kb);
      *reinterpret_cast<uint4*>(ldsB + off) = vb;
    }
    __syncthreads();
    #pragma unroll
    for (int kk = 0; kk < 4; ++kk){
      int kbyte = kk*64 + (l >> 4)*16;
      short8 af[4], bf[4];
      #pragma unroll
      for (int m = 0; m < 4; ++m){
        int fr = wm + m*16 + (l & 15);
        af[m] = *reinterpret_cast<const short8*>(ldsA + (fr << 8) + (kbyte ^ ((fr & 7) << 4)));
      }
      #pragma unroll
      for (int n = 0; n < 4; ++n){
        int fc = wn + n*16 + (l & 15);
        bf[n] = *reinterpret_cast<const short8*>(ldsB + (fc << 8) + (kbyte ^ ((fc & 7) << 4)));
      }
      #pragma unroll
      for (int m = 0; m < 4; ++m)
        #pragma unroll
        for (int n = 0; n < 4; ++n)
          acc[m][n] = __builtin_amdgcn_mfma_f32_16x16x32_bf16(af[m], bf[n], acc[m][n], 0, 0, 0);
    }
    __syncthreads();
  }
  #pragma unroll
  for (int n = 0; n < 4; ++n){
    int gcol = nbase + wn + n*16 + (l & 15);
    float bv = bias ? bias[gcol] : 0.f;
    #pragma unroll
    for (int m = 0; m < 4; ++m){
      int grow = mbase + wm + m*16 + (l >> 4)*4;
      #pragma unroll
      for (int r = 0; r < 4; ++r){
        int gr = grow + r;
        if (gr < M){
          float val = acc[m][n][r] + bv;
          if (MODE == 1){
            o_f0[(size_t)gr*128 + gcol] = val;
          } else {
            int seg = gcol >> 8, c = gcol & 255;
            if      (seg == 0) o_f0[(size_t)gr*256 + c] = val;
            else if (seg == 1) o_h0[(size_t)gr*256 + c] = f2bf(val);
            else if (seg == 2) o_h1[(size_t)gr*256 + c] = f2bf(val);
            else               o_f1[(size_t)gr*256 + c] = val;
          }
        }
      }
    }
  }
}

// -------------- single-pass fused attention + skip + LN (lane-partitioned)
__global__ void k_attn(const float* __restrict__ q, const unsigned short* __restrict__ kbuf,
                       const unsigned short* __restrict__ vbuf, const float* __restrict__ sbuf,
                       const int* __restrict__ rowptr, const int* __restrict__ csrc,
                       const float* __restrict__ ltg, const float* __restrict__ ltb,
                       unsigned short* __restrict__ outb, int N){
  int n = blockIdx.x*4 + (threadIdx.x >> 6);
  if (n >= N) return;
  int l = threadIdx.x & 63;
  int lo = rowptr[n], hi = rowptr[n+1];
  size_t base = (size_t)n*256 + l*4;
  const int l4 = l*4;
  float4 qv = *reinterpret_cast<const float4*>(q + base);
  qv.x *= 0.125f; qv.y *= 0.125f; qv.z *= 0.125f; qv.w *= 0.125f;
  float o0 = 0.f, o1 = 0.f, o2 = 0.f, o3 = 0.f, s = 0.f;
  int i = lo;
  for (; i + 8 <= hi; i += 8){
    ushort4 kk[8], vv[8];
    #pragma unroll
    for (int j = 0; j < 8; ++j){
      int c = csrc[i + j];
      kk[j] = *reinterpret_cast<const ushort4*>(kbuf + (size_t)c*256 + l4);
      vv[j] = *reinterpret_cast<const ushort4*>(vbuf + (size_t)c*256 + l4);
    }
    float a[8];
    #pragma unroll
    for (int j = 0; j < 8; ++j)
      a[j] = qv.x*bf2f(kk[j].x) + qv.y*bf2f(kk[j].y) + qv.z*bf2f(kk[j].z) + qv.w*bf2f(kk[j].w);
    #pragma unroll
    for (int m = 1; m < 16; m <<= 1){
      #pragma unroll
      for (int j = 0; j < 8; ++j) a[j] += __shfl_xor(a[j], m, 64);
    }
    #pragma unroll
    for (int j = 0; j < 8; ++j){
      float w = __expf(a[j]);
      s += w;
      o0 += w*bf2f(vv[j].x); o1 += w*bf2f(vv[j].y);
      o2 += w*bf2f(vv[j].z); o3 += w*bf2f(vv[j].w);
    }
  }
  for (; i < hi; ++i){
    size_t sb = (size_t)csrc[i]*256 + l4;
    ushort4 kv = *reinterpret_cast<const ushort4*>(kbuf + sb);
    ushort4 vv = *reinterpret_cast<const ushort4*>(vbuf + sb);
    float a = qv.x*bf2f(kv.x) + qv.y*bf2f(kv.y) + qv.z*bf2f(kv.z) + qv.w*bf2f(kv.w);
    #pragma unroll
    for (int m = 1; m < 16; m <<= 1) a += __shfl_xor(a, m, 64);
    float w = __expf(a);
    s += w;
    o0 += w*bf2f(vv.x); o1 += w*bf2f(vv.y); o2 += w*bf2f(vv.z); o3 += w*bf2f(vv.w);
  }
  float4 t = *reinterpret_cast<const float4*>(sbuf + base);
  if (hi > lo){
    float r = 1.f / s;
    t.x += o0*r; t.y += o1*r; t.z += o2*r; t.w += o3*r;
  }
  float mean = wave_sum(t.x + t.y + t.z + t.w) * (1.f/256.f);
  float dx = t.x - mean, dy = t.y - mean, dz = t.z - mean, dw = t.w - mean;
  float var = wave_sum(dx*dx + dy*dy + dz*dz + dw*dw) * (1.f/256.f);
  float rs = rsqrtf(var + 1e-5f);
  float4 g = *reinterpret_cast<const float4*>(ltg + l4);
  float4 b = *reinterpret_cast<const float4*>(ltb + l4);
  ushort4 o;
  o.x = f2bf(dx*rs*g.x + b.x);
  o.y = f2bf(dy*rs*g.y + b.y);
  o.z = f2bf(dz*rs*g.z + b.z);
  o.w = f2bf(dw*rs*g.w + b.w);
  *reinterpret_cast<ushort4*>(outb + base) = o;
}

// ------ gated fusion (nf) + agg-space edge update + NEXT iter's comb-LN
__global__ __launch_bounds__(256) void k_gate_agg(
    float* __restrict__ nf, float* __restrict__ agg,
    const float* __restrict__ pnP,
    const int* __restrict__ rowptr, const int* __restrict__ csrc,
    const float* __restrict__ gfw, const float* __restrict__ gfb,
    const float* __restrict__ peb,
    const float* __restrict__ cg, const float* __restrict__ cbv,
    unsigned short* __restrict__ comb, int doComb, int N){
  __shared__ float s_w[128 * 64];
  int tid = threadIdx.x;
  for (int idx = tid; idx < 128*64; idx += 256) s_w[idx] = gfw[idx];
  __syncthreads();
  int wv = tid >> 6, l = tid & 63;
  float gb = gfb[l], pebl = peb[l];
  for (int n = blockIdx.x*4 + wv; n < N; n += gridDim.x*4){
    float nfv = nf[(size_t)n*64 + l];
    float pnv = pnP[(size_t)n*128 + l];
    float g = gb;
    #pragma unroll 8
    for (int k = 0; k < 64; ++k){
      g += __shfl(nfv, k, 64) * s_w[k*64 + l];
      g += __shfl(pnv, k, 64) * s_w[(64 + k)*64 + l];
    }
    g = sigm(g);
    float nfn = nfv * (1.f + g) + pnv * (1.f - g);
    nf[(size_t)n*64 + l] = nfn;
    int lo = rowptr[n], hi = rowptr[n+1];
    float sp = 0.f;
    int i = lo;
    for (; i + 8 <= hi; i += 8){
      float pv[8];
      #pragma unroll
      for (int j = 0; j < 8; ++j)
        pv[j] = pnP[(size_t)csrc[i+j]*128 + 64 + l];
      #pragma unroll
      for (int j = 0; j < 8; ++j) sp += pv[j];
    }
    for (; i < hi; ++i) sp += pnP[(size_t)csrc[i]*128 + 64 + l];
    float Pn = pnP[(size_t)n*128 + 64 + l];
    float aggn = agg[(size_t)n*64 + l] + sp - (float)(hi - lo) * (Pn - pebl);
    agg[(size_t)n*64 + l] = aggn;
    if (doComb){
      float v0 = nfn, v1 = aggn - nfn;
      float mean = wave_sum(v0 + v1) * (1.f/128.f);
      float d0 = v0 - mean, d1 = v1 - mean;
      float var = wave_sum(d0*d0 + d1*d1) * (1.f/128.f);
      float rs = rsqrtf(var + 1e-5f);
      comb[(size_t)n*128 + l]      = f2bf(d0 * rs * cg[l]      + cbv[l]);
      comb[(size_t)n*128 + 64 + l] = f2bf(d1 * rs * cg[64 + l] + cbv[64 + l]);
    }
  }
}

// ------------------------------------------------------------- classifier
template<int K, int BN>
__global__ __launch_bounds__(256) void k_gemm(
    const float* __restrict__ in, const float* __restrict__ W, int ldw,
    const float* __restrict__ bias, float* __restrict__ out, int ldo, int nrows){
  constexpr int PAD = BN + 4;
  __shared__ float s_in[K * PAD];
  int n0 = blockIdx.x * BN;
  int tid = threadIdx.x;
  for (int idx = tid; idx < BN * K; idx += 256){
    int r = idx / K, k = idx - r * K;
    float v = (n0 + r < nrows) ? in[(size_t)(n0 + r) * K + k] : 0.f;
    s_in[k * PAD + r] = v;
  }
  __syncthreads();
  int tx = tid & 15, ty = tid >> 4;
  constexpr int NT = BN / 16;
  int col0 = blockIdx.y * 64 + tx * 4;
  float acc[NT][4] = {};
  for (int k = 0; k < K; ++k){
    const float4 wv = *reinterpret_cast<const float4*>(&W[(size_t)k * ldw + col0]);
    #pragma unroll
    for (int i = 0; i < NT; ++i){
      float cv = s_in[k * PAD + ty * NT + i];
      acc[i][0] += cv * wv.x;
      acc[i][1] += cv * wv.y;
      acc[i][2] += cv * wv.z;
      acc[i][3] += cv * wv.w;
    }
  }
  #pragma unroll
  for (int i = 0; i < NT; ++i){
    int n = n0 + ty * NT + i;
    if (n < nrows){
      float4 o = make_float4(acc[i][0], acc[i][1], acc[i][2], acc[i][3]);
      *reinterpret_cast<float4*>(&out[(size_t)n * ldo + col0]) = o;
    }
  }
}

__global__ void k_final(const float* __restrict__ AB,
                        const int* __restrict__ ei, const float* __restrict__ cb1,
                        const float* __restrict__ cw2, const float* __restrict__ cb2,
                        float* __restrict__ dout, int E){
  int e = blockIdx.x*4 + (threadIdx.x >> 6);
  if (e >= E) return;
  int l = threadIdx.x & 63;
  int i0 = ei[e], i1 = ei[E + e];
  float h = fmaxf(AB[(size_t)i0*128 + l] + AB[(size_t)i1*128 + 64 + l] + cb1[l], 0.f);
  float p = wave_sum(h * cw2[l]);
  if (l == 0) dout[e] = p + cb2[0];
}

// ===========================================================================
extern "C" void kernel_launch(void* const* d_in, const int* in_sizes, int n_in,
                              void* d_out, int out_size, void* d_ws, size_t ws_size,
                              hipStream_t stream){
  const float* x         = (const float*)d_in[0];
  const float* edge_attr = (const float*)d_in[1];
  const float* node_w    = (const float*)d_in[2];
  const float* node_b    = (const float*)d_in[3];
  const float* edge_w    = (const float*)d_in[4];
  const float* edge_b    = (const float*)d_in[5];
  const float* z_emb     = (const float*)d_in[6];
  const float* cn_w1     = (const float*)d_in[7];
  const float* cn_b1     = (const float*)d_in[8];
  const float* cn_w2     = (const float*)d_in[9];
  const float* cn_b2     = (const float*)d_in[10];
  const float* cn_cw     = (const float*)d_in[11];
  const float* cn_cb     = (const float*)d_in[12];
  const float* ce_w1     = (const float*)d_in[13];
  const float* ce_b1     = (const float*)d_in[14];
  const float* ce_w2     = (const float*)d_in[15];
  const float* ce_b2     = (const float*)d_in[16];
  const float* ce_cw     = (const float*)d_in[17];
  const float* ce_cb     = (const float*)d_in[18];
  const float* Wq        = (const float*)d_in[19];
  const float* bq        = (const float*)d_in[20];
  const float* Wk        = (const float*)d_in[21];
  const float* bk        = (const float*)d_in[22];
  const float* Wv        = (const float*)d_in[23];
  const float* bv        = (const float*)d_in[24];
  const float* Ws        = (const float*)d_in[25];
  const float* bs        = (const float*)d_in[26];
  const float* lt_g      = (const float*)d_in[27];
  const float* lt_b      = (const float*)d_in[28];
  const float* lc_g      = (const float*)d_in[29];
  const float* lc_b      = (const float*)d_in[30];
  const float* pe_w      = (const float*)d_in[31];
  const float* pe_b      = (const float*)d_in[32];
  const float* pn_w      = (const float*)d_in[33];
  const float* pn_b      = (const float*)d_in[34];
  const float* gf_w      = (const float*)d_in[35];
  const float* gf_b      = (const float*)d_in[36];
  const float* c_w1      = (const float*)d_in[37];
  const float* c_b1      = (const float*)d_in[38];
  const float* c_w2      = (const float*)d_in[39];
  const float* c_b2      = (const float*)d_in[40];
  const int*   edge_index= (const int*)d_in[41];

  const int N  = in_sizes[0] / 6;
  const int E  = in_sizes[1] / 4;
  const int E2 = 2 * E;

  // ---------------- workspace layout
  char* p = (char*)d_ws;
  auto alloc = [&](size_t bytes)->char*{
    char* r = p; p += (bytes + 255) & ~(size_t)255; return r;
  };
  int*            w_src    = (int*)           alloc((size_t)E2 * 4);
  int*            w_dst    = (int*)           alloc((size_t)E2 * 4);
  int*            w_deg    = (int*)           alloc((size_t)N * 4);
  int*            w_rowptr = (int*)           alloc((size_t)(N + 1) * 4);
  int*            w_cur    = (int*)           alloc((size_t)N * 4);
  int*            w_csrc   = (int*)           alloc((size_t)E2 * 4);
  int*            w_epos   = (int*)           alloc((size_t)E2 * 4);
  float*          w_re8    = (float*)         alloc((size_t)E2 * 8 * 4);
  float*          w_nf     = (float*)         alloc((size_t)N * 64 * 4);
  float*          w_agg    = (float*)         alloc((size_t)N * 64 * 4);
  float*          w_ef0    = (float*)         alloc((size_t)E2 * 64 * 4);
  float*          w_se     = (float*)         alloc((size_t)E2 * 4);
  unsigned short* w_comb   = (unsigned short*)alloc((size_t)N * 128 * 2);
  float*          w_q      = (float*)         alloc((size_t)N * 256 * 4);
  unsigned short* w_k      = (unsigned short*)alloc((size_t)N * 256 * 2);
  unsigned short* w_v      = (unsigned short*)alloc((size_t)N * 256 * 2);
  float*          w_s      = (float*)         alloc((size_t)N * 256 * 4);
  unsigned short* w_outb   = (unsigned short*)alloc((size_t)N * 256 * 2);
  float*          w_pnP    = (float*)         alloc((size_t)N * 128 * 4);
  float*          w_rp     = (float*)         alloc((size_t)E2 * 2 * 4);
  float*          w_AB     = (float*)         alloc((size_t)N * 128 * 4);
  float*          w_Wp     = (float*)         alloc((size_t)64 * 128 * 4);
  unsigned short* w_Bt     = (unsigned short*)alloc((size_t)3 * 1024 * 128 * 2);
  float*          w_bias   = (float*)         alloc((size_t)3 * 1024 * 4);
  unsigned short* w_Bt2    = (unsigned short*)alloc((size_t)3 * 128 * 256 * 2);
  float*          w_bias2  = (float*)         alloc((size_t)3 * 128 * 4);
  unsigned*       w_pmax   = (unsigned*)      alloc(64 * 4);
  float*          w_psum   = (float*)         alloc(64 * 4);
  float*          w_ch     = (float*)         alloc(64 * 4);
  unsigned*       w_pmax2  = (unsigned*)      alloc(64 * 4);
  float*          w_psum2  = (float*)         alloc(64 * 4);
  float*          w_ch2    = (float*)         alloc(64 * 4);

  hipMemsetAsync(w_deg,  0, (size_t)N * 4, stream);
  hipMemsetAsync(w_cur,  0, (size_t)N * 4, stream);
  hipMemsetAsync(w_pmax, 0, 64 * 4, stream);
  hipMemsetAsync(w_psum, 0, 64 * 4, stream);
  hipMemsetAsync(w_pmax2,0, 64 * 4, stream);
  hipMemsetAsync(w_psum2,0, 64 * 4, stream);

  // ---------------- CSR + raw-edge gather + node embedding/CBAM
  k_build_edges<<<(E2 + 255)/256, 256, 0, stream>>>(edge_index, E2, E, w_src, w_dst, w_deg);
  k_scan<<<1, 1024, 0, stream>>>(w_deg, w_rowptr, N);
  k_fill<<<(E2 + 255)/256, 256, 0, stream>>>(w_src, w_dst, w_rowptr, w_cur, w_csrc, w_epos,
                                             x, edge_attr, w_re8, E2, E);
  k_embed_pool<<<512, 256, 0, stream>>>(x, node_w, node_b, z_emb, w_nf, w_pmax, w_psum, N);
  k_cbam_mlp<<<1, 64, 0, stream>>>(w_pmax, w_psum, 1.f/(float)N,
                                   cn_w1, cn_b1, cn_w2, cn_b2, w_ch);
  k_chmul_rowpool<<<(N + 3)/4, 256, 0, stream>>>(w_nf, w_ch, w_rp, N);
  k_spatial<<<(N + 3)/4, 256, 0, stream>>>(w_nf, w_rp, cn_cw, cn_cb, N);

  // ---------------- edge CBAM (streamed) -> ef0 (CSR order) -> agg0 + comb0
  k_ecol<<<2048, 256, 0, stream>>>(w_re8, edge_w, edge_b, w_pmax2, w_psum2, E2);
  k_cbam_mlp<<<1, 64, 0, stream>>>(w_pmax2, w_psum2, 1.f/(float)E2,
                                   ce_w1, ce_b1, ce_w2, ce_b2, w_ch2);
  k_erp2<<<2048, 256, 0, stream>>>(w_re8, w_epos, edge_w, edge_b, w_ch2,
                                   w_rp, w_ef0, E2);
  k_se<<<(E2 + 255)/256, 256, 0, stream>>>(w_rp, w_epos, ce_cw, ce_cb, w_se, E2);
  k_aggb<<<(N + 3)/4, 256, 0, stream>>>(w_ef0, w_se, w_rowptr, w_nf,
                                        lc_g, lc_b, w_agg, w_comb, N);

  // ---------------- pack all iteration weights
  k_packT1<<<dim3(4, 6, 4), 256, 0, stream>>>(Wq, Wk, Wv, Ws, w_Bt);
  k_packT2<<<dim3(1, 12, 2), 256, 0, stream>>>(pn_w, pe_w, w_Bt2);
  k_biasp<<<3, 1024, 0, stream>>>(bq, bk, bv, bs, pn_b, w_bias, w_bias2);
  k_packC<<<32, 256, 0, stream>>>(c_w1, w_Wp);

  // ---------------- message-passing iterations
  const int MB = (N + 127) / 128;
  for (int i = 0; i < 3; ++i){
    k_mfma<1,0><<<dim3(8, MB), 256, 0, stream>>>(w_comb, 128,
                                                 w_Bt + (size_t)i*1024*128, 128,
                                                 w_bias + (size_t)i*1024,
                                                 w_q, w_k, w_v, w_s, N);
    k_attn<<<(N + 3)/4, 256, 0, stream>>>(w_q, w_k, w_v, w_s, w_rowptr, w_csrc,
                                          lt_g + (size_t)i*256, lt_b + (size_t)i*256,
                                          w_outb, N);
    k_mfma<2,1><<<dim3(1, MB), 256, 0, stream>>>(w_outb, 256,
                                                 w_Bt2 + (size_t)i*128*256, 256,
                                                 w_bias2 + (size_t)i*128,
                                                 w_pnP, nullptr, nullptr, nullptr, N);
    int doComb = (i < 2) ? 1 : 0;
    const float* cg  = lc_g + (size_t)(i < 2 ? i+1 : 0)*128;
    const float* cbv = lc_b + (size_t)(i < 2 ? i+1 : 0)*128;
    k_gate_agg<<<1250, 256, 0, stream>>>(w_nf, w_agg, w_pnP, w_rowptr, w_csrc,
                                         gf_w + (size_t)i*128*64, gf_b + (size_t)i*64,
                                         pe_b + (size_t)i*64,
                                         cg, cbv, w_comb, doComb, N);
  }

  // ---------------- classifier (fused A|B GEMM, then edge head)
  dim3 gAB((N + 63)/64, 2);
  k_gemm<64,64><<<gAB, 256, 0, stream>>>(w_nf, w_Wp, 128, nullptr, w_AB, 128, N);
  k_final<<<(E + 3)/4, 256, 0, stream>>>(w_AB, edge_index, c_b1, c_w2, c_b2,
                                         (float*)d_out, E);
}

// Round 7
// 856.223 us; speedup vs baseline: 2.3695x; 1.0034x over previous
//
#include <hip/hip_runtime.h>
#include <math.h>

typedef __attribute__((ext_vector_type(8))) short short8;
typedef __attribute__((ext_vector_type(4))) float f32x4;

// ---------------------------------------------------------------- utilities
__device__ __forceinline__ float wave_sum(float v){
  #pragma unroll
  for (int m = 32; m; m >>= 1) v += __shfl_xor(v, m, 64);
  return v;
}
__device__ __forceinline__ float wave_max(float v){
  #pragma unroll
  for (int m = 32; m; m >>= 1) v = fmaxf(v, __shfl_xor(v, m, 64));
  return v;
}
__device__ __forceinline__ unsigned fenc(float f){
  unsigned u = __float_as_uint(f);
  return (u >> 31) ? ~u : (u | 0x80000000u);
}
__device__ __forceinline__ float fdec(unsigned e){
  return (e >> 31) ? __uint_as_float(e & 0x7fffffffu) : __uint_as_float(~e);
}
__device__ __forceinline__ float sigm(float x){ return 1.f / (1.f + __expf(-x)); }
__device__ __forceinline__ unsigned short f2bf(float f){
  union { float f; unsigned u; } x; x.f = f;
  unsigned r = x.u + 0x7fffu + ((x.u >> 16) & 1u);
  return (unsigned short)(r >> 16);
}
__device__ __forceinline__ float bf2f(unsigned short h){
  union { unsigned u; float f; } x; x.u = ((unsigned)h) << 16;
  return x.f;
}

// ------------------------------------------------------------ CSR building
__global__ void k_build_edges(const int* __restrict__ ei, int E2, int E,
                              int* __restrict__ src, int* __restrict__ dst,
                              int* __restrict__ deg){
  int e = blockIdx.x * blockDim.x + threadIdx.x;
  if (e >= E2) return;
  int s = ei[e];
  int d = (e < E) ? ei[e + E] : ei[e - E];
  src[e] = s; dst[e] = d;
  atomicAdd(&deg[d], 1);
}

__global__ void k_scan(const int* __restrict__ deg, int* __restrict__ rowptr, int N){
  __shared__ int part[1024];
  int t = threadIdx.x;
  int chunk = (N + 1023) / 1024;
  int lo = t * chunk, hi = lo + chunk; if (hi > N) hi = N;
  int s = 0;
  for (int i = lo; i < hi; ++i) s += deg[i];
  part[t] = s;
  __syncthreads();
  for (int off = 1; off < 1024; off <<= 1){
    int v = (t >= off) ? part[t - off] : 0;
    __syncthreads();
    part[t] += v;
    __syncthreads();
  }
  int run = part[t] - s;
  for (int i = lo; i < hi; ++i){ rowptr[i] = run; run += deg[i]; }
  if (t == 1023) rowptr[N] = part[1023];
}

// fill CSR + gather raw edge features once (edge-per-lane, lane-parallel)
__global__ void k_fill(const int* __restrict__ src, const int* __restrict__ dst,
                       const int* __restrict__ rowptr,
                       int* __restrict__ cur, int* __restrict__ csrc,
                       int* __restrict__ epos,
                       const float* __restrict__ x, const float* __restrict__ ea,
                       float* __restrict__ re8, int E2, int E){
  int e = blockIdx.x * blockDim.x + threadIdx.x;
  if (e >= E2) return;
  int s = src[e], d = dst[e];
  int pos = rowptr[d] + atomicAdd(&cur[d], 1);
  csrc[pos] = s;
  epos[e] = pos;
  int row = (e < E) ? e : e - E;
  float4 eav = *reinterpret_cast<const float4*>(ea + (size_t)row*4);
  float r0 = x[s*6]     - x[d*6];
  float r1 = x[s*6 + 1] - x[d*6 + 1];
  float r2 = x[s*6 + 2] - x[d*6 + 2];
  *reinterpret_cast<float4*>(re8 + (size_t)e*8)     = eav;
  *reinterpret_cast<float4*>(re8 + (size_t)e*8 + 4) = make_float4(r0, r1, r2, 0.f);
}

// ------------------------- fused node embedding + column pool (max/mean)
__global__ void k_embed_pool(const float* __restrict__ x, const float* __restrict__ nw,
                             const float* __restrict__ nb, const float* __restrict__ zemb,
                             float* __restrict__ nf,
                             unsigned* __restrict__ pmax, float* __restrict__ psum, int N){
  int tx = threadIdx.x & 63;
  int ty = threadIdx.x >> 6;
  const float allowed[6] = {8.f, 23.f, 39.f, 54.f, 90.f, 180.f};
  float m = -INFINITY, s = 0.f;
  for (int n = blockIdx.x*4 + ty; n < N; n += gridDim.x*4){
    float xv[6];
    #pragma unroll
    for (int k = 0; k < 6; ++k) xv[k] = x[n*6 + k];
    float v = nb[tx];
    #pragma unroll
    for (int k = 0; k < 6; ++k) v += xv[k] * nw[k*64 + tx];
    v = fmaxf(v, 0.f);
    float r = rintf(xv[2]);
    int zi = 0; float bd = fabsf(r - allowed[0]);
    #pragma unroll
    for (int k = 1; k < 6; ++k){ float d = fabsf(r - allowed[k]); if (d < bd){ bd = d; zi = k; } }
    v += zemb[zi*64 + tx];
    nf[(size_t)n*64 + tx] = v;
    m = fmaxf(m, v); s += v;
  }
  __shared__ float sm[4][64], ss[4][64];
  sm[ty][tx] = m; ss[ty][tx] = s;
  __syncthreads();
  if (ty == 0){
    #pragma unroll
    for (int k = 1; k < 4; ++k){ m = fmaxf(m, sm[k][tx]); s += ss[k][tx]; }
    atomicMax(&pmax[tx], fenc(m));
    atomicAdd(&psum[tx], s);
  }
}

// ------------------------------------------------------------------- CBAM MLP
__global__ void k_cbam_mlp(const unsigned* __restrict__ pmax, const float* __restrict__ psum,
                           float invR,
                           const float* __restrict__ w1, const float* __restrict__ b1,
                           const float* __restrict__ w2, const float* __restrict__ b2,
                           float* __restrict__ ch){
  __shared__ float pool[128];
  __shared__ float h[4];
  int t = threadIdx.x;
  pool[t]      = fdec(pmax[t]);
  pool[64 + t] = psum[t] * invR;
  __syncthreads();
  if (t < 4){
    float a = b1[t];
    for (int k = 0; k < 128; ++k) a += pool[k] * w1[k*4 + t];
    h[t] = fmaxf(a, 0.f);
  }
  __syncthreads();
  float a = b2[t];
  #pragma unroll
  for (int k = 0; k < 4; ++k) a += h[k] * w2[k*64 + t];
  ch[t] = sigm(a);
}

__global__ void k_chmul_rowpool(float* __restrict__ buf, const float* __restrict__ ch,
                                float* __restrict__ rp, int R){
  int r = blockIdx.x*4 + (threadIdx.x >> 6);
  if (r >= R) return;
  int l = threadIdx.x & 63;
  float v = buf[(size_t)r*64 + l] * ch[l];
  buf[(size_t)r*64 + l] = v;
  float m = wave_max(v);
  float s = wave_sum(v);
  if (l == 0){ rp[(size_t)r*2] = m; rp[(size_t)r*2 + 1] = s * (1.f/64.f); }
}

__global__ void k_spatial(float* __restrict__ buf, const float* __restrict__ rp,
                          const float* __restrict__ cw, const float* __restrict__ cb, int R){
  int r = blockIdx.x*4 + (threadIdx.x >> 6);
  if (r >= R) return;
  int l = threadIdx.x & 63;
  float sp = cb[0];
  #pragma unroll
  for (int t = 0; t < 7; ++t){
    int rr = r + t - 3;
    if (rr >= 0 && rr < R)
      sp += cw[t] * rp[(size_t)rr*2] + cw[7 + t] * rp[(size_t)rr*2 + 1];
  }
  buf[(size_t)r*64 + l] *= sigm(sp);
}

// --------------- edge column-pool over raw features (streamed via LDS)
__global__ __launch_bounds__(256) void k_ecol(
    const float* __restrict__ re8,
    const float* __restrict__ ew, const float* __restrict__ eb,
    unsigned* __restrict__ pmax, float* __restrict__ psum, int E2){
  __shared__ float s_ew[448];
  __shared__ float s_re[256];
  int tid = threadIdx.x;
  for (int idx = tid; idx < 448; idx += 256) s_ew[idx] = ew[idx];
  int tx = tid & 63, wv = tid >> 6;
  float ebl = eb[tx];
  float m = -INFINITY, s = 0.f;
  for (int base = blockIdx.x*32; base < E2; base += gridDim.x*32){
    __syncthreads();
    int gidx = base*8 + tid;
    s_re[tid] = (gidx < E2*8) ? re8[gidx] : 0.f;
    __syncthreads();
    #pragma unroll
    for (int j = 0; j < 8; ++j){
      int e = base + wv*8 + j;
      if (e >= E2) break;
      const float* r = &s_re[(wv*8 + j)*8];
      float v = ebl;
      #pragma unroll
      for (int k = 0; k < 7; ++k) v += r[k] * s_ew[k*64 + tx];
      v = fmaxf(v, 0.f);
      m = fmaxf(m, v); s += v;
    }
  }
  __shared__ float sm[4][64], ss[4][64];
  sm[wv][tx] = m; ss[wv][tx] = s;
  __syncthreads();
  if (wv == 0){
    #pragma unroll
    for (int k = 1; k < 4; ++k){ m = fmaxf(m, sm[k][tx]); s += ss[k][tx]; }
    atomicMax(&pmax[tx], fenc(m));
    atomicAdd(&psum[tx], s);
  }
}

// ------ edge row-pool + scatter-store ef0=raw*ch (streamed via LDS)
__global__ __launch_bounds__(256) void k_erp2(
    const float* __restrict__ re8, const int* __restrict__ epos,
    const float* __restrict__ ew, const float* __restrict__ eb,
    const float* __restrict__ ch,
    float* __restrict__ rp, float* __restrict__ ef0, int E2){
  __shared__ float s_ew[448];
  __shared__ float s_re[256];
  __shared__ int   s_ep[32];
  int tid = threadIdx.x;
  for (int idx = tid; idx < 448; idx += 256) s_ew[idx] = ew[idx];
  int tx = tid & 63, wv = tid >> 6;
  float ebl = eb[tx], chl = ch[tx];
  for (int base = blockIdx.x*32; base < E2; base += gridDim.x*32){
    __syncthreads();
    int gidx = base*8 + tid;
    s_re[tid] = (gidx < E2*8) ? re8[gidx] : 0.f;
    if (tid < 32 && base + tid < E2) s_ep[tid] = epos[base + tid];
    __syncthreads();
    #pragma unroll
    for (int j = 0; j < 8; ++j){
      int e = base + wv*8 + j;
      if (e >= E2) break;
      const float* r = &s_re[(wv*8 + j)*8];
      float v = ebl;
      #pragma unroll
      for (int k = 0; k < 7; ++k) v += r[k] * s_ew[k*64 + tx];
      v = fmaxf(v, 0.f) * chl;
      float mm = wave_max(v);
      float sm2 = wave_sum(v);
      if (tx == 0){ rp[(size_t)e*2] = mm; rp[(size_t)e*2 + 1] = sm2 * (1.f/64.f); }
      ef0[(size_t)s_ep[wv*8 + j]*64 + tx] = v;
    }
  }
}

// ------------------- per-edge spatial sigmoid, stored in CSR slot
__global__ void k_se(const float* __restrict__ rp, const int* __restrict__ epos,
                     const float* __restrict__ ccw, const float* __restrict__ ccb,
                     float* __restrict__ se, int E2){
  int e = blockIdx.x * blockDim.x + threadIdx.x;
  if (e >= E2) return;
  float sp = ccb[0];
  #pragma unroll
  for (int t = 0; t < 7; ++t){
    int rr = e + t - 3;
    if (rr >= 0 && rr < E2)
      sp += ccw[t] * rp[(size_t)rr*2] + ccw[7+t] * rp[(size_t)rr*2 + 1];
  }
  se[epos[e]] = sigm(sp);
}

// ------------- agg0 = streamed sum(se*ef0) over CSR + fused concat-LN comb0
__global__ void k_aggb(const float* __restrict__ ef0, const float* __restrict__ se,
                       const int* __restrict__ rowptr, const float* __restrict__ nf,
                       const float* __restrict__ g, const float* __restrict__ b,
                       float* __restrict__ agg, unsigned short* __restrict__ comb, int N){
  int n = blockIdx.x*4 + (threadIdx.x >> 6);
  if (n >= N) return;
  int l = threadIdx.x & 63;
  int lo = rowptr[n], hi = rowptr[n+1];
  float acc = 0.f;
  int i = lo;
  for (; i + 4 <= hi; i += 4){
    float s0 = se[i], s1 = se[i+1], s2 = se[i+2], s3 = se[i+3];
    float e0 = ef0[(size_t)i*64 + l];
    float e1 = ef0[(size_t)(i+1)*64 + l];
    float e2 = ef0[(size_t)(i+2)*64 + l];
    float e3 = ef0[(size_t)(i+3)*64 + l];
    acc += s0*e0 + s1*e1 + s2*e2 + s3*e3;
  }
  for (; i < hi; ++i) acc += se[i] * ef0[(size_t)i*64 + l];
  agg[(size_t)n*64 + l] = acc;
  float a = nf[(size_t)n*64 + l];
  float v0 = a, v1 = acc - a;
  float mean = wave_sum(v0 + v1) * (1.f/128.f);
  float d0 = v0 - mean, d1 = v1 - mean;
  float var = wave_sum(d0*d0 + d1*d1) * (1.f/128.f);
  float rs = rsqrtf(var + 1e-5f);
  comb[(size_t)n*128 + l]      = f2bf(d0 * rs * g[l]      + b[l]);
  comb[(size_t)n*128 + 64 + l] = f2bf(d1 * rs * g[64 + l] + b[64 + l]);
}

// ------------------------------- coalesced LDS-transpose weight packs
__global__ __launch_bounds__(256) void k_packT1(
    const float* __restrict__ Wq, const float* __restrict__ Wk,
    const float* __restrict__ Wv, const float* __restrict__ Ws,
    unsigned short* __restrict__ Bt){
  __shared__ float t[64][65];
  int bx = blockIdx.x, by = blockIdx.y, bz = blockIdx.z;
  const float* W = (bz == 0) ? Wq : (bz == 1) ? Wk : (bz == 2) ? Wv : Ws;
  int tx = threadIdx.x & 63, ty = threadIdx.x >> 6;
  int R0 = by*64, C0 = bx*64;
  for (int r = ty; r < 64; r += 4)
    t[r][tx] = W[(size_t)(R0 + r)*256 + C0 + tx];
  __syncthreads();
  int iter = by >> 1, kr0 = (by & 1)*64;
  for (int r = ty; r < 64; r += 4)
    Bt[(size_t)iter*1024*128 + (size_t)(bz*256 + C0 + r)*128 + kr0 + tx] = f2bf(t[tx][r]);
}

__global__ __launch_bounds__(256) void k_packT2(
    const float* __restrict__ Wn, const float* __restrict__ We,
    unsigned short* __restrict__ Bt2){
  __shared__ float t[64][65];
  int by = blockIdx.y, bz = blockIdx.z;
  const float* W = (bz == 0) ? Wn : We;
  int tx = threadIdx.x & 63, ty = threadIdx.x >> 6;
  int R0 = by*64;
  for (int r = ty; r < 64; r += 4)
    t[r][tx] = W[(size_t)(R0 + r)*64 + tx];
  __syncthreads();
  int iter = by >> 2, kr0 = (by & 3)*64;
  for (int r = ty; r < 64; r += 4)
    Bt2[(size_t)iter*128*256 + (size_t)(bz*64 + r)*256 + kr0 + tx] = f2bf(t[tx][r]);
}

__global__ void k_biasp(const float* __restrict__ bq, const float* __restrict__ bk,
                        const float* __restrict__ bv, const float* __restrict__ bs,
                        const float* __restrict__ pnb,
                        float* __restrict__ bias, float* __restrict__ bias2){
  int i = blockIdx.x, t = threadIdx.x;
  const float* bb = (t < 256) ? bq : (t < 512) ? bk : (t < 768) ? bv : bs;
  bias[i*1024 + t] = bb[i*256 + (t & 255)];
  if (t < 64)       bias2[i*128 + t] = pnb[i*64 + t];
  else if (t < 128) bias2[i*128 + t] = 0.f;
}

__global__ void k_packC(const float* __restrict__ cw1, float* __restrict__ Wp){
  int idx = blockIdx.x * blockDim.x + threadIdx.x;
  if (idx >= 64*128) return;
  int k = idx >> 7, j = idx & 127;
  Wp[idx] = (j < 64) ? cw1[k*64 + j] : cw1[(64 + k)*64 + (j - 64)];
}

// ---------------------------------------------------------- MFMA bf16 GEMM
template<int NSTEPS, int MODE>
__global__ __launch_bounds__(256) void k_mfma(
    const unsigned short* __restrict__ A, int lda,
    const unsigned short* __restrict__ Bt, int ldb,
    const float* __restrict__ bias,
    float* __restrict__ o_f0, unsigned short* __restrict__ o_h0,
    unsigned short* __restrict__ o_h1, float* __restrict__ o_f1, int M){
  __shared__ char lds[65536];
  char* ldsA = lds;
  char* ldsB = lds + 32768;
  int tid = threadIdx.x;
  int nbase = blockIdx.x * 128;
  int mbase = blockIdx.y * 128;
  int l = tid & 63, wid = tid >> 6;
  int wm = (wid >> 1) * 64, wn = (wid & 1) * 64;
  f32x4 acc[4][4] = {};
  const char* Ab  = (const char*)A;
  const char* Btb = (const char*)Bt;
  for (int ks = 0; ks < NSTEPS; ++ks){
    #pragma unroll
    for (int it = 0; it < 8; ++it){
      int c = tid + it*256;
      int row = c >> 4;
      int kb = (c & 15) << 4;
      int off = (row << 8) + (kb ^ ((row & 7) << 4));
      uint4 va = make_uint4(0,0,0,0);
      int gr = mbase + row;
      if (gr < M)
        va = *reinterpret_cast<const uint4*>(Ab + (size_t)gr*(lda*2) + ks*256 + kb);
      *reinterpret_cast<uint4*>(ldsA + off) = va;
      uint4 vb = *reinterpret_cast<const uint4*>(
                   Btb + (size_t)(nbase + row)*(ldb*2) + ks*256 + kb);
      *reinterpret_cast<uint4*>(ldsB + off) = vb;
    }
    __syncthreads();
    #pragma unroll
    for (int kk = 0; kk < 4; ++kk){
      int kbyte = kk*64 + (l >> 4)*16;
      short8 af[4], bf[4];
      #pragma unroll
      for (int m = 0; m < 4; ++m){
        int fr = wm + m*16 + (l & 15);
        af[m] = *reinterpret_cast<const short8*>(ldsA + (fr << 8) + (kbyte ^ ((fr & 7) << 4)));
      }
      #pragma unroll
      for (int n = 0; n < 4; ++n){
        int fc = wn + n*16 + (l & 15);
        bf[n] = *reinterpret_cast<const short8*>(ldsB + (fc << 8) + (kbyte ^ ((fc & 7) << 4)));
      }
      #pragma unroll
      for (int m = 0; m < 4; ++m)
        #pragma unroll
        for (int n = 0; n < 4; ++n)
          acc[m][n] = __builtin_amdgcn_mfma_f32_16x16x32_bf16(af[m], bf[n], acc[m][n], 0, 0, 0);
    }
    __syncthreads();
  }
  #pragma unroll
  for (int n = 0; n < 4; ++n){
    int gcol = nbase + wn + n*16 + (l & 15);
    float bv = bias ? bias[gcol] : 0.f;
    #pragma unroll
    for (int m = 0; m < 4; ++m){
      int grow = mbase + wm + m*16 + (l >> 4)*4;
      #pragma unroll
      for (int r = 0; r < 4; ++r){
        int gr = grow + r;
        if (gr < M){
          float val = acc[m][n][r] + bv;
          if (MODE == 1){
            o_f0[(size_t)gr*128 + gcol] = val;
          } else {
            int seg = gcol >> 8, c = gcol & 255;
            if      (seg == 0) o_f0[(size_t)gr*256 + c] = val;
            else if (seg == 1) o_h0[(size_t)gr*256 + c] = f2bf(val);
            else if (seg == 2) o_h1[(size_t)gr*256 + c] = f2bf(val);
            else               o_f1[(size_t)gr*256 + c] = val;
          }
        }
      }
    }
  }
}

// -------------- single-pass fused attention + skip + LN (lane-partitioned)
__global__ void k_attn(const float* __restrict__ q, const unsigned short* __restrict__ kbuf,
                       const unsigned short* __restrict__ vbuf, const float* __restrict__ sbuf,
                       const int* __restrict__ rowptr, const int* __restrict__ csrc,
                       const float* __restrict__ ltg, const float* __restrict__ ltb,
                       unsigned short* __restrict__ outb, int N){
  int n = blockIdx.x*4 + (threadIdx.x >> 6);
  if (n >= N) return;
  int l = threadIdx.x & 63;
  int lo = rowptr[n], hi = rowptr[n+1];
  size_t base = (size_t)n*256 + l*4;
  const int l4 = l*4;
  float4 qv = *reinterpret_cast<const float4*>(q + base);
  qv.x *= 0.125f; qv.y *= 0.125f; qv.z *= 0.125f; qv.w *= 0.125f;
  float o0 = 0.f, o1 = 0.f, o2 = 0.f, o3 = 0.f, s = 0.f;
  int i = lo;
  for (; i + 8 <= hi; i += 8){
    ushort4 kk[8], vv[8];
    #pragma unroll
    for (int j = 0; j < 8; ++j){
      int c = csrc[i + j];
      kk[j] = *reinterpret_cast<const ushort4*>(kbuf + (size_t)c*256 + l4);
      vv[j] = *reinterpret_cast<const ushort4*>(vbuf + (size_t)c*256 + l4);
    }
    float a[8];
    #pragma unroll
    for (int j = 0; j < 8; ++j)
      a[j] = qv.x*bf2f(kk[j].x) + qv.y*bf2f(kk[j].y) + qv.z*bf2f(kk[j].z) + qv.w*bf2f(kk[j].w);
    #pragma unroll
    for (int m = 1; m < 16; m <<= 1){
      #pragma unroll
      for (int j = 0; j < 8; ++j) a[j] += __shfl_xor(a[j], m, 64);
    }
    #pragma unroll
    for (int j = 0; j < 8; ++j){
      float w = __expf(a[j]);
      s += w;
      o0 += w*bf2f(vv[j].x); o1 += w*bf2f(vv[j].y);
      o2 += w*bf2f(vv[j].z); o3 += w*bf2f(vv[j].w);
    }
  }
  for (; i < hi; ++i){
    size_t sb = (size_t)csrc[i]*256 + l4;
    ushort4 kv = *reinterpret_cast<const ushort4*>(kbuf + sb);
    ushort4 vv = *reinterpret_cast<const ushort4*>(vbuf + sb);
    float a = qv.x*bf2f(kv.x) + qv.y*bf2f(kv.y) + qv.z*bf2f(kv.z) + qv.w*bf2f(kv.w);
    #pragma unroll
    for (int m = 1; m < 16; m <<= 1) a += __shfl_xor(a, m, 64);
    float w = __expf(a);
    s += w;
    o0 += w*bf2f(vv.x); o1 += w*bf2f(vv.y); o2 += w*bf2f(vv.z); o3 += w*bf2f(vv.w);
  }
  float4 t = *reinterpret_cast<const float4*>(sbuf + base);
  if (hi > lo){
    float r = 1.f / s;
    t.x += o0*r; t.y += o1*r; t.z += o2*r; t.w += o3*r;
  }
  float mean = wave_sum(t.x + t.y + t.z + t.w) * (1.f/256.f);
  float dx = t.x - mean, dy = t.y - mean, dz = t.z - mean, dw = t.w - mean;
  float var = wave_sum(dx*dx + dy*dy + dz*dz + dw*dw) * (1.f/256.f);
  float rs = rsqrtf(var + 1e-5f);
  float4 g = *reinterpret_cast<const float4*>(ltg + l4);
  float4 b = *reinterpret_cast<const float4*>(ltb + l4);
  ushort4 o;
  o.x = f2bf(dx*rs*g.x + b.x);
  o.y = f2bf(dy*rs*g.y + b.y);
  o.z = f2bf(dz*rs*g.z + b.z);
  o.w = f2bf(dw*rs*g.w + b.w);
  *reinterpret_cast<ushort4*>(outb + base) = o;
}

// ------ gated fusion (nf) + agg-space edge update + NEXT iter's comb-LN
__global__ __launch_bounds__(256) void k_gate_agg(
    float* __restrict__ nf, float* __restrict__ agg,
    const float* __restrict__ pnP,
    const int* __restrict__ rowptr, const int* __restrict__ csrc,
    const float* __restrict__ gfw, const float* __restrict__ gfb,
    const float* __restrict__ peb,
    const float* __restrict__ cg, const float* __restrict__ cbv,
    unsigned short* __restrict__ comb, int doComb, int N){
  __shared__ float s_w[128 * 64];
  int tid = threadIdx.x;
  for (int idx = tid; idx < 128*64; idx += 256) s_w[idx] = gfw[idx];
  __syncthreads();
  int wv = tid >> 6, l = tid & 63;
  float gb = gfb[l], pebl = peb[l];
  for (int n = blockIdx.x*4 + wv; n < N; n += gridDim.x*4){
    float nfv = nf[(size_t)n*64 + l];
    float pnv = pnP[(size_t)n*128 + l];
    float g = gb;
    #pragma unroll 8
    for (int k = 0; k < 64; ++k){
      g += __shfl(nfv, k, 64) * s_w[k*64 + l];
      g += __shfl(pnv, k, 64) * s_w[(64 + k)*64 + l];
    }
    g = sigm(g);
    float nfn = nfv * (1.f + g) + pnv * (1.f - g);
    nf[(size_t)n*64 + l] = nfn;
    int lo = rowptr[n], hi = rowptr[n+1];
    float sp = 0.f;
    int i = lo;
    for (; i + 8 <= hi; i += 8){
      float pv[8];
      #pragma unroll
      for (int j = 0; j < 8; ++j)
        pv[j] = pnP[(size_t)csrc[i+j]*128 + 64 + l];
      #pragma unroll
      for (int j = 0; j < 8; ++j) sp += pv[j];
    }
    for (; i < hi; ++i) sp += pnP[(size_t)csrc[i]*128 + 64 + l];
    float Pn = pnP[(size_t)n*128 + 64 + l];
    float aggn = agg[(size_t)n*64 + l] + sp - (float)(hi - lo) * (Pn - pebl);
    agg[(size_t)n*64 + l] = aggn;
    if (doComb){
      float v0 = nfn, v1 = aggn - nfn;
      float mean = wave_sum(v0 + v1) * (1.f/128.f);
      float d0 = v0 - mean, d1 = v1 - mean;
      float var = wave_sum(d0*d0 + d1*d1) * (1.f/128.f);
      float rs = rsqrtf(var + 1e-5f);
      comb[(size_t)n*128 + l]      = f2bf(d0 * rs * cg[l]      + cbv[l]);
      comb[(size_t)n*128 + 64 + l] = f2bf(d1 * rs * cg[64 + l] + cbv[64 + l]);
    }
  }
}

// ------------------------------------------------------------- classifier
template<int K, int BN>
__global__ __launch_bounds__(256) void k_gemm(
    const float* __restrict__ in, const float* __restrict__ W, int ldw,
    const float* __restrict__ bias, float* __restrict__ out, int ldo, int nrows){
  constexpr int PAD = BN + 4;
  __shared__ float s_in[K * PAD];
  int n0 = blockIdx.x * BN;
  int tid = threadIdx.x;
  for (int idx = tid; idx < BN * K; idx += 256){
    int r = idx / K, k = idx - r * K;
    float v = (n0 + r < nrows) ? in[(size_t)(n0 + r) * K + k] : 0.f;
    s_in[k * PAD + r] = v;
  }
  __syncthreads();
  int tx = tid & 15, ty = tid >> 4;
  constexpr int NT = BN / 16;
  int col0 = blockIdx.y * 64 + tx * 4;
  float acc[NT][4] = {};
  for (int k = 0; k < K; ++k){
    const float4 wv = *reinterpret_cast<const float4*>(&W[(size_t)k * ldw + col0]);
    #pragma unroll
    for (int i = 0; i < NT; ++i){
      float cv = s_in[k * PAD + ty * NT + i];
      acc[i][0] += cv * wv.x;
      acc[i][1] += cv * wv.y;
      acc[i][2] += cv * wv.z;
      acc[i][3] += cv * wv.w;
    }
  }
  #pragma unroll
  for (int i = 0; i < NT; ++i){
    int n = n0 + ty * NT + i;
    if (n < nrows){
      float4 o = make_float4(acc[i][0], acc[i][1], acc[i][2], acc[i][3]);
      *reinterpret_cast<float4*>(&out[(size_t)n * ldo + col0]) = o;
    }
  }
}

__global__ void k_final(const float* __restrict__ AB,
                        const int* __restrict__ ei, const float* __restrict__ cb1,
                        const float* __restrict__ cw2, const float* __restrict__ cb2,
                        float* __restrict__ dout, int E){
  int e = blockIdx.x*4 + (threadIdx.x >> 6);
  if (e >= E) return;
  int l = threadIdx.x & 63;
  int i0 = ei[e], i1 = ei[E + e];
  float h = fmaxf(AB[(size_t)i0*128 + l] + AB[(size_t)i1*128 + 64 + l] + cb1[l], 0.f);
  float p = wave_sum(h * cw2[l]);
  if (l == 0) dout[e] = p + cb2[0];
}

// ===========================================================================
extern "C" void kernel_launch(void* const* d_in, const int* in_sizes, int n_in,
                              void* d_out, int out_size, void* d_ws, size_t ws_size,
                              hipStream_t stream){
  const float* x         = (const float*)d_in[0];
  const float* edge_attr = (const float*)d_in[1];
  const float* node_w    = (const float*)d_in[2];
  const float* node_b    = (const float*)d_in[3];
  const float* edge_w    = (const float*)d_in[4];
  const float* edge_b    = (const float*)d_in[5];
  const float* z_emb     = (const float*)d_in[6];
  const float* cn_w1     = (const float*)d_in[7];
  const float* cn_b1     = (const float*)d_in[8];
  const float* cn_w2     = (const float*)d_in[9];
  const float* cn_b2     = (const float*)d_in[10];
  const float* cn_cw     = (const float*)d_in[11];
  const float* cn_cb     = (const float*)d_in[12];
  const float* ce_w1     = (const float*)d_in[13];
  const float* ce_b1     = (const float*)d_in[14];
  const float* ce_w2     = (const float*)d_in[15];
  const float* ce_b2     = (const float*)d_in[16];
  const float* ce_cw     = (const float*)d_in[17];
  const float* ce_cb     = (const float*)d_in[18];
  const float* Wq        = (const float*)d_in[19];
  const float* bq        = (const float*)d_in[20];
  const float* Wk        = (const float*)d_in[21];
  const float* bk        = (const float*)d_in[22];
  const float* Wv        = (const float*)d_in[23];
  const float* bv        = (const float*)d_in[24];
  const float* Ws        = (const float*)d_in[25];
  const float* bs        = (const float*)d_in[26];
  const float* lt_g      = (const float*)d_in[27];
  const float* lt_b      = (const float*)d_in[28];
  const float* lc_g      = (const float*)d_in[29];
  const float* lc_b      = (const float*)d_in[30];
  const float* pe_w      = (const float*)d_in[31];
  const float* pe_b      = (const float*)d_in[32];
  const float* pn_w      = (const float*)d_in[33];
  const float* pn_b      = (const float*)d_in[34];
  const float* gf_w      = (const float*)d_in[35];
  const float* gf_b      = (const float*)d_in[36];
  const float* c_w1      = (const float*)d_in[37];
  const float* c_b1      = (const float*)d_in[38];
  const float* c_w2      = (const float*)d_in[39];
  const float* c_b2      = (const float*)d_in[40];
  const int*   edge_index= (const int*)d_in[41];

  const int N  = in_sizes[0] / 6;
  const int E  = in_sizes[1] / 4;
  const int E2 = 2 * E;

  // ---------------- workspace layout
  char* p = (char*)d_ws;
  auto alloc = [&](size_t bytes)->char*{
    char* r = p; p += (bytes + 255) & ~(size_t)255; return r;
  };
  int*            w_src    = (int*)           alloc((size_t)E2 * 4);
  int*            w_dst    = (int*)           alloc((size_t)E2 * 4);
  int*            w_deg    = (int*)           alloc((size_t)N * 4);
  int*            w_rowptr = (int*)           alloc((size_t)(N + 1) * 4);
  int*            w_cur    = (int*)           alloc((size_t)N * 4);
  int*            w_csrc   = (int*)           alloc((size_t)E2 * 4);
  int*            w_epos   = (int*)           alloc((size_t)E2 * 4);
  float*          w_re8    = (float*)         alloc((size_t)E2 * 8 * 4);
  float*          w_nf     = (float*)         alloc((size_t)N * 64 * 4);
  float*          w_agg    = (float*)         alloc((size_t)N * 64 * 4);
  float*          w_ef0    = (float*)         alloc((size_t)E2 * 64 * 4);
  float*          w_se     = (float*)         alloc((size_t)E2 * 4);
  unsigned short* w_comb   = (unsigned short*)alloc((size_t)N * 128 * 2);
  float*          w_q      = (float*)         alloc((size_t)N * 256 * 4);
  unsigned short* w_k      = (unsigned short*)alloc((size_t)N * 256 * 2);
  unsigned short* w_v      = (unsigned short*)alloc((size_t)N * 256 * 2);
  float*          w_s      = (float*)         alloc((size_t)N * 256 * 4);
  unsigned short* w_outb   = (unsigned short*)alloc((size_t)N * 256 * 2);
  float*          w_pnP    = (float*)         alloc((size_t)N * 128 * 4);
  float*          w_rp     = (float*)         alloc((size_t)E2 * 2 * 4);
  float*          w_AB     = (float*)         alloc((size_t)N * 128 * 4);
  float*          w_Wp     = (float*)         alloc((size_t)64 * 128 * 4);
  unsigned short* w_Bt     = (unsigned short*)alloc((size_t)3 * 1024 * 128 * 2);
  float*          w_bias   = (float*)         alloc((size_t)3 * 1024 * 4);
  unsigned short* w_Bt2    = (unsigned short*)alloc((size_t)3 * 128 * 256 * 2);
  float*          w_bias2  = (float*)         alloc((size_t)3 * 128 * 4);
  unsigned*       w_pmax   = (unsigned*)      alloc(64 * 4);
  float*          w_psum   = (float*)         alloc(64 * 4);
  float*          w_ch     = (float*)         alloc(64 * 4);
  unsigned*       w_pmax2  = (unsigned*)      alloc(64 * 4);
  float*          w_psum2  = (float*)         alloc(64 * 4);
  float*          w_ch2    = (float*)         alloc(64 * 4);

  hipMemsetAsync(w_deg,  0, (size_t)N * 4, stream);
  hipMemsetAsync(w_cur,  0, (size_t)N * 4, stream);
  hipMemsetAsync(w_pmax, 0, 64 * 4, stream);
  hipMemsetAsync(w_psum, 0, 64 * 4, stream);
  hipMemsetAsync(w_pmax2,0, 64 * 4, stream);
  hipMemsetAsync(w_psum2,0, 64 * 4, stream);

  // ---------------- CSR + raw-edge gather + node embedding/CBAM
  k_build_edges<<<(E2 + 255)/256, 256, 0, stream>>>(edge_index, E2, E, w_src, w_dst, w_deg);
  k_scan<<<1, 1024, 0, stream>>>(w_deg, w_rowptr, N);
  k_fill<<<(E2 + 255)/256, 256, 0, stream>>>(w_src, w_dst, w_rowptr, w_cur, w_csrc, w_epos,
                                             x, edge_attr, w_re8, E2, E);
  k_embed_pool<<<512, 256, 0, stream>>>(x, node_w, node_b, z_emb, w_nf, w_pmax, w_psum, N);
  k_cbam_mlp<<<1, 64, 0, stream>>>(w_pmax, w_psum, 1.f/(float)N,
                                   cn_w1, cn_b1, cn_w2, cn_b2, w_ch);
  k_chmul_rowpool<<<(N + 3)/4, 256, 0, stream>>>(w_nf, w_ch, w_rp, N);
  k_spatial<<<(N + 3)/4, 256, 0, stream>>>(w_nf, w_rp, cn_cw, cn_cb, N);

  // ---------------- edge CBAM (streamed) -> ef0 (CSR order) -> agg0 + comb0
  k_ecol<<<2048, 256, 0, stream>>>(w_re8, edge_w, edge_b, w_pmax2, w_psum2, E2);
  k_cbam_mlp<<<1, 64, 0, stream>>>(w_pmax2, w_psum2, 1.f/(float)E2,
                                   ce_w1, ce_b1, ce_w2, ce_b2, w_ch2);
  k_erp2<<<2048, 256, 0, stream>>>(w_re8, w_epos, edge_w, edge_b, w_ch2,
                                   w_rp, w_ef0, E2);
  k_se<<<(E2 + 255)/256, 256, 0, stream>>>(w_rp, w_epos, ce_cw, ce_cb, w_se, E2);
  k_aggb<<<(N + 3)/4, 256, 0, stream>>>(w_ef0, w_se, w_rowptr, w_nf,
                                        lc_g, lc_b, w_agg, w_comb, N);

  // ---------------- pack all iteration weights
  k_packT1<<<dim3(4, 6, 4), 256, 0, stream>>>(Wq, Wk, Wv, Ws, w_Bt);
  k_packT2<<<dim3(1, 12, 2), 256, 0, stream>>>(pn_w, pe_w, w_Bt2);
  k_biasp<<<3, 1024, 0, stream>>>(bq, bk, bv, bs, pn_b, w_bias, w_bias2);
  k_packC<<<32, 256, 0, stream>>>(c_w1, w_Wp);

  // ---------------- message-passing iterations
  const int MB = (N + 127) / 128;
  for (int i = 0; i < 3; ++i){
    k_mfma<1,0><<<dim3(8, MB), 256, 0, stream>>>(w_comb, 128,
                                                 w_Bt + (size_t)i*1024*128, 128,
                                                 w_bias + (size_t)i*1024,
                                                 w_q, w_k, w_v, w_s, N);
    k_attn<<<(N + 3)/4, 256, 0, stream>>>(w_q, w_k, w_v, w_s, w_rowptr, w_csrc,
                                          lt_g + (size_t)i*256, lt_b + (size_t)i*256,
                                          w_outb, N);
    k_mfma<2,1><<<dim3(1, MB), 256, 0, stream>>>(w_outb, 256,
                                                 w_Bt2 + (size_t)i*128*256, 256,
                                                 w_bias2 + (size_t)i*128,
                                                 w_pnP, nullptr, nullptr, nullptr, N);
    int doComb = (i < 2) ? 1 : 0;
    const float* cg  = lc_g + (size_t)(i < 2 ? i+1 : 0)*128;
    const float* cbv = lc_b + (size_t)(i < 2 ? i+1 : 0)*128;
    k_gate_agg<<<1250, 256, 0, stream>>>(w_nf, w_agg, w_pnP, w_rowptr, w_csrc,
                                         gf_w + (size_t)i*128*64, gf_b + (size_t)i*64,
                                         pe_b + (size_t)i*64,
                                         cg, cbv, w_comb, doComb, N);
  }

  // ---------------- classifier (fused A|B GEMM, then edge head)
  dim3 gAB((N + 63)/64, 2);
  k_gemm<64,64><<<gAB, 256, 0, stream>>>(w_nf, w_Wp, 128, nullptr, w_AB, 128, N);
  k_final<<<(E + 3)/4, 256, 0, stream>>>(w_AB, edge_index, c_b1, c_w2, c_b2,
                                         (float*)d_out, E);
}

// Round 8
// 786.946 us; speedup vs baseline: 2.5781x; 1.0880x over previous
//
#include <hip/hip_runtime.h>
#include <math.h>

typedef __attribute__((ext_vector_type(8))) short short8;
typedef __attribute__((ext_vector_type(4))) float f32x4;

// ---------------------------------------------------------------- utilities
__device__ __forceinline__ float wave_sum(float v){
  #pragma unroll
  for (int m = 32; m; m >>= 1) v += __shfl_xor(v, m, 64);
  return v;
}
__device__ __forceinline__ float wave_max(float v){
  #pragma unroll
  for (int m = 32; m; m >>= 1) v = fmaxf(v, __shfl_xor(v, m, 64));
  return v;
}
__device__ __forceinline__ unsigned fenc(float f){
  unsigned u = __float_as_uint(f);
  return (u >> 31) ? ~u : (u | 0x80000000u);
}
__device__ __forceinline__ float fdec(unsigned e){
  return (e >> 31) ? __uint_as_float(e & 0x7fffffffu) : __uint_as_float(~e);
}
__device__ __forceinline__ float sigm(float x){ return 1.f / (1.f + __expf(-x)); }
__device__ __forceinline__ unsigned short f2bf(float f){
  union { float f; unsigned u; } x; x.f = f;
  unsigned r = x.u + 0x7fffu + ((x.u >> 16) & 1u);
  return (unsigned short)(r >> 16);
}
__device__ __forceinline__ float bf2f(unsigned short h){
  union { unsigned u; float f; } x; x.u = ((unsigned)h) << 16;
  return x.f;
}

// ------------------------------------------------------------ CSR building
__global__ void k_build_edges(const int* __restrict__ ei, int E2, int E,
                              int* __restrict__ src, int* __restrict__ dst,
                              int* __restrict__ deg){
  int e = blockIdx.x * blockDim.x + threadIdx.x;
  if (e >= E2) return;
  int s = ei[e];
  int d = (e < E) ? ei[e + E] : ei[e - E];
  src[e] = s; dst[e] = d;
  atomicAdd(&deg[d], 1);
}

__global__ void k_scan(const int* __restrict__ deg, int* __restrict__ rowptr, int N){
  __shared__ int part[1024];
  int t = threadIdx.x;
  int chunk = (N + 1023) / 1024;
  int lo = t * chunk, hi = lo + chunk; if (hi > N) hi = N;
  int s = 0;
  for (int i = lo; i < hi; ++i) s += deg[i];
  part[t] = s;
  __syncthreads();
  for (int off = 1; off < 1024; off <<= 1){
    int v = (t >= off) ? part[t - off] : 0;
    __syncthreads();
    part[t] += v;
    __syncthreads();
  }
  int run = part[t] - s;
  for (int i = lo; i < hi; ++i){ rowptr[i] = run; run += deg[i]; }
  if (t == 1023) rowptr[N] = part[1023];
}

// fill CSR + gather raw edge features once (edge-per-lane, lane-parallel)
__global__ void k_fill(const int* __restrict__ src, const int* __restrict__ dst,
                       const int* __restrict__ rowptr,
                       int* __restrict__ cur, int* __restrict__ csrc,
                       int* __restrict__ epos,
                       const float* __restrict__ x, const float* __restrict__ ea,
                       float* __restrict__ re8, int E2, int E){
  int e = blockIdx.x * blockDim.x + threadIdx.x;
  if (e >= E2) return;
  int s = src[e], d = dst[e];
  int pos = rowptr[d] + atomicAdd(&cur[d], 1);
  csrc[pos] = s;
  epos[e] = pos;
  int row = (e < E) ? e : e - E;
  float4 eav = *reinterpret_cast<const float4*>(ea + (size_t)row*4);
  float r0 = x[s*6]     - x[d*6];
  float r1 = x[s*6 + 1] - x[d*6 + 1];
  float r2 = x[s*6 + 2] - x[d*6 + 2];
  *reinterpret_cast<float4*>(re8 + (size_t)e*8)     = eav;
  *reinterpret_cast<float4*>(re8 + (size_t)e*8 + 4) = make_float4(r0, r1, r2, 0.f);
}

// ------------------------- fused node embedding + column pool (max/mean)
__global__ void k_embed_pool(const float* __restrict__ x, const float* __restrict__ nw,
                             const float* __restrict__ nb, const float* __restrict__ zemb,
                             float* __restrict__ nf,
                             unsigned* __restrict__ pmax, float* __restrict__ psum, int N){
  int tx = threadIdx.x & 63;
  int ty = threadIdx.x >> 6;
  const float allowed[6] = {8.f, 23.f, 39.f, 54.f, 90.f, 180.f};
  float m = -INFINITY, s = 0.f;
  for (int n = blockIdx.x*4 + ty; n < N; n += gridDim.x*4){
    float xv[6];
    #pragma unroll
    for (int k = 0; k < 6; ++k) xv[k] = x[n*6 + k];
    float v = nb[tx];
    #pragma unroll
    for (int k = 0; k < 6; ++k) v += xv[k] * nw[k*64 + tx];
    v = fmaxf(v, 0.f);
    float r = rintf(xv[2]);
    int zi = 0; float bd = fabsf(r - allowed[0]);
    #pragma unroll
    for (int k = 1; k < 6; ++k){ float d = fabsf(r - allowed[k]); if (d < bd){ bd = d; zi = k; } }
    v += zemb[zi*64 + tx];
    nf[(size_t)n*64 + tx] = v;
    m = fmaxf(m, v); s += v;
  }
  __shared__ float sm[4][64], ss[4][64];
  sm[ty][tx] = m; ss[ty][tx] = s;
  __syncthreads();
  if (ty == 0){
    #pragma unroll
    for (int k = 1; k < 4; ++k){ m = fmaxf(m, sm[k][tx]); s += ss[k][tx]; }
    atomicMax(&pmax[tx], fenc(m));
    atomicAdd(&psum[tx], s);
  }
}

// ------------------------------------------------------------------- CBAM MLP
__global__ void k_cbam_mlp(const unsigned* __restrict__ pmax, const float* __restrict__ psum,
                           float invR,
                           const float* __restrict__ w1, const float* __restrict__ b1,
                           const float* __restrict__ w2, const float* __restrict__ b2,
                           float* __restrict__ ch){
  __shared__ float pool[128];
  __shared__ float h[4];
  int t = threadIdx.x;
  pool[t]      = fdec(pmax[t]);
  pool[64 + t] = psum[t] * invR;
  __syncthreads();
  if (t < 4){
    float a = b1[t];
    for (int k = 0; k < 128; ++k) a += pool[k] * w1[k*4 + t];
    h[t] = fmaxf(a, 0.f);
  }
  __syncthreads();
  float a = b2[t];
  #pragma unroll
  for (int k = 0; k < 4; ++k) a += h[k] * w2[k*64 + t];
  ch[t] = sigm(a);
}

__global__ void k_chmul_rowpool(float* __restrict__ buf, const float* __restrict__ ch,
                                float* __restrict__ rp, int R){
  int r = blockIdx.x*4 + (threadIdx.x >> 6);
  if (r >= R) return;
  int l = threadIdx.x & 63;
  float v = buf[(size_t)r*64 + l] * ch[l];
  buf[(size_t)r*64 + l] = v;
  float m = wave_max(v);
  float s = wave_sum(v);
  if (l == 0){ rp[(size_t)r*2] = m; rp[(size_t)r*2 + 1] = s * (1.f/64.f); }
}

// node spatial (final nf0) + bf16 copy into gin low half (gate GEMM input)
__global__ void k_spatial(float* __restrict__ buf, const float* __restrict__ rp,
                          const float* __restrict__ cw, const float* __restrict__ cb,
                          unsigned short* __restrict__ gin, int R){
  int r = blockIdx.x*4 + (threadIdx.x >> 6);
  if (r >= R) return;
  int l = threadIdx.x & 63;
  float sp = cb[0];
  #pragma unroll
  for (int t = 0; t < 7; ++t){
    int rr = r + t - 3;
    if (rr >= 0 && rr < R)
      sp += cw[t] * rp[(size_t)rr*2] + cw[7 + t] * rp[(size_t)rr*2 + 1];
  }
  float v = buf[(size_t)r*64 + l] * sigm(sp);
  buf[(size_t)r*64 + l] = v;
  gin[(size_t)r*128 + l] = f2bf(v);
}

// --------------- edge column-pool over raw features (streamed via LDS)
__global__ __launch_bounds__(256) void k_ecol(
    const float* __restrict__ re8,
    const float* __restrict__ ew, const float* __restrict__ eb,
    unsigned* __restrict__ pmax, float* __restrict__ psum, int E2){
  __shared__ float s_ew[448];
  __shared__ float s_re[256];
  int tid = threadIdx.x;
  for (int idx = tid; idx < 448; idx += 256) s_ew[idx] = ew[idx];
  int tx = tid & 63, wv = tid >> 6;
  float ebl = eb[tx];
  float m = -INFINITY, s = 0.f;
  for (int base = blockIdx.x*32; base < E2; base += gridDim.x*32){
    __syncthreads();
    int gidx = base*8 + tid;
    s_re[tid] = (gidx < E2*8) ? re8[gidx] : 0.f;
    __syncthreads();
    #pragma unroll
    for (int j = 0; j < 8; ++j){
      int e = base + wv*8 + j;
      if (e >= E2) break;
      const float* r = &s_re[(wv*8 + j)*8];
      float v = ebl;
      #pragma unroll
      for (int k = 0; k < 7; ++k) v += r[k] * s_ew[k*64 + tx];
      v = fmaxf(v, 0.f);
      m = fmaxf(m, v); s += v;
    }
  }
  __shared__ float sm[4][64], ss[4][64];
  sm[wv][tx] = m; ss[wv][tx] = s;
  __syncthreads();
  if (wv == 0){
    #pragma unroll
    for (int k = 1; k < 4; ++k){ m = fmaxf(m, sm[k][tx]); s += ss[k][tx]; }
    atomicMax(&pmax[tx], fenc(m));
    atomicAdd(&psum[tx], s);
  }
}

// ------ edge row-pool + scatter-store ef0=raw*ch (streamed via LDS)
__global__ __launch_bounds__(256) void k_erp2(
    const float* __restrict__ re8, const int* __restrict__ epos,
    const float* __restrict__ ew, const float* __restrict__ eb,
    const float* __restrict__ ch,
    float* __restrict__ rp, float* __restrict__ ef0, int E2){
  __shared__ float s_ew[448];
  __shared__ float s_re[256];
  __shared__ int   s_ep[32];
  int tid = threadIdx.x;
  for (int idx = tid; idx < 448; idx += 256) s_ew[idx] = ew[idx];
  int tx = tid & 63, wv = tid >> 6;
  float ebl = eb[tx], chl = ch[tx];
  for (int base = blockIdx.x*32; base < E2; base += gridDim.x*32){
    __syncthreads();
    int gidx = base*8 + tid;
    s_re[tid] = (gidx < E2*8) ? re8[gidx] : 0.f;
    if (tid < 32 && base + tid < E2) s_ep[tid] = epos[base + tid];
    __syncthreads();
    #pragma unroll
    for (int j = 0; j < 8; ++j){
      int e = base + wv*8 + j;
      if (e >= E2) break;
      const float* r = &s_re[(wv*8 + j)*8];
      float v = ebl;
      #pragma unroll
      for (int k = 0; k < 7; ++k) v += r[k] * s_ew[k*64 + tx];
      v = fmaxf(v, 0.f) * chl;
      float mm = wave_max(v);
      float sm2 = wave_sum(v);
      if (tx == 0){ rp[(size_t)e*2] = mm; rp[(size_t)e*2 + 1] = sm2 * (1.f/64.f); }
      ef0[(size_t)s_ep[wv*8 + j]*64 + tx] = v;
    }
  }
}

// ------------------- per-edge spatial sigmoid, stored in CSR slot
__global__ void k_se(const float* __restrict__ rp, const int* __restrict__ epos,
                     const float* __restrict__ ccw, const float* __restrict__ ccb,
                     float* __restrict__ se, int E2){
  int e = blockIdx.x * blockDim.x + threadIdx.x;
  if (e >= E2) return;
  float sp = ccb[0];
  #pragma unroll
  for (int t = 0; t < 7; ++t){
    int rr = e + t - 3;
    if (rr >= 0 && rr < E2)
      sp += ccw[t] * rp[(size_t)rr*2] + ccw[7+t] * rp[(size_t)rr*2 + 1];
  }
  se[epos[e]] = sigm(sp);
}

// ------------- agg0 = streamed sum(se*ef0) over CSR + fused concat-LN comb0
__global__ void k_aggb(const float* __restrict__ ef0, const float* __restrict__ se,
                       const int* __restrict__ rowptr, const float* __restrict__ nf,
                       const float* __restrict__ g, const float* __restrict__ b,
                       float* __restrict__ agg, unsigned short* __restrict__ comb, int N){
  int n = blockIdx.x*4 + (threadIdx.x >> 6);
  if (n >= N) return;
  int l = threadIdx.x & 63;
  int lo = rowptr[n], hi = rowptr[n+1];
  float acc = 0.f;
  int i = lo;
  for (; i + 4 <= hi; i += 4){
    float s0 = se[i], s1 = se[i+1], s2 = se[i+2], s3 = se[i+3];
    float e0 = ef0[(size_t)i*64 + l];
    float e1 = ef0[(size_t)(i+1)*64 + l];
    float e2 = ef0[(size_t)(i+2)*64 + l];
    float e3 = ef0[(size_t)(i+3)*64 + l];
    acc += s0*e0 + s1*e1 + s2*e2 + s3*e3;
  }
  for (; i < hi; ++i) acc += se[i] * ef0[(size_t)i*64 + l];
  agg[(size_t)n*64 + l] = acc;
  float a = nf[(size_t)n*64 + l];
  float v0 = a, v1 = acc - a;
  float mean = wave_sum(v0 + v1) * (1.f/128.f);
  float d0 = v0 - mean, d1 = v1 - mean;
  float var = wave_sum(d0*d0 + d1*d1) * (1.f/128.f);
  float rs = rsqrtf(var + 1e-5f);
  comb[(size_t)n*128 + l]      = f2bf(d0 * rs * g[l]      + b[l]);
  comb[(size_t)n*128 + 64 + l] = f2bf(d1 * rs * g[64 + l] + b[64 + l]);
}

// ------------------------------- coalesced LDS-transpose weight packs
__global__ __launch_bounds__(256) void k_packT1(
    const float* __restrict__ Wq, const float* __restrict__ Wk,
    const float* __restrict__ Wv, const float* __restrict__ Ws,
    unsigned short* __restrict__ Bt){
  __shared__ float t[64][65];
  int bx = blockIdx.x, by = blockIdx.y, bz = blockIdx.z;
  const float* W = (bz == 0) ? Wq : (bz == 1) ? Wk : (bz == 2) ? Wv : Ws;
  int tx = threadIdx.x & 63, ty = threadIdx.x >> 6;
  int R0 = by*64, C0 = bx*64;
  for (int r = ty; r < 64; r += 4)
    t[r][tx] = W[(size_t)(R0 + r)*256 + C0 + tx];
  __syncthreads();
  int iter = by >> 1, kr0 = (by & 1)*64;
  for (int r = ty; r < 64; r += 4)
    Bt[(size_t)iter*1024*128 + (size_t)(bz*256 + C0 + r)*128 + kr0 + tx] = f2bf(t[tx][r]);
}

__global__ __launch_bounds__(256) void k_packT2(
    const float* __restrict__ Wn, const float* __restrict__ We,
    unsigned short* __restrict__ Bt2){
  __shared__ float t[64][65];
  int by = blockIdx.y, bz = blockIdx.z;
  const float* W = (bz == 0) ? Wn : We;
  int tx = threadIdx.x & 63, ty = threadIdx.x >> 6;
  int R0 = by*64;
  for (int r = ty; r < 64; r += 4)
    t[r][tx] = W[(size_t)(R0 + r)*64 + tx];
  __syncthreads();
  int iter = by >> 2, kr0 = (by & 3)*64;
  for (int r = ty; r < 64; r += 4)
    Bt2[(size_t)iter*128*256 + (size_t)(bz*64 + r)*256 + kr0 + tx] = f2bf(t[tx][r]);
}

// gate weight pack: BtG[i][col][k] = bf16(gf_w[i][k][col]) for col<64 else 0
__global__ void k_packG(const float* __restrict__ gfw, unsigned short* __restrict__ BtG){
  int b = blockIdx.x;              // 3*128: iter*128 + col
  int iter = b >> 7, col = b & 127;
  int k = threadIdx.x;             // 0..127
  unsigned short v = 0;
  if (col < 64) v = f2bf(gfw[(size_t)iter*128*64 + (size_t)k*64 + col]);
  BtG[(size_t)b*128 + k] = v;
}

__global__ void k_biasp(const float* __restrict__ bq, const float* __restrict__ bk,
                        const float* __restrict__ bv, const float* __restrict__ bs,
                        const float* __restrict__ pnb, const float* __restrict__ gfb,
                        float* __restrict__ bias, float* __restrict__ bias2,
                        float* __restrict__ bias3){
  int i = blockIdx.x, t = threadIdx.x;
  const float* bb = (t < 256) ? bq : (t < 512) ? bk : (t < 768) ? bv : bs;
  bias[i*1024 + t] = bb[i*256 + (t & 255)];
  if (t < 64){
    bias2[i*128 + t] = pnb[i*64 + t];
    bias3[i*128 + t] = gfb[i*64 + t];
  } else if (t < 128){
    bias2[i*128 + t] = 0.f;
    bias3[i*128 + t] = 0.f;
  }
}

__global__ void k_packC(const float* __restrict__ cw1, float* __restrict__ Wp){
  int idx = blockIdx.x * blockDim.x + threadIdx.x;
  if (idx >= 64*128) return;
  int k = idx >> 7, j = idx & 127;
  Wp[idx] = (j < 64) ? cw1[k*64 + j] : cw1[(64 + k)*64 + (j - 64)];
}

// ---------------------------------------------------------- MFMA bf16 GEMM
// MODE 0: qkvs (cols 0-255 q f32, 256-511 k bf16, 512-767 v bf16, 768-1023 s f32)
// MODE 1: pnP f32 [M,128]; also writes bf16(pn) to gin[:,64:128] for cols<64
// MODE 2: gate_arg f32 [M,64] (only cols<64 stored)
template<int NSTEPS, int MODE>
__global__ __launch_bounds__(256) void k_mfma(
    const unsigned short* __restrict__ A, int lda,
    const unsigned short* __restrict__ Bt, int ldb,
    const float* __restrict__ bias,
    float* __restrict__ o_f0, unsigned short* __restrict__ o_h0,
    unsigned short* __restrict__ o_h1, float* __restrict__ o_f1, int M){
  __shared__ char lds[65536];
  char* ldsA = lds;
  char* ldsB = lds + 32768;
  int tid = threadIdx.x;
  int nbase = blockIdx.x * 128;
  int mbase = blockIdx.y * 128;
  int l = tid & 63, wid = tid >> 6;
  int wm = (wid >> 1) * 64, wn = (wid & 1) * 64;
  f32x4 acc[4][4] = {};
  const char* Ab  = (const char*)A;
  const char* Btb = (const char*)Bt;
  for (int ks = 0; ks < NSTEPS; ++ks){
    #pragma unroll
    for (int it = 0; it < 8; ++it){
      int c = tid + it*256;
      int row = c >> 4;
      int kb = (c & 15) << 4;
      int off = (row << 8) + (kb ^ ((row & 7) << 4));
      uint4 va = make_uint4(0,0,0,0);
      int gr = mbase + row;
      if (gr < M)
        va = *reinterpret_cast<const uint4*>(Ab + (size_t)gr*(lda*2) + ks*256 + kb);
      *reinterpret_cast<uint4*>(ldsA + off) = va;
      uint4 vb = *reinterpret_cast<const uint4*>(
                   Btb + (size_t)(nbase + row)*(ldb*2) + ks*256 + kb);
      *reinterpret_cast<uint4*>(ldsB + off) = vb;
    }
    __syncthreads();
    #pragma unroll
    for (int kk = 0; kk < 4; ++kk){
      int kbyte = kk*64 + (l >> 4)*16;
      short8 af[4], bf[4];
      #pragma unroll
      for (int m = 0; m < 4; ++m){
        int fr = wm + m*16 + (l & 15);
        af[m] = *reinterpret_cast<const short8*>(ldsA + (fr << 8) + (kbyte ^ ((fr & 7) << 4)));
      }
      #pragma unroll
      for (int n = 0; n < 4; ++n){
        int fc = wn + n*16 + (l & 15);
        bf[n] = *reinterpret_cast<const short8*>(ldsB + (fc << 8) + (kbyte ^ ((fc & 7) << 4)));
      }
      #pragma unroll
      for (int m = 0; m < 4; ++m)
        #pragma unroll
        for (int n = 0; n < 4; ++n)
          acc[m][n] = __builtin_amdgcn_mfma_f32_16x16x32_bf16(af[m], bf[n], acc[m][n], 0, 0, 0);
    }
    __syncthreads();
  }
  #pragma unroll
  for (int n = 0; n < 4; ++n){
    int gcol = nbase + wn + n*16 + (l & 15);
    float bv = bias ? bias[gcol] : 0.f;
    #pragma unroll
    for (int m = 0; m < 4; ++m){
      int grow = mbase + wm + m*16 + (l >> 4)*4;
      #pragma unroll
      for (int r = 0; r < 4; ++r){
        int gr = grow + r;
        if (gr < M){
          float val = acc[m][n][r] + bv;
          if (MODE == 1){
            o_f0[(size_t)gr*128 + gcol] = val;
            if (gcol < 64) o_h0[(size_t)gr*128 + 64 + gcol] = f2bf(val);
          } else if (MODE == 2){
            if (gcol < 64) o_f0[(size_t)gr*64 + gcol] = val;
          } else {
            int seg = gcol >> 8, c = gcol & 255;
            if      (seg == 0) o_f0[(size_t)gr*256 + c] = val;
            else if (seg == 1) o_h0[(size_t)gr*256 + c] = f2bf(val);
            else if (seg == 2) o_h1[(size_t)gr*256 + c] = f2bf(val);
            else               o_f1[(size_t)gr*256 + c] = val;
          }
        }
      }
    }
  }
}

// -------------- single-pass fused attention + skip + LN (lane-partitioned)
__global__ void k_attn(const float* __restrict__ q, const unsigned short* __restrict__ kbuf,
                       const unsigned short* __restrict__ vbuf, const float* __restrict__ sbuf,
                       const int* __restrict__ rowptr, const int* __restrict__ csrc,
                       const float* __restrict__ ltg, const float* __restrict__ ltb,
                       unsigned short* __restrict__ outb, int N){
  int n = blockIdx.x*4 + (threadIdx.x >> 6);
  if (n >= N) return;
  int l = threadIdx.x & 63;
  int lo = rowptr[n], hi = rowptr[n+1];
  size_t base = (size_t)n*256 + l*4;
  const int l4 = l*4;
  float4 qv = *reinterpret_cast<const float4*>(q + base);
  qv.x *= 0.125f; qv.y *= 0.125f; qv.z *= 0.125f; qv.w *= 0.125f;
  float o0 = 0.f, o1 = 0.f, o2 = 0.f, o3 = 0.f, s = 0.f;
  int i = lo;
  for (; i + 8 <= hi; i += 8){
    ushort4 kk[8], vv[8];
    #pragma unroll
    for (int j = 0; j < 8; ++j){
      int c = csrc[i + j];
      kk[j] = *reinterpret_cast<const ushort4*>(kbuf + (size_t)c*256 + l4);
      vv[j] = *reinterpret_cast<const ushort4*>(vbuf + (size_t)c*256 + l4);
    }
    float a[8];
    #pragma unroll
    for (int j = 0; j < 8; ++j)
      a[j] = qv.x*bf2f(kk[j].x) + qv.y*bf2f(kk[j].y) + qv.z*bf2f(kk[j].z) + qv.w*bf2f(kk[j].w);
    #pragma unroll
    for (int m = 1; m < 16; m <<= 1){
      #pragma unroll
      for (int j = 0; j < 8; ++j) a[j] += __shfl_xor(a[j], m, 64);
    }
    #pragma unroll
    for (int j = 0; j < 8; ++j){
      float w = __expf(a[j]);
      s += w;
      o0 += w*bf2f(vv[j].x); o1 += w*bf2f(vv[j].y);
      o2 += w*bf2f(vv[j].z); o3 += w*bf2f(vv[j].w);
    }
  }
  for (; i < hi; ++i){
    size_t sb = (size_t)csrc[i]*256 + l4;
    ushort4 kv = *reinterpret_cast<const ushort4*>(kbuf + sb);
    ushort4 vv = *reinterpret_cast<const ushort4*>(vbuf + sb);
    float a = qv.x*bf2f(kv.x) + qv.y*bf2f(kv.y) + qv.z*bf2f(kv.z) + qv.w*bf2f(kv.w);
    #pragma unroll
    for (int m = 1; m < 16; m <<= 1) a += __shfl_xor(a, m, 64);
    float w = __expf(a);
    s += w;
    o0 += w*bf2f(vv.x); o1 += w*bf2f(vv.y); o2 += w*bf2f(vv.z); o3 += w*bf2f(vv.w);
  }
  float4 t = *reinterpret_cast<const float4*>(sbuf + base);
  if (hi > lo){
    float r = 1.f / s;
    t.x += o0*r; t.y += o1*r; t.z += o2*r; t.w += o3*r;
  }
  float mean = wave_sum(t.x + t.y + t.z + t.w) * (1.f/256.f);
  float dx = t.x - mean, dy = t.y - mean, dz = t.z - mean, dw = t.w - mean;
  float var = wave_sum(dx*dx + dy*dy + dz*dz + dw*dw) * (1.f/256.f);
  float rs = rsqrtf(var + 1e-5f);
  float4 g = *reinterpret_cast<const float4*>(ltg + l4);
  float4 b = *reinterpret_cast<const float4*>(ltb + l4);
  ushort4 o;
  o.x = f2bf(dx*rs*g.x + b.x);
  o.y = f2bf(dy*rs*g.y + b.y);
  o.z = f2bf(dz*rs*g.z + b.z);
  o.w = f2bf(dw*rs*g.w + b.w);
  *reinterpret_cast<ushort4*>(outb + base) = o;
}

// ------ gated fusion (gate precomputed by MFMA) + agg update + comb-LN
__global__ __launch_bounds__(256) void k_gate2(
    float* __restrict__ nf, float* __restrict__ agg,
    const float* __restrict__ pnP, const float* __restrict__ gate_arg,
    const int* __restrict__ rowptr, const int* __restrict__ csrc,
    const float* __restrict__ peb,
    const float* __restrict__ cg, const float* __restrict__ cbv,
    unsigned short* __restrict__ comb, unsigned short* __restrict__ gin,
    int doComb, int N){
  int n = blockIdx.x*4 + (threadIdx.x >> 6);
  if (n >= N) return;
  int l = threadIdx.x & 63;
  float g = sigm(gate_arg[(size_t)n*64 + l]);
  float nfv = nf[(size_t)n*64 + l];
  float pnv = pnP[(size_t)n*128 + l];
  float nfn = nfv * (1.f + g) + pnv * (1.f - g);
  nf[(size_t)n*64 + l] = nfn;
  gin[(size_t)n*128 + l] = f2bf(nfn);
  int lo = rowptr[n], hi = rowptr[n+1];
  float sp = 0.f;
  int i = lo;
  for (; i + 8 <= hi; i += 8){
    float pv[8];
    #pragma unroll
    for (int j = 0; j < 8; ++j)
      pv[j] = pnP[(size_t)csrc[i+j]*128 + 64 + l];
    #pragma unroll
    for (int j = 0; j < 8; ++j) sp += pv[j];
  }
  for (; i < hi; ++i) sp += pnP[(size_t)csrc[i]*128 + 64 + l];
  float Pn = pnP[(size_t)n*128 + 64 + l];
  float aggn = agg[(size_t)n*64 + l] + sp - (float)(hi - lo) * (Pn - peb[l]);
  agg[(size_t)n*64 + l] = aggn;
  if (doComb){
    float v0 = nfn, v1 = aggn - nfn;
    float mean = wave_sum(v0 + v1) * (1.f/128.f);
    float d0 = v0 - mean, d1 = v1 - mean;
    float var = wave_sum(d0*d0 + d1*d1) * (1.f/128.f);
    float rs = rsqrtf(var + 1e-5f);
    comb[(size_t)n*128 + l]      = f2bf(d0 * rs * cg[l]      + cbv[l]);
    comb[(size_t)n*128 + 64 + l] = f2bf(d1 * rs * cg[64 + l] + cbv[64 + l]);
  }
}

// ------------------------------------------------------------- classifier
template<int K, int BN>
__global__ __launch_bounds__(256) void k_gemm(
    const float* __restrict__ in, const float* __restrict__ W, int ldw,
    const float* __restrict__ bias, float* __restrict__ out, int ldo, int nrows){
  constexpr int PAD = BN + 4;
  __shared__ float s_in[K * PAD];
  int n0 = blockIdx.x * BN;
  int tid = threadIdx.x;
  for (int idx = tid; idx < BN * K; idx += 256){
    int r = idx / K, k = idx - r * K;
    float v = (n0 + r < nrows) ? in[(size_t)(n0 + r) * K + k] : 0.f;
    s_in[k * PAD + r] = v;
  }
  __syncthreads();
  int tx = tid & 15, ty = tid >> 4;
  constexpr int NT = BN / 16;
  int col0 = blockIdx.y * 64 + tx * 4;
  float acc[NT][4] = {};
  for (int k = 0; k < K; ++k){
    const float4 wv = *reinterpret_cast<const float4*>(&W[(size_t)k * ldw + col0]);
    #pragma unroll
    for (int i = 0; i < NT; ++i){
      float cv = s_in[k * PAD + ty * NT + i];
      acc[i][0] += cv * wv.x;
      acc[i][1] += cv * wv.y;
      acc[i][2] += cv * wv.z;
      acc[i][3] += cv * wv.w;
    }
  }
  #pragma unroll
  for (int i = 0; i < NT; ++i){
    int n = n0 + ty * NT + i;
    if (n < nrows){
      float4 o = make_float4(acc[i][0], acc[i][1], acc[i][2], acc[i][3]);
      *reinterpret_cast<float4*>(&out[(size_t)n * ldo + col0]) = o;
    }
  }
}

__global__ void k_final(const float* __restrict__ AB,
                        const int* __restrict__ ei, const float* __restrict__ cb1,
                        const float* __restrict__ cw2, const float* __restrict__ cb2,
                        float* __restrict__ dout, int E){
  int e = blockIdx.x*4 + (threadIdx.x >> 6);
  if (e >= E) return;
  int l = threadIdx.x & 63;
  int i0 = ei[e], i1 = ei[E + e];
  float h = fmaxf(AB[(size_t)i0*128 + l] + AB[(size_t)i1*128 + 64 + l] + cb1[l], 0.f);
  float p = wave_sum(h * cw2[l]);
  if (l == 0) dout[e] = p + cb2[0];
}

// ===========================================================================
extern "C" void kernel_launch(void* const* d_in, const int* in_sizes, int n_in,
                              void* d_out, int out_size, void* d_ws, size_t ws_size,
                              hipStream_t stream){
  const float* x         = (const float*)d_in[0];
  const float* edge_attr = (const float*)d_in[1];
  const float* node_w    = (const float*)d_in[2];
  const float* node_b    = (const float*)d_in[3];
  const float* edge_w    = (const float*)d_in[4];
  const float* edge_b    = (const float*)d_in[5];
  const float* z_emb     = (const float*)d_in[6];
  const float* cn_w1     = (const float*)d_in[7];
  const float* cn_b1     = (const float*)d_in[8];
  const float* cn_w2     = (const float*)d_in[9];
  const float* cn_b2     = (const float*)d_in[10];
  const float* cn_cw     = (const float*)d_in[11];
  const float* cn_cb     = (const float*)d_in[12];
  const float* ce_w1     = (const float*)d_in[13];
  const float* ce_b1     = (const float*)d_in[14];
  const float* ce_w2     = (const float*)d_in[15];
  const float* ce_b2     = (const float*)d_in[16];
  const float* ce_cw     = (const float*)d_in[17];
  const float* ce_cb     = (const float*)d_in[18];
  const float* Wq        = (const float*)d_in[19];
  const float* bq        = (const float*)d_in[20];
  const float* Wk        = (const float*)d_in[21];
  const float* bk        = (const float*)d_in[22];
  const float* Wv        = (const float*)d_in[23];
  const float* bv        = (const float*)d_in[24];
  const float* Ws        = (const float*)d_in[25];
  const float* bs        = (const float*)d_in[26];
  const float* lt_g      = (const float*)d_in[27];
  const float* lt_b      = (const float*)d_in[28];
  const float* lc_g      = (const float*)d_in[29];
  const float* lc_b      = (const float*)d_in[30];
  const float* pe_w      = (const float*)d_in[31];
  const float* pe_b      = (const float*)d_in[32];
  const float* pn_w      = (const float*)d_in[33];
  const float* pn_b      = (const float*)d_in[34];
  const float* gf_w      = (const float*)d_in[35];
  const float* gf_b      = (const float*)d_in[36];
  const float* c_w1      = (const float*)d_in[37];
  const float* c_b1      = (const float*)d_in[38];
  const float* c_w2      = (const float*)d_in[39];
  const float* c_b2      = (const float*)d_in[40];
  const int*   edge_index= (const int*)d_in[41];

  const int N  = in_sizes[0] / 6;
  const int E  = in_sizes[1] / 4;
  const int E2 = 2 * E;

  // ---------------- workspace layout
  char* p = (char*)d_ws;
  auto alloc = [&](size_t bytes)->char*{
    char* r = p; p += (bytes + 255) & ~(size_t)255; return r;
  };
  int*            w_src    = (int*)           alloc((size_t)E2 * 4);
  int*            w_dst    = (int*)           alloc((size_t)E2 * 4);
  int*            w_deg    = (int*)           alloc((size_t)N * 4);
  int*            w_rowptr = (int*)           alloc((size_t)(N + 1) * 4);
  int*            w_cur    = (int*)           alloc((size_t)N * 4);
  int*            w_csrc   = (int*)           alloc((size_t)E2 * 4);
  int*            w_epos   = (int*)           alloc((size_t)E2 * 4);
  float*          w_re8    = (float*)         alloc((size_t)E2 * 8 * 4);
  float*          w_nf     = (float*)         alloc((size_t)N * 64 * 4);
  float*          w_agg    = (float*)         alloc((size_t)N * 64 * 4);
  float*          w_ef0    = (float*)         alloc((size_t)E2 * 64 * 4);
  float*          w_se     = (float*)         alloc((size_t)E2 * 4);
  unsigned short* w_comb   = (unsigned short*)alloc((size_t)N * 128 * 2);
  unsigned short* w_gin    = (unsigned short*)alloc((size_t)N * 128 * 2);
  float*          w_gate   = (float*)         alloc((size_t)N * 64 * 4);
  float*          w_q      = (float*)         alloc((size_t)N * 256 * 4);
  unsigned short* w_k      = (unsigned short*)alloc((size_t)N * 256 * 2);
  unsigned short* w_v      = (unsigned short*)alloc((size_t)N * 256 * 2);
  float*          w_s      = (float*)         alloc((size_t)N * 256 * 4);
  unsigned short* w_outb   = (unsigned short*)alloc((size_t)N * 256 * 2);
  float*          w_pnP    = (float*)         alloc((size_t)N * 128 * 4);
  float*          w_rp     = (float*)         alloc((size_t)E2 * 2 * 4);
  float*          w_AB     = (float*)         alloc((size_t)N * 128 * 4);
  float*          w_Wp     = (float*)         alloc((size_t)64 * 128 * 4);
  unsigned short* w_Bt     = (unsigned short*)alloc((size_t)3 * 1024 * 128 * 2);
  float*          w_bias   = (float*)         alloc((size_t)3 * 1024 * 4);
  unsigned short* w_Bt2    = (unsigned short*)alloc((size_t)3 * 128 * 256 * 2);
  float*          w_bias2  = (float*)         alloc((size_t)3 * 128 * 4);
  unsigned short* w_BtG    = (unsigned short*)alloc((size_t)3 * 128 * 128 * 2);
  float*          w_bias3  = (float*)         alloc((size_t)3 * 128 * 4);
  unsigned*       w_pmax   = (unsigned*)      alloc(64 * 4);
  float*          w_psum   = (float*)         alloc(64 * 4);
  float*          w_ch     = (float*)         alloc(64 * 4);
  unsigned*       w_pmax2  = (unsigned*)      alloc(64 * 4);
  float*          w_psum2  = (float*)         alloc(64 * 4);
  float*          w_ch2    = (float*)         alloc(64 * 4);

  hipMemsetAsync(w_deg,  0, (size_t)N * 4, stream);
  hipMemsetAsync(w_cur,  0, (size_t)N * 4, stream);
  hipMemsetAsync(w_pmax, 0, 64 * 4, stream);
  hipMemsetAsync(w_psum, 0, 64 * 4, stream);
  hipMemsetAsync(w_pmax2,0, 64 * 4, stream);
  hipMemsetAsync(w_psum2,0, 64 * 4, stream);

  // ---------------- CSR + raw-edge gather + node embedding/CBAM
  k_build_edges<<<(E2 + 255)/256, 256, 0, stream>>>(edge_index, E2, E, w_src, w_dst, w_deg);
  k_scan<<<1, 1024, 0, stream>>>(w_deg, w_rowptr, N);
  k_fill<<<(E2 + 255)/256, 256, 0, stream>>>(w_src, w_dst, w_rowptr, w_cur, w_csrc, w_epos,
                                             x, edge_attr, w_re8, E2, E);
  k_embed_pool<<<512, 256, 0, stream>>>(x, node_w, node_b, z_emb, w_nf, w_pmax, w_psum, N);
  k_cbam_mlp<<<1, 64, 0, stream>>>(w_pmax, w_psum, 1.f/(float)N,
                                   cn_w1, cn_b1, cn_w2, cn_b2, w_ch);
  k_chmul_rowpool<<<(N + 3)/4, 256, 0, stream>>>(w_nf, w_ch, w_rp, N);
  k_spatial<<<(N + 3)/4, 256, 0, stream>>>(w_nf, w_rp, cn_cw, cn_cb, w_gin, N);

  // ---------------- edge CBAM (streamed) -> ef0 (CSR order) -> agg0 + comb0
  k_ecol<<<2048, 256, 0, stream>>>(w_re8, edge_w, edge_b, w_pmax2, w_psum2, E2);
  k_cbam_mlp<<<1, 64, 0, stream>>>(w_pmax2, w_psum2, 1.f/(float)E2,
                                   ce_w1, ce_b1, ce_w2, ce_b2, w_ch2);
  k_erp2<<<2048, 256, 0, stream>>>(w_re8, w_epos, edge_w, edge_b, w_ch2,
                                   w_rp, w_ef0, E2);
  k_se<<<(E2 + 255)/256, 256, 0, stream>>>(w_rp, w_epos, ce_cw, ce_cb, w_se, E2);
  k_aggb<<<(N + 3)/4, 256, 0, stream>>>(w_ef0, w_se, w_rowptr, w_nf,
                                        lc_g, lc_b, w_agg, w_comb, N);

  // ---------------- pack all iteration weights
  k_packT1<<<dim3(4, 6, 4), 256, 0, stream>>>(Wq, Wk, Wv, Ws, w_Bt);
  k_packT2<<<dim3(1, 12, 2), 256, 0, stream>>>(pn_w, pe_w, w_Bt2);
  k_packG<<<3*128, 128, 0, stream>>>(gf_w, w_BtG);
  k_biasp<<<3, 1024, 0, stream>>>(bq, bk, bv, bs, pn_b, gf_b, w_bias, w_bias2, w_bias3);
  k_packC<<<32, 256, 0, stream>>>(c_w1, w_Wp);

  // ---------------- message-passing iterations
  const int MB = (N + 127) / 128;
  for (int i = 0; i < 3; ++i){
    k_mfma<1,0><<<dim3(8, MB), 256, 0, stream>>>(w_comb, 128,
                                                 w_Bt + (size_t)i*1024*128, 128,
                                                 w_bias + (size_t)i*1024,
                                                 w_q, w_k, w_v, w_s, N);
    k_attn<<<(N + 3)/4, 256, 0, stream>>>(w_q, w_k, w_v, w_s, w_rowptr, w_csrc,
                                          lt_g + (size_t)i*256, lt_b + (size_t)i*256,
                                          w_outb, N);
    k_mfma<2,1><<<dim3(1, MB), 256, 0, stream>>>(w_outb, 256,
                                                 w_Bt2 + (size_t)i*128*256, 256,
                                                 w_bias2 + (size_t)i*128,
                                                 w_pnP, w_gin, nullptr, nullptr, N);
    k_mfma<1,2><<<dim3(1, MB), 256, 0, stream>>>(w_gin, 128,
                                                 w_BtG + (size_t)i*128*128, 128,
                                                 w_bias3 + (size_t)i*128,
                                                 w_gate, nullptr, nullptr, nullptr, N);
    int doComb = (i < 2) ? 1 : 0;
    const float* cg  = lc_g + (size_t)(i < 2 ? i+1 : 0)*128;
    const float* cbv = lc_b + (size_t)(i < 2 ? i+1 : 0)*128;
    k_gate2<<<(N + 3)/4, 256, 0, stream>>>(w_nf, w_agg, w_pnP, w_gate,
                                           w_rowptr, w_csrc,
                                           pe_b + (size_t)i*64,
                                           cg, cbv, w_comb, w_gin, doComb, N);
  }

  // ---------------- classifier (fused A|B GEMM, then edge head)
  dim3 gAB((N + 63)/64, 2);
  k_gemm<64,64><<<gAB, 256, 0, stream>>>(w_nf, w_Wp, 128, nullptr, w_AB, 128, N);
  k_final<<<(E + 3)/4, 256, 0, stream>>>(w_AB, edge_index, c_b1, c_w2, c_b2,
                                         (float*)d_out, E);
}

// Round 9
// 770.543 us; speedup vs baseline: 2.6330x; 1.0213x over previous
//
#include <hip/hip_runtime.h>
#include <math.h>

typedef __attribute__((ext_vector_type(8))) short short8;
typedef __attribute__((ext_vector_type(4))) float f32x4;

// ---------------------------------------------------------------- utilities
__device__ __forceinline__ float wave_sum(float v){
  #pragma unroll
  for (int m = 32; m; m >>= 1) v += __shfl_xor(v, m, 64);
  return v;
}
__device__ __forceinline__ float wave_max(float v){
  #pragma unroll
  for (int m = 32; m; m >>= 1) v = fmaxf(v, __shfl_xor(v, m, 64));
  return v;
}
__device__ __forceinline__ unsigned fenc(float f){
  unsigned u = __float_as_uint(f);
  return (u >> 31) ? ~u : (u | 0x80000000u);
}
__device__ __forceinline__ float fdec(unsigned e){
  return (e >> 31) ? __uint_as_float(e & 0x7fffffffu) : __uint_as_float(~e);
}
__device__ __forceinline__ float sigm(float x){ return 1.f / (1.f + __expf(-x)); }
__device__ __forceinline__ unsigned short f2bf(float f){
  union { float f; unsigned u; } x; x.f = f;
  unsigned r = x.u + 0x7fffu + ((x.u >> 16) & 1u);
  return (unsigned short)(r >> 16);
}
__device__ __forceinline__ float bf2f(unsigned short h){
  union { unsigned u; float f; } x; x.u = ((unsigned)h) << 16;
  return x.f;
}

// ------------------------------------------------------------ CSR building
__global__ void k_build_edges(const int* __restrict__ ei, int E2, int E,
                              int* __restrict__ src, int* __restrict__ dst,
                              int* __restrict__ deg){
  int e = blockIdx.x * blockDim.x + threadIdx.x;
  if (e >= E2) return;
  int s = ei[e];
  int d = (e < E) ? ei[e + E] : ei[e - E];
  src[e] = s; dst[e] = d;
  atomicAdd(&deg[d], 1);
}

__global__ void k_scan(const int* __restrict__ deg, int* __restrict__ rowptr, int N){
  __shared__ int part[1024];
  int t = threadIdx.x;
  int chunk = (N + 1023) / 1024;
  int lo = t * chunk, hi = lo + chunk; if (hi > N) hi = N;
  int s = 0;
  for (int i = lo; i < hi; ++i) s += deg[i];
  part[t] = s;
  __syncthreads();
  for (int off = 1; off < 1024; off <<= 1){
    int v = (t >= off) ? part[t - off] : 0;
    __syncthreads();
    part[t] += v;
    __syncthreads();
  }
  int run = part[t] - s;
  for (int i = lo; i < hi; ++i){ rowptr[i] = run; run += deg[i]; }
  if (t == 1023) rowptr[N] = part[1023];
}

// fill CSR + gather raw edge features once (edge-per-lane, lane-parallel)
__global__ void k_fill(const int* __restrict__ src, const int* __restrict__ dst,
                       const int* __restrict__ rowptr,
                       int* __restrict__ cur, int* __restrict__ csrc,
                       int* __restrict__ epos,
                       const float* __restrict__ x, const float* __restrict__ ea,
                       float* __restrict__ re8, int E2, int E){
  int e = blockIdx.x * blockDim.x + threadIdx.x;
  if (e >= E2) return;
  int s = src[e], d = dst[e];
  int pos = rowptr[d] + atomicAdd(&cur[d], 1);
  csrc[pos] = s;
  epos[e] = pos;
  int row = (e < E) ? e : e - E;
  float4 eav = *reinterpret_cast<const float4*>(ea + (size_t)row*4);
  float r0 = x[s*6]     - x[d*6];
  float r1 = x[s*6 + 1] - x[d*6 + 1];
  float r2 = x[s*6 + 2] - x[d*6 + 2];
  *reinterpret_cast<float4*>(re8 + (size_t)e*8)     = eav;
  *reinterpret_cast<float4*>(re8 + (size_t)e*8 + 4) = make_float4(r0, r1, r2, 0.f);
}

// ------------------------- fused node embedding + column pool (max/mean)
__global__ void k_embed_pool(const float* __restrict__ x, const float* __restrict__ nw,
                             const float* __restrict__ nb, const float* __restrict__ zemb,
                             float* __restrict__ nf,
                             unsigned* __restrict__ pmax, float* __restrict__ psum, int N){
  int tx = threadIdx.x & 63;
  int ty = threadIdx.x >> 6;
  const float allowed[6] = {8.f, 23.f, 39.f, 54.f, 90.f, 180.f};
  float m = -INFINITY, s = 0.f;
  for (int n = blockIdx.x*4 + ty; n < N; n += gridDim.x*4){
    float xv[6];
    #pragma unroll
    for (int k = 0; k < 6; ++k) xv[k] = x[n*6 + k];
    float v = nb[tx];
    #pragma unroll
    for (int k = 0; k < 6; ++k) v += xv[k] * nw[k*64 + tx];
    v = fmaxf(v, 0.f);
    float r = rintf(xv[2]);
    int zi = 0; float bd = fabsf(r - allowed[0]);
    #pragma unroll
    for (int k = 1; k < 6; ++k){ float d = fabsf(r - allowed[k]); if (d < bd){ bd = d; zi = k; } }
    v += zemb[zi*64 + tx];
    nf[(size_t)n*64 + tx] = v;
    m = fmaxf(m, v); s += v;
  }
  __shared__ float sm[4][64], ss[4][64];
  sm[ty][tx] = m; ss[ty][tx] = s;
  __syncthreads();
  if (ty == 0){
    #pragma unroll
    for (int k = 1; k < 4; ++k){ m = fmaxf(m, sm[k][tx]); s += ss[k][tx]; }
    atomicMax(&pmax[tx], fenc(m));
    atomicAdd(&psum[tx], s);
  }
}

// ------------------------------------------------------------------- CBAM MLP
__global__ void k_cbam_mlp(const unsigned* __restrict__ pmax, const float* __restrict__ psum,
                           float invR,
                           const float* __restrict__ w1, const float* __restrict__ b1,
                           const float* __restrict__ w2, const float* __restrict__ b2,
                           float* __restrict__ ch){
  __shared__ float pool[128];
  __shared__ float h[4];
  int t = threadIdx.x;
  pool[t]      = fdec(pmax[t]);
  pool[64 + t] = psum[t] * invR;
  __syncthreads();
  if (t < 4){
    float a = b1[t];
    for (int k = 0; k < 128; ++k) a += pool[k] * w1[k*4 + t];
    h[t] = fmaxf(a, 0.f);
  }
  __syncthreads();
  float a = b2[t];
  #pragma unroll
  for (int k = 0; k < 4; ++k) a += h[k] * w2[k*64 + t];
  ch[t] = sigm(a);
}

__global__ void k_chmul_rowpool(float* __restrict__ buf, const float* __restrict__ ch,
                                float* __restrict__ rp, int R){
  int r = blockIdx.x*4 + (threadIdx.x >> 6);
  if (r >= R) return;
  int l = threadIdx.x & 63;
  float v = buf[(size_t)r*64 + l] * ch[l];
  buf[(size_t)r*64 + l] = v;
  float m = wave_max(v);
  float s = wave_sum(v);
  if (l == 0){ rp[(size_t)r*2] = m; rp[(size_t)r*2 + 1] = s * (1.f/64.f); }
}

// node spatial (final nf0) + bf16 copy into gin low half (gate GEMM input)
__global__ void k_spatial(float* __restrict__ buf, const float* __restrict__ rp,
                          const float* __restrict__ cw, const float* __restrict__ cb,
                          unsigned short* __restrict__ gin, int R){
  int r = blockIdx.x*4 + (threadIdx.x >> 6);
  if (r >= R) return;
  int l = threadIdx.x & 63;
  float sp = cb[0];
  #pragma unroll
  for (int t = 0; t < 7; ++t){
    int rr = r + t - 3;
    if (rr >= 0 && rr < R)
      sp += cw[t] * rp[(size_t)rr*2] + cw[7 + t] * rp[(size_t)rr*2 + 1];
  }
  float v = buf[(size_t)r*64 + l] * sigm(sp);
  buf[(size_t)r*64 + l] = v;
  gin[(size_t)r*128 + l] = f2bf(v);
}

// --------------- edge column-pool over raw features (streamed via LDS)
// NOTE: small grid (256) — epilogue atomics to 64 shared addresses serialize
// per-address; 2048-deep chains cost ~60us, 256-deep ~8us.
__global__ __launch_bounds__(256) void k_ecol(
    const float* __restrict__ re8,
    const float* __restrict__ ew, const float* __restrict__ eb,
    unsigned* __restrict__ pmax, float* __restrict__ psum, int E2){
  __shared__ float s_ew[448];
  __shared__ float s_re[256];
  int tid = threadIdx.x;
  for (int idx = tid; idx < 448; idx += 256) s_ew[idx] = ew[idx];
  int tx = tid & 63, wv = tid >> 6;
  float ebl = eb[tx];
  float m = -INFINITY, s = 0.f;
  for (int base = blockIdx.x*32; base < E2; base += gridDim.x*32){
    __syncthreads();
    int gidx = base*8 + tid;
    s_re[tid] = (gidx < E2*8) ? re8[gidx] : 0.f;
    __syncthreads();
    #pragma unroll
    for (int j = 0; j < 8; ++j){
      int e = base + wv*8 + j;
      if (e >= E2) break;
      const float* r = &s_re[(wv*8 + j)*8];
      float v = ebl;
      #pragma unroll
      for (int k = 0; k < 7; ++k) v += r[k] * s_ew[k*64 + tx];
      v = fmaxf(v, 0.f);
      m = fmaxf(m, v); s += v;
    }
  }
  __shared__ float sm[4][64], ss[4][64];
  sm[wv][tx] = m; ss[wv][tx] = s;
  __syncthreads();
  if (wv == 0){
    #pragma unroll
    for (int k = 1; k < 4; ++k){ m = fmaxf(m, sm[k][tx]); s += ss[k][tx]; }
    atomicMax(&pmax[tx], fenc(m));
    atomicAdd(&psum[tx], s);
  }
}

// ------ edge row-pool + scatter-store ef0=raw*ch (streamed via LDS)
__global__ __launch_bounds__(256) void k_erp2(
    const float* __restrict__ re8, const int* __restrict__ epos,
    const float* __restrict__ ew, const float* __restrict__ eb,
    const float* __restrict__ ch,
    float* __restrict__ rp, float* __restrict__ ef0, int E2){
  __shared__ float s_ew[448];
  __shared__ float s_re[256];
  __shared__ int   s_ep[32];
  int tid = threadIdx.x;
  for (int idx = tid; idx < 448; idx += 256) s_ew[idx] = ew[idx];
  int tx = tid & 63, wv = tid >> 6;
  float ebl = eb[tx], chl = ch[tx];
  for (int base = blockIdx.x*32; base < E2; base += gridDim.x*32){
    __syncthreads();
    int gidx = base*8 + tid;
    s_re[tid] = (gidx < E2*8) ? re8[gidx] : 0.f;
    if (tid < 32 && base + tid < E2) s_ep[tid] = epos[base + tid];
    __syncthreads();
    #pragma unroll
    for (int j = 0; j < 8; ++j){
      int e = base + wv*8 + j;
      if (e >= E2) break;
      const float* r = &s_re[(wv*8 + j)*8];
      float v = ebl;
      #pragma unroll
      for (int k = 0; k < 7; ++k) v += r[k] * s_ew[k*64 + tx];
      v = fmaxf(v, 0.f) * chl;
      float mm = wave_max(v);
      float sm2 = wave_sum(v);
      if (tx == 0){ rp[(size_t)e*2] = mm; rp[(size_t)e*2 + 1] = sm2 * (1.f/64.f); }
      ef0[(size_t)s_ep[wv*8 + j]*64 + tx] = v;
    }
  }
}

// ------------------- per-edge spatial sigmoid, stored in CSR slot
__global__ void k_se(const float* __restrict__ rp, const int* __restrict__ epos,
                     const float* __restrict__ ccw, const float* __restrict__ ccb,
                     float* __restrict__ se, int E2){
  int e = blockIdx.x * blockDim.x + threadIdx.x;
  if (e >= E2) return;
  float sp = ccb[0];
  #pragma unroll
  for (int t = 0; t < 7; ++t){
    int rr = e + t - 3;
    if (rr >= 0 && rr < E2)
      sp += ccw[t] * rp[(size_t)rr*2] + ccw[7+t] * rp[(size_t)rr*2 + 1];
  }
  se[epos[e]] = sigm(sp);
}

// ------------- agg0 = streamed sum(se*ef0) over CSR + fused concat-LN comb0
__global__ void k_aggb(const float* __restrict__ ef0, const float* __restrict__ se,
                       const int* __restrict__ rowptr, const float* __restrict__ nf,
                       const float* __restrict__ g, const float* __restrict__ b,
                       float* __restrict__ agg, unsigned short* __restrict__ comb, int N){
  int n = blockIdx.x*4 + (threadIdx.x >> 6);
  if (n >= N) return;
  int l = threadIdx.x & 63;
  int lo = rowptr[n], hi = rowptr[n+1];
  float acc = 0.f;
  int i = lo;
  for (; i + 4 <= hi; i += 4){
    float s0 = se[i], s1 = se[i+1], s2 = se[i+2], s3 = se[i+3];
    float e0 = ef0[(size_t)i*64 + l];
    float e1 = ef0[(size_t)(i+1)*64 + l];
    float e2 = ef0[(size_t)(i+2)*64 + l];
    float e3 = ef0[(size_t)(i+3)*64 + l];
    acc += s0*e0 + s1*e1 + s2*e2 + s3*e3;
  }
  for (; i < hi; ++i) acc += se[i] * ef0[(size_t)i*64 + l];
  agg[(size_t)n*64 + l] = acc;
  float a = nf[(size_t)n*64 + l];
  float v0 = a, v1 = acc - a;
  float mean = wave_sum(v0 + v1) * (1.f/128.f);
  float d0 = v0 - mean, d1 = v1 - mean;
  float var = wave_sum(d0*d0 + d1*d1) * (1.f/128.f);
  float rs = rsqrtf(var + 1e-5f);
  comb[(size_t)n*128 + l]      = f2bf(d0 * rs * g[l]      + b[l]);
  comb[(size_t)n*128 + 64 + l] = f2bf(d1 * rs * g[64 + l] + b[64 + l]);
}

// ------------------------------- coalesced LDS-transpose weight packs
__global__ __launch_bounds__(256) void k_packT1(
    const float* __restrict__ Wq, const float* __restrict__ Wk,
    const float* __restrict__ Wv, const float* __restrict__ Ws,
    unsigned short* __restrict__ Bt){
  __shared__ float t[64][65];
  int bx = blockIdx.x, by = blockIdx.y, bz = blockIdx.z;
  const float* W = (bz == 0) ? Wq : (bz == 1) ? Wk : (bz == 2) ? Wv : Ws;
  int tx = threadIdx.x & 63, ty = threadIdx.x >> 6;
  int R0 = by*64, C0 = bx*64;
  for (int r = ty; r < 64; r += 4)
    t[r][tx] = W[(size_t)(R0 + r)*256 + C0 + tx];
  __syncthreads();
  int iter = by >> 1, kr0 = (by & 1)*64;
  for (int r = ty; r < 64; r += 4)
    Bt[(size_t)iter*1024*128 + (size_t)(bz*256 + C0 + r)*128 + kr0 + tx] = f2bf(t[tx][r]);
}

__global__ __launch_bounds__(256) void k_packT2(
    const float* __restrict__ Wn, const float* __restrict__ We,
    unsigned short* __restrict__ Bt2){
  __shared__ float t[64][65];
  int by = blockIdx.y, bz = blockIdx.z;
  const float* W = (bz == 0) ? Wn : We;
  int tx = threadIdx.x & 63, ty = threadIdx.x >> 6;
  int R0 = by*64;
  for (int r = ty; r < 64; r += 4)
    t[r][tx] = W[(size_t)(R0 + r)*64 + tx];
  __syncthreads();
  int iter = by >> 2, kr0 = (by & 3)*64;
  for (int r = ty; r < 64; r += 4)
    Bt2[(size_t)iter*128*256 + (size_t)(bz*64 + r)*256 + kr0 + tx] = f2bf(t[tx][r]);
}

// gate weight pack: BtG[i][col][k] = bf16(gf_w[i][k][col]) for col<64 else 0
__global__ void k_packG(const float* __restrict__ gfw, unsigned short* __restrict__ BtG){
  int b = blockIdx.x;              // 3*128: iter*128 + col
  int iter = b >> 7, col = b & 127;
  int k = threadIdx.x;             // 0..127
  unsigned short v = 0;
  if (col < 64) v = f2bf(gfw[(size_t)iter*128*64 + (size_t)k*64 + col]);
  BtG[(size_t)b*128 + k] = v;
}

__global__ void k_biasp(const float* __restrict__ bq, const float* __restrict__ bk,
                        const float* __restrict__ bv, const float* __restrict__ bs,
                        const float* __restrict__ pnb, const float* __restrict__ gfb,
                        float* __restrict__ bias, float* __restrict__ bias2,
                        float* __restrict__ bias3){
  int i = blockIdx.x, t = threadIdx.x;
  const float* bb = (t < 256) ? bq : (t < 512) ? bk : (t < 768) ? bv : bs;
  bias[i*1024 + t] = bb[i*256 + (t & 255)];
  if (t < 64){
    bias2[i*128 + t] = pnb[i*64 + t];
    bias3[i*128 + t] = gfb[i*64 + t];
  } else if (t < 128){
    bias2[i*128 + t] = 0.f;
    bias3[i*128 + t] = 0.f;
  }
}

__global__ void k_packC(const float* __restrict__ cw1, float* __restrict__ Wp){
  int idx = blockIdx.x * blockDim.x + threadIdx.x;
  if (idx >= 64*128) return;
  int k = idx >> 7, j = idx & 127;
  Wp[idx] = (j < 64) ? cw1[k*64 + j] : cw1[(64 + k)*64 + (j - 64)];
}

// ---------------------------------------------------------- MFMA bf16 GEMM
// MODE 0: qkvs (cols 0-255 q f32, 256-511 k bf16, 512-767 v bf16, 768-1023 s f32)
// MODE 1: pnP f32 [M,128]; also writes bf16(pn) to gin[:,64:128] for cols<64
// MODE 2: gate_arg f32 [M,64] (only cols<64 stored)
template<int NSTEPS, int MODE>
__global__ __launch_bounds__(256) void k_mfma(
    const unsigned short* __restrict__ A, int lda,
    const unsigned short* __restrict__ Bt, int ldb,
    const float* __restrict__ bias,
    float* __restrict__ o_f0, unsigned short* __restrict__ o_h0,
    unsigned short* __restrict__ o_h1, float* __restrict__ o_f1, int M){
  __shared__ char lds[65536];
  char* ldsA = lds;
  char* ldsB = lds + 32768;
  int tid = threadIdx.x;
  int nbase = blockIdx.x * 128;
  int mbase = blockIdx.y * 128;
  int l = tid & 63, wid = tid >> 6;
  int wm = (wid >> 1) * 64, wn = (wid & 1) * 64;
  f32x4 acc[4][4] = {};
  const char* Ab  = (const char*)A;
  const char* Btb = (const char*)Bt;
  for (int ks = 0; ks < NSTEPS; ++ks){
    #pragma unroll
    for (int it = 0; it < 8; ++it){
      int c = tid + it*256;
      int row = c >> 4;
      int kb = (c & 15) << 4;
      int off = (row << 8) + (kb ^ ((row & 7) << 4));
      uint4 va = make_uint4(0,0,0,0);
      int gr = mbase + row;
      if (gr < M)
        va = *reinterpret_cast<const uint4*>(Ab + (size_t)gr*(lda*2) + ks*256 + kb);
      *reinterpret_cast<uint4*>(ldsA + off) = va;
      uint4 vb = *reinterpret_cast<const uint4*>(
                   Btb + (size_t)(nbase + row)*(ldb*2) + ks*256 + kb);
      *reinterpret_cast<uint4*>(ldsB + off) = vb;
    }
    __syncthreads();
    #pragma unroll
    for (int kk = 0; kk < 4; ++kk){
      int kbyte = kk*64 + (l >> 4)*16;
      short8 af[4], bf[4];
      #pragma unroll
      for (int m = 0; m < 4; ++m){
        int fr = wm + m*16 + (l & 15);
        af[m] = *reinterpret_cast<const short8*>(ldsA + (fr << 8) + (kbyte ^ ((fr & 7) << 4)));
      }
      #pragma unroll
      for (int n = 0; n < 4; ++n){
        int fc = wn + n*16 + (l & 15);
        bf[n] = *reinterpret_cast<const short8*>(ldsB + (fc << 8) + (kbyte ^ ((fc & 7) << 4)));
      }
      #pragma unroll
      for (int m = 0; m < 4; ++m)
        #pragma unroll
        for (int n = 0; n < 4; ++n)
          acc[m][n] = __builtin_amdgcn_mfma_f32_16x16x32_bf16(af[m], bf[n], acc[m][n], 0, 0, 0);
    }
    __syncthreads();
  }
  #pragma unroll
  for (int n = 0; n < 4; ++n){
    int gcol = nbase + wn + n*16 + (l & 15);
    float bv = bias ? bias[gcol] : 0.f;
    #pragma unroll
    for (int m = 0; m < 4; ++m){
      int grow = mbase + wm + m*16 + (l >> 4)*4;
      #pragma unroll
      for (int r = 0; r < 4; ++r){
        int gr = grow + r;
        if (gr < M){
          float val = acc[m][n][r] + bv;
          if (MODE == 1){
            o_f0[(size_t)gr*128 + gcol] = val;
            if (gcol < 64) o_h0[(size_t)gr*128 + 64 + gcol] = f2bf(val);
          } else if (MODE == 2){
            if (gcol < 64) o_f0[(size_t)gr*64 + gcol] = val;
          } else {
            int seg = gcol >> 8, c = gcol & 255;
            if      (seg == 0) o_f0[(size_t)gr*256 + c] = val;
            else if (seg == 1) o_h0[(size_t)gr*256 + c] = f2bf(val);
            else if (seg == 2) o_h1[(size_t)gr*256 + c] = f2bf(val);
            else               o_f1[(size_t)gr*256 + c] = val;
          }
        }
      }
    }
  }
}

// -------------- single-pass fused attention + skip + LN (lane-partitioned)
__global__ void k_attn(const float* __restrict__ q, const unsigned short* __restrict__ kbuf,
                       const unsigned short* __restrict__ vbuf, const float* __restrict__ sbuf,
                       const int* __restrict__ rowptr, const int* __restrict__ csrc,
                       const float* __restrict__ ltg, const float* __restrict__ ltb,
                       unsigned short* __restrict__ outb, int N){
  int n = blockIdx.x*4 + (threadIdx.x >> 6);
  if (n >= N) return;
  int l = threadIdx.x & 63;
  int lo = rowptr[n], hi = rowptr[n+1];
  size_t base = (size_t)n*256 + l*4;
  const int l4 = l*4;
  float4 qv = *reinterpret_cast<const float4*>(q + base);
  qv.x *= 0.125f; qv.y *= 0.125f; qv.z *= 0.125f; qv.w *= 0.125f;
  float o0 = 0.f, o1 = 0.f, o2 = 0.f, o3 = 0.f, s = 0.f;
  int i = lo;
  for (; i + 8 <= hi; i += 8){
    ushort4 kk[8], vv[8];
    #pragma unroll
    for (int j = 0; j < 8; ++j){
      int c = csrc[i + j];
      kk[j] = *reinterpret_cast<const ushort4*>(kbuf + (size_t)c*256 + l4);
      vv[j] = *reinterpret_cast<const ushort4*>(vbuf + (size_t)c*256 + l4);
    }
    float a[8];
    #pragma unroll
    for (int j = 0; j < 8; ++j)
      a[j] = qv.x*bf2f(kk[j].x) + qv.y*bf2f(kk[j].y) + qv.z*bf2f(kk[j].z) + qv.w*bf2f(kk[j].w);
    #pragma unroll
    for (int m = 1; m < 16; m <<= 1){
      #pragma unroll
      for (int j = 0; j < 8; ++j) a[j] += __shfl_xor(a[j], m, 64);
    }
    #pragma unroll
    for (int j = 0; j < 8; ++j){
      float w = __expf(a[j]);
      s += w;
      o0 += w*bf2f(vv[j].x); o1 += w*bf2f(vv[j].y);
      o2 += w*bf2f(vv[j].z); o3 += w*bf2f(vv[j].w);
    }
  }
  for (; i < hi; ++i){
    size_t sb = (size_t)csrc[i]*256 + l4;
    ushort4 kv = *reinterpret_cast<const ushort4*>(kbuf + sb);
    ushort4 vv = *reinterpret_cast<const ushort4*>(vbuf + sb);
    float a = qv.x*bf2f(kv.x) + qv.y*bf2f(kv.y) + qv.z*bf2f(kv.z) + qv.w*bf2f(kv.w);
    #pragma unroll
    for (int m = 1; m < 16; m <<= 1) a += __shfl_xor(a, m, 64);
    float w = __expf(a);
    s += w;
    o0 += w*bf2f(vv.x); o1 += w*bf2f(vv.y); o2 += w*bf2f(vv.z); o3 += w*bf2f(vv.w);
  }
  float4 t = *reinterpret_cast<const float4*>(sbuf + base);
  if (hi > lo){
    float r = 1.f / s;
    t.x += o0*r; t.y += o1*r; t.z += o2*r; t.w += o3*r;
  }
  float mean = wave_sum(t.x + t.y + t.z + t.w) * (1.f/256.f);
  float dx = t.x - mean, dy = t.y - mean, dz = t.z - mean, dw = t.w - mean;
  float var = wave_sum(dx*dx + dy*dy + dz*dz + dw*dw) * (1.f/256.f);
  float rs = rsqrtf(var + 1e-5f);
  float4 g = *reinterpret_cast<const float4*>(ltg + l4);
  float4 b = *reinterpret_cast<const float4*>(ltb + l4);
  ushort4 o;
  o.x = f2bf(dx*rs*g.x + b.x);
  o.y = f2bf(dy*rs*g.y + b.y);
  o.z = f2bf(dz*rs*g.z + b.z);
  o.w = f2bf(dw*rs*g.w + b.w);
  *reinterpret_cast<ushort4*>(outb + base) = o;
}

// ------ gated fusion (gate precomputed by MFMA) + agg update + comb-LN
__global__ __launch_bounds__(256) void k_gate2(
    float* __restrict__ nf, float* __restrict__ agg,
    const float* __restrict__ pnP, const float* __restrict__ gate_arg,
    const int* __restrict__ rowptr, const int* __restrict__ csrc,
    const float* __restrict__ peb,
    const float* __restrict__ cg, const float* __restrict__ cbv,
    unsigned short* __restrict__ comb, unsigned short* __restrict__ gin,
    int doComb, int N){
  int n = blockIdx.x*4 + (threadIdx.x >> 6);
  if (n >= N) return;
  int l = threadIdx.x & 63;
  float g = sigm(gate_arg[(size_t)n*64 + l]);
  float nfv = nf[(size_t)n*64 + l];
  float pnv = pnP[(size_t)n*128 + l];
  float nfn = nfv * (1.f + g) + pnv * (1.f - g);
  nf[(size_t)n*64 + l] = nfn;
  gin[(size_t)n*128 + l] = f2bf(nfn);
  int lo = rowptr[n], hi = rowptr[n+1];
  float sp = 0.f;
  int i = lo;
  for (; i + 8 <= hi; i += 8){
    float pv[8];
    #pragma unroll
    for (int j = 0; j < 8; ++j)
      pv[j] = pnP[(size_t)csrc[i+j]*128 + 64 + l];
    #pragma unroll
    for (int j = 0; j < 8; ++j) sp += pv[j];
  }
  for (; i < hi; ++i) sp += pnP[(size_t)csrc[i]*128 + 64 + l];
  float Pn = pnP[(size_t)n*128 + 64 + l];
  float aggn = agg[(size_t)n*64 + l] + sp - (float)(hi - lo) * (Pn - peb[l]);
  agg[(size_t)n*64 + l] = aggn;
  if (doComb){
    float v0 = nfn, v1 = aggn - nfn;
    float mean = wave_sum(v0 + v1) * (1.f/128.f);
    float d0 = v0 - mean, d1 = v1 - mean;
    float var = wave_sum(d0*d0 + d1*d1) * (1.f/128.f);
    float rs = rsqrtf(var + 1e-5f);
    comb[(size_t)n*128 + l]      = f2bf(d0 * rs * cg[l]      + cbv[l]);
    comb[(size_t)n*128 + 64 + l] = f2bf(d1 * rs * cg[64 + l] + cbv[64 + l]);
  }
}

// ------------------------------------------------------------- classifier
template<int K, int BN>
__global__ __launch_bounds__(256) void k_gemm(
    const float* __restrict__ in, const float* __restrict__ W, int ldw,
    const float* __restrict__ bias, float* __restrict__ out, int ldo, int nrows){
  constexpr int PAD = BN + 4;
  __shared__ float s_in[K * PAD];
  int n0 = blockIdx.x * BN;
  int tid = threadIdx.x;
  for (int idx = tid; idx < BN * K; idx += 256){
    int r = idx / K, k = idx - r * K;
    float v = (n0 + r < nrows) ? in[(size_t)(n0 + r) * K + k] : 0.f;
    s_in[k * PAD + r] = v;
  }
  __syncthreads();
  int tx = tid & 15, ty = tid >> 4;
  constexpr int NT = BN / 16;
  int col0 = blockIdx.y * 64 + tx * 4;
  float acc[NT][4] = {};
  for (int k = 0; k < K; ++k){
    const float4 wv = *reinterpret_cast<const float4*>(&W[(size_t)k * ldw + col0]);
    #pragma unroll
    for (int i = 0; i < NT; ++i){
      float cv = s_in[k * PAD + ty * NT + i];
      acc[i][0] += cv * wv.x;
      acc[i][1] += cv * wv.y;
      acc[i][2] += cv * wv.z;
      acc[i][3] += cv * wv.w;
    }
  }
  #pragma unroll
  for (int i = 0; i < NT; ++i){
    int n = n0 + ty * NT + i;
    if (n < nrows){
      float4 o = make_float4(acc[i][0], acc[i][1], acc[i][2], acc[i][3]);
      *reinterpret_cast<float4*>(&out[(size_t)n * ldo + col0]) = o;
    }
  }
}

__global__ void k_final(const float* __restrict__ AB,
                        const int* __restrict__ ei, const float* __restrict__ cb1,
                        const float* __restrict__ cw2, const float* __restrict__ cb2,
                        float* __restrict__ dout, int E){
  int e = blockIdx.x*4 + (threadIdx.x >> 6);
  if (e >= E) return;
  int l = threadIdx.x & 63;
  int i0 = ei[e], i1 = ei[E + e];
  float h = fmaxf(AB[(size_t)i0*128 + l] + AB[(size_t)i1*128 + 64 + l] + cb1[l], 0.f);
  float p = wave_sum(h * cw2[l]);
  if (l == 0) dout[e] = p + cb2[0];
}

// ===========================================================================
extern "C" void kernel_launch(void* const* d_in, const int* in_sizes, int n_in,
                              void* d_out, int out_size, void* d_ws, size_t ws_size,
                              hipStream_t stream){
  const float* x         = (const float*)d_in[0];
  const float* edge_attr = (const float*)d_in[1];
  const float* node_w    = (const float*)d_in[2];
  const float* node_b    = (const float*)d_in[3];
  const float* edge_w    = (const float*)d_in[4];
  const float* edge_b    = (const float*)d_in[5];
  const float* z_emb     = (const float*)d_in[6];
  const float* cn_w1     = (const float*)d_in[7];
  const float* cn_b1     = (const float*)d_in[8];
  const float* cn_w2     = (const float*)d_in[9];
  const float* cn_b2     = (const float*)d_in[10];
  const float* cn_cw     = (const float*)d_in[11];
  const float* cn_cb     = (const float*)d_in[12];
  const float* ce_w1     = (const float*)d_in[13];
  const float* ce_b1     = (const float*)d_in[14];
  const float* ce_w2     = (const float*)d_in[15];
  const float* ce_b2     = (const float*)d_in[16];
  const float* ce_cw     = (const float*)d_in[17];
  const float* ce_cb     = (const float*)d_in[18];
  const float* Wq        = (const float*)d_in[19];
  const float* bq        = (const float*)d_in[20];
  const float* Wk        = (const float*)d_in[21];
  const float* bk        = (const float*)d_in[22];
  const float* Wv        = (const float*)d_in[23];
  const float* bv        = (const float*)d_in[24];
  const float* Ws        = (const float*)d_in[25];
  const float* bs        = (const float*)d_in[26];
  const float* lt_g      = (const float*)d_in[27];
  const float* lt_b      = (const float*)d_in[28];
  const float* lc_g      = (const float*)d_in[29];
  const float* lc_b      = (const float*)d_in[30];
  const float* pe_w      = (const float*)d_in[31];
  const float* pe_b      = (const float*)d_in[32];
  const float* pn_w      = (const float*)d_in[33];
  const float* pn_b      = (const float*)d_in[34];
  const float* gf_w      = (const float*)d_in[35];
  const float* gf_b      = (const float*)d_in[36];
  const float* c_w1      = (const float*)d_in[37];
  const float* c_b1      = (const float*)d_in[38];
  const float* c_w2      = (const float*)d_in[39];
  const float* c_b2      = (const float*)d_in[40];
  const int*   edge_index= (const int*)d_in[41];

  const int N  = in_sizes[0] / 6;
  const int E  = in_sizes[1] / 4;
  const int E2 = 2 * E;

  // ---------------- workspace layout
  char* p = (char*)d_ws;
  auto alloc = [&](size_t bytes)->char*{
    char* r = p; p += (bytes + 255) & ~(size_t)255; return r;
  };
  // --- zero-init region (one memset covers all of these, incl. padding) ---
  char* zbase = p;
  int*            w_deg    = (int*)           alloc((size_t)N * 4);
  int*            w_cur    = (int*)           alloc((size_t)N * 4);
  unsigned*       w_pmax   = (unsigned*)      alloc(64 * 4);
  float*          w_psum   = (float*)         alloc(64 * 4);
  unsigned*       w_pmax2  = (unsigned*)      alloc(64 * 4);
  float*          w_psum2  = (float*)         alloc(64 * 4);
  size_t zbytes = (size_t)(p - zbase);
  // --- rest ---
  int*            w_src    = (int*)           alloc((size_t)E2 * 4);
  int*            w_dst    = (int*)           alloc((size_t)E2 * 4);
  int*            w_rowptr = (int*)           alloc((size_t)(N + 1) * 4);
  int*            w_csrc   = (int*)           alloc((size_t)E2 * 4);
  int*            w_epos   = (int*)           alloc((size_t)E2 * 4);
  float*          w_re8    = (float*)         alloc((size_t)E2 * 8 * 4);
  float*          w_nf     = (float*)         alloc((size_t)N * 64 * 4);
  float*          w_agg    = (float*)         alloc((size_t)N * 64 * 4);
  float*          w_ef0    = (float*)         alloc((size_t)E2 * 64 * 4);
  float*          w_se     = (float*)         alloc((size_t)E2 * 4);
  unsigned short* w_comb   = (unsigned short*)alloc((size_t)N * 128 * 2);
  unsigned short* w_gin    = (unsigned short*)alloc((size_t)N * 128 * 2);
  float*          w_gate   = (float*)         alloc((size_t)N * 64 * 4);
  float*          w_q      = (float*)         alloc((size_t)N * 256 * 4);
  unsigned short* w_k      = (unsigned short*)alloc((size_t)N * 256 * 2);
  unsigned short* w_v      = (unsigned short*)alloc((size_t)N * 256 * 2);
  float*          w_s      = (float*)         alloc((size_t)N * 256 * 4);
  unsigned short* w_outb   = (unsigned short*)alloc((size_t)N * 256 * 2);
  float*          w_pnP    = (float*)         alloc((size_t)N * 128 * 4);
  float*          w_rp     = (float*)         alloc((size_t)E2 * 2 * 4);
  float*          w_AB     = (float*)         alloc((size_t)N * 128 * 4);
  float*          w_Wp     = (float*)         alloc((size_t)64 * 128 * 4);
  unsigned short* w_Bt     = (unsigned short*)alloc((size_t)3 * 1024 * 128 * 2);
  float*          w_bias   = (float*)         alloc((size_t)3 * 1024 * 4);
  unsigned short* w_Bt2    = (unsigned short*)alloc((size_t)3 * 128 * 256 * 2);
  float*          w_bias2  = (float*)         alloc((size_t)3 * 128 * 4);
  unsigned short* w_BtG    = (unsigned short*)alloc((size_t)3 * 128 * 128 * 2);
  float*          w_bias3  = (float*)         alloc((size_t)3 * 128 * 4);
  float*          w_ch     = (float*)         alloc(64 * 4);
  float*          w_ch2    = (float*)         alloc(64 * 4);

  hipMemsetAsync(zbase, 0, zbytes, stream);

  // ---------------- CSR + raw-edge gather + node embedding/CBAM
  k_build_edges<<<(E2 + 255)/256, 256, 0, stream>>>(edge_index, E2, E, w_src, w_dst, w_deg);
  k_scan<<<1, 1024, 0, stream>>>(w_deg, w_rowptr, N);
  k_fill<<<(E2 + 255)/256, 256, 0, stream>>>(w_src, w_dst, w_rowptr, w_cur, w_csrc, w_epos,
                                             x, edge_attr, w_re8, E2, E);
  k_embed_pool<<<256, 256, 0, stream>>>(x, node_w, node_b, z_emb, w_nf, w_pmax, w_psum, N);
  k_cbam_mlp<<<1, 64, 0, stream>>>(w_pmax, w_psum, 1.f/(float)N,
                                   cn_w1, cn_b1, cn_w2, cn_b2, w_ch);
  k_chmul_rowpool<<<(N + 3)/4, 256, 0, stream>>>(w_nf, w_ch, w_rp, N);
  k_spatial<<<(N + 3)/4, 256, 0, stream>>>(w_nf, w_rp, cn_cw, cn_cb, w_gin, N);

  // ---------------- edge CBAM (streamed) -> ef0 (CSR order) -> agg0 + comb0
  k_ecol<<<256, 256, 0, stream>>>(w_re8, edge_w, edge_b, w_pmax2, w_psum2, E2);
  k_cbam_mlp<<<1, 64, 0, stream>>>(w_pmax2, w_psum2, 1.f/(float)E2,
                                   ce_w1, ce_b1, ce_w2, ce_b2, w_ch2);
  k_erp2<<<2048, 256, 0, stream>>>(w_re8, w_epos, edge_w, edge_b, w_ch2,
                                   w_rp, w_ef0, E2);
  k_se<<<(E2 + 255)/256, 256, 0, stream>>>(w_rp, w_epos, ce_cw, ce_cb, w_se, E2);
  k_aggb<<<(N + 3)/4, 256, 0, stream>>>(w_ef0, w_se, w_rowptr, w_nf,
                                        lc_g, lc_b, w_agg, w_comb, N);

  // ---------------- pack all iteration weights
  k_packT1<<<dim3(4, 6, 4), 256, 0, stream>>>(Wq, Wk, Wv, Ws, w_Bt);
  k_packT2<<<dim3(1, 12, 2), 256, 0, stream>>>(pn_w, pe_w, w_Bt2);
  k_packG<<<3*128, 128, 0, stream>>>(gf_w, w_BtG);
  k_biasp<<<3, 1024, 0, stream>>>(bq, bk, bv, bs, pn_b, gf_b, w_bias, w_bias2, w_bias3);
  k_packC<<<32, 256, 0, stream>>>(c_w1, w_Wp);

  // ---------------- message-passing iterations
  const int MB = (N + 127) / 128;
  for (int i = 0; i < 3; ++i){
    k_mfma<1,0><<<dim3(8, MB), 256, 0, stream>>>(w_comb, 128,
                                                 w_Bt + (size_t)i*1024*128, 128,
                                                 w_bias + (size_t)i*1024,
                                                 w_q, w_k, w_v, w_s, N);
    k_attn<<<(N + 3)/4, 256, 0, stream>>>(w_q, w_k, w_v, w_s, w_rowptr, w_csrc,
                                          lt_g + (size_t)i*256, lt_b + (size_t)i*256,
                                          w_outb, N);
    k_mfma<2,1><<<dim3(1, MB), 256, 0, stream>>>(w_outb, 256,
                                                 w_Bt2 + (size_t)i*128*256, 256,
                                                 w_bias2 + (size_t)i*128,
                                                 w_pnP, w_gin, nullptr, nullptr, N);
    k_mfma<1,2><<<dim3(1, MB), 256, 0, stream>>>(w_gin, 128,
                                                 w_BtG + (size_t)i*128*128, 128,
                                                 w_bias3 + (size_t)i*128,
                                                 w_gate, nullptr, nullptr, nullptr, N);
    int doComb = (i < 2) ? 1 : 0;
    const float* cg  = lc_g + (size_t)(i < 2 ? i+1 : 0)*128;
    const float* cbv = lc_b + (size_t)(i < 2 ? i+1 : 0)*128;
    k_gate2<<<(N + 3)/4, 256, 0, stream>>>(w_nf, w_agg, w_pnP, w_gate,
                                           w_rowptr, w_csrc,
                                           pe_b + (size_t)i*64,
                                           cg, cbv, w_comb, w_gin, doComb, N);
  }

  // ---------------- classifier (fused A|B GEMM, then edge head)
  dim3 gAB((N + 63)/64, 2);
  k_gemm<64,64><<<gAB, 256, 0, stream>>>(w_nf, w_Wp, 128, nullptr, w_AB, 128, N);
  k_final<<<(E + 3)/4, 256, 0, stream>>>(w_AB, edge_index, c_b1, c_w2, c_b2,
                                         (float*)d_out, E);
}

// Round 10
// 753.892 us; speedup vs baseline: 2.6912x; 1.0221x over previous
//
#include <hip/hip_runtime.h>
#include <math.h>

typedef __attribute__((ext_vector_type(8))) short short8;
typedef __attribute__((ext_vector_type(4))) float f32x4;

// ---------------------------------------------------------------- utilities
__device__ __forceinline__ float wave_sum(float v){
  #pragma unroll
  for (int m = 32; m; m >>= 1) v += __shfl_xor(v, m, 64);
  return v;
}
__device__ __forceinline__ float wave_max(float v){
  #pragma unroll
  for (int m = 32; m; m >>= 1) v = fmaxf(v, __shfl_xor(v, m, 64));
  return v;
}
__device__ __forceinline__ unsigned fenc(float f){
  unsigned u = __float_as_uint(f);
  return (u >> 31) ? ~u : (u | 0x80000000u);
}
__device__ __forceinline__ float fdec(unsigned e){
  return (e >> 31) ? __uint_as_float(e & 0x7fffffffu) : __uint_as_float(~e);
}
__device__ __forceinline__ float sigm(float x){ return 1.f / (1.f + __expf(-x)); }
__device__ __forceinline__ unsigned short f2bf(float f){
  union { float f; unsigned u; } x; x.f = f;
  unsigned r = x.u + 0x7fffu + ((x.u >> 16) & 1u);
  return (unsigned short)(r >> 16);
}
__device__ __forceinline__ float bf2f(unsigned short h){
  union { unsigned u; float f; } x; x.u = ((unsigned)h) << 16;
  return x.f;
}

// ------------------------------------------------------------ CSR building
__global__ void k_build_edges(const int* __restrict__ ei, int E2, int E,
                              int* __restrict__ src, int* __restrict__ dst,
                              int* __restrict__ deg){
  int e = blockIdx.x * blockDim.x + threadIdx.x;
  if (e >= E2) return;
  int s = ei[e];
  int d = (e < E) ? ei[e + E] : ei[e - E];
  src[e] = s; dst[e] = d;
  atomicAdd(&deg[d], 1);
}

__global__ void k_scan(const int* __restrict__ deg, int* __restrict__ rowptr, int N){
  __shared__ int part[1024];
  int t = threadIdx.x;
  int chunk = (N + 1023) / 1024;
  int lo = t * chunk, hi = lo + chunk; if (hi > N) hi = N;
  int s = 0;
  for (int i = lo; i < hi; ++i) s += deg[i];
  part[t] = s;
  __syncthreads();
  for (int off = 1; off < 1024; off <<= 1){
    int v = (t >= off) ? part[t - off] : 0;
    __syncthreads();
    part[t] += v;
    __syncthreads();
  }
  int run = part[t] - s;
  for (int i = lo; i < hi; ++i){ rowptr[i] = run; run += deg[i]; }
  if (t == 1023) rowptr[N] = part[1023];
}

// fill CSR + gather raw edge features once (edge-per-lane, lane-parallel)
__global__ void k_fill(const int* __restrict__ src, const int* __restrict__ dst,
                       const int* __restrict__ rowptr,
                       int* __restrict__ cur, int* __restrict__ csrc,
                       int* __restrict__ epos,
                       const float* __restrict__ x, const float* __restrict__ ea,
                       float* __restrict__ re8, int E2, int E){
  int e = blockIdx.x * blockDim.x + threadIdx.x;
  if (e >= E2) return;
  int s = src[e], d = dst[e];
  int pos = rowptr[d] + atomicAdd(&cur[d], 1);
  csrc[pos] = s;
  epos[e] = pos;
  int row = (e < E) ? e : e - E;
  float4 eav = *reinterpret_cast<const float4*>(ea + (size_t)row*4);
  float r0 = x[s*6]     - x[d*6];
  float r1 = x[s*6 + 1] - x[d*6 + 1];
  float r2 = x[s*6 + 2] - x[d*6 + 2];
  *reinterpret_cast<float4*>(re8 + (size_t)e*8)     = eav;
  *reinterpret_cast<float4*>(re8 + (size_t)e*8 + 4) = make_float4(r0, r1, r2, 0.f);
}

// ------------------------- fused node embedding + column pool (max/mean)
__global__ void k_embed_pool(const float* __restrict__ x, const float* __restrict__ nw,
                             const float* __restrict__ nb, const float* __restrict__ zemb,
                             float* __restrict__ nf,
                             unsigned* __restrict__ pmax, float* __restrict__ psum, int N){
  int tx = threadIdx.x & 63;
  int ty = threadIdx.x >> 6;
  const float allowed[6] = {8.f, 23.f, 39.f, 54.f, 90.f, 180.f};
  float m = -INFINITY, s = 0.f;
  for (int n = blockIdx.x*4 + ty; n < N; n += gridDim.x*4){
    float xv[6];
    #pragma unroll
    for (int k = 0; k < 6; ++k) xv[k] = x[n*6 + k];
    float v = nb[tx];
    #pragma unroll
    for (int k = 0; k < 6; ++k) v += xv[k] * nw[k*64 + tx];
    v = fmaxf(v, 0.f);
    float r = rintf(xv[2]);
    int zi = 0; float bd = fabsf(r - allowed[0]);
    #pragma unroll
    for (int k = 1; k < 6; ++k){ float d = fabsf(r - allowed[k]); if (d < bd){ bd = d; zi = k; } }
    v += zemb[zi*64 + tx];
    nf[(size_t)n*64 + tx] = v;
    m = fmaxf(m, v); s += v;
  }
  __shared__ float sm[4][64], ss[4][64];
  sm[ty][tx] = m; ss[ty][tx] = s;
  __syncthreads();
  if (ty == 0){
    #pragma unroll
    for (int k = 1; k < 4; ++k){ m = fmaxf(m, sm[k][tx]); s += ss[k][tx]; }
    atomicMax(&pmax[tx], fenc(m));
    atomicAdd(&psum[tx], s);
  }
}

// ------------------------------------------------------------------- CBAM MLP
__global__ void k_cbam_mlp(const unsigned* __restrict__ pmax, const float* __restrict__ psum,
                           float invR,
                           const float* __restrict__ w1, const float* __restrict__ b1,
                           const float* __restrict__ w2, const float* __restrict__ b2,
                           float* __restrict__ ch){
  __shared__ float pool[128];
  __shared__ float h[4];
  int t = threadIdx.x;
  pool[t]      = fdec(pmax[t]);
  pool[64 + t] = psum[t] * invR;
  __syncthreads();
  if (t < 4){
    float a = b1[t];
    for (int k = 0; k < 128; ++k) a += pool[k] * w1[k*4 + t];
    h[t] = fmaxf(a, 0.f);
  }
  __syncthreads();
  float a = b2[t];
  #pragma unroll
  for (int k = 0; k < 4; ++k) a += h[k] * w2[k*64 + t];
  ch[t] = sigm(a);
}

__global__ void k_chmul_rowpool(float* __restrict__ buf, const float* __restrict__ ch,
                                float* __restrict__ rp, int R){
  int r = blockIdx.x*4 + (threadIdx.x >> 6);
  if (r >= R) return;
  int l = threadIdx.x & 63;
  float v = buf[(size_t)r*64 + l] * ch[l];
  buf[(size_t)r*64 + l] = v;
  float m = wave_max(v);
  float s = wave_sum(v);
  if (l == 0){ rp[(size_t)r*2] = m; rp[(size_t)r*2 + 1] = s * (1.f/64.f); }
}

// node spatial (final nf0) + bf16 copy into gin low half (gate GEMM input)
__global__ void k_spatial(float* __restrict__ buf, const float* __restrict__ rp,
                          const float* __restrict__ cw, const float* __restrict__ cb,
                          unsigned short* __restrict__ gin, int R){
  int r = blockIdx.x*4 + (threadIdx.x >> 6);
  if (r >= R) return;
  int l = threadIdx.x & 63;
  float sp = cb[0];
  #pragma unroll
  for (int t = 0; t < 7; ++t){
    int rr = r + t - 3;
    if (rr >= 0 && rr < R)
      sp += cw[t] * rp[(size_t)rr*2] + cw[7 + t] * rp[(size_t)rr*2 + 1];
  }
  float v = buf[(size_t)r*64 + l] * sigm(sp);
  buf[(size_t)r*64 + l] = v;
  gin[(size_t)r*128 + l] = f2bf(v);
}

// --------------- edge column-pool over raw features
// v2: register-hoisted ew (no per-edge LDS reads for weights), double-buffered
// re8 staging (prefetch chunk i+1 while computing chunk i), CHUNK=128 edges.
__global__ __launch_bounds__(256) void k_ecol(
    const float* __restrict__ re8,
    const float* __restrict__ ew, const float* __restrict__ eb,
    unsigned* __restrict__ pmax, float* __restrict__ psum, int E2){
  __shared__ float s_re[2][1024];   // 128 edges x 8 floats, double buffered
  int tid = threadIdx.x;
  int tx = tid & 63, wv = tid >> 6;
  float ewr[7];
  #pragma unroll
  for (int k = 0; k < 7; ++k) ewr[k] = ew[k*64 + tx];
  float ebl = eb[tx];
  const int CHUNK = 128;
  int base0  = blockIdx.x * CHUNK;
  int stride = gridDim.x * CHUNK;
  float m = -INFINITY, s = 0.f;
  if (base0 < E2){
    int g0 = base0 * 8;
    #pragma unroll
    for (int q = 0; q < 4; ++q){
      int idx = q*256 + tid;
      int gi = g0 + idx;
      s_re[0][idx] = (gi < E2*8) ? re8[gi] : 0.f;
    }
  }
  int buf = 0;
  for (int base = base0; base < E2; base += stride){
    __syncthreads();                      // s_re[buf] ready for all waves
    int nb = base + stride;
    if (nb < E2){                         // prefetch next chunk into buf^1
      int g0 = nb * 8;
      #pragma unroll
      for (int q = 0; q < 4; ++q){
        int idx = q*256 + tid;
        int gi = g0 + idx;
        s_re[buf ^ 1][idx] = (gi < E2*8) ? re8[gi] : 0.f;
      }
    }
    const float* sb = s_re[buf];
    #pragma unroll
    for (int j = 0; j < 32; ++j){         // 32 edges per wave
      int e = base + wv*32 + j;
      if (e < E2){
        const float* r = &sb[(wv*32 + j)*8];
        float v = ebl;
        #pragma unroll
        for (int k = 0; k < 7; ++k) v += r[k] * ewr[k];
        v = fmaxf(v, 0.f);
        m = fmaxf(m, v); s += v;
      }
    }
    buf ^= 1;
  }
  __shared__ float sm[4][64], ss[4][64];
  sm[wv][tx] = m; ss[wv][tx] = s;
  __syncthreads();
  if (wv == 0){
    #pragma unroll
    for (int k = 1; k < 4; ++k){ m = fmaxf(m, sm[k][tx]); s += ss[k][tx]; }
    atomicMax(&pmax[tx], fenc(m));
    atomicAdd(&psum[tx], s);
  }
}

// ------ edge row-pool + scatter-store ef0=raw*ch (streamed via LDS)
// v2: register-hoisted ew/eb/ch (no s_ew LDS in inner loop)
__global__ __launch_bounds__(256) void k_erp2(
    const float* __restrict__ re8, const int* __restrict__ epos,
    const float* __restrict__ ew, const float* __restrict__ eb,
    const float* __restrict__ ch,
    float* __restrict__ rp, float* __restrict__ ef0, int E2){
  __shared__ float s_re[256];
  __shared__ int   s_ep[32];
  int tid = threadIdx.x;
  int tx = tid & 63, wv = tid >> 6;
  float ewr[7];
  #pragma unroll
  for (int k = 0; k < 7; ++k) ewr[k] = ew[k*64 + tx];
  float ebl = eb[tx], chl = ch[tx];
  for (int base = blockIdx.x*32; base < E2; base += gridDim.x*32){
    __syncthreads();
    int gidx = base*8 + tid;
    s_re[tid] = (gidx < E2*8) ? re8[gidx] : 0.f;
    if (tid < 32 && base + tid < E2) s_ep[tid] = epos[base + tid];
    __syncthreads();
    #pragma unroll
    for (int j = 0; j < 8; ++j){
      int e = base + wv*8 + j;
      if (e >= E2) break;
      const float* r = &s_re[(wv*8 + j)*8];
      float v = ebl;
      #pragma unroll
      for (int k = 0; k < 7; ++k) v += r[k] * ewr[k];
      v = fmaxf(v, 0.f) * chl;
      float mm = wave_max(v);
      float sm2 = wave_sum(v);
      if (tx == 0){ rp[(size_t)e*2] = mm; rp[(size_t)e*2 + 1] = sm2 * (1.f/64.f); }
      ef0[(size_t)s_ep[wv*8 + j]*64 + tx] = v;
    }
  }
}

// ------------------- per-edge spatial sigmoid, stored in CSR slot
__global__ void k_se(const float* __restrict__ rp, const int* __restrict__ epos,
                     const float* __restrict__ ccw, const float* __restrict__ ccb,
                     float* __restrict__ se, int E2){
  int e = blockIdx.x * blockDim.x + threadIdx.x;
  if (e >= E2) return;
  float sp = ccb[0];
  #pragma unroll
  for (int t = 0; t < 7; ++t){
    int rr = e + t - 3;
    if (rr >= 0 && rr < E2)
      sp += ccw[t] * rp[(size_t)rr*2] + ccw[7+t] * rp[(size_t)rr*2 + 1];
  }
  se[epos[e]] = sigm(sp);
}

// ------------- agg0 = streamed sum(se*ef0) over CSR + fused concat-LN comb0
__global__ void k_aggb(const float* __restrict__ ef0, const float* __restrict__ se,
                       const int* __restrict__ rowptr, const float* __restrict__ nf,
                       const float* __restrict__ g, const float* __restrict__ b,
                       float* __restrict__ agg, unsigned short* __restrict__ comb, int N){
  int n = blockIdx.x*4 + (threadIdx.x >> 6);
  if (n >= N) return;
  int l = threadIdx.x & 63;
  int lo = rowptr[n], hi = rowptr[n+1];
  float acc = 0.f;
  int i = lo;
  for (; i + 4 <= hi; i += 4){
    float s0 = se[i], s1 = se[i+1], s2 = se[i+2], s3 = se[i+3];
    float e0 = ef0[(size_t)i*64 + l];
    float e1 = ef0[(size_t)(i+1)*64 + l];
    float e2 = ef0[(size_t)(i+2)*64 + l];
    float e3 = ef0[(size_t)(i+3)*64 + l];
    acc += s0*e0 + s1*e1 + s2*e2 + s3*e3;
  }
  for (; i < hi; ++i) acc += se[i] * ef0[(size_t)i*64 + l];
  agg[(size_t)n*64 + l] = acc;
  float a = nf[(size_t)n*64 + l];
  float v0 = a, v1 = acc - a;
  float mean = wave_sum(v0 + v1) * (1.f/128.f);
  float d0 = v0 - mean, d1 = v1 - mean;
  float var = wave_sum(d0*d0 + d1*d1) * (1.f/128.f);
  float rs = rsqrtf(var + 1e-5f);
  comb[(size_t)n*128 + l]      = f2bf(d0 * rs * g[l]      + b[l]);
  comb[(size_t)n*128 + 64 + l] = f2bf(d1 * rs * g[64 + l] + b[64 + l]);
}

// ------------------------------- coalesced LDS-transpose weight packs
__global__ __launch_bounds__(256) void k_packT1(
    const float* __restrict__ Wq, const float* __restrict__ Wk,
    const float* __restrict__ Wv, const float* __restrict__ Ws,
    unsigned short* __restrict__ Bt){
  __shared__ float t[64][65];
  int bx = blockIdx.x, by = blockIdx.y, bz = blockIdx.z;
  const float* W = (bz == 0) ? Wq : (bz == 1) ? Wk : (bz == 2) ? Wv : Ws;
  int tx = threadIdx.x & 63, ty = threadIdx.x >> 6;
  int R0 = by*64, C0 = bx*64;
  for (int r = ty; r < 64; r += 4)
    t[r][tx] = W[(size_t)(R0 + r)*256 + C0 + tx];
  __syncthreads();
  int iter = by >> 1, kr0 = (by & 1)*64;
  for (int r = ty; r < 64; r += 4)
    Bt[(size_t)iter*1024*128 + (size_t)(bz*256 + C0 + r)*128 + kr0 + tx] = f2bf(t[tx][r]);
}

__global__ __launch_bounds__(256) void k_packT2(
    const float* __restrict__ Wn, const float* __restrict__ We,
    unsigned short* __restrict__ Bt2){
  __shared__ float t[64][65];
  int by = blockIdx.y, bz = blockIdx.z;
  const float* W = (bz == 0) ? Wn : We;
  int tx = threadIdx.x & 63, ty = threadIdx.x >> 6;
  int R0 = by*64;
  for (int r = ty; r < 64; r += 4)
    t[r][tx] = W[(size_t)(R0 + r)*64 + tx];
  __syncthreads();
  int iter = by >> 2, kr0 = (by & 3)*64;
  for (int r = ty; r < 64; r += 4)
    Bt2[(size_t)iter*128*256 + (size_t)(bz*64 + r)*256 + kr0 + tx] = f2bf(t[tx][r]);
}

// gate weight pack: BtG[i][col][k] = bf16(gf_w[i][k][col]) for col<64 else 0
__global__ void k_packG(const float* __restrict__ gfw, unsigned short* __restrict__ BtG){
  int b = blockIdx.x;              // 3*128: iter*128 + col
  int iter = b >> 7, col = b & 127;
  int k = threadIdx.x;             // 0..127
  unsigned short v = 0;
  if (col < 64) v = f2bf(gfw[(size_t)iter*128*64 + (size_t)k*64 + col]);
  BtG[(size_t)b*128 + k] = v;
}

__global__ void k_biasp(const float* __restrict__ bq, const float* __restrict__ bk,
                        const float* __restrict__ bv, const float* __restrict__ bs,
                        const float* __restrict__ pnb, const float* __restrict__ gfb,
                        float* __restrict__ bias, float* __restrict__ bias2,
                        float* __restrict__ bias3){
  int i = blockIdx.x, t = threadIdx.x;
  const float* bb = (t < 256) ? bq : (t < 512) ? bk : (t < 768) ? bv : bs;
  bias[i*1024 + t] = bb[i*256 + (t & 255)];
  if (t < 64){
    bias2[i*128 + t] = pnb[i*64 + t];
    bias3[i*128 + t] = gfb[i*64 + t];
  } else if (t < 128){
    bias2[i*128 + t] = 0.f;
    bias3[i*128 + t] = 0.f;
  }
}

__global__ void k_packC(const float* __restrict__ cw1, float* __restrict__ Wp){
  int idx = blockIdx.x * blockDim.x + threadIdx.x;
  if (idx >= 64*128) return;
  int k = idx >> 7, j = idx & 127;
  Wp[idx] = (j < 64) ? cw1[k*64 + j] : cw1[(64 + k)*64 + (j - 64)];
}

// ---------------------------------------------------------- MFMA bf16 GEMM
// MODE 0: qkvs (cols 0-255 q f32, 256-511 k bf16, 512-767 v bf16, 768-1023 s f32)
// MODE 1: pnP f32 [M,128]; also writes bf16(pn) to gin[:,64:128] for cols<64
// MODE 2: gate_arg f32 [M,64] (only cols<64 stored)
template<int NSTEPS, int MODE>
__global__ __launch_bounds__(256) void k_mfma(
    const unsigned short* __restrict__ A, int lda,
    const unsigned short* __restrict__ Bt, int ldb,
    const float* __restrict__ bias,
    float* __restrict__ o_f0, unsigned short* __restrict__ o_h0,
    unsigned short* __restrict__ o_h1, float* __restrict__ o_f1, int M){
  __shared__ char lds[65536];
  char* ldsA = lds;
  char* ldsB = lds + 32768;
  int tid = threadIdx.x;
  int nbase = blockIdx.x * 128;
  int mbase = blockIdx.y * 128;
  int l = tid & 63, wid = tid >> 6;
  int wm = (wid >> 1) * 64, wn = (wid & 1) * 64;
  f32x4 acc[4][4] = {};
  const char* Ab  = (const char*)A;
  const char* Btb = (const char*)Bt;
  for (int ks = 0; ks < NSTEPS; ++ks){
    #pragma unroll
    for (int it = 0; it < 8; ++it){
      int c = tid + it*256;
      int row = c >> 4;
      int kb = (c & 15) << 4;
      int off = (row << 8) + (kb ^ ((row & 7) << 4));
      uint4 va = make_uint4(0,0,0,0);
      int gr = mbase + row;
      if (gr < M)
        va = *reinterpret_cast<const uint4*>(Ab + (size_t)gr*(lda*2) + ks*256 + kb);
      *reinterpret_cast<uint4*>(ldsA + off) = va;
      uint4 vb = *reinterpret_cast<const uint4*>(
                   Btb + (size_t)(nbase + row)*(ldb*2) + ks*256 + kb);
      *reinterpret_cast<uint4*>(ldsB + off) = vb;
    }
    __syncthreads();
    #pragma unroll
    for (int kk = 0; kk < 4; ++kk){
      int kbyte = kk*64 + (l >> 4)*16;
      short8 af[4], bf[4];
      #pragma unroll
      for (int m = 0; m < 4; ++m){
        int fr = wm + m*16 + (l & 15);
        af[m] = *reinterpret_cast<const short8*>(ldsA + (fr << 8) + (kbyte ^ ((fr & 7) << 4)));
      }
      #pragma unroll
      for (int n = 0; n < 4; ++n){
        int fc = wn + n*16 + (l & 15);
        bf[n] = *reinterpret_cast<const short8*>(ldsB + (fc << 8) + (kbyte ^ ((fc & 7) << 4)));
      }
      #pragma unroll
      for (int m = 0; m < 4; ++m)
        #pragma unroll
        for (int n = 0; n < 4; ++n)
          acc[m][n] = __builtin_amdgcn_mfma_f32_16x16x32_bf16(af[m], bf[n], acc[m][n], 0, 0, 0);
    }
    __syncthreads();
  }
  #pragma unroll
  for (int n = 0; n < 4; ++n){
    int gcol = nbase + wn + n*16 + (l & 15);
    float bv = bias ? bias[gcol] : 0.f;
    #pragma unroll
    for (int m = 0; m < 4; ++m){
      int grow = mbase + wm + m*16 + (l >> 4)*4;
      #pragma unroll
      for (int r = 0; r < 4; ++r){
        int gr = grow + r;
        if (gr < M){
          float val = acc[m][n][r] + bv;
          if (MODE == 1){
            o_f0[(size_t)gr*128 + gcol] = val;
            if (gcol < 64) o_h0[(size_t)gr*128 + 64 + gcol] = f2bf(val);
          } else if (MODE == 2){
            if (gcol < 64) o_f0[(size_t)gr*64 + gcol] = val;
          } else {
            int seg = gcol >> 8, c = gcol & 255;
            if      (seg == 0) o_f0[(size_t)gr*256 + c] = val;
            else if (seg == 1) o_h0[(size_t)gr*256 + c] = f2bf(val);
            else if (seg == 2) o_h1[(size_t)gr*256 + c] = f2bf(val);
            else               o_f1[(size_t)gr*256 + c] = val;
          }
        }
      }
    }
  }
}

// -------------- single-pass fused attention + skip + LN (lane-partitioned)
__global__ void k_attn(const float* __restrict__ q, const unsigned short* __restrict__ kbuf,
                       const unsigned short* __restrict__ vbuf, const float* __restrict__ sbuf,
                       const int* __restrict__ rowptr, const int* __restrict__ csrc,
                       const float* __restrict__ ltg, const float* __restrict__ ltb,
                       unsigned short* __restrict__ outb, int N){
  int n = blockIdx.x*4 + (threadIdx.x >> 6);
  if (n >= N) return;
  int l = threadIdx.x & 63;
  int lo = rowptr[n], hi = rowptr[n+1];
  size_t base = (size_t)n*256 + l*4;
  const int l4 = l*4;
  float4 qv = *reinterpret_cast<const float4*>(q + base);
  qv.x *= 0.125f; qv.y *= 0.125f; qv.z *= 0.125f; qv.w *= 0.125f;
  float o0 = 0.f, o1 = 0.f, o2 = 0.f, o3 = 0.f, s = 0.f;
  int i = lo;
  for (; i + 8 <= hi; i += 8){
    ushort4 kk[8], vv[8];
    #pragma unroll
    for (int j = 0; j < 8; ++j){
      int c = csrc[i + j];
      kk[j] = *reinterpret_cast<const ushort4*>(kbuf + (size_t)c*256 + l4);
      vv[j] = *reinterpret_cast<const ushort4*>(vbuf + (size_t)c*256 + l4);
    }
    float a[8];
    #pragma unroll
    for (int j = 0; j < 8; ++j)
      a[j] = qv.x*bf2f(kk[j].x) + qv.y*bf2f(kk[j].y) + qv.z*bf2f(kk[j].z) + qv.w*bf2f(kk[j].w);
    #pragma unroll
    for (int m = 1; m < 16; m <<= 1){
      #pragma unroll
      for (int j = 0; j < 8; ++j) a[j] += __shfl_xor(a[j], m, 64);
    }
    #pragma unroll
    for (int j = 0; j < 8; ++j){
      float w = __expf(a[j]);
      s += w;
      o0 += w*bf2f(vv[j].x); o1 += w*bf2f(vv[j].y);
      o2 += w*bf2f(vv[j].z); o3 += w*bf2f(vv[j].w);
    }
  }
  for (; i < hi; ++i){
    size_t sb = (size_t)csrc[i]*256 + l4;
    ushort4 kv = *reinterpret_cast<const ushort4*>(kbuf + sb);
    ushort4 vv = *reinterpret_cast<const ushort4*>(vbuf + sb);
    float a = qv.x*bf2f(kv.x) + qv.y*bf2f(kv.y) + qv.z*bf2f(kv.z) + qv.w*bf2f(kv.w);
    #pragma unroll
    for (int m = 1; m < 16; m <<= 1) a += __shfl_xor(a, m, 64);
    float w = __expf(a);
    s += w;
    o0 += w*bf2f(vv.x); o1 += w*bf2f(vv.y); o2 += w*bf2f(vv.z); o3 += w*bf2f(vv.w);
  }
  float4 t = *reinterpret_cast<const float4*>(sbuf + base);
  if (hi > lo){
    float r = 1.f / s;
    t.x += o0*r; t.y += o1*r; t.z += o2*r; t.w += o3*r;
  }
  float mean = wave_sum(t.x + t.y + t.z + t.w) * (1.f/256.f);
  float dx = t.x - mean, dy = t.y - mean, dz = t.z - mean, dw = t.w - mean;
  float var = wave_sum(dx*dx + dy*dy + dz*dz + dw*dw) * (1.f/256.f);
  float rs = rsqrtf(var + 1e-5f);
  float4 g = *reinterpret_cast<const float4*>(ltg + l4);
  float4 b = *reinterpret_cast<const float4*>(ltb + l4);
  ushort4 o;
  o.x = f2bf(dx*rs*g.x + b.x);
  o.y = f2bf(dy*rs*g.y + b.y);
  o.z = f2bf(dz*rs*g.z + b.z);
  o.w = f2bf(dw*rs*g.w + b.w);
  *reinterpret_cast<ushort4*>(outb + base) = o;
}

// ------ gated fusion (gate precomputed by MFMA) + agg update + comb-LN
__global__ __launch_bounds__(256) void k_gate2(
    float* __restrict__ nf, float* __restrict__ agg,
    const float* __restrict__ pnP, const float* __restrict__ gate_arg,
    const int* __restrict__ rowptr, const int* __restrict__ csrc,
    const float* __restrict__ peb,
    const float* __restrict__ cg, const float* __restrict__ cbv,
    unsigned short* __restrict__ comb, unsigned short* __restrict__ gin,
    int doComb, int N){
  int n = blockIdx.x*4 + (threadIdx.x >> 6);
  if (n >= N) return;
  int l = threadIdx.x & 63;
  float g = sigm(gate_arg[(size_t)n*64 + l]);
  float nfv = nf[(size_t)n*64 + l];
  float pnv = pnP[(size_t)n*128 + l];
  float nfn = nfv * (1.f + g) + pnv * (1.f - g);
  nf[(size_t)n*64 + l] = nfn;
  gin[(size_t)n*128 + l] = f2bf(nfn);
  int lo = rowptr[n], hi = rowptr[n+1];
  float sp = 0.f;
  int i = lo;
  for (; i + 8 <= hi; i += 8){
    float pv[8];
    #pragma unroll
    for (int j = 0; j < 8; ++j)
      pv[j] = pnP[(size_t)csrc[i+j]*128 + 64 + l];
    #pragma unroll
    for (int j = 0; j < 8; ++j) sp += pv[j];
  }
  for (; i < hi; ++i) sp += pnP[(size_t)csrc[i]*128 + 64 + l];
  float Pn = pnP[(size_t)n*128 + 64 + l];
  float aggn = agg[(size_t)n*64 + l] + sp - (float)(hi - lo) * (Pn - peb[l]);
  agg[(size_t)n*64 + l] = aggn;
  if (doComb){
    float v0 = nfn, v1 = aggn - nfn;
    float mean = wave_sum(v0 + v1) * (1.f/128.f);
    float d0 = v0 - mean, d1 = v1 - mean;
    float var = wave_sum(d0*d0 + d1*d1) * (1.f/128.f);
    float rs = rsqrtf(var + 1e-5f);
    comb[(size_t)n*128 + l]      = f2bf(d0 * rs * cg[l]      + cbv[l]);
    comb[(size_t)n*128 + 64 + l] = f2bf(d1 * rs * cg[64 + l] + cbv[64 + l]);
  }
}

// ------------------------------------------------------------- classifier
template<int K, int BN>
__global__ __launch_bounds__(256) void k_gemm(
    const float* __restrict__ in, const float* __restrict__ W, int ldw,
    const float* __restrict__ bias, float* __restrict__ out, int ldo, int nrows){
  constexpr int PAD = BN + 4;
  __shared__ float s_in[K * PAD];
  int n0 = blockIdx.x * BN;
  int tid = threadIdx.x;
  for (int idx = tid; idx < BN * K; idx += 256){
    int r = idx / K, k = idx - r * K;
    float v = (n0 + r < nrows) ? in[(size_t)(n0 + r) * K + k] : 0.f;
    s_in[k * PAD + r] = v;
  }
  __syncthreads();
  int tx = tid & 15, ty = tid >> 4;
  constexpr int NT = BN / 16;
  int col0 = blockIdx.y * 64 + tx * 4;
  float acc[NT][4] = {};
  for (int k = 0; k < K; ++k){
    const float4 wv = *reinterpret_cast<const float4*>(&W[(size_t)k * ldw + col0]);
    #pragma unroll
    for (int i = 0; i < NT; ++i){
      float cv = s_in[k * PAD + ty * NT + i];
      acc[i][0] += cv * wv.x;
      acc[i][1] += cv * wv.y;
      acc[i][2] += cv * wv.z;
      acc[i][3] += cv * wv.w;
    }
  }
  #pragma unroll
  for (int i = 0; i < NT; ++i){
    int n = n0 + ty * NT + i;
    if (n < nrows){
      float4 o = make_float4(acc[i][0], acc[i][1], acc[i][2], acc[i][3]);
      *reinterpret_cast<float4*>(&out[(size_t)n * ldo + col0]) = o;
    }
  }
}

__global__ void k_final(const float* __restrict__ AB,
                        const int* __restrict__ ei, const float* __restrict__ cb1,
                        const float* __restrict__ cw2, const float* __restrict__ cb2,
                        float* __restrict__ dout, int E){
  int e = blockIdx.x*4 + (threadIdx.x >> 6);
  if (e >= E) return;
  int l = threadIdx.x & 63;
  int i0 = ei[e], i1 = ei[E + e];
  float h = fmaxf(AB[(size_t)i0*128 + l] + AB[(size_t)i1*128 + 64 + l] + cb1[l], 0.f);
  float p = wave_sum(h * cw2[l]);
  if (l == 0) dout[e] = p + cb2[0];
}

// ===========================================================================
extern "C" void kernel_launch(void* const* d_in, const int* in_sizes, int n_in,
                              void* d_out, int out_size, void* d_ws, size_t ws_size,
                              hipStream_t stream){
  const float* x         = (const float*)d_in[0];
  const float* edge_attr = (const float*)d_in[1];
  const float* node_w    = (const float*)d_in[2];
  const float* node_b    = (const float*)d_in[3];
  const float* edge_w    = (const float*)d_in[4];
  const float* edge_b    = (const float*)d_in[5];
  const float* z_emb     = (const float*)d_in[6];
  const float* cn_w1     = (const float*)d_in[7];
  const float* cn_b1     = (const float*)d_in[8];
  const float* cn_w2     = (const float*)d_in[9];
  const float* cn_b2     = (const float*)d_in[10];
  const float* cn_cw     = (const float*)d_in[11];
  const float* cn_cb     = (const float*)d_in[12];
  const float* ce_w1     = (const float*)d_in[13];
  const float* ce_b1     = (const float*)d_in[14];
  const float* ce_w2     = (const float*)d_in[15];
  const float* ce_b2     = (const float*)d_in[16];
  const float* ce_cw     = (const float*)d_in[17];
  const float* ce_cb     = (const float*)d_in[18];
  const float* Wq        = (const float*)d_in[19];
  const float* bq        = (const float*)d_in[20];
  const float* Wk        = (const float*)d_in[21];
  const float* bk        = (const float*)d_in[22];
  const float* Wv        = (const float*)d_in[23];
  const float* bv        = (const float*)d_in[24];
  const float* Ws        = (const float*)d_in[25];
  const float* bs        = (const float*)d_in[26];
  const float* lt_g      = (const float*)d_in[27];
  const float* lt_b      = (const float*)d_in[28];
  const float* lc_g      = (const float*)d_in[29];
  const float* lc_b      = (const float*)d_in[30];
  const float* pe_w      = (const float*)d_in[31];
  const float* pe_b      = (const float*)d_in[32];
  const float* pn_w      = (const float*)d_in[33];
  const float* pn_b      = (const float*)d_in[34];
  const float* gf_w      = (const float*)d_in[35];
  const float* gf_b      = (const float*)d_in[36];
  const float* c_w1      = (const float*)d_in[37];
  const float* c_b1      = (const float*)d_in[38];
  const float* c_w2      = (const float*)d_in[39];
  const float* c_b2      = (const float*)d_in[40];
  const int*   edge_index= (const int*)d_in[41];

  const int N  = in_sizes[0] / 6;
  const int E  = in_sizes[1] / 4;
  const int E2 = 2 * E;

  // ---------------- workspace layout
  char* p = (char*)d_ws;
  auto alloc = [&](size_t bytes)->char*{
    char* r = p; p += (bytes + 255) & ~(size_t)255; return r;
  };
  // --- zero-init region (one memset covers all of these, incl. padding) ---
  char* zbase = p;
  int*            w_deg    = (int*)           alloc((size_t)N * 4);
  int*            w_cur    = (int*)           alloc((size_t)N * 4);
  unsigned*       w_pmax   = (unsigned*)      alloc(64 * 4);
  float*          w_psum   = (float*)         alloc(64 * 4);
  unsigned*       w_pmax2  = (unsigned*)      alloc(64 * 4);
  float*          w_psum2  = (float*)         alloc(64 * 4);
  size_t zbytes = (size_t)(p - zbase);
  // --- rest ---
  int*            w_src    = (int*)           alloc((size_t)E2 * 4);
  int*            w_dst    = (int*)           alloc((size_t)E2 * 4);
  int*            w_rowptr = (int*)           alloc((size_t)(N + 1) * 4);
  int*            w_csrc   = (int*)           alloc((size_t)E2 * 4);
  int*            w_epos   = (int*)           alloc((size_t)E2 * 4);
  float*          w_re8    = (float*)         alloc((size_t)E2 * 8 * 4);
  float*          w_nf     = (float*)         alloc((size_t)N * 64 * 4);
  float*          w_agg    = (float*)         alloc((size_t)N * 64 * 4);
  float*          w_ef0    = (float*)         alloc((size_t)E2 * 64 * 4);
  float*          w_se     = (float*)         alloc((size_t)E2 * 4);
  unsigned short* w_comb   = (unsigned short*)alloc((size_t)N * 128 * 2);
  unsigned short* w_gin    = (unsigned short*)alloc((size_t)N * 128 * 2);
  float*          w_gate   = (float*)         alloc((size_t)N * 64 * 4);
  float*          w_q      = (float*)         alloc((size_t)N * 256 * 4);
  unsigned short* w_k      = (unsigned short*)alloc((size_t)N * 256 * 2);
  unsigned short* w_v      = (unsigned short*)alloc((size_t)N * 256 * 2);
  float*          w_s      = (float*)         alloc((size_t)N * 256 * 4);
  unsigned short* w_outb   = (unsigned short*)alloc((size_t)N * 256 * 2);
  float*          w_pnP    = (float*)         alloc((size_t)N * 128 * 4);
  float*          w_rp     = (float*)         alloc((size_t)E2 * 2 * 4);
  float*          w_AB     = (float*)         alloc((size_t)N * 128 * 4);
  float*          w_Wp     = (float*)         alloc((size_t)64 * 128 * 4);
  unsigned short* w_Bt     = (unsigned short*)alloc((size_t)3 * 1024 * 128 * 2);
  float*          w_bias   = (float*)         alloc((size_t)3 * 1024 * 4);
  unsigned short* w_Bt2    = (unsigned short*)alloc((size_t)3 * 128 * 256 * 2);
  float*          w_bias2  = (float*)         alloc((size_t)3 * 128 * 4);
  unsigned short* w_BtG    = (unsigned short*)alloc((size_t)3 * 128 * 128 * 2);
  float*          w_bias3  = (float*)         alloc((size_t)3 * 128 * 4);
  float*          w_ch     = (float*)         alloc(64 * 4);
  float*          w_ch2    = (float*)         alloc(64 * 4);

  hipMemsetAsync(zbase, 0, zbytes, stream);

  // ---------------- CSR + raw-edge gather + node embedding/CBAM
  k_build_edges<<<(E2 + 255)/256, 256, 0, stream>>>(edge_index, E2, E, w_src, w_dst, w_deg);
  k_scan<<<1, 1024, 0, stream>>>(w_deg, w_rowptr, N);
  k_fill<<<(E2 + 255)/256, 256, 0, stream>>>(w_src, w_dst, w_rowptr, w_cur, w_csrc, w_epos,
                                             x, edge_attr, w_re8, E2, E);
  k_embed_pool<<<256, 256, 0, stream>>>(x, node_w, node_b, z_emb, w_nf, w_pmax, w_psum, N);
  k_cbam_mlp<<<1, 64, 0, stream>>>(w_pmax, w_psum, 1.f/(float)N,
                                   cn_w1, cn_b1, cn_w2, cn_b2, w_ch);
  k_chmul_rowpool<<<(N + 3)/4, 256, 0, stream>>>(w_nf, w_ch, w_rp, N);
  k_spatial<<<(N + 3)/4, 256, 0, stream>>>(w_nf, w_rp, cn_cw, cn_cb, w_gin, N);

  // ---------------- edge CBAM (streamed) -> ef0 (CSR order) -> agg0 + comb0
  k_ecol<<<256, 256, 0, stream>>>(w_re8, edge_w, edge_b, w_pmax2, w_psum2, E2);
  k_cbam_mlp<<<1, 64, 0, stream>>>(w_pmax2, w_psum2, 1.f/(float)E2,
                                   ce_w1, ce_b1, ce_w2, ce_b2, w_ch2);
  k_erp2<<<2048, 256, 0, stream>>>(w_re8, w_epos, edge_w, edge_b, w_ch2,
                                   w_rp, w_ef0, E2);
  k_se<<<(E2 + 255)/256, 256, 0, stream>>>(w_rp, w_epos, ce_cw, ce_cb, w_se, E2);
  k_aggb<<<(N + 3)/4, 256, 0, stream>>>(w_ef0, w_se, w_rowptr, w_nf,
                                        lc_g, lc_b, w_agg, w_comb, N);

  // ---------------- pack all iteration weights
  k_packT1<<<dim3(4, 6, 4), 256, 0, stream>>>(Wq, Wk, Wv, Ws, w_Bt);
  k_packT2<<<dim3(1, 12, 2), 256, 0, stream>>>(pn_w, pe_w, w_Bt2);
  k_packG<<<3*128, 128, 0, stream>>>(gf_w, w_BtG);
  k_biasp<<<3, 1024, 0, stream>>>(bq, bk, bv, bs, pn_b, gf_b, w_bias, w_bias2, w_bias3);
  k_packC<<<32, 256, 0, stream>>>(c_w1, w_Wp);

  // ---------------- message-passing iterations
  const int MB = (N + 127) / 128;
  for (int i = 0; i < 3; ++i){
    k_mfma<1,0><<<dim3(8, MB), 256, 0, stream>>>(w_comb, 128,
                                                 w_Bt + (size_t)i*1024*128, 128,
                                                 w_bias + (size_t)i*1024,
                                                 w_q, w_k, w_v, w_s, N);
    k_attn<<<(N + 3)/4, 256, 0, stream>>>(w_q, w_k, w_v, w_s, w_rowptr, w_csrc,
                                          lt_g + (size_t)i*256, lt_b + (size_t)i*256,
                                          w_outb, N);
    k_mfma<2,1><<<dim3(1, MB), 256, 0, stream>>>(w_outb, 256,
                                                 w_Bt2 + (size_t)i*128*256, 256,
                                                 w_bias2 + (size_t)i*128,
                                                 w_pnP, w_gin, nullptr, nullptr, N);
    k_mfma<1,2><<<dim3(1, MB), 256, 0, stream>>>(w_gin, 128,
                                                 w_BtG + (size_t)i*128*128, 128,
                                                 w_bias3 + (size_t)i*128,
                                                 w_gate, nullptr, nullptr, nullptr, N);
    int doComb = (i < 2) ? 1 : 0;
    const float* cg  = lc_g + (size_t)(i < 2 ? i+1 : 0)*128;
    const float* cbv = lc_b + (size_t)(i < 2 ? i+1 : 0)*128;
    k_gate2<<<(N + 3)/4, 256, 0, stream>>>(w_nf, w_agg, w_pnP, w_gate,
                                           w_rowptr, w_csrc,
                                           pe_b + (size_t)i*64,
                                           cg, cbv, w_comb, w_gin, doComb, N);
  }

  // ---------------- classifier (fused A|B GEMM, then edge head)
  dim3 gAB((N + 63)/64, 2);
  k_gemm<64,64><<<gAB, 256, 0, stream>>>(w_nf, w_Wp, 128, nullptr, w_AB, 128, N);
  k_final<<<(E + 3)/4, 256, 0, stream>>>(w_AB, edge_index, c_b1, c_w2, c_b2,
                                         (float*)d_out, E);
}

// Round 11
// 745.853 us; speedup vs baseline: 2.7202x; 1.0108x over previous
//
#include <hip/hip_runtime.h>
#include <math.h>

typedef __attribute__((ext_vector_type(8))) short short8;
typedef __attribute__((ext_vector_type(4))) float f32x4;

// ---------------------------------------------------------------- utilities
__device__ __forceinline__ float wave_sum(float v){
  #pragma unroll
  for (int m = 32; m; m >>= 1) v += __shfl_xor(v, m, 64);
  return v;
}
__device__ __forceinline__ float wave_max(float v){
  #pragma unroll
  for (int m = 32; m; m >>= 1) v = fmaxf(v, __shfl_xor(v, m, 64));
  return v;
}
__device__ __forceinline__ unsigned fenc(float f){
  unsigned u = __float_as_uint(f);
  return (u >> 31) ? ~u : (u | 0x80000000u);
}
__device__ __forceinline__ float fdec(unsigned e){
  return (e >> 31) ? __uint_as_float(e & 0x7fffffffu) : __uint_as_float(~e);
}
__device__ __forceinline__ float sigm(float x){ return 1.f / (1.f + __expf(-x)); }
__device__ __forceinline__ unsigned short f2bf(float f){
  union { float f; unsigned u; } x; x.f = f;
  unsigned r = x.u + 0x7fffu + ((x.u >> 16) & 1u);
  return (unsigned short)(r >> 16);
}
__device__ __forceinline__ float bf2f(unsigned short h){
  union { unsigned u; float f; } x; x.u = ((unsigned)h) << 16;
  return x.f;
}

// ------------------------------------------------------------ CSR building
__global__ void k_build_edges(const int* __restrict__ ei, int E2, int E,
                              int* __restrict__ src, int* __restrict__ dst,
                              int* __restrict__ deg){
  int e = blockIdx.x * blockDim.x + threadIdx.x;
  if (e >= E2) return;
  int s = ei[e];
  int d = (e < E) ? ei[e + E] : ei[e - E];
  src[e] = s; dst[e] = d;
  atomicAdd(&deg[d], 1);
}

__global__ void k_scan(const int* __restrict__ deg, int* __restrict__ rowptr, int N){
  __shared__ int part[1024];
  int t = threadIdx.x;
  int chunk = (N + 1023) / 1024;
  int lo = t * chunk, hi = lo + chunk; if (hi > N) hi = N;
  int s = 0;
  for (int i = lo; i < hi; ++i) s += deg[i];
  part[t] = s;
  __syncthreads();
  for (int off = 1; off < 1024; off <<= 1){
    int v = (t >= off) ? part[t - off] : 0;
    __syncthreads();
    part[t] += v;
    __syncthreads();
  }
  int run = part[t] - s;
  for (int i = lo; i < hi; ++i){ rowptr[i] = run; run += deg[i]; }
  if (t == 1023) rowptr[N] = part[1023];
}

// fill CSR + gather raw edge features once (edge-per-lane, lane-parallel)
__global__ void k_fill(const int* __restrict__ src, const int* __restrict__ dst,
                       const int* __restrict__ rowptr,
                       int* __restrict__ cur, int* __restrict__ csrc,
                       int* __restrict__ epos,
                       const float* __restrict__ x, const float* __restrict__ ea,
                       float* __restrict__ re8, int E2, int E){
  int e = blockIdx.x * blockDim.x + threadIdx.x;
  if (e >= E2) return;
  int s = src[e], d = dst[e];
  int pos = rowptr[d] + atomicAdd(&cur[d], 1);
  csrc[pos] = s;
  epos[e] = pos;
  int row = (e < E) ? e : e - E;
  float4 eav = *reinterpret_cast<const float4*>(ea + (size_t)row*4);
  float r0 = x[s*6]     - x[d*6];
  float r1 = x[s*6 + 1] - x[d*6 + 1];
  float r2 = x[s*6 + 2] - x[d*6 + 2];
  *reinterpret_cast<float4*>(re8 + (size_t)e*8)     = eav;
  *reinterpret_cast<float4*>(re8 + (size_t)e*8 + 4) = make_float4(r0, r1, r2, 0.f);
}

// ------------------------- fused node embedding + column pool (max/mean)
__global__ void k_embed_pool(const float* __restrict__ x, const float* __restrict__ nw,
                             const float* __restrict__ nb, const float* __restrict__ zemb,
                             float* __restrict__ nf,
                             unsigned* __restrict__ pmax, float* __restrict__ psum, int N){
  int tx = threadIdx.x & 63;
  int ty = threadIdx.x >> 6;
  const float allowed[6] = {8.f, 23.f, 39.f, 54.f, 90.f, 180.f};
  float m = -INFINITY, s = 0.f;
  for (int n = blockIdx.x*4 + ty; n < N; n += gridDim.x*4){
    float xv[6];
    #pragma unroll
    for (int k = 0; k < 6; ++k) xv[k] = x[n*6 + k];
    float v = nb[tx];
    #pragma unroll
    for (int k = 0; k < 6; ++k) v += xv[k] * nw[k*64 + tx];
    v = fmaxf(v, 0.f);
    float r = rintf(xv[2]);
    int zi = 0; float bd = fabsf(r - allowed[0]);
    #pragma unroll
    for (int k = 1; k < 6; ++k){ float d = fabsf(r - allowed[k]); if (d < bd){ bd = d; zi = k; } }
    v += zemb[zi*64 + tx];
    nf[(size_t)n*64 + tx] = v;
    m = fmaxf(m, v); s += v;
  }
  __shared__ float sm[4][64], ss[4][64];
  sm[ty][tx] = m; ss[ty][tx] = s;
  __syncthreads();
  if (ty == 0){
    #pragma unroll
    for (int k = 1; k < 4; ++k){ m = fmaxf(m, sm[k][tx]); s += ss[k][tx]; }
    atomicMax(&pmax[tx], fenc(m));
    atomicAdd(&psum[tx], s);
  }
}

// ------------------------------------------------------------------- CBAM MLP
__global__ void k_cbam_mlp(const unsigned* __restrict__ pmax, const float* __restrict__ psum,
                           float invR,
                           const float* __restrict__ w1, const float* __restrict__ b1,
                           const float* __restrict__ w2, const float* __restrict__ b2,
                           float* __restrict__ ch){
  __shared__ float pool[128];
  __shared__ float h[4];
  int t = threadIdx.x;
  pool[t]      = fdec(pmax[t]);
  pool[64 + t] = psum[t] * invR;
  __syncthreads();
  if (t < 4){
    float a = b1[t];
    for (int k = 0; k < 128; ++k) a += pool[k] * w1[k*4 + t];
    h[t] = fmaxf(a, 0.f);
  }
  __syncthreads();
  float a = b2[t];
  #pragma unroll
  for (int k = 0; k < 4; ++k) a += h[k] * w2[k*64 + t];
  ch[t] = sigm(a);
}

__global__ void k_chmul_rowpool(float* __restrict__ buf, const float* __restrict__ ch,
                                float* __restrict__ rp, int R){
  int r = blockIdx.x*4 + (threadIdx.x >> 6);
  if (r >= R) return;
  int l = threadIdx.x & 63;
  float v = buf[(size_t)r*64 + l] * ch[l];
  buf[(size_t)r*64 + l] = v;
  float m = wave_max(v);
  float s = wave_sum(v);
  if (l == 0){ rp[(size_t)r*2] = m; rp[(size_t)r*2 + 1] = s * (1.f/64.f); }
}

// node spatial (final nf0) + bf16 copy into gin low half (gate GEMM input)
__global__ void k_spatial(float* __restrict__ buf, const float* __restrict__ rp,
                          const float* __restrict__ cw, const float* __restrict__ cb,
                          unsigned short* __restrict__ gin, int R){
  int r = blockIdx.x*4 + (threadIdx.x >> 6);
  if (r >= R) return;
  int l = threadIdx.x & 63;
  float sp = cb[0];
  #pragma unroll
  for (int t = 0; t < 7; ++t){
    int rr = r + t - 3;
    if (rr >= 0 && rr < R)
      sp += cw[t] * rp[(size_t)rr*2] + cw[7 + t] * rp[(size_t)rr*2 + 1];
  }
  float v = buf[(size_t)r*64 + l] * sigm(sp);
  buf[(size_t)r*64 + l] = v;
  gin[(size_t)r*128 + l] = f2bf(v);
}

// --------------- edge column-pool over raw features (reg weights + dbuf)
__global__ __launch_bounds__(256) void k_ecol(
    const float* __restrict__ re8,
    const float* __restrict__ ew, const float* __restrict__ eb,
    unsigned* __restrict__ pmax, float* __restrict__ psum, int E2){
  __shared__ float s_re[2][1024];   // 128 edges x 8 floats, double buffered
  int tid = threadIdx.x;
  int tx = tid & 63, wv = tid >> 6;
  float ewr[7];
  #pragma unroll
  for (int k = 0; k < 7; ++k) ewr[k] = ew[k*64 + tx];
  float ebl = eb[tx];
  const int CHUNK = 128;
  int base0  = blockIdx.x * CHUNK;
  int stride = gridDim.x * CHUNK;
  float m = -INFINITY, s = 0.f;
  if (base0 < E2){
    int g0 = base0 * 8;
    #pragma unroll
    for (int q = 0; q < 4; ++q){
      int idx = q*256 + tid;
      int gi = g0 + idx;
      s_re[0][idx] = (gi < E2*8) ? re8[gi] : 0.f;
    }
  }
  int buf = 0;
  for (int base = base0; base < E2; base += stride){
    __syncthreads();
    int nb = base + stride;
    if (nb < E2){
      int g0 = nb * 8;
      #pragma unroll
      for (int q = 0; q < 4; ++q){
        int idx = q*256 + tid;
        int gi = g0 + idx;
        s_re[buf ^ 1][idx] = (gi < E2*8) ? re8[gi] : 0.f;
      }
    }
    const float* sb = s_re[buf];
    #pragma unroll
    for (int j = 0; j < 32; ++j){
      int e = base + wv*32 + j;
      if (e < E2){
        const float* r = &sb[(wv*32 + j)*8];
        float v = ebl;
        #pragma unroll
        for (int k = 0; k < 7; ++k) v += r[k] * ewr[k];
        v = fmaxf(v, 0.f);
        m = fmaxf(m, v); s += v;
      }
    }
    buf ^= 1;
  }
  __shared__ float sm[4][64], ss[4][64];
  sm[wv][tx] = m; ss[wv][tx] = s;
  __syncthreads();
  if (wv == 0){
    #pragma unroll
    for (int k = 1; k < 4; ++k){ m = fmaxf(m, sm[k][tx]); s += ss[k][tx]; }
    atomicMax(&pmax[tx], fenc(m));
    atomicAdd(&psum[tx], s);
  }
}

// ------ edge row-pool + scatter-store ef0=bf16(raw*ch), CHUNK=128 dbuf
__global__ __launch_bounds__(256) void k_erp2(
    const float* __restrict__ re8, const int* __restrict__ epos,
    const float* __restrict__ ew, const float* __restrict__ eb,
    const float* __restrict__ ch,
    float* __restrict__ rp, unsigned short* __restrict__ ef0, int E2){
  __shared__ float s_re[2][1024];
  __shared__ int   s_ep[2][128];
  int tid = threadIdx.x;
  int tx = tid & 63, wv = tid >> 6;
  float ewr[7];
  #pragma unroll
  for (int k = 0; k < 7; ++k) ewr[k] = ew[k*64 + tx];
  float ebl = eb[tx], chl = ch[tx];
  const int CHUNK = 128;
  int base0  = blockIdx.x * CHUNK;
  int stride = gridDim.x * CHUNK;
  if (base0 < E2){
    int g0 = base0 * 8;
    #pragma unroll
    for (int q = 0; q < 4; ++q){
      int idx = q*256 + tid;
      int gi = g0 + idx;
      s_re[0][idx] = (gi < E2*8) ? re8[gi] : 0.f;
    }
    if (tid < 128 && base0 + tid < E2) s_ep[0][tid] = epos[base0 + tid];
  }
  int buf = 0;
  for (int base = base0; base < E2; base += stride){
    __syncthreads();
    int nb = base + stride;
    if (nb < E2){
      int g0 = nb * 8;
      #pragma unroll
      for (int q = 0; q < 4; ++q){
        int idx = q*256 + tid;
        int gi = g0 + idx;
        s_re[buf ^ 1][idx] = (gi < E2*8) ? re8[gi] : 0.f;
      }
      if (tid < 128 && nb + tid < E2) s_ep[buf ^ 1][tid] = epos[nb + tid];
    }
    const float* sb = s_re[buf];
    const int* sep = s_ep[buf];
    #pragma unroll
    for (int j = 0; j < 32; ++j){
      int e = base + wv*32 + j;
      if (e < E2){
        const float* r = &sb[(wv*32 + j)*8];
        float v = ebl;
        #pragma unroll
        for (int k = 0; k < 7; ++k) v += r[k] * ewr[k];
        v = fmaxf(v, 0.f) * chl;
        float mm = wave_max(v);
        float sm2 = wave_sum(v);
        if (tx == 0){ rp[(size_t)e*2] = mm; rp[(size_t)e*2 + 1] = sm2 * (1.f/64.f); }
        ef0[(size_t)sep[wv*32 + j]*64 + tx] = f2bf(v);
      }
    }
    buf ^= 1;
  }
}

// ------------------- per-edge spatial sigmoid, stored in CSR slot
__global__ void k_se(const float* __restrict__ rp, const int* __restrict__ epos,
                     const float* __restrict__ ccw, const float* __restrict__ ccb,
                     float* __restrict__ se, int E2){
  int e = blockIdx.x * blockDim.x + threadIdx.x;
  if (e >= E2) return;
  float sp = ccb[0];
  #pragma unroll
  for (int t = 0; t < 7; ++t){
    int rr = e + t - 3;
    if (rr >= 0 && rr < E2)
      sp += ccw[t] * rp[(size_t)rr*2] + ccw[7+t] * rp[(size_t)rr*2 + 1];
  }
  se[epos[e]] = sigm(sp);
}

// ------------- agg0 = streamed sum(se*ef0) over CSR + fused concat-LN comb0
__global__ void k_aggb(const unsigned short* __restrict__ ef0, const float* __restrict__ se,
                       const int* __restrict__ rowptr, const float* __restrict__ nf,
                       const float* __restrict__ g, const float* __restrict__ b,
                       float* __restrict__ agg, unsigned short* __restrict__ comb, int N){
  int n = blockIdx.x*4 + (threadIdx.x >> 6);
  if (n >= N) return;
  int l = threadIdx.x & 63;
  int lo = rowptr[n], hi = rowptr[n+1];
  float acc = 0.f;
  int i = lo;
  for (; i + 8 <= hi; i += 8){
    float sv[8], ev[8];
    #pragma unroll
    for (int j = 0; j < 8; ++j) sv[j] = se[i + j];
    #pragma unroll
    for (int j = 0; j < 8; ++j) ev[j] = bf2f(ef0[(size_t)(i + j)*64 + l]);
    #pragma unroll
    for (int j = 0; j < 8; ++j) acc += sv[j] * ev[j];
  }
  for (; i < hi; ++i) acc += se[i] * bf2f(ef0[(size_t)i*64 + l]);
  agg[(size_t)n*64 + l] = acc;
  float a = nf[(size_t)n*64 + l];
  float v0 = a, v1 = acc - a;
  float mean = wave_sum(v0 + v1) * (1.f/128.f);
  float d0 = v0 - mean, d1 = v1 - mean;
  float var = wave_sum(d0*d0 + d1*d1) * (1.f/128.f);
  float rs = rsqrtf(var + 1e-5f);
  comb[(size_t)n*128 + l]      = f2bf(d0 * rs * g[l]      + b[l]);
  comb[(size_t)n*128 + 64 + l] = f2bf(d1 * rs * g[64 + l] + b[64 + l]);
}

// ------------------------------- coalesced LDS-transpose weight packs
__global__ __launch_bounds__(256) void k_packT1(
    const float* __restrict__ Wq, const float* __restrict__ Wk,
    const float* __restrict__ Wv, const float* __restrict__ Ws,
    unsigned short* __restrict__ Bt){
  __shared__ float t[64][65];
  int bx = blockIdx.x, by = blockIdx.y, bz = blockIdx.z;
  const float* W = (bz == 0) ? Wq : (bz == 1) ? Wk : (bz == 2) ? Wv : Ws;
  int tx = threadIdx.x & 63, ty = threadIdx.x >> 6;
  int R0 = by*64, C0 = bx*64;
  for (int r = ty; r < 64; r += 4)
    t[r][tx] = W[(size_t)(R0 + r)*256 + C0 + tx];
  __syncthreads();
  int iter = by >> 1, kr0 = (by & 1)*64;
  for (int r = ty; r < 64; r += 4)
    Bt[(size_t)iter*1024*128 + (size_t)(bz*256 + C0 + r)*128 + kr0 + tx] = f2bf(t[tx][r]);
}

__global__ __launch_bounds__(256) void k_packT2(
    const float* __restrict__ Wn, const float* __restrict__ We,
    unsigned short* __restrict__ Bt2){
  __shared__ float t[64][65];
  int by = blockIdx.y, bz = blockIdx.z;
  const float* W = (bz == 0) ? Wn : We;
  int tx = threadIdx.x & 63, ty = threadIdx.x >> 6;
  int R0 = by*64;
  for (int r = ty; r < 64; r += 4)
    t[r][tx] = W[(size_t)(R0 + r)*64 + tx];
  __syncthreads();
  int iter = by >> 2, kr0 = (by & 3)*64;
  for (int r = ty; r < 64; r += 4)
    Bt2[(size_t)iter*128*256 + (size_t)(bz*64 + r)*256 + kr0 + tx] = f2bf(t[tx][r]);
}

// gate weight pack: BtG[i][col][k] = bf16(gf_w[i][k][col]) for col<64 else 0
__global__ void k_packG(const float* __restrict__ gfw, unsigned short* __restrict__ BtG){
  int b = blockIdx.x;              // 3*128: iter*128 + col
  int iter = b >> 7, col = b & 127;
  int k = threadIdx.x;             // 0..127
  unsigned short v = 0;
  if (col < 64) v = f2bf(gfw[(size_t)iter*128*64 + (size_t)k*64 + col]);
  BtG[(size_t)b*128 + k] = v;
}

__global__ void k_biasp(const float* __restrict__ bq, const float* __restrict__ bk,
                        const float* __restrict__ bv, const float* __restrict__ bs,
                        const float* __restrict__ pnb, const float* __restrict__ gfb,
                        float* __restrict__ bias, float* __restrict__ bias2,
                        float* __restrict__ bias3){
  int i = blockIdx.x, t = threadIdx.x;
  const float* bb = (t < 256) ? bq : (t < 512) ? bk : (t < 768) ? bv : bs;
  bias[i*1024 + t] = bb[i*256 + (t & 255)];
  if (t < 64){
    bias2[i*128 + t] = pnb[i*64 + t];
    bias3[i*128 + t] = gfb[i*64 + t];
  } else if (t < 128){
    bias2[i*128 + t] = 0.f;
    bias3[i*128 + t] = 0.f;
  }
}

__global__ void k_packC(const float* __restrict__ cw1, float* __restrict__ Wp){
  int idx = blockIdx.x * blockDim.x + threadIdx.x;
  if (idx >= 64*128) return;
  int k = idx >> 7, j = idx & 127;
  Wp[idx] = (j < 64) ? cw1[k*64 + j] : cw1[(64 + k)*64 + (j - 64)];
}

// ---------------------------------------------------------- MFMA bf16 GEMM
// MODE 0: cols 0-255 -> q f32; 256-511 -> kv[gr][c] bf16; 512-767 -> kv[gr][256+c]
//         bf16; 768-1023 -> s f32.  (kv row stride 512)
// MODE 1: pnP f32 [M,128]; also writes bf16(pn) to gin[:,64:128] for cols<64
// MODE 2: gate_arg f32 [M,64] (only cols<64 stored)
template<int NSTEPS, int MODE>
__global__ __launch_bounds__(256) void k_mfma(
    const unsigned short* __restrict__ A, int lda,
    const unsigned short* __restrict__ Bt, int ldb,
    const float* __restrict__ bias,
    float* __restrict__ o_f0, unsigned short* __restrict__ o_h0,
    float* __restrict__ o_f1, int M){
  __shared__ char lds[65536];
  char* ldsA = lds;
  char* ldsB = lds + 32768;
  int tid = threadIdx.x;
  int nbase = blockIdx.x * 128;
  int mbase = blockIdx.y * 128;
  int l = tid & 63, wid = tid >> 6;
  int wm = (wid >> 1) * 64, wn = (wid & 1) * 64;
  f32x4 acc[4][4] = {};
  const char* Ab  = (const char*)A;
  const char* Btb = (const char*)Bt;
  for (int ks = 0; ks < NSTEPS; ++ks){
    #pragma unroll
    for (int it = 0; it < 8; ++it){
      int c = tid + it*256;
      int row = c >> 4;
      int kb = (c & 15) << 4;
      int off = (row << 8) + (kb ^ ((row & 7) << 4));
      uint4 va = make_uint4(0,0,0,0);
      int gr = mbase + row;
      if (gr < M)
        va = *reinterpret_cast<const uint4*>(Ab + (size_t)gr*(lda*2) + ks*256 + kb);
      *reinterpret_cast<uint4*>(ldsA + off) = va;
      uint4 vb = *reinterpret_cast<const uint4*>(
                   Btb + (size_t)(nbase + row)*(ldb*2) + ks*256 + kb);
      *reinterpret_cast<uint4*>(ldsB + off) = vb;
    }
    __syncthreads();
    #pragma unroll
    for (int kk = 0; kk < 4; ++kk){
      int kbyte = kk*64 + (l >> 4)*16;
      short8 af[4], bf[4];
      #pragma unroll
      for (int m = 0; m < 4; ++m){
        int fr = wm + m*16 + (l & 15);
        af[m] = *reinterpret_cast<const short8*>(ldsA + (fr << 8) + (kbyte ^ ((fr & 7) << 4)));
      }
      #pragma unroll
      for (int n = 0; n < 4; ++n){
        int fc = wn + n*16 + (l & 15);
        bf[n] = *reinterpret_cast<const short8*>(ldsB + (fc << 8) + (kbyte ^ ((fc & 7) << 4)));
      }
      #pragma unroll
      for (int m = 0; m < 4; ++m)
        #pragma unroll
        for (int n = 0; n < 4; ++n)
          acc[m][n] = __builtin_amdgcn_mfma_f32_16x16x32_bf16(af[m], bf[n], acc[m][n], 0, 0, 0);
    }
    __syncthreads();
  }
  #pragma unroll
  for (int n = 0; n < 4; ++n){
    int gcol = nbase + wn + n*16 + (l & 15);
    float bv = bias ? bias[gcol] : 0.f;
    #pragma unroll
    for (int m = 0; m < 4; ++m){
      int grow = mbase + wm + m*16 + (l >> 4)*4;
      #pragma unroll
      for (int r = 0; r < 4; ++r){
        int gr = grow + r;
        if (gr < M){
          float val = acc[m][n][r] + bv;
          if (MODE == 1){
            o_f0[(size_t)gr*128 + gcol] = val;
            if (gcol < 64) o_h0[(size_t)gr*128 + 64 + gcol] = f2bf(val);
          } else if (MODE == 2){
            if (gcol < 64) o_f0[(size_t)gr*64 + gcol] = val;
          } else {
            int seg = gcol >> 8, c = gcol & 255;
            if      (seg == 0) o_f0[(size_t)gr*256 + c] = val;
            else if (seg == 1) o_h0[(size_t)gr*512 + c] = f2bf(val);
            else if (seg == 2) o_h0[(size_t)gr*512 + 256 + c] = f2bf(val);
            else               o_f1[(size_t)gr*256 + c] = val;
          }
        }
      }
    }
  }
}

// -------------- single-pass fused attention + skip + LN (lane-partitioned)
// K and V share one row: kv[n][0:256]=K, kv[n][256:512]=V
__global__ void k_attn(const float* __restrict__ q, const unsigned short* __restrict__ kv,
                       const float* __restrict__ sbuf,
                       const int* __restrict__ rowptr, const int* __restrict__ csrc,
                       const float* __restrict__ ltg, const float* __restrict__ ltb,
                       unsigned short* __restrict__ outb, int N){
  int n = blockIdx.x*4 + (threadIdx.x >> 6);
  if (n >= N) return;
  int l = threadIdx.x & 63;
  int lo = rowptr[n], hi = rowptr[n+1];
  size_t base = (size_t)n*256 + l*4;
  const int l4 = l*4;
  float4 qv = *reinterpret_cast<const float4*>(q + base);
  qv.x *= 0.125f; qv.y *= 0.125f; qv.z *= 0.125f; qv.w *= 0.125f;
  float o0 = 0.f, o1 = 0.f, o2 = 0.f, o3 = 0.f, s = 0.f;
  int i = lo;
  for (; i + 8 <= hi; i += 8){
    ushort4 kk[8], vv[8];
    #pragma unroll
    for (int j = 0; j < 8; ++j){
      const unsigned short* row = kv + (size_t)csrc[i + j]*512 + l4;
      kk[j] = *reinterpret_cast<const ushort4*>(row);
      vv[j] = *reinterpret_cast<const ushort4*>(row + 256);
    }
    float a[8];
    #pragma unroll
    for (int j = 0; j < 8; ++j)
      a[j] = qv.x*bf2f(kk[j].x) + qv.y*bf2f(kk[j].y) + qv.z*bf2f(kk[j].z) + qv.w*bf2f(kk[j].w);
    #pragma unroll
    for (int m = 1; m < 16; m <<= 1){
      #pragma unroll
      for (int j = 0; j < 8; ++j) a[j] += __shfl_xor(a[j], m, 64);
    }
    #pragma unroll
    for (int j = 0; j < 8; ++j){
      float w = __expf(a[j]);
      s += w;
      o0 += w*bf2f(vv[j].x); o1 += w*bf2f(vv[j].y);
      o2 += w*bf2f(vv[j].z); o3 += w*bf2f(vv[j].w);
    }
  }
  for (; i < hi; ++i){
    const unsigned short* row = kv + (size_t)csrc[i]*512 + l4;
    ushort4 kk = *reinterpret_cast<const ushort4*>(row);
    ushort4 vv = *reinterpret_cast<const ushort4*>(row + 256);
    float a = qv.x*bf2f(kk.x) + qv.y*bf2f(kk.y) + qv.z*bf2f(kk.z) + qv.w*bf2f(kk.w);
    #pragma unroll
    for (int m = 1; m < 16; m <<= 1) a += __shfl_xor(a, m, 64);
    float w = __expf(a);
    s += w;
    o0 += w*bf2f(vv.x); o1 += w*bf2f(vv.y); o2 += w*bf2f(vv.z); o3 += w*bf2f(vv.w);
  }
  float4 t = *reinterpret_cast<const float4*>(sbuf + base);
  if (hi > lo){
    float r = 1.f / s;
    t.x += o0*r; t.y += o1*r; t.z += o2*r; t.w += o3*r;
  }
  float mean = wave_sum(t.x + t.y + t.z + t.w) * (1.f/256.f);
  float dx = t.x - mean, dy = t.y - mean, dz = t.z - mean, dw = t.w - mean;
  float var = wave_sum(dx*dx + dy*dy + dz*dz + dw*dw) * (1.f/256.f);
  float rs = rsqrtf(var + 1e-5f);
  float4 g = *reinterpret_cast<const float4*>(ltg + l4);
  float4 b = *reinterpret_cast<const float4*>(ltb + l4);
  ushort4 o;
  o.x = f2bf(dx*rs*g.x + b.x);
  o.y = f2bf(dy*rs*g.y + b.y);
  o.z = f2bf(dz*rs*g.z + b.z);
  o.w = f2bf(dw*rs*g.w + b.w);
  *reinterpret_cast<ushort4*>(outb + base) = o;
}

// ------ gated fusion (gate precomputed by MFMA) + agg update + comb-LN
__global__ __launch_bounds__(256) void k_gate2(
    float* __restrict__ nf, float* __restrict__ agg,
    const float* __restrict__ pnP, const float* __restrict__ gate_arg,
    const int* __restrict__ rowptr, const int* __restrict__ csrc,
    const float* __restrict__ peb,
    const float* __restrict__ cg, const float* __restrict__ cbv,
    unsigned short* __restrict__ comb, unsigned short* __restrict__ gin,
    int doComb, int N){
  int n = blockIdx.x*4 + (threadIdx.x >> 6);
  if (n >= N) return;
  int l = threadIdx.x & 63;
  float g = sigm(gate_arg[(size_t)n*64 + l]);
  float nfv = nf[(size_t)n*64 + l];
  float pnv = pnP[(size_t)n*128 + l];
  float nfn = nfv * (1.f + g) + pnv * (1.f - g);
  nf[(size_t)n*64 + l] = nfn;
  gin[(size_t)n*128 + l] = f2bf(nfn);
  int lo = rowptr[n], hi = rowptr[n+1];
  float sp = 0.f;
  int i = lo;
  for (; i + 8 <= hi; i += 8){
    float pv[8];
    #pragma unroll
    for (int j = 0; j < 8; ++j)
      pv[j] = pnP[(size_t)csrc[i+j]*128 + 64 + l];
    #pragma unroll
    for (int j = 0; j < 8; ++j) sp += pv[j];
  }
  for (; i < hi; ++i) sp += pnP[(size_t)csrc[i]*128 + 64 + l];
  float Pn = pnP[(size_t)n*128 + 64 + l];
  float aggn = agg[(size_t)n*64 + l] + sp - (float)(hi - lo) * (Pn - peb[l]);
  agg[(size_t)n*64 + l] = aggn;
  if (doComb){
    float v0 = nfn, v1 = aggn - nfn;
    float mean = wave_sum(v0 + v1) * (1.f/128.f);
    float d0 = v0 - mean, d1 = v1 - mean;
    float var = wave_sum(d0*d0 + d1*d1) * (1.f/128.f);
    float rs = rsqrtf(var + 1e-5f);
    comb[(size_t)n*128 + l]      = f2bf(d0 * rs * cg[l]      + cbv[l]);
    comb[(size_t)n*128 + 64 + l] = f2bf(d1 * rs * cg[64 + l] + cbv[64 + l]);
  }
}

// ------------------------------------------------------------- classifier
template<int K, int BN>
__global__ __launch_bounds__(256) void k_gemm(
    const float* __restrict__ in, const float* __restrict__ W, int ldw,
    const float* __restrict__ bias, float* __restrict__ out, int ldo, int nrows){
  constexpr int PAD = BN + 4;
  __shared__ float s_in[K * PAD];
  int n0 = blockIdx.x * BN;
  int tid = threadIdx.x;
  for (int idx = tid; idx < BN * K; idx += 256){
    int r = idx / K, k = idx - r * K;
    float v = (n0 + r < nrows) ? in[(size_t)(n0 + r) * K + k] : 0.f;
    s_in[k * PAD + r] = v;
  }
  __syncthreads();
  int tx = tid & 15, ty = tid >> 4;
  constexpr int NT = BN / 16;
  int col0 = blockIdx.y * 64 + tx * 4;
  float acc[NT][4] = {};
  for (int k = 0; k < K; ++k){
    const float4 wv = *reinterpret_cast<const float4*>(&W[(size_t)k * ldw + col0]);
    #pragma unroll
    for (int i = 0; i < NT; ++i){
      float cv = s_in[k * PAD + ty * NT + i];
      acc[i][0] += cv * wv.x;
      acc[i][1] += cv * wv.y;
      acc[i][2] += cv * wv.z;
      acc[i][3] += cv * wv.w;
    }
  }
  #pragma unroll
  for (int i = 0; i < NT; ++i){
    int n = n0 + ty * NT + i;
    if (n < nrows){
      float4 o = make_float4(acc[i][0], acc[i][1], acc[i][2], acc[i][3]);
      *reinterpret_cast<float4*>(&out[(size_t)n * ldo + col0]) = o;
    }
  }
}

__global__ void k_final(const float* __restrict__ AB,
                        const int* __restrict__ ei, const float* __restrict__ cb1,
                        const float* __restrict__ cw2, const float* __restrict__ cb2,
                        float* __restrict__ dout, int E){
  int e = blockIdx.x*4 + (threadIdx.x >> 6);
  if (e >= E) return;
  int l = threadIdx.x & 63;
  int i0 = ei[e], i1 = ei[E + e];
  float h = fmaxf(AB[(size_t)i0*128 + l] + AB[(size_t)i1*128 + 64 + l] + cb1[l], 0.f);
  float p = wave_sum(h * cw2[l]);
  if (l == 0) dout[e] = p + cb2[0];
}

// ===========================================================================
extern "C" void kernel_launch(void* const* d_in, const int* in_sizes, int n_in,
                              void* d_out, int out_size, void* d_ws, size_t ws_size,
                              hipStream_t stream){
  const float* x         = (const float*)d_in[0];
  const float* edge_attr = (const float*)d_in[1];
  const float* node_w    = (const float*)d_in[2];
  const float* node_b    = (const float*)d_in[3];
  const float* edge_w    = (const float*)d_in[4];
  const float* edge_b    = (const float*)d_in[5];
  const float* z_emb     = (const float*)d_in[6];
  const float* cn_w1     = (const float*)d_in[7];
  const float* cn_b1     = (const float*)d_in[8];
  const float* cn_w2     = (const float*)d_in[9];
  const float* cn_b2     = (const float*)d_in[10];
  const float* cn_cw     = (const float*)d_in[11];
  const float* cn_cb     = (const float*)d_in[12];
  const float* ce_w1     = (const float*)d_in[13];
  const float* ce_b1     = (const float*)d_in[14];
  const float* ce_w2     = (const float*)d_in[15];
  const float* ce_b2     = (const float*)d_in[16];
  const float* ce_cw     = (const float*)d_in[17];
  const float* ce_cb     = (const float*)d_in[18];
  const float* Wq        = (const float*)d_in[19];
  const float* bq        = (const float*)d_in[20];
  const float* Wk        = (const float*)d_in[21];
  const float* bk        = (const float*)d_in[22];
  const float* Wv        = (const float*)d_in[23];
  const float* bv        = (const float*)d_in[24];
  const float* Ws        = (const float*)d_in[25];
  const float* bs        = (const float*)d_in[26];
  const float* lt_g      = (const float*)d_in[27];
  const float* lt_b      = (const float*)d_in[28];
  const float* lc_g      = (const float*)d_in[29];
  const float* lc_b      = (const float*)d_in[30];
  const float* pe_w      = (const float*)d_in[31];
  const float* pe_b      = (const float*)d_in[32];
  const float* pn_w      = (const float*)d_in[33];
  const float* pn_b      = (const float*)d_in[34];
  const float* gf_w      = (const float*)d_in[35];
  const float* gf_b      = (const float*)d_in[36];
  const float* c_w1      = (const float*)d_in[37];
  const float* c_b1      = (const float*)d_in[38];
  const float* c_w2      = (const float*)d_in[39];
  const float* c_b2      = (const float*)d_in[40];
  const int*   edge_index= (const int*)d_in[41];

  const int N  = in_sizes[0] / 6;
  const int E  = in_sizes[1] / 4;
  const int E2 = 2 * E;

  // ---------------- workspace layout
  char* p = (char*)d_ws;
  auto alloc = [&](size_t bytes)->char*{
    char* r = p; p += (bytes + 255) & ~(size_t)255; return r;
  };
  // --- zero-init region (one memset covers all of these, incl. padding) ---
  char* zbase = p;
  int*            w_deg    = (int*)           alloc((size_t)N * 4);
  int*            w_cur    = (int*)           alloc((size_t)N * 4);
  unsigned*       w_pmax   = (unsigned*)      alloc(64 * 4);
  float*          w_psum   = (float*)         alloc(64 * 4);
  unsigned*       w_pmax2  = (unsigned*)      alloc(64 * 4);
  float*          w_psum2  = (float*)         alloc(64 * 4);
  size_t zbytes = (size_t)(p - zbase);
  // --- rest ---
  int*            w_src    = (int*)           alloc((size_t)E2 * 4);
  int*            w_dst    = (int*)           alloc((size_t)E2 * 4);
  int*            w_rowptr = (int*)           alloc((size_t)(N + 1) * 4);
  int*            w_csrc   = (int*)           alloc((size_t)E2 * 4);
  int*            w_epos   = (int*)           alloc((size_t)E2 * 4);
  float*          w_re8    = (float*)         alloc((size_t)E2 * 8 * 4);
  float*          w_nf     = (float*)         alloc((size_t)N * 64 * 4);
  float*          w_agg    = (float*)         alloc((size_t)N * 64 * 4);
  unsigned short* w_ef0    = (unsigned short*)alloc((size_t)E2 * 64 * 2);
  float*          w_se     = (float*)         alloc((size_t)E2 * 4);
  unsigned short* w_comb   = (unsigned short*)alloc((size_t)N * 128 * 2);
  unsigned short* w_gin    = (unsigned short*)alloc((size_t)N * 128 * 2);
  float*          w_gate   = (float*)         alloc((size_t)N * 64 * 4);
  float*          w_q      = (float*)         alloc((size_t)N * 256 * 4);
  unsigned short* w_kv     = (unsigned short*)alloc((size_t)N * 512 * 2);
  float*          w_s      = (float*)         alloc((size_t)N * 256 * 4);
  unsigned short* w_outb   = (unsigned short*)alloc((size_t)N * 256 * 2);
  float*          w_pnP    = (float*)         alloc((size_t)N * 128 * 4);
  float*          w_rp     = (float*)         alloc((size_t)E2 * 2 * 4);
  float*          w_AB     = (float*)         alloc((size_t)N * 128 * 4);
  float*          w_Wp     = (float*)         alloc((size_t)64 * 128 * 4);
  unsigned short* w_Bt     = (unsigned short*)alloc((size_t)3 * 1024 * 128 * 2);
  float*          w_bias   = (float*)         alloc((size_t)3 * 1024 * 4);
  unsigned short* w_Bt2    = (unsigned short*)alloc((size_t)3 * 128 * 256 * 2);
  float*          w_bias2  = (float*)         alloc((size_t)3 * 128 * 4);
  unsigned short* w_BtG    = (unsigned short*)alloc((size_t)3 * 128 * 128 * 2);
  float*          w_bias3  = (float*)         alloc((size_t)3 * 128 * 4);
  float*          w_ch     = (float*)         alloc(64 * 4);
  float*          w_ch2    = (float*)         alloc(64 * 4);

  hipMemsetAsync(zbase, 0, zbytes, stream);

  // ---------------- CSR + raw-edge gather + node embedding/CBAM
  k_build_edges<<<(E2 + 255)/256, 256, 0, stream>>>(edge_index, E2, E, w_src, w_dst, w_deg);
  k_scan<<<1, 1024, 0, stream>>>(w_deg, w_rowptr, N);
  k_fill<<<(E2 + 255)/256, 256, 0, stream>>>(w_src, w_dst, w_rowptr, w_cur, w_csrc, w_epos,
                                             x, edge_attr, w_re8, E2, E);
  k_embed_pool<<<256, 256, 0, stream>>>(x, node_w, node_b, z_emb, w_nf, w_pmax, w_psum, N);
  k_cbam_mlp<<<1, 64, 0, stream>>>(w_pmax, w_psum, 1.f/(float)N,
                                   cn_w1, cn_b1, cn_w2, cn_b2, w_ch);
  k_chmul_rowpool<<<(N + 3)/4, 256, 0, stream>>>(w_nf, w_ch, w_rp, N);
  k_spatial<<<(N + 3)/4, 256, 0, stream>>>(w_nf, w_rp, cn_cw, cn_cb, w_gin, N);

  // ---------------- edge CBAM (streamed) -> ef0 (CSR order) -> agg0 + comb0
  k_ecol<<<256, 256, 0, stream>>>(w_re8, edge_w, edge_b, w_pmax2, w_psum2, E2);
  k_cbam_mlp<<<1, 64, 0, stream>>>(w_pmax2, w_psum2, 1.f/(float)E2,
                                   ce_w1, ce_b1, ce_w2, ce_b2, w_ch2);
  k_erp2<<<1024, 256, 0, stream>>>(w_re8, w_epos, edge_w, edge_b, w_ch2,
                                   w_rp, w_ef0, E2);
  k_se<<<(E2 + 255)/256, 256, 0, stream>>>(w_rp, w_epos, ce_cw, ce_cb, w_se, E2);
  k_aggb<<<(N + 3)/4, 256, 0, stream>>>(w_ef0, w_se, w_rowptr, w_nf,
                                        lc_g, lc_b, w_agg, w_comb, N);

  // ---------------- pack all iteration weights
  k_packT1<<<dim3(4, 6, 4), 256, 0, stream>>>(Wq, Wk, Wv, Ws, w_Bt);
  k_packT2<<<dim3(1, 12, 2), 256, 0, stream>>>(pn_w, pe_w, w_Bt2);
  k_packG<<<3*128, 128, 0, stream>>>(gf_w, w_BtG);
  k_biasp<<<3, 1024, 0, stream>>>(bq, bk, bv, bs, pn_b, gf_b, w_bias, w_bias2, w_bias3);
  k_packC<<<32, 256, 0, stream>>>(c_w1, w_Wp);

  // ---------------- message-passing iterations
  const int MB = (N + 127) / 128;
  for (int i = 0; i < 3; ++i){
    k_mfma<1,0><<<dim3(8, MB), 256, 0, stream>>>(w_comb, 128,
                                                 w_Bt + (size_t)i*1024*128, 128,
                                                 w_bias + (size_t)i*1024,
                                                 w_q, w_kv, w_s, N);
    k_attn<<<(N + 3)/4, 256, 0, stream>>>(w_q, w_kv, w_s, w_rowptr, w_csrc,
                                          lt_g + (size_t)i*256, lt_b + (size_t)i*256,
                                          w_outb, N);
    k_mfma<2,1><<<dim3(1, MB), 256, 0, stream>>>(w_outb, 256,
                                                 w_Bt2 + (size_t)i*128*256, 256,
                                                 w_bias2 + (size_t)i*128,
                                                 w_pnP, w_gin, nullptr, N);
    k_mfma<1,2><<<dim3(1, MB), 256, 0, stream>>>(w_gin, 128,
                                                 w_BtG + (size_t)i*128*128, 128,
                                                 w_bias3 + (size_t)i*128,
                                                 w_gate, nullptr, nullptr, N);
    int doComb = (i < 2) ? 1 : 0;
    const float* cg  = lc_g + (size_t)(i < 2 ? i+1 : 0)*128;
    const float* cbv = lc_b + (size_t)(i < 2 ? i+1 : 0)*128;
    k_gate2<<<(N + 3)/4, 256, 0, stream>>>(w_nf, w_agg, w_pnP, w_gate,
                                           w_rowptr, w_csrc,
                                           pe_b + (size_t)i*64,
                                           cg, cbv, w_comb, w_gin, doComb, N);
  }

  // ---------------- classifier (fused A|B GEMM, then edge head)
  dim3 gAB((N + 63)/64, 2);
  k_gemm<64,64><<<gAB, 256, 0, stream>>>(w_nf, w_Wp, 128, nullptr, w_AB, 128, N);
  k_final<<<(E + 3)/4, 256, 0, stream>>>(w_AB, edge_index, c_b1, c_w2, c_b2,
                                         (float*)d_out, E);
}